// Round 6
// baseline (324891.162 us; speedup 1.0000x reference)
//
#include <hip/hip_runtime.h>
#include <hip/hip_bf16.h>

#define BS 4
#define SEQL 2048
#define DM 512
#define DIN 1024
#define NH 16
#define HD 64
#define DST 64
#define NC 8
#define CKS 256
#define DIP 2192
#define CVD 1152
#define NROWS (BS*SEQL)          /* 8192 */
#define NTOK (BS*SEQL*DM)        /* 4194304 */

// ---------------- elementwise ----------------
__global__ void k_add_flip(float* __restrict__ dst, const float* __restrict__ src, int flip){
  int i = blockIdx.x*256 + threadIdx.x;
  if(i >= NTOK) return;
  int d = i & (DM-1);
  int l = (i >> 9) & (SEQL-1);
  int b = i >> 20;
  int sl = flip ? (SEQL-1-l) : l;
  dst[i] += src[(b*SEQL + sl)*DM + d];
}

__global__ void k_flip(float* __restrict__ dst, const float* __restrict__ src){
  int i = blockIdx.x*256 + threadIdx.x;
  if(i >= NTOK) return;
  int d = i & (DM-1);
  int l = (i >> 9) & (SEQL-1);
  int b = i >> 20;
  dst[i] = src[(b*SEQL + (SEQL-1-l))*DM + d];
}

// LayerNorm over rows of 512
__global__ void k_ln(const float* __restrict__ X, const float* __restrict__ w,
                     const float* __restrict__ bb, float* __restrict__ O){
  int row = blockIdx.x, tid = threadIdx.x;
  const float* x = X + (size_t)row*DM;
  float* o = O + (size_t)row*DM;
  float s=0.f, s2=0.f;
  for(int j=tid;j<DM;j+=256){ float v=x[j]; s+=v; s2+=v*v; }
  __shared__ float r1[256], r2[256];
  r1[tid]=s; r2[tid]=s2; __syncthreads();
  for(int off=128;off>0;off>>=1){
    if(tid<off){ r1[tid]+=r1[tid+off]; r2[tid]+=r2[tid+off]; }
    __syncthreads();
  }
  float m = r1[0]*(1.f/DM);
  float var = r2[0]*(1.f/DM) - m*m;
  float inv = rsqrtf(var + 1e-5f);
  for(int j=tid;j<DM;j+=256) o[j] = (x[j]-m)*inv*w[j] + bb[j];
}

// RMSNorm over rows of 1024, in place, with gamma
__global__ void k_rms(float* __restrict__ Y, const float* __restrict__ gw){
  int row = blockIdx.x, tid = threadIdx.x;
  float* y = Y + (size_t)row*DIN;
  float ss=0.f;
  for(int j=tid;j<DIN;j+=256){ float v=y[j]; ss+=v*v; }
  __shared__ float red[256];
  red[tid]=ss; __syncthreads();
  for(int off=128;off>0;off>>=1){
    if(tid<off) red[tid]+=red[tid+off];
    __syncthreads();
  }
  float inv = rsqrtf(red[0]*(1.f/DIN) + 1e-5f);
  for(int j=tid;j<DIN;j+=256) y[j] = y[j]*inv*gw[j];
}

// ---------------- GEMM: C = act(A@B + bias) + res ----------------
__global__ void k_gemm(const float* __restrict__ A, const float* __restrict__ B,
                       const float* __restrict__ bias, const float* __restrict__ res,
                       float* __restrict__ C, int M, int N, int K, int act){
  __shared__ float As[64][17];
  __shared__ float Bs[16][65];
  int tx = threadIdx.x, ty = threadIdx.y;
  int tid = ty*16+tx;
  int r0 = blockIdx.y*64, c0 = blockIdx.x*64;
  float acc[4][4];
  #pragma unroll
  for(int i=0;i<4;i++)
    #pragma unroll
    for(int j=0;j<4;j++) acc[i][j]=0.f;
  for(int k0=0;k0<K;k0+=16){
    #pragma unroll
    for(int e=0;e<4;e++){
      int idx = tid + e*256;
      int ar = idx>>4, ac = idx&15;
      As[ar][ac] = A[(size_t)(r0+ar)*K + k0+ac];
      int br = idx>>6, bc = idx&63;
      float bv = 0.f;
      if(c0+bc < N) bv = B[(size_t)(k0+br)*N + c0+bc];
      Bs[br][bc] = bv;
    }
    __syncthreads();
    #pragma unroll
    for(int kk=0;kk<16;kk++){
      float a0=As[ty*4+0][kk],a1=As[ty*4+1][kk],a2=As[ty*4+2][kk],a3=As[ty*4+3][kk];
      float b0=Bs[kk][tx*4+0],b1=Bs[kk][tx*4+1],b2=Bs[kk][tx*4+2],b3=Bs[kk][tx*4+3];
      acc[0][0]+=a0*b0; acc[0][1]+=a0*b1; acc[0][2]+=a0*b2; acc[0][3]+=a0*b3;
      acc[1][0]+=a1*b0; acc[1][1]+=a1*b1; acc[1][2]+=a1*b2; acc[1][3]+=a1*b3;
      acc[2][0]+=a2*b0; acc[2][1]+=a2*b1; acc[2][2]+=a2*b2; acc[2][3]+=a2*b3;
      acc[3][0]+=a3*b0; acc[3][1]+=a3*b1; acc[3][2]+=a3*b2; acc[3][3]+=a3*b3;
    }
    __syncthreads();
  }
  #pragma unroll
  for(int i=0;i<4;i++){
    int r = r0 + ty*4 + i;
    #pragma unroll
    for(int j=0;j<4;j++){
      int c = c0 + tx*4 + j;
      if(c < N){
        float v = acc[i][j];
        if(bias) v += bias[c];
        if(act==1) v = 0.5f*v*(1.f+erff(v*0.70710678118654752f));
        if(res) v += res[(size_t)r*N + c];
        C[(size_t)r*N + c] = v;
      }
    }
  }
}

// ---------------- mamba pieces ----------------
__global__ void k_conv(const float* __restrict__ ZB, const float* __restrict__ cw,
                       const float* __restrict__ cb, float* __restrict__ XC){
  int i = blockIdx.x*256 + threadIdx.x;
  if(i >= BS*SEQL*CVD) return;
  int cch = i % CVD;
  int l = (i / CVD) & (SEQL-1);
  int b = i / (CVD*SEQL);
  float v = cb[cch];
  #pragma unroll
  for(int k=0;k<4;k++){
    int sl = l + k - 3;
    if(sl >= 0) v += ZB[(size_t)(b*SEQL+sl)*DIP + DIN + cch] * cw[cch*4 + k];
  }
  float sig = 1.f/(1.f+expf(-v));
  XC[i] = v*sig;
}

__global__ void k_dt(const float* __restrict__ ZB, const float* __restrict__ dtb,
                     const float* __restrict__ Alog, float* __restrict__ DT,
                     float* __restrict__ DA){
  int i = blockIdx.x*256 + threadIdx.x;
  if(i >= BS*SEQL*NH) return;
  int h = i & (NH-1);
  int row = i >> 4;
  float raw = ZB[(size_t)row*DIP + (DIN+CVD) + h] + dtb[h];
  float dt = fmaxf(raw,0.f) + log1pf(expf(-fabsf(raw)));
  DT[i] = dt;
  DA[i] = dt * (-expf(Alog[h]));
}

__global__ void k_acum(const float* __restrict__ DA, float* __restrict__ ACUM,
                       float* __restrict__ CDEC){
  int blk = blockIdx.x;                  // (b*8+c)*16+h
  int h = blk & 15, c = (blk>>4)&7, b = blk>>7;
  int l = threadIdx.x;
  __shared__ float s[256];
  int gl = c*CKS + l;
  s[l] = DA[(size_t)(b*SEQL + gl)*NH + h];
  __syncthreads();
  for(int off=1; off<256; off<<=1){
    float v = (l>=off) ? s[l-off] : 0.f;
    __syncthreads();
    s[l] += v;
    __syncthreads();
  }
  ACUM[(size_t)blk*CKS + l] = s[l];
  if(l==255) CDEC[blk] = expf(s[255]);
}

__global__ void k_ydiag(const float* __restrict__ XC, const float* __restrict__ DT,
                        const float* __restrict__ ACUM, float* __restrict__ Y){
  int blk = blockIdx.x;                  // ((b*8+c)*16+h)*4 + lt
  int lt = blk & 3, h = (blk>>2)&15, c = (blk>>6)&7, b = blk>>9;
  int tid = threadIdx.x;
  int p = tid & 63, lq = tid >> 6;
  __shared__ float Ac[256];
  __shared__ float Bt[32][65];
  __shared__ float Xt[32][65];
  __shared__ float Ct[64][65];
  __shared__ float Gt[64][33];
  const float* xcb = XC + (size_t)b*SEQL*CVD;
  Ac[tid] = ACUM[(size_t)((b*8+c)*16+h)*CKS + tid];
  #pragma unroll
  for(int e=0;e<16;e++){
    int idx = tid + e*256;
    int ll = idx>>6, n = idx&63;
    Ct[ll][n] = xcb[(size_t)(c*CKS + lt*64 + ll)*CVD + (DIN+DST) + n];
  }
  float acc[16];
  #pragma unroll
  for(int j=0;j<16;j++) acc[j]=0.f;
  int ntiles = 2*lt+2;
  for(int st=0; st<ntiles; ++st){
    int s0 = st*32;
    __syncthreads();
    #pragma unroll
    for(int e=0;e<8;e++){
      int idx = tid + e*256;
      int sl = idx>>6, n = idx&63;
      int gs = c*CKS + s0 + sl;
      Bt[sl][n] = xcb[(size_t)gs*CVD + DIN + n];
      Xt[sl][n] = xcb[(size_t)gs*CVD + h*HD + n] * DT[(size_t)(b*SEQL+gs)*NH + h];
    }
    __syncthreads();
    #pragma unroll
    for(int e=0;e<8;e++){
      int idx = tid*8 + e;
      int ll = idx>>5, sp = idx&31;
      int l = lt*64 + ll;
      int sg = s0 + sp;
      float g = 0.f;
      if(sg <= l){
        float dot=0.f;
        #pragma unroll
        for(int n=0;n<64;n++) dot += Ct[ll][n]*Bt[sp][n];
        g = expf(Ac[l]-Ac[sg]) * dot;
      }
      Gt[ll][sp] = g;
    }
    __syncthreads();
    #pragma unroll
    for(int j=0;j<16;j++){
      int ll = lq*16 + j;
      float a = 0.f;
      #pragma unroll
      for(int sp=0;sp<32;sp++) a += Gt[ll][sp]*Xt[sp][p];
      acc[j] += a;
    }
  }
  #pragma unroll
  for(int j=0;j<16;j++){
    int l = lt*64 + lq*16 + j;
    Y[(size_t)(b*SEQL + c*CKS + l)*DIN + h*HD + p] = acc[j];
  }
}

__global__ void k_states(const float* __restrict__ XC, const float* __restrict__ DT,
                         const float* __restrict__ ACUM, float* __restrict__ ST){
  int blk = blockIdx.x;                  // (b*8+c)*16+h
  int h = blk & 15, c = (blk>>4)&7, b = blk>>7;
  int tid = threadIdx.x;
  int n = tid & 63, pq = tid >> 6;
  __shared__ float Ac[256];
  __shared__ float Bt[32][64];
  __shared__ float Xt[32][64];
  Ac[tid] = ACUM[(size_t)blk*CKS + tid];
  float acc[16];
  #pragma unroll
  for(int k=0;k<16;k++) acc[k]=0.f;
  const float* xcb = XC + (size_t)b*SEQL*CVD;
  for(int st=0; st<8; ++st){
    __syncthreads();
    #pragma unroll
    for(int e=0;e<8;e++){
      int idx = tid + e*256;
      int sl = idx>>6, nn = idx&63;
      int gs = c*CKS + st*32 + sl;
      Bt[sl][nn] = xcb[(size_t)gs*CVD + DIN + nn];
      float dec = expf(Ac[255] - Ac[st*32+sl]);
      Xt[sl][nn] = xcb[(size_t)gs*CVD + h*HD + nn] * DT[(size_t)(b*SEQL+gs)*NH + h] * dec;
    }
    __syncthreads();
    #pragma unroll
    for(int l=0;l<32;l++){
      float bv = Bt[l][n];
      #pragma unroll
      for(int k=0;k<16;k++) acc[k] += bv * Xt[l][pq + 4*k];
    }
  }
  #pragma unroll
  for(int k=0;k<16;k++){
    int p = pq + 4*k;
    ST[(size_t)blk*4096 + p*64 + n] = acc[k];
  }
}

__global__ void k_scan(const float* __restrict__ ST, const float* __restrict__ CDEC,
                       float* __restrict__ PREV){
  int i = blockIdx.x*256 + threadIdx.x;    // BS*NH*4096
  if(i >= BS*NH*4096) return;
  int pn = i & 4095;
  int h = (i>>12) & 15;
  int b = i >> 16;
  float run = 0.f;
  for(int c=0;c<8;c++){
    size_t idx = (size_t)((b*8+c)*16+h)*4096 + pn;
    PREV[idx] = run;
    run = run*CDEC[(b*8+c)*16+h] + ST[idx];
  }
}

__global__ void k_yfinal(const float* __restrict__ XC, const float* __restrict__ ACUM,
                         const float* __restrict__ PREV, const float* __restrict__ ZB,
                         const float* __restrict__ Dp, float* __restrict__ Y){
  int i = blockIdx.x*256 + threadIdx.x;    // BS*SEQL*DIN
  if(i >= BS*SEQL*DIN) return;
  int p = i & 63;
  int h = (i>>6) & 15;
  int l = (i>>10) & (SEQL-1);
  int b = i >> 21;
  int c = l >> 8;
  int lc = l & 255;
  const float* prev = PREV + (size_t)((b*8+c)*16+h)*4096 + p*64;
  const float* crow = XC + (size_t)(b*SEQL+l)*CVD + (DIN+DST);
  float s = 0.f;
  #pragma unroll
  for(int n=0;n<64;n++) s += crow[n]*prev[n];
  float yoff = expf(ACUM[(size_t)((b*8+c)*16+h)*CKS + lc]) * s;
  float xh = XC[(size_t)(b*SEQL+l)*CVD + h*HD + p];
  float z  = ZB[(size_t)(b*SEQL+l)*DIP + h*HD + p];
  float v = Y[i] + yoff + Dp[h]*xh;
  float sig = 1.f/(1.f+expf(-z));
  Y[i] = v * (z*sig);
}

// ---------------- attention ----------------
__global__ void k_extract(const float* __restrict__ HF, float* __restrict__ QIN,
                          float* __restrict__ CIN){
  int i = blockIdx.x*256 + threadIdx.x;    // BS*1024*DM
  if(i >= BS*1024*DM) return;
  int d = i & (DM-1);
  int q = (i>>9) & 1023;
  int b = i >> 19;
  QIN[i] = HF[(size_t)(b*SEQL + 1024 + q)*DM + d];
  CIN[i] = HF[(size_t)(b*SEQL + q)*DM + d];
}

__global__ void k_attn(const float* __restrict__ Q, const float* __restrict__ K,
                       const float* __restrict__ V, float* __restrict__ O){
  int blk = blockIdx.x;                    // (b*4+h)*1024 + q
  int q = blk & 1023, h = (blk>>10)&3, b = blk>>12;
  int tid = threadIdx.x;
  __shared__ float qrow[128];
  __shared__ float p[1024];
  __shared__ float red[256];
  const float* qptr = Q + (size_t)(b*1024+q)*DM + h*128;
  if(tid < 128) qrow[tid] = qptr[tid];
  __syncthreads();
  const float scale = 0.088388347648318447f;  // 1/sqrt(128)
  float lmax = -1e30f;
  for(int k=tid;k<1024;k+=256){
    const float* kptr = K + (size_t)(b*1024+k)*DM + h*128;
    float s = 0.f;
    for(int d=0;d<128;d++) s += qrow[d]*kptr[d];
    s *= scale;
    p[k] = s;
    lmax = fmaxf(lmax, s);
  }
  red[tid]=lmax; __syncthreads();
  for(int off=128;off>0;off>>=1){
    if(tid<off) red[tid]=fmaxf(red[tid],red[tid+off]);
    __syncthreads();
  }
  float m = red[0];
  __syncthreads();
  float lsum = 0.f;
  for(int k=tid;k<1024;k+=256){ float e=expf(p[k]-m); p[k]=e; lsum+=e; }
  red[tid]=lsum; __syncthreads();
  for(int off=128;off>0;off>>=1){
    if(tid<off) red[tid]+=red[tid+off];
    __syncthreads();
  }
  float inv = 1.f/red[0];
  if(tid < 128){
    int d = tid;
    float acc = 0.f;
    for(int k=0;k<1024;k++) acc += p[k]*V[(size_t)(b*1024+k)*DM + h*128 + d];
    O[(size_t)(b*1024+q)*DM + h*128 + d] = acc*inv;
  }
}

// ================= PROBE APPENDIX (runs AFTER d_out is written) =================
typedef unsigned short u16;
typedef __bf16 bf16x8 __attribute__((ext_vector_type(8)));
typedef float f32x4 __attribute__((ext_vector_type(4)));

__device__ __forceinline__ u16 cvt_bf16(float f){
  unsigned int x = __float_as_uint(f);
  unsigned int r = x + 0x7fffu + ((x>>16)&1u);
  return (u16)(r>>16);
}

__global__ void k_cvt(const float* __restrict__ src, u16* __restrict__ dst, int n4){
  int i = blockIdx.x*256 + threadIdx.x;
  if(i >= n4) return;
  float4 f = reinterpret_cast<const float4*>(src)[i];
  ushort4 o; o.x=cvt_bf16(f.x); o.y=cvt_bf16(f.y); o.z=cvt_bf16(f.z); o.w=cvt_bf16(f.w);
  reinterpret_cast<ushort4*>(dst)[i] = o;
}

__global__ void k_wt(const float* __restrict__ src, u16* __restrict__ dst, int K, int N){
  __shared__ float t[32][33];
  int z = blockIdx.z;
  src += (size_t)z*K*N;
  dst += (size_t)z*N*K;
  int n0 = blockIdx.x*32, k0 = blockIdx.y*32;
  int tx = threadIdx.x, ty = threadIdx.y;
  #pragma unroll
  for(int i=0;i<32;i+=8){
    int k = k0+ty+i, n = n0+tx;
    t[ty+i][tx] = (n<N) ? src[(size_t)k*N+n] : 0.f;
  }
  __syncthreads();
  #pragma unroll
  for(int i=0;i<32;i+=8){
    int n = n0+ty+i, k = k0+tx;
    if(n<N) dst[(size_t)n*K+k] = cvt_bf16(t[tx][ty+i]);
  }
}

__global__ void k_wtchk(const float* __restrict__ src, const u16* __restrict__ dst,
                        int K, int N, float* flg){
  int i = blockIdx.x*256 + threadIdx.x;
  if(i >= K*N) return;
  int k = i / N, n = i % N;
  if(dst[(size_t)n*K+k] != cvt_bf16(src[i])) atomicAdd(flg, 1.f);
}

// f32 reference: C[8192][768] = A[8192][512] @ B[512][2192][:, :768]
__global__ void k_refgemm(const float* __restrict__ A, const float* __restrict__ B,
                          float* __restrict__ C){
  int col = blockIdx.x*64 + (threadIdx.x & 63);
  int row = blockIdx.y*4 + (threadIdx.x >> 6);
  float s = 0.f;
  for(int k=0;k<512;k++) s += A[(size_t)row*512+k]*B[(size_t)k*2192+col];
  C[(size_t)row*768+col] = s;
}

__global__ __launch_bounds__(256) void k_mgemm(
    const u16* __restrict__ A, const u16* __restrict__ BT,
    float* __restrict__ C, int M, int N, int K, int lda, int ldb, int ldc)
{
  __shared__ uint4 As4[128*5];
  __shared__ uint4 Bs4[128*5];
  const int tid = threadIdx.x;
  const int row0 = blockIdx.y*128, col0 = blockIdx.x*128;
  const int lane = tid & 63, wave = tid >> 6;
  const int wm = wave >> 1, wn = wave & 1;
  const int lr = lane & 15, ksg = (lane >> 4);
  f32x4 acc[4][4];
  #pragma unroll
  for(int i=0;i<4;i++)
    #pragma unroll
    for(int j=0;j<4;j++) acc[i][j] = (f32x4){0.f,0.f,0.f,0.f};
  for(int k0=0;k0<K;k0+=32){
    #pragma unroll
    for(int i=0;i<2;i++){
      int t2 = tid + i*256;
      int rr = t2 >> 2, sg = (t2 & 3);
      uint4 av = *reinterpret_cast<const uint4*>(A + (size_t)(row0+rr)*lda + k0 + sg*8);
      uint4 bv = {0u,0u,0u,0u};
      if(col0+rr < N) bv = *reinterpret_cast<const uint4*>(BT + (size_t)(col0+rr)*ldb + k0 + sg*8);
      As4[rr*5 + sg] = av;
      Bs4[rr*5 + sg] = bv;
    }
    __syncthreads();
    bf16x8 afr[4], bfr[4];
    #pragma unroll
    for(int i=0;i<4;i++) afr[i] = *reinterpret_cast<const bf16x8*>(&As4[(wm*64+i*16+lr)*5 + ksg]);
    #pragma unroll
    for(int j=0;j<4;j++) bfr[j] = *reinterpret_cast<const bf16x8*>(&Bs4[(wn*64+j*16+lr)*5 + ksg]);
    #pragma unroll
    for(int i=0;i<4;i++)
      #pragma unroll
      for(int j=0;j<4;j++)
        acc[i][j] = __builtin_amdgcn_mfma_f32_16x16x32_bf16(afr[i], bfr[j], acc[i][j], 0, 0, 0);
    __syncthreads();
  }
  const int lq = lane >> 4;
  #pragma unroll
  for(int i=0;i<4;i++)
    #pragma unroll
    for(int j=0;j<4;j++)
      #pragma unroll
      for(int r=0;r<4;r++){
        int row = row0 + wm*64 + i*16 + lq*4 + r;
        int col = col0 + wn*64 + j*16 + lr;
        if(col < N) C[(size_t)row*ldc + col] = acc[i][j][r];
      }
}

// transposed-epilogue canary
__global__ __launch_bounds__(256) void k_mgemm3(
    const u16* __restrict__ A, const u16* __restrict__ BT,
    float* __restrict__ C, int M, int N, int K, int lda, int ldb, int ldc)
{
  __shared__ uint4 As4[128*5];
  __shared__ uint4 Bs4[128*5];
  const int tid = threadIdx.x;
  const int row0 = blockIdx.y*128, col0 = blockIdx.x*128;
  const int lane = tid & 63, wave = tid >> 6;
  const int wm = wave >> 1, wn = wave & 1;
  const int lr = lane & 15, ksg = (lane >> 4);
  f32x4 acc[4][4];
  #pragma unroll
  for(int i=0;i<4;i++)
    #pragma unroll
    for(int j=0;j<4;j++) acc[i][j] = (f32x4){0.f,0.f,0.f,0.f};
  for(int k0=0;k0<K;k0+=32){
    #pragma unroll
    for(int i=0;i<2;i++){
      int t2 = tid + i*256;
      int rr = t2 >> 2, sg = (t2 & 3);
      uint4 av = *reinterpret_cast<const uint4*>(A + (size_t)(row0+rr)*lda + k0 + sg*8);
      uint4 bv = {0u,0u,0u,0u};
      if(col0+rr < N) bv = *reinterpret_cast<const uint4*>(BT + (size_t)(col0+rr)*ldb + k0 + sg*8);
      As4[rr*5 + sg] = av;
      Bs4[rr*5 + sg] = bv;
    }
    __syncthreads();
    bf16x8 afr[4], bfr[4];
    #pragma unroll
    for(int i=0;i<4;i++) afr[i] = *reinterpret_cast<const bf16x8*>(&As4[(wm*64+i*16+lr)*5 + ksg]);
    #pragma unroll
    for(int j=0;j<4;j++) bfr[j] = *reinterpret_cast<const bf16x8*>(&Bs4[(wn*64+j*16+lr)*5 + ksg]);
    #pragma unroll
    for(int i=0;i<4;i++)
      #pragma unroll
      for(int j=0;j<4;j++)
        acc[i][j] = __builtin_amdgcn_mfma_f32_16x16x32_bf16(afr[i], bfr[j], acc[i][j], 0, 0, 0);
    __syncthreads();
  }
  const int lq = lane >> 4;
  #pragma unroll
  for(int i=0;i<4;i++)
    #pragma unroll
    for(int j=0;j<4;j++)
      #pragma unroll
      for(int r=0;r<4;r++){
        int row = row0 + wm*64 + i*16 + lr;           // swapped
        int col = col0 + wn*64 + j*16 + lq*4 + r;     // swapped
        if(col < N) C[(size_t)row*ldc + col] = acc[i][j][r];
      }
}

__global__ void k_diff(const float* __restrict__ a, const float* __restrict__ b,
                       long n, float tol, float* flg){
  long i = (long)blockIdx.x*256 + threadIdx.x;
  int bad = 0;
  for(; i<n; i += (long)gridDim.x*256){
    float d = a[i]-b[i];
    if(!(fabsf(d) <= tol)) bad++;
  }
  if(bad) atomicAdd(flg, (float)bad);
}

__global__ void k_setflag(float* f){ *f = 1.f; }

// dependent-FMA burn: duration encodes flag state; no exotic builtins
__global__ void k_burn(const float* __restrict__ flg, int idx, long iters,
                       float* __restrict__ sink){
  if(flg[idx] == 0.f) return;
  float a = 1.0f + flg[idx]*1e-38f;
  const float b = 0.9999999f;
  for(long i=0;i<iters;i++) a = __builtin_fmaf(a, b, 1e-38f);
  if(a == 2.0f) *sink = a;   // never true; keeps chain live
}

// ---------------- host ----------------
static inline void gemm(hipStream_t st, const float*A, const float*B, const float*bias,
                        const float*res, float*C, int M, int N, int K, int act){
  dim3 g((N+63)/64, M/64), b(16,16);
  k_gemm<<<g,b,0,st>>>(A,B,bias,res,C,M,N,K,act);
}

extern "C" void kernel_launch(void* const* d_in, const int* in_sizes, int n_in,
                              void* d_out, int out_size, void* d_ws, size_t ws_size,
                              hipStream_t stream) {
  (void)in_sizes; (void)n_in; (void)out_size; (void)ws_size;
  const float* x_enc     = (const float*)d_in[0];
  const float* in_proj_w = (const float*)d_in[2];
  const float* conv_w    = (const float*)d_in[3];
  const float* conv_b    = (const float*)d_in[4];
  const float* dt_bias   = (const float*)d_in[5];
  const float* A_log     = (const float*)d_in[6];
  const float* D_param   = (const float*)d_in[7];
  const float* gnorm_w   = (const float*)d_in[8];
  const float* out_proj_w= (const float*)d_in[9];
  const float* norm_w    = (const float*)d_in[10];
  const float* norm_b    = (const float*)d_in[11];
  const float* normf_w   = (const float*)d_in[12];
  const float* normf_b   = (const float*)d_in[13];
  const float* ca_nq_w   = (const float*)d_in[14];
  const float* ca_nq_b   = (const float*)d_in[15];
  const float* ca_nkv_w  = (const float*)d_in[16];
  const float* ca_nkv_b  = (const float*)d_in[17];
  const float* ca_qw     = (const float*)d_in[18];
  const float* ca_kw     = (const float*)d_in[19];
  const float* ca_vw     = (const float*)d_in[20];
  const float* ca_ow     = (const float*)d_in[21];
  const float* ca_qb     = (const float*)d_in[22];
  const float* ca_kb     = (const float*)d_in[23];
  const float* ca_vb     = (const float*)d_in[24];
  const float* ca_ob     = (const float*)d_in[25];
  const float* qp_w      = (const float*)d_in[26];
  const float* qp_b      = (const float*)d_in[27];
  const float* cp_w      = (const float*)d_in[28];
  const float* cp_b      = (const float*)d_in[29];
  const float* dec1_w    = (const float*)d_in[30];
  const float* dec1_b    = (const float*)d_in[31];
  const float* dec2_w    = (const float*)d_in[32];
  const float* dec2_b    = (const float*)d_in[33];

  float* W = (float*)d_ws;
  size_t off = 0;
  auto alloc = [&](size_t n){ float* pp = W + off; off += n; return pp; };
  float* RES  = alloc((size_t)NTOK);
  float* H    = alloc((size_t)NTOK);
  float* HN   = alloc((size_t)NTOK);
  float* HNF  = alloc((size_t)NTOK);
  float* ZB   = alloc((size_t)NROWS*DIP);        // 17,956,864
  float* XC   = alloc((size_t)NROWS*CVD);        //  9,437,184
  float* DT   = alloc((size_t)NROWS*NH);
  float* DA   = alloc((size_t)NROWS*NH);
  float* ACUM = alloc((size_t)BS*NC*NH*CKS);
  float* CDEC = alloc((size_t)BS*NC*NH);
  float* Y    = alloc((size_t)NROWS*DIN);        //  8,388,608
  float* ST   = alloc((size_t)BS*NC*NH*4096);
  float* PREV = alloc((size_t)BS*NC*NH*4096);
  float* YD   = alloc((size_t)NTOK);
  float* HF   = alloc((size_t)NTOK);
  // total = 61,768,192 floats — byte-identical layout to the round-1 PASS

  const int TPB = 256;
  const int gTok = (NTOK+TPB-1)/TPB;

  // ================= MAIN PIPELINE — round-1 code, unmodified =================
  hipMemcpyAsync(RES, x_enc, (size_t)NTOK*4, hipMemcpyDeviceToDevice, stream);

  for(int layer=0; layer<2; ++layer){
    if(layer>0) k_add_flip<<<gTok,TPB,0,stream>>>(RES, H, 0);
    k_ln<<<NROWS,TPB,0,stream>>>(RES, norm_w + layer*DM, norm_b + layer*DM, HN);
    hipMemsetAsync(H, 0, (size_t)NTOK*4, stream);
    for(int dir=0; dir<2; ++dir){
      const float* U = HN;
      if(dir==1){ k_flip<<<gTok,TPB,0,stream>>>(HNF, HN); U = HNF; }
      int idx = layer*2 + dir;
      const float* Win  = in_proj_w + (size_t)idx*DM*DIP;
      const float* cw   = conv_w   + (size_t)idx*CVD*4;
      const float* cb   = conv_b   + (size_t)idx*CVD;
      const float* dtb  = dt_bias  + (size_t)idx*NH;
      const float* Alog = A_log    + (size_t)idx*NH;
      const float* Dp   = D_param  + (size_t)idx*NH;
      const float* gw   = gnorm_w  + (size_t)idx*DIN;
      const float* Wout = out_proj_w + (size_t)idx*DIN*DM;

      gemm(stream, U, Win, nullptr, nullptr, ZB, NROWS, DIP, DM, 0);
      k_conv<<<(BS*SEQL*CVD+TPB-1)/TPB,TPB,0,stream>>>(ZB, cw, cb, XC);
      k_dt<<<(BS*SEQL*NH+TPB-1)/TPB,TPB,0,stream>>>(ZB, dtb, Alog, DT, DA);
      k_acum<<<BS*NC*NH,256,0,stream>>>(DA, ACUM, CDEC);
      k_ydiag<<<BS*NC*NH*4,256,0,stream>>>(XC, DT, ACUM, Y);
      k_states<<<BS*NC*NH,256,0,stream>>>(XC, DT, ACUM, ST);
      k_scan<<<(BS*NH*4096+TPB-1)/TPB,TPB,0,stream>>>(ST, CDEC, PREV);
      k_yfinal<<<(BS*SEQL*DIN+TPB-1)/TPB,TPB,0,stream>>>(XC, ACUM, PREV, ZB, Dp, Y);
      k_rms<<<NROWS,256,0,stream>>>(Y, gw);
      gemm(stream, Y, Wout, nullptr, nullptr, YD, NROWS, DM, DIN, 0);
      k_add_flip<<<gTok,TPB,0,stream>>>(H, YD, dir);
    }
  }
  k_add_flip<<<gTok,TPB,0,stream>>>(RES, H, 0);
  k_ln<<<NROWS,TPB,0,stream>>>(RES, normf_w, normf_b, HF);

  // attention head (round-1 aliases into dead ZB/XC/Y)
  float* QIN = ZB + 0*2097152;
  float* CIN = ZB + 1*2097152;
  float* QPb = ZB + 2*2097152;
  float* CPb = ZB + 3*2097152;
  float* QN  = ZB + 4*2097152;
  float* CN  = ZB + 5*2097152;
  float* QQ  = ZB + 6*2097152;
  float* KK  = ZB + 7*2097152;
  float* VV  = XC + 0*2097152;
  float* AO  = XC + 1*2097152;
  float* O1  = XC + 2*2097152;
  float* D1  = Y;

  const int M2 = BS*1024;   // 4096
  k_extract<<<(BS*1024*DM+TPB-1)/TPB,TPB,0,stream>>>(HF, QIN, CIN);
  gemm(stream, QIN, qp_w, qp_b, nullptr, QPb, M2, DM, DM, 0);
  gemm(stream, CIN, cp_w, cp_b, nullptr, CPb, M2, DM, DM, 0);
  k_ln<<<M2,TPB,0,stream>>>(QPb, ca_nq_w, ca_nq_b, QN);
  k_ln<<<M2,TPB,0,stream>>>(CPb, ca_nkv_w, ca_nkv_b, CN);
  gemm(stream, QN, ca_qw, ca_qb, nullptr, QQ, M2, DM, DM, 0);
  gemm(stream, CN, ca_kw, ca_kb, nullptr, KK, M2, DM, DM, 0);
  gemm(stream, CN, ca_vw, ca_vb, nullptr, VV, M2, DM, DM, 0);
  k_attn<<<BS*4*1024,256,0,stream>>>(QQ, KK, VV, AO);
  gemm(stream, AO, ca_ow, ca_ob, QPb, O1, M2, DM, DM, 0);
  gemm(stream, O1, dec1_w, dec1_b, nullptr, D1, M2, 1024, DM, 1);
  gemm(stream, D1, dec2_w, dec2_b, nullptr, (float*)d_out, M2, 10, 1024, 0);
  // ======================= d_out is now complete =======================

  // ================= PROBES (touch only dead ws regions) =================
  float* FLG  = DT;                      // dead
  u16*   WinT = (u16*)ZB;                // 4,489,216 u16 (dead region)
  u16*   HFbf = (u16*)(ZB + 4194304);    // 4,194,304 u16
  float* REFp = Y;                       // 8192*768 = 6,291,456 (dead)
  float* OUTp = XC;                      // 6,291,456 (dead)
  dim3 tb(32,8);

  hipMemsetAsync(FLG, 0, 64*sizeof(float), stream);
  k_setflag<<<1,1,0,stream>>>(FLG+0);                                   // CAL always on
  k_wt<<<dim3(69,16,4),tb,0,stream>>>(in_proj_w, WinT, 512, 2192);
  k_wtchk<<<(512*2192+TPB-1)/TPB,TPB,0,stream>>>(in_proj_w, WinT, 512, 2192, FLG+2);
  k_cvt<<<(1048576+TPB-1)/TPB,TPB,0,stream>>>(HF, HFbf, 1048576);
  k_refgemm<<<dim3(12,2048),256,0,stream>>>(HF, in_proj_w, REFp);
  k_mgemm <<<dim3(6,64),256,0,stream>>>(HFbf, WinT, OUTp, 8192, 2192, 512, 512, 512, 768);
  k_diff<<<2048,TPB,0,stream>>>(REFp, OUTp, (long)8192*768, 0.1f, FLG+2);
  k_mgemm3<<<dim3(6,64),256,0,stream>>>(HFbf, WinT, OUTp, 8192, 2192, 512, 512, 512, 768);
  k_diff<<<2048,TPB,0,stream>>>(REFp, OUTp, (long)8192*768, 0.1f, FLG+3);
  // burn spins: dur_us decodes flag state
  k_burn<<<1,64,0,stream>>>(FLG, 0,  3000000L, FLG+8);   // CAL: ~5-9 ms always
  k_burn<<<1,64,0,stream>>>(FLG, 3, 18000000L, FLG+8);   // CANARY dirty: +30-50 ms (expected if V1 correct)
  k_burn<<<1,64,0,stream>>>(FLG, 2, 96000000L, FLG+8);   // V1-MISMATCH dirty: +160-275 ms
}

// Round 9
// 6527.979 us; speedup vs baseline: 49.7690x; 49.7690x over previous
//
#include <hip/hip_runtime.h>
#include <hip/hip_bf16.h>

#define BS 4
#define SEQL 2048
#define DM 512
#define DIN 1024
#define NH 16
#define HD 64
#define DST 64
#define NC 8
#define CKS 256
#define DIP 2192
#define CVD 1152
#define NROWS (BS*SEQL)          /* 8192 */
#define NTOK (BS*SEQL*DM)        /* 4194304 */

typedef unsigned short u16;
typedef __bf16 bf16x8 __attribute__((ext_vector_type(8)));
typedef float f32x4 __attribute__((ext_vector_type(4)));

__device__ __forceinline__ u16 cvt_bf16(float f){
  unsigned int x = __float_as_uint(f);
  unsigned int r = x + 0x7fffu + ((x>>16)&1u);
  return (u16)(r>>16);
}

// ---------------- elementwise (round-1 proven) ----------------
__global__ void k_add_flip(float* __restrict__ dst, const float* __restrict__ src, int flip){
  int i = blockIdx.x*256 + threadIdx.x;
  if(i >= NTOK) return;
  int d = i & (DM-1);
  int l = (i >> 9) & (SEQL-1);
  int b = i >> 20;
  int sl = flip ? (SEQL-1-l) : l;
  dst[i] += src[(b*SEQL + sl)*DM + d];
}

__global__ void k_flip(float* __restrict__ dst, const float* __restrict__ src){
  int i = blockIdx.x*256 + threadIdx.x;
  if(i >= NTOK) return;
  int d = i & (DM-1);
  int l = (i >> 9) & (SEQL-1);
  int b = i >> 20;
  dst[i] = src[(b*SEQL + (SEQL-1-l))*DM + d];
}

// f32 -> bf16 (verified round-8)
__global__ void k_cvt(const float* __restrict__ src, u16* __restrict__ dst, int n4){
  int i = blockIdx.x*256 + threadIdx.x;
  if(i >= n4) return;
  float4 f = reinterpret_cast<const float4*>(src)[i];
  ushort4 o; o.x=cvt_bf16(f.x); o.y=cvt_bf16(f.y); o.z=cvt_bf16(f.z); o.w=cvt_bf16(f.w);
  reinterpret_cast<ushort4*>(dst)[i] = o;
}

__global__ void k_ln(const float* __restrict__ X, const float* __restrict__ w,
                     const float* __restrict__ bb, float* __restrict__ O){
  int row = blockIdx.x, tid = threadIdx.x;
  const float* x = X + (size_t)row*DM;
  float* o = O + (size_t)row*DM;
  float s=0.f, s2=0.f;
  for(int j=tid;j<DM;j+=256){ float v=x[j]; s+=v; s2+=v*v; }
  __shared__ float r1[256], r2[256];
  r1[tid]=s; r2[tid]=s2; __syncthreads();
  for(int off=128;off>0;off>>=1){
    if(tid<off){ r1[tid]+=r1[tid+off]; r2[tid]+=r2[tid+off]; }
    __syncthreads();
  }
  float m = r1[0]*(1.f/DM);
  float var = r2[0]*(1.f/DM) - m*m;
  float inv = rsqrtf(var + 1e-5f);
  for(int j=tid;j<DM;j+=256) o[j] = (x[j]-m)*inv*w[j] + bb[j];
}

__global__ void k_rms(float* __restrict__ Y, const float* __restrict__ gw){
  int row = blockIdx.x, tid = threadIdx.x;
  float* y = Y + (size_t)row*DIN;
  float ss=0.f;
  for(int j=tid;j<DIN;j+=256){ float v=y[j]; ss+=v*v; }
  __shared__ float red[256];
  red[tid]=ss; __syncthreads();
  for(int off=128;off>0;off>>=1){
    if(tid<off) red[tid]+=red[tid+off];
    __syncthreads();
  }
  float inv = rsqrtf(red[0]*(1.f/DIN) + 1e-5f);
  for(int j=tid;j<DIN;j+=256) y[j] = y[j]*inv*gw[j];
}

// ---------------- f32 GEMM (attention-side + head, proven) ----------------
__global__ void k_gemm(const float* __restrict__ A, const float* __restrict__ B,
                       const float* __restrict__ bias, const float* __restrict__ res,
                       float* __restrict__ C, int M, int N, int K, int act){
  __shared__ float As[64][17];
  __shared__ float Bs[16][65];
  int tx = threadIdx.x, ty = threadIdx.y;
  int tid = ty*16+tx;
  int r0 = blockIdx.y*64, c0 = blockIdx.x*64;
  float acc[4][4];
  #pragma unroll
  for(int i=0;i<4;i++)
    #pragma unroll
    for(int j=0;j<4;j++) acc[i][j]=0.f;
  for(int k0=0;k0<K;k0+=16){
    #pragma unroll
    for(int e=0;e<4;e++){
      int idx = tid + e*256;
      int ar = idx>>4, ac = idx&15;
      As[ar][ac] = A[(size_t)(r0+ar)*K + k0+ac];
      int br = idx>>6, bc = idx&63;
      float bv = 0.f;
      if(c0+bc < N) bv = B[(size_t)(k0+br)*N + c0+bc];
      Bs[br][bc] = bv;
    }
    __syncthreads();
    #pragma unroll
    for(int kk=0;kk<16;kk++){
      float a0=As[ty*4+0][kk],a1=As[ty*4+1][kk],a2=As[ty*4+2][kk],a3=As[ty*4+3][kk];
      float b0=Bs[kk][tx*4+0],b1=Bs[kk][tx*4+1],b2=Bs[kk][tx*4+2],b3=Bs[kk][tx*4+3];
      acc[0][0]+=a0*b0; acc[0][1]+=a0*b1; acc[0][2]+=a0*b2; acc[0][3]+=a0*b3;
      acc[1][0]+=a1*b0; acc[1][1]+=a1*b1; acc[1][2]+=a1*b2; acc[1][3]+=a1*b3;
      acc[2][0]+=a2*b0; acc[2][1]+=a2*b1; acc[2][2]+=a2*b2; acc[2][3]+=a2*b3;
      acc[3][0]+=a3*b0; acc[3][1]+=a3*b1; acc[3][2]+=a3*b2; acc[3][3]+=a3*b3;
    }
    __syncthreads();
  }
  #pragma unroll
  for(int i=0;i<4;i++){
    int r = r0 + ty*4 + i;
    #pragma unroll
    for(int j=0;j<4;j++){
      int c = c0 + tx*4 + j;
      if(c < N){
        float v = acc[i][j];
        if(bias) v += bias[c];
        if(act==1) v = 0.5f*v*(1.f+erff(v*0.70710678118654752f));
        if(res) v += res[(size_t)r*N + c];
        C[(size_t)r*N + c] = v;
      }
    }
  }
}

// weight transpose-convert (verified bit-exact round-8)
__global__ void k_wt(const float* __restrict__ src, u16* __restrict__ dst, int K, int N){
  __shared__ float t[32][33];
  int n0 = blockIdx.x*32, k0 = blockIdx.y*32;
  int tx = threadIdx.x, ty = threadIdx.y;
  #pragma unroll
  for(int i=0;i<32;i+=8){
    int k = k0+ty+i, n = n0+tx;
    t[ty+i][tx] = (n<N) ? src[(size_t)k*N+n] : 0.f;
  }
  __syncthreads();
  #pragma unroll
  for(int i=0;i<32;i+=8){
    int n = n0+ty+i, k = k0+tx;
    if(n<N) dst[(size_t)n*K+k] = cvt_bf16(t[tx][ty+i]);
  }
}

// ---------------- MFMA bf16 GEMM, emap0 (HW-verified round-8: b0/b4/b6 clean) ----------------
__global__ __launch_bounds__(256) void k_mg(
    const u16* __restrict__ A, const u16* __restrict__ BT,
    float* __restrict__ C, int M, int N, int K, int lda, int ldb, int ldc)
{
  __shared__ uint4 As4[128*5];
  __shared__ uint4 Bs4[128*5];
  const int tid = threadIdx.x;
  const int row0 = blockIdx.y*128, col0 = blockIdx.x*128;
  const int lane = tid & 63, wave = tid >> 6;
  const int wm = wave >> 1, wn = wave & 1;
  const int lr = lane & 15, ksg = (lane >> 4);
  f32x4 acc[4][4];
  #pragma unroll
  for(int i=0;i<4;i++)
    #pragma unroll
    for(int j=0;j<4;j++) acc[i][j] = (f32x4){0.f,0.f,0.f,0.f};
  for(int k0=0;k0<K;k0+=32){
    #pragma unroll
    for(int i=0;i<2;i++){
      int t2 = tid + i*256;
      int rr = t2 >> 2, sg = (t2 & 3);
      uint4 av = *reinterpret_cast<const uint4*>(A + (size_t)(row0+rr)*lda + k0 + sg*8);
      uint4 bv = {0u,0u,0u,0u};
      if(col0+rr < N) bv = *reinterpret_cast<const uint4*>(BT + (size_t)(col0+rr)*ldb + k0 + sg*8);
      As4[rr*5 + sg] = av;
      Bs4[rr*5 + sg] = bv;
    }
    __syncthreads();
    bf16x8 afr[4], bfr[4];
    #pragma unroll
    for(int i=0;i<4;i++) afr[i] = *reinterpret_cast<const bf16x8*>(&As4[(wm*64+i*16+lr)*5 + ksg]);
    #pragma unroll
    for(int j=0;j<4;j++) bfr[j] = *reinterpret_cast<const bf16x8*>(&Bs4[(wn*64+j*16+lr)*5 + ksg]);
    #pragma unroll
    for(int i=0;i<4;i++)
      #pragma unroll
      for(int j=0;j<4;j++)
        acc[i][j] = __builtin_amdgcn_mfma_f32_16x16x32_bf16(afr[i], bfr[j], acc[i][j], 0, 0, 0);
    __syncthreads();
  }
  const int hi = lane >> 4, lo = lane & 15;
  #pragma unroll
  for(int i=0;i<4;i++)
    #pragma unroll
    for(int j=0;j<4;j++)
      #pragma unroll
      for(int r=0;r<4;r++){
        int row = row0 + wm*64 + i*16 + 4*hi + r;    // emap0 — verified
        int col = col0 + wn*64 + j*16 + lo;
        if(col < N) C[(size_t)row*ldc + col] = acc[i][j][r];
      }
}

// ---------------- mamba pieces (proven) ----------------
__global__ void k_conv(const float* __restrict__ ZB, const float* __restrict__ cw,
                       const float* __restrict__ cb, float* __restrict__ XC){
  int i = blockIdx.x*256 + threadIdx.x;
  if(i >= BS*SEQL*CVD) return;
  int cch = i % CVD;
  int l = (i / CVD) & (SEQL-1);
  int b = i / (CVD*SEQL);
  float v = cb[cch];
  #pragma unroll
  for(int k=0;k<4;k++){
    int sl = l + k - 3;
    if(sl >= 0) v += ZB[(size_t)(b*SEQL+sl)*DIP + DIN + cch] * cw[cch*4 + k];
  }
  float sig = 1.f/(1.f+expf(-v));
  XC[i] = v*sig;
}

__global__ void k_dt(const float* __restrict__ ZB, const float* __restrict__ dtb,
                     const float* __restrict__ Alog, float* __restrict__ DT,
                     float* __restrict__ DA){
  int i = blockIdx.x*256 + threadIdx.x;
  if(i >= BS*SEQL*NH) return;
  int h = i & (NH-1);
  int row = i >> 4;
  float raw = ZB[(size_t)row*DIP + (DIN+CVD) + h] + dtb[h];
  float dt = fmaxf(raw,0.f) + log1pf(expf(-fabsf(raw)));
  DT[i] = dt;
  DA[i] = dt * (-expf(Alog[h]));
}

__global__ void k_acum(const float* __restrict__ DA, float* __restrict__ ACUM,
                       float* __restrict__ CDEC){
  int blk = blockIdx.x;
  int h = blk & 15, c = (blk>>4)&7, b = blk>>7;
  int l = threadIdx.x;
  __shared__ float s[256];
  int gl = c*CKS + l;
  s[l] = DA[(size_t)(b*SEQL + gl)*NH + h];
  __syncthreads();
  for(int off=1; off<256; off<<=1){
    float v = (l>=off) ? s[l-off] : 0.f;
    __syncthreads();
    s[l] += v;
    __syncthreads();
  }
  ACUM[(size_t)blk*CKS + l] = s[l];
  if(l==255) CDEC[blk] = expf(s[255]);
}

__global__ void k_ydiag(const float* __restrict__ XC, const float* __restrict__ DT,
                        const float* __restrict__ ACUM, float* __restrict__ Y){
  int blk = blockIdx.x;
  int lt = blk & 3, h = (blk>>2)&15, c = (blk>>6)&7, b = blk>>9;
  int tid = threadIdx.x;
  int p = tid & 63, lq = tid >> 6;
  __shared__ float Ac[256];
  __shared__ float Bt[32][65];
  __shared__ float Xt[32][65];
  __shared__ float Ct[64][65];
  __shared__ float Gt[64][33];
  const float* xcb = XC + (size_t)b*SEQL*CVD;
  Ac[tid] = ACUM[(size_t)((b*8+c)*16+h)*CKS + tid];
  #pragma unroll
  for(int e=0;e<16;e++){
    int idx = tid + e*256;
    int ll = idx>>6, n = idx&63;
    Ct[ll][n] = xcb[(size_t)(c*CKS + lt*64 + ll)*CVD + (DIN+DST) + n];
  }
  float acc[16];
  #pragma unroll
  for(int j=0;j<16;j++) acc[j]=0.f;
  int ntiles = 2*lt+2;
  for(int st=0; st<ntiles; ++st){
    int s0 = st*32;
    __syncthreads();
    #pragma unroll
    for(int e=0;e<8;e++){
      int idx = tid + e*256;
      int sl = idx>>6, n = idx&63;
      int gs = c*CKS + s0 + sl;
      Bt[sl][n] = xcb[(size_t)gs*CVD + DIN + n];
      Xt[sl][n] = xcb[(size_t)gs*CVD + h*HD + n] * DT[(size_t)(b*SEQL+gs)*NH + h];
    }
    __syncthreads();
    #pragma unroll
    for(int e=0;e<8;e++){
      int idx = tid*8 + e;
      int ll = idx>>5, sp = idx&31;
      int l = lt*64 + ll;
      int sg = s0 + sp;
      float g = 0.f;
      if(sg <= l){
        float dot=0.f;
        #pragma unroll
        for(int n=0;n<64;n++) dot += Ct[ll][n]*Bt[sp][n];
        g = expf(Ac[l]-Ac[sg]) * dot;
      }
      Gt[ll][sp] = g;
    }
    __syncthreads();
    #pragma unroll
    for(int j=0;j<16;j++){
      int ll = lq*16 + j;
      float a = 0.f;
      #pragma unroll
      for(int sp=0;sp<32;sp++) a += Gt[ll][sp]*Xt[sp][p];
      acc[j] += a;
    }
  }
  #pragma unroll
  for(int j=0;j<16;j++){
    int l = lt*64 + lq*16 + j;
    Y[(size_t)(b*SEQL + c*CKS + l)*DIN + h*HD + p] = acc[j];
  }
}

__global__ void k_states(const float* __restrict__ XC, const float* __restrict__ DT,
                         const float* __restrict__ ACUM, float* __restrict__ ST){
  int blk = blockIdx.x;
  int h = blk & 15, c = (blk>>4)&7, b = blk>>7;
  int tid = threadIdx.x;
  int n = tid & 63, pq = tid >> 6;
  __shared__ float Ac[256];
  __shared__ float Bt[32][64];
  __shared__ float Xt[32][64];
  Ac[tid] = ACUM[(size_t)blk*CKS + tid];
  float acc[16];
  #pragma unroll
  for(int k=0;k<16;k++) acc[k]=0.f;
  const float* xcb = XC + (size_t)b*SEQL*CVD;
  for(int st=0; st<8; ++st){
    __syncthreads();
    #pragma unroll
    for(int e=0;e<8;e++){
      int idx = tid + e*256;
      int sl = idx>>6, nn = idx&63;
      int gs = c*CKS + st*32 + sl;
      Bt[sl][nn] = xcb[(size_t)gs*CVD + DIN + nn];
      float dec = expf(Ac[255] - Ac[st*32+sl]);
      Xt[sl][nn] = xcb[(size_t)gs*CVD + h*HD + nn] * DT[(size_t)(b*SEQL+gs)*NH + h] * dec;
    }
    __syncthreads();
    #pragma unroll
    for(int l=0;l<32;l++){
      float bv = Bt[l][n];
      #pragma unroll
      for(int k=0;k<16;k++) acc[k] += bv * Xt[l][pq + 4*k];
    }
  }
  #pragma unroll
  for(int k=0;k<16;k++){
    int p = pq + 4*k;
    ST[(size_t)blk*4096 + p*64 + n] = acc[k];
  }
}

__global__ void k_scan(const float* __restrict__ ST, const float* __restrict__ CDEC,
                       float* __restrict__ PREV){
  int i = blockIdx.x*256 + threadIdx.x;
  if(i >= BS*NH*4096) return;
  int pn = i & 4095;
  int h = (i>>12) & 15;
  int b = i >> 16;
  float run = 0.f;
  for(int c=0;c<8;c++){
    size_t idx = (size_t)((b*8+c)*16+h)*4096 + pn;
    PREV[idx] = run;
    run = run*CDEC[(b*8+c)*16+h] + ST[idx];
  }
}

__global__ void k_yfinal(const float* __restrict__ XC, const float* __restrict__ ACUM,
                         const float* __restrict__ PREV, const float* __restrict__ ZB,
                         const float* __restrict__ Dp, float* __restrict__ Y){
  int i = blockIdx.x*256 + threadIdx.x;
  if(i >= BS*SEQL*DIN) return;
  int p = i & 63;
  int h = (i>>6) & 15;
  int l = (i>>10) & (SEQL-1);
  int b = i >> 21;
  int c = l >> 8;
  int lc = l & 255;
  const float* prev = PREV + (size_t)((b*8+c)*16+h)*4096 + p*64;
  const float* crow = XC + (size_t)(b*SEQL+l)*CVD + (DIN+DST);
  float s = 0.f;
  #pragma unroll
  for(int n=0;n<64;n++) s += crow[n]*prev[n];
  float yoff = expf(ACUM[(size_t)((b*8+c)*16+h)*CKS + lc]) * s;
  float xh = XC[(size_t)(b*SEQL+l)*CVD + h*HD + p];
  float z  = ZB[(size_t)(b*SEQL+l)*DIP + h*HD + p];
  float v = Y[i] + yoff + Dp[h]*xh;
  float sig = 1.f/(1.f+expf(-z));
  Y[i] = v * (z*sig);
}

// ---------------- attention (round-1 f32, proven) ----------------
__global__ void k_extract(const float* __restrict__ HF, float* __restrict__ QIN,
                          float* __restrict__ CIN){
  int i = blockIdx.x*256 + threadIdx.x;
  if(i >= BS*1024*DM) return;
  int d = i & (DM-1);
  int q = (i>>9) & 1023;
  int b = i >> 19;
  QIN[i] = HF[(size_t)(b*SEQL + 1024 + q)*DM + d];
  CIN[i] = HF[(size_t)(b*SEQL + q)*DM + d];
}

__global__ void k_attn(const float* __restrict__ Q, const float* __restrict__ K,
                       const float* __restrict__ V, float* __restrict__ O){
  int blk = blockIdx.x;
  int q = blk & 1023, h = (blk>>10)&3, b = blk>>12;
  int tid = threadIdx.x;
  __shared__ float qrow[128];
  __shared__ float p[1024];
  __shared__ float red[256];
  const float* qptr = Q + (size_t)(b*1024+q)*DM + h*128;
  if(tid < 128) qrow[tid] = qptr[tid];
  __syncthreads();
  const float scale = 0.088388347648318447f;
  float lmax = -1e30f;
  for(int k=tid;k<1024;k+=256){
    const float* kptr = K + (size_t)(b*1024+k)*DM + h*128;
    float s = 0.f;
    for(int d=0;d<128;d++) s += qrow[d]*kptr[d];
    s *= scale;
    p[k] = s;
    lmax = fmaxf(lmax, s);
  }
  red[tid]=lmax; __syncthreads();
  for(int off=128;off>0;off>>=1){
    if(tid<off) red[tid]=fmaxf(red[tid],red[tid+off]);
    __syncthreads();
  }
  float m = red[0];
  __syncthreads();
  float lsum = 0.f;
  for(int k=tid;k<1024;k+=256){ float e=expf(p[k]-m); p[k]=e; lsum+=e; }
  red[tid]=lsum; __syncthreads();
  for(int off=128;off>0;off>>=1){
    if(tid<off) red[tid]+=red[tid+off];
    __syncthreads();
  }
  float inv = 1.f/red[0];
  if(tid < 128){
    int d = tid;
    float acc = 0.f;
    for(int k=0;k<1024;k++) acc += p[k]*V[(size_t)(b*1024+k)*DM + h*128 + d];
    O[(size_t)(b*1024+q)*DM + h*128 + d] = acc*inv;
  }
}

// ---------------- host ----------------
static inline void gemm(hipStream_t st, const float*A, const float*B, const float*bias,
                        const float*res, float*C, int M, int N, int K, int act){
  dim3 g((N+63)/64, M/64), b(16,16);
  k_gemm<<<g,b,0,st>>>(A,B,bias,res,C,M,N,K,act);
}

extern "C" void kernel_launch(void* const* d_in, const int* in_sizes, int n_in,
                              void* d_out, int out_size, void* d_ws, size_t ws_size,
                              hipStream_t stream) {
  (void)in_sizes; (void)n_in; (void)out_size; (void)ws_size;
  const float* x_enc     = (const float*)d_in[0];
  const float* in_proj_w = (const float*)d_in[2];
  const float* conv_w    = (const float*)d_in[3];
  const float* conv_b    = (const float*)d_in[4];
  const float* dt_bias   = (const float*)d_in[5];
  const float* A_log     = (const float*)d_in[6];
  const float* D_param   = (const float*)d_in[7];
  const float* gnorm_w   = (const float*)d_in[8];
  const float* out_proj_w= (const float*)d_in[9];
  const float* norm_w    = (const float*)d_in[10];
  const float* norm_b    = (const float*)d_in[11];
  const float* normf_w   = (const float*)d_in[12];
  const float* normf_b   = (const float*)d_in[13];
  const float* ca_nq_w   = (const float*)d_in[14];
  const float* ca_nq_b   = (const float*)d_in[15];
  const float* ca_nkv_w  = (const float*)d_in[16];
  const float* ca_nkv_b  = (const float*)d_in[17];
  const float* ca_qw     = (const float*)d_in[18];
  const float* ca_kw     = (const float*)d_in[19];
  const float* ca_vw     = (const float*)d_in[20];
  const float* ca_ow     = (const float*)d_in[21];
  const float* ca_qb     = (const float*)d_in[22];
  const float* ca_kb     = (const float*)d_in[23];
  const float* ca_vb     = (const float*)d_in[24];
  const float* ca_ob     = (const float*)d_in[25];
  const float* qp_w      = (const float*)d_in[26];
  const float* qp_b      = (const float*)d_in[27];
  const float* cp_w      = (const float*)d_in[28];
  const float* cp_b      = (const float*)d_in[29];
  const float* dec1_w    = (const float*)d_in[30];
  const float* dec1_b    = (const float*)d_in[31];
  const float* dec2_w    = (const float*)d_in[32];
  const float* dec2_b    = (const float*)d_in[33];

  float* W = (float*)d_ws;
  size_t off = 0;
  auto alloc = [&](size_t n){ float* pp = W + off; off += n; return pp; };
  float* RES  = alloc((size_t)NTOK);
  float* H    = alloc((size_t)NTOK);
  float* HN   = alloc((size_t)NTOK);
  float* HNF  = alloc((size_t)NTOK);
  float* ZB   = alloc((size_t)NROWS*DIP);        // 17,956,864
  float* XC   = alloc((size_t)NROWS*CVD);        //  9,437,184
  float* DT   = alloc((size_t)NROWS*NH);
  float* DA   = alloc((size_t)NROWS*NH);
  float* ACUM = alloc((size_t)BS*NC*NH*CKS);
  float* CDEC = alloc((size_t)BS*NC*NH);
  float* Y    = alloc((size_t)NROWS*DIN);        //  8,388,608
  float* ST   = alloc((size_t)BS*NC*NH*4096);
  float* PREV = alloc((size_t)BS*NC*NH*4096);
  float* YD   = alloc((size_t)NTOK);
  float* HF   = alloc((size_t)NTOK);
  // byte-identical to the proven round-1 layout (61,768,192 floats)

  // staging aliases in dead regions (mamba loop only; HF/HNF rewritten later):
  u16* Ubf    = (u16*)HF;                        // 4,194,304 u16
  u16* WinTc  = (u16*)(HF + 2097152);            // 1,122,304 u16
  u16* WoutTc = (u16*)(HF + 2097152 + 561152);   //   524,288 u16 (ends at HF+2,920,448 fl)
  u16* Ybf    = (u16*)HNF;                       // 8,388,608 u16 (HNF consumed before rms)

  const int TPB = 256;
  const int gTok = (NTOK+TPB-1)/TPB;
  dim3 tb(32,8);

  hipMemcpyAsync(RES, x_enc, (size_t)NTOK*4, hipMemcpyDeviceToDevice, stream);

  for(int layer=0; layer<2; ++layer){
    if(layer>0) k_add_flip<<<gTok,TPB,0,stream>>>(RES, H, 0);
    k_ln<<<NROWS,TPB,0,stream>>>(RES, norm_w + layer*DM, norm_b + layer*DM, HN);
    hipMemsetAsync(H, 0, (size_t)NTOK*4, stream);
    for(int dir=0; dir<2; ++dir){
      int idx = layer*2 + dir;
      const float* cw   = conv_w   + (size_t)idx*CVD*4;
      const float* cb   = conv_b   + (size_t)idx*CVD;
      const float* dtb  = dt_bias  + (size_t)idx*NH;
      const float* Alog = A_log    + (size_t)idx*NH;
      const float* Dp   = D_param  + (size_t)idx*NH;
      const float* gw   = gnorm_w  + (size_t)idx*DIN;

      // A-staging: proven flip + verified cvt (no fused bf16 producers)
      if(dir==0){
        k_cvt<<<(NTOK/4+TPB-1)/TPB,TPB,0,stream>>>(HN, Ubf, NTOK/4);
      }else{
        k_flip<<<gTok,TPB,0,stream>>>(HNF, HN);
        k_cvt<<<(NTOK/4+TPB-1)/TPB,TPB,0,stream>>>(HNF, Ubf, NTOK/4);
      }
      k_wt<<<dim3(69,16),tb,0,stream>>>(in_proj_w + (size_t)idx*DM*DIP, WinTc, 512, 2192);
      // in_proj (verified shape: grid 18x64, ldc 2192, emap0)
      k_mg<<<dim3(18,64),256,0,stream>>>(Ubf, WinTc, ZB, 8192, 2192, 512, 512, 512, 2192);

      k_conv<<<(BS*SEQL*CVD+TPB-1)/TPB,TPB,0,stream>>>(ZB, cw, cb, XC);
      k_dt<<<(BS*SEQL*NH+TPB-1)/TPB,TPB,0,stream>>>(ZB, dtb, Alog, DT, DA);
      k_acum<<<BS*NC*NH,256,0,stream>>>(DA, ACUM, CDEC);
      k_ydiag<<<BS*NC*NH*4,256,0,stream>>>(XC, DT, ACUM, Y);
      k_states<<<BS*NC*NH,256,0,stream>>>(XC, DT, ACUM, ST);
      k_scan<<<(BS*NH*4096+TPB-1)/TPB,TPB,0,stream>>>(ST, CDEC, PREV);
      k_yfinal<<<(BS*SEQL*DIN+TPB-1)/TPB,TPB,0,stream>>>(XC, ACUM, PREV, ZB, Dp, Y);
      k_rms<<<NROWS,256,0,stream>>>(Y, gw);

      // out_proj via MFMA (K=1024 variant verified b4)
      k_cvt<<<(2097152+TPB-1)/TPB,TPB,0,stream>>>(Y, Ybf, 2097152);
      k_wt<<<dim3(16,32),tb,0,stream>>>(out_proj_w + (size_t)idx*DIN*DM, WoutTc, 1024, 512);
      k_mg<<<dim3(4,64),256,0,stream>>>(Ybf, WoutTc, YD, 8192, 512, 1024, 1024, 1024, 512);

      k_add_flip<<<gTok,TPB,0,stream>>>(H, YD, dir);
    }
  }
  k_add_flip<<<gTok,TPB,0,stream>>>(RES, H, 0);
  k_ln<<<NROWS,TPB,0,stream>>>(RES, normf_w, normf_b, HF);

  // ----- attention head (round-1 f32, proven) -----
  float* QIN = ZB + 0*2097152;
  float* CIN = ZB + 1*2097152;
  float* QPb = ZB + 2*2097152;
  float* CPb = ZB + 3*2097152;
  float* QN  = ZB + 4*2097152;
  float* CN  = ZB + 5*2097152;
  float* QQ  = ZB + 6*2097152;
  float* KK  = ZB + 7*2097152;
  float* VV  = XC + 0*2097152;
  float* AO  = XC + 1*2097152;
  float* O1  = XC + 2*2097152;
  float* D1  = Y;

  const int M2 = BS*1024;
  k_extract<<<(BS*1024*DM+TPB-1)/TPB,TPB,0,stream>>>(HF, QIN, CIN);
  gemm(stream, QIN, qp_w, qp_b, nullptr, QPb, M2, DM, DM, 0);
  gemm(stream, CIN, cp_w, cp_b, nullptr, CPb, M2, DM, DM, 0);
  k_ln<<<M2,TPB,0,stream>>>(QPb, ca_nq_w, ca_nq_b, QN);
  k_ln<<<M2,TPB,0,stream>>>(CPb, ca_nkv_w, ca_nkv_b, CN);
  gemm(stream, QN, ca_qw, ca_qb, nullptr, QQ, M2, DM, DM, 0);
  gemm(stream, CN, ca_kw, ca_kb, nullptr, KK, M2, DM, DM, 0);
  gemm(stream, CN, ca_vw, ca_vb, nullptr, VV, M2, DM, DM, 0);
  k_attn<<<BS*4*1024,256,0,stream>>>(QQ, KK, VV, AO);
  gemm(stream, AO, ca_ow, ca_ob, QPb, O1, M2, DM, DM, 0);
  gemm(stream, O1, dec1_w, dec1_b, nullptr, D1, M2, 1024, DM, 1);
  gemm(stream, D1, dec2_w, dec2_b, nullptr, (float*)d_out, M2, 10, 1024, 0);
}

// Round 10
// 5364.474 us; speedup vs baseline: 60.5635x; 1.2169x over previous
//
#include <hip/hip_runtime.h>
#include <hip/hip_bf16.h>

#define BS 4
#define SEQL 2048
#define DM 512
#define DIN 1024
#define NH 16
#define HD 64
#define DST 64
#define NC 8
#define CKS 256
#define DIP 2192
#define CVD 1152
#define NROWS (BS*SEQL)          /* 8192 */
#define NTOK (BS*SEQL*DM)        /* 4194304 */

typedef unsigned short u16;
typedef __bf16 bf16x8 __attribute__((ext_vector_type(8)));
typedef float f32x4 __attribute__((ext_vector_type(4)));

__device__ __forceinline__ u16 cvt_bf16(float f){
  unsigned int x = __float_as_uint(f);
  unsigned int r = x + 0x7fffu + ((x>>16)&1u);
  return (u16)(r>>16);
}
__device__ __forceinline__ float bf2f(u16 u){
  return __uint_as_float(((unsigned int)u)<<16);
}

// ---------------- elementwise (proven) ----------------
__global__ void k_add_flip(float* __restrict__ dst, const float* __restrict__ src, int flip){
  int i = blockIdx.x*256 + threadIdx.x;
  if(i >= NTOK) return;
  int d = i & (DM-1);
  int l = (i >> 9) & (SEQL-1);
  int b = i >> 20;
  int sl = flip ? (SEQL-1-l) : l;
  dst[i] += src[(b*SEQL + sl)*DM + d];
}

__global__ void k_flip(float* __restrict__ dst, const float* __restrict__ src){
  int i = blockIdx.x*256 + threadIdx.x;
  if(i >= NTOK) return;
  int d = i & (DM-1);
  int l = (i >> 9) & (SEQL-1);
  int b = i >> 20;
  dst[i] = src[(b*SEQL + (SEQL-1-l))*DM + d];
}

// f32 -> bf16 (verified round-8)
__global__ void k_cvt(const float* __restrict__ src, u16* __restrict__ dst, int n4){
  int i = blockIdx.x*256 + threadIdx.x;
  if(i >= n4) return;
  float4 f = reinterpret_cast<const float4*>(src)[i];
  ushort4 o; o.x=cvt_bf16(f.x); o.y=cvt_bf16(f.y); o.z=cvt_bf16(f.z); o.w=cvt_bf16(f.w);
  reinterpret_cast<ushort4*>(dst)[i] = o;
}

__global__ void k_ln(const float* __restrict__ X, const float* __restrict__ w,
                     const float* __restrict__ bb, float* __restrict__ O){
  int row = blockIdx.x, tid = threadIdx.x;
  const float* x = X + (size_t)row*DM;
  float* o = O + (size_t)row*DM;
  float s=0.f, s2=0.f;
  for(int j=tid;j<DM;j+=256){ float v=x[j]; s+=v; s2+=v*v; }
  __shared__ float r1[256], r2[256];
  r1[tid]=s; r2[tid]=s2; __syncthreads();
  for(int off=128;off>0;off>>=1){
    if(tid<off){ r1[tid]+=r1[tid+off]; r2[tid]+=r2[tid+off]; }
    __syncthreads();
  }
  float m = r1[0]*(1.f/DM);
  float var = r2[0]*(1.f/DM) - m*m;
  float inv = rsqrtf(var + 1e-5f);
  for(int j=tid;j<DM;j+=256) o[j] = (x[j]-m)*inv*w[j] + bb[j];
}

__global__ void k_rms(float* __restrict__ Y, const float* __restrict__ gw){
  int row = blockIdx.x, tid = threadIdx.x;
  float* y = Y + (size_t)row*DIN;
  float ss=0.f;
  for(int j=tid;j<DIN;j+=256){ float v=y[j]; ss+=v*v; }
  __shared__ float red[256];
  red[tid]=ss; __syncthreads();
  for(int off=128;off>0;off>>=1){
    if(tid<off) red[tid]+=red[tid+off];
    __syncthreads();
  }
  float inv = rsqrtf(red[0]*(1.f/DIN) + 1e-5f);
  for(int j=tid;j<DIN;j+=256) y[j] = y[j]*inv*gw[j];
}

// ---------------- f32 GEMM (dec2 only) ----------------
__global__ void k_gemm(const float* __restrict__ A, const float* __restrict__ B,
                       const float* __restrict__ bias, const float* __restrict__ res,
                       float* __restrict__ C, int M, int N, int K, int act){
  __shared__ float As[64][17];
  __shared__ float Bs[16][65];
  int tx = threadIdx.x, ty = threadIdx.y;
  int tid = ty*16+tx;
  int r0 = blockIdx.y*64, c0 = blockIdx.x*64;
  float acc[4][4];
  #pragma unroll
  for(int i=0;i<4;i++)
    #pragma unroll
    for(int j=0;j<4;j++) acc[i][j]=0.f;
  for(int k0=0;k0<K;k0+=16){
    #pragma unroll
    for(int e=0;e<4;e++){
      int idx = tid + e*256;
      int ar = idx>>4, ac = idx&15;
      As[ar][ac] = A[(size_t)(r0+ar)*K + k0+ac];
      int br = idx>>6, bc = idx&63;
      float bv = 0.f;
      if(c0+bc < N) bv = B[(size_t)(k0+br)*N + c0+bc];
      Bs[br][bc] = bv;
    }
    __syncthreads();
    #pragma unroll
    for(int kk=0;kk<16;kk++){
      float a0=As[ty*4+0][kk],a1=As[ty*4+1][kk],a2=As[ty*4+2][kk],a3=As[ty*4+3][kk];
      float b0=Bs[kk][tx*4+0],b1=Bs[kk][tx*4+1],b2=Bs[kk][tx*4+2],b3=Bs[kk][tx*4+3];
      acc[0][0]+=a0*b0; acc[0][1]+=a0*b1; acc[0][2]+=a0*b2; acc[0][3]+=a0*b3;
      acc[1][0]+=a1*b0; acc[1][1]+=a1*b1; acc[1][2]+=a1*b2; acc[1][3]+=a1*b3;
      acc[2][0]+=a2*b0; acc[2][1]+=a2*b1; acc[2][2]+=a2*b2; acc[2][3]+=a2*b3;
      acc[3][0]+=a3*b0; acc[3][1]+=a3*b1; acc[3][2]+=a3*b2; acc[3][3]+=a3*b3;
    }
    __syncthreads();
  }
  #pragma unroll
  for(int i=0;i<4;i++){
    int r = r0 + ty*4 + i;
    #pragma unroll
    for(int j=0;j<4;j++){
      int c = c0 + tx*4 + j;
      if(c < N){
        float v = acc[i][j];
        if(bias) v += bias[c];
        if(act==1) v = 0.5f*v*(1.f+erff(v*0.70710678118654752f));
        if(res) v += res[(size_t)r*N + c];
        C[(size_t)r*N + c] = v;
      }
    }
  }
}

// transpose-convert with explicit src ld (verified at lds==N round-8):
// src[K][lds] f32 (cols n<N used) -> dst[N][K] bf16
__global__ void k_wt2(const float* __restrict__ src, u16* __restrict__ dst,
                      int K, int N, int lds){
  __shared__ float t[32][33];
  int n0 = blockIdx.x*32, k0 = blockIdx.y*32;
  int tx = threadIdx.x, ty = threadIdx.y;
  #pragma unroll
  for(int i=0;i<32;i+=8){
    int k = k0+ty+i, n = n0+tx;
    t[ty+i][tx] = (n<N) ? src[(size_t)k*lds+n] : 0.f;
  }
  __syncthreads();
  #pragma unroll
  for(int i=0;i<32;i+=8){
    int n = n0+ty+i, k = k0+tx;
    if(n<N) dst[(size_t)n*K+k] = cvt_bf16(t[tx][ty+i]);
  }
}

// ---------------- MFMA bf16 GEMM, emap0 (HW-verified) — mamba version ----------------
__global__ __launch_bounds__(256) void k_mg(
    const u16* __restrict__ A, const u16* __restrict__ BT,
    float* __restrict__ C, int M, int N, int K, int lda, int ldb, int ldc)
{
  __shared__ uint4 As4[128*5];
  __shared__ uint4 Bs4[128*5];
  const int tid = threadIdx.x;
  const int row0 = blockIdx.y*128, col0 = blockIdx.x*128;
  const int lane = tid & 63, wave = tid >> 6;
  const int wm = wave >> 1, wn = wave & 1;
  const int lr = lane & 15, ksg = (lane >> 4);
  f32x4 acc[4][4];
  #pragma unroll
  for(int i=0;i<4;i++)
    #pragma unroll
    for(int j=0;j<4;j++) acc[i][j] = (f32x4){0.f,0.f,0.f,0.f};
  for(int k0=0;k0<K;k0+=32){
    #pragma unroll
    for(int i=0;i<2;i++){
      int t2 = tid + i*256;
      int rr = t2 >> 2, sg = (t2 & 3);
      uint4 av = *reinterpret_cast<const uint4*>(A + (size_t)(row0+rr)*lda + k0 + sg*8);
      uint4 bv = {0u,0u,0u,0u};
      if(col0+rr < N) bv = *reinterpret_cast<const uint4*>(BT + (size_t)(col0+rr)*ldb + k0 + sg*8);
      As4[rr*5 + sg] = av;
      Bs4[rr*5 + sg] = bv;
    }
    __syncthreads();
    bf16x8 afr[4], bfr[4];
    #pragma unroll
    for(int i=0;i<4;i++) afr[i] = *reinterpret_cast<const bf16x8*>(&As4[(wm*64+i*16+lr)*5 + ksg]);
    #pragma unroll
    for(int j=0;j<4;j++) bfr[j] = *reinterpret_cast<const bf16x8*>(&Bs4[(wn*64+j*16+lr)*5 + ksg]);
    #pragma unroll
    for(int i=0;i<4;i++)
      #pragma unroll
      for(int j=0;j<4;j++)
        acc[i][j] = __builtin_amdgcn_mfma_f32_16x16x32_bf16(afr[i], bfr[j], acc[i][j], 0, 0, 0);
    __syncthreads();
  }
  const int hi = lane >> 4, lo = lane & 15;
  #pragma unroll
  for(int i=0;i<4;i++)
    #pragma unroll
    for(int j=0;j<4;j++)
      #pragma unroll
      for(int r=0;r<4;r++){
        int row = row0 + wm*64 + i*16 + 4*hi + r;    // emap0 — verified
        int col = col0 + wn*64 + j*16 + lo;
        if(col < N) C[(size_t)row*ldc + col] = acc[i][j][r];
      }
}

// same verified core + arithmetic epilogue (bias/scale/GELU/res, f32 or bf16 out)
__global__ __launch_bounds__(256) void k_mge(
    const u16* __restrict__ A, const u16* __restrict__ BT,
    const float* __restrict__ bias, const float* __restrict__ res,
    float* __restrict__ C, u16* __restrict__ Cbf,
    int M, int N, int K, int lda, int ldb, int ldc, float scale, int act)
{
  __shared__ uint4 As4[128*5];
  __shared__ uint4 Bs4[128*5];
  const int tid = threadIdx.x;
  const int row0 = blockIdx.y*128, col0 = blockIdx.x*128;
  const int lane = tid & 63, wave = tid >> 6;
  const int wm = wave >> 1, wn = wave & 1;
  const int lr = lane & 15, ksg = (lane >> 4);
  f32x4 acc[4][4];
  #pragma unroll
  for(int i=0;i<4;i++)
    #pragma unroll
    for(int j=0;j<4;j++) acc[i][j] = (f32x4){0.f,0.f,0.f,0.f};
  for(int k0=0;k0<K;k0+=32){
    #pragma unroll
    for(int i=0;i<2;i++){
      int t2 = tid + i*256;
      int rr = t2 >> 2, sg = (t2 & 3);
      uint4 av = *reinterpret_cast<const uint4*>(A + (size_t)(row0+rr)*lda + k0 + sg*8);
      uint4 bv = {0u,0u,0u,0u};
      if(col0+rr < N) bv = *reinterpret_cast<const uint4*>(BT + (size_t)(col0+rr)*ldb + k0 + sg*8);
      As4[rr*5 + sg] = av;
      Bs4[rr*5 + sg] = bv;
    }
    __syncthreads();
    bf16x8 afr[4], bfr[4];
    #pragma unroll
    for(int i=0;i<4;i++) afr[i] = *reinterpret_cast<const bf16x8*>(&As4[(wm*64+i*16+lr)*5 + ksg]);
    #pragma unroll
    for(int j=0;j<4;j++) bfr[j] = *reinterpret_cast<const bf16x8*>(&Bs4[(wn*64+j*16+lr)*5 + ksg]);
    #pragma unroll
    for(int i=0;i<4;i++)
      #pragma unroll
      for(int j=0;j<4;j++)
        acc[i][j] = __builtin_amdgcn_mfma_f32_16x16x32_bf16(afr[i], bfr[j], acc[i][j], 0, 0, 0);
    __syncthreads();
  }
  const int hi = lane >> 4, lo = lane & 15;
  #pragma unroll
  for(int i=0;i<4;i++)
    #pragma unroll
    for(int j=0;j<4;j++)
      #pragma unroll
      for(int r=0;r<4;r++){
        int row = row0 + wm*64 + i*16 + 4*hi + r;    // emap0 — verified
        int col = col0 + wn*64 + j*16 + lo;
        if(col < N){
          float v = acc[i][j][r];
          if(bias) v += bias[col];
          v *= scale;
          if(act==1) v = 0.5f*v*(1.f+erff(v*0.70710678118654752f));
          size_t ci = (size_t)row*ldc + col;
          if(res) v += res[ci];
          if(C) C[ci] = v;
          else  Cbf[ci] = cvt_bf16(v);
        }
      }
}

// in-place row softmax over 1024 bf16
__global__ void k_sm(u16* __restrict__ S){
  size_t row = blockIdx.x;
  u16* p = S + row*1024;
  int tid = threadIdx.x;
  ushort4 u = reinterpret_cast<ushort4*>(p)[tid];
  float v0=bf2f(u.x), v1=bf2f(u.y), v2=bf2f(u.z), v3=bf2f(u.w);
  float m = fmaxf(fmaxf(v0,v1),fmaxf(v2,v3));
  __shared__ float red[256];
  red[tid]=m; __syncthreads();
  for(int o=128;o>0;o>>=1){ if(tid<o) red[tid]=fmaxf(red[tid],red[tid+o]); __syncthreads(); }
  m = red[0]; __syncthreads();
  v0=__expf(v0-m); v1=__expf(v1-m); v2=__expf(v2-m); v3=__expf(v3-m);
  float s = v0+v1+v2+v3;
  red[tid]=s; __syncthreads();
  for(int o=128;o>0;o>>=1){ if(tid<o) red[tid]+=red[tid+o]; __syncthreads(); }
  float inv = 1.f/red[0];
  ushort4 o4; o4.x=cvt_bf16(v0*inv); o4.y=cvt_bf16(v1*inv); o4.z=cvt_bf16(v2*inv); o4.w=cvt_bf16(v3*inv);
  reinterpret_cast<ushort4*>(p)[tid] = o4;
}

// ---------------- mamba pieces (proven) ----------------
__global__ void k_conv(const float* __restrict__ ZB, const float* __restrict__ cw,
                       const float* __restrict__ cb, float* __restrict__ XC){
  int i = blockIdx.x*256 + threadIdx.x;
  if(i >= BS*SEQL*CVD) return;
  int cch = i % CVD;
  int l = (i / CVD) & (SEQL-1);
  int b = i / (CVD*SEQL);
  float v = cb[cch];
  #pragma unroll
  for(int k=0;k<4;k++){
    int sl = l + k - 3;
    if(sl >= 0) v += ZB[(size_t)(b*SEQL+sl)*DIP + DIN + cch] * cw[cch*4 + k];
  }
  float sig = 1.f/(1.f+expf(-v));
  XC[i] = v*sig;
}

__global__ void k_dt(const float* __restrict__ ZB, const float* __restrict__ dtb,
                     const float* __restrict__ Alog, float* __restrict__ DT,
                     float* __restrict__ DA){
  int i = blockIdx.x*256 + threadIdx.x;
  if(i >= BS*SEQL*NH) return;
  int h = i & (NH-1);
  int row = i >> 4;
  float raw = ZB[(size_t)row*DIP + (DIN+CVD) + h] + dtb[h];
  float dt = fmaxf(raw,0.f) + log1pf(expf(-fabsf(raw)));
  DT[i] = dt;
  DA[i] = dt * (-expf(Alog[h]));
}

__global__ void k_acum(const float* __restrict__ DA, float* __restrict__ ACUM,
                       float* __restrict__ CDEC){
  int blk = blockIdx.x;
  int h = blk & 15, c = (blk>>4)&7, b = blk>>7;
  int l = threadIdx.x;
  __shared__ float s[256];
  int gl = c*CKS + l;
  s[l] = DA[(size_t)(b*SEQL + gl)*NH + h];
  __syncthreads();
  for(int off=1; off<256; off<<=1){
    float v = (l>=off) ? s[l-off] : 0.f;
    __syncthreads();
    s[l] += v;
    __syncthreads();
  }
  ACUM[(size_t)blk*CKS + l] = s[l];
  if(l==255) CDEC[blk] = expf(s[255]);
}

__global__ void k_ydiag(const float* __restrict__ XC, const float* __restrict__ DT,
                        const float* __restrict__ ACUM, float* __restrict__ Y){
  int blk = blockIdx.x;
  int lt = blk & 3, h = (blk>>2)&15, c = (blk>>6)&7, b = blk>>9;
  int tid = threadIdx.x;
  int p = tid & 63, lq = tid >> 6;
  __shared__ float Ac[256];
  __shared__ float Bt[32][65];
  __shared__ float Xt[32][65];
  __shared__ float Ct[64][65];
  __shared__ float Gt[64][33];
  const float* xcb = XC + (size_t)b*SEQL*CVD;
  Ac[tid] = ACUM[(size_t)((b*8+c)*16+h)*CKS + tid];
  #pragma unroll
  for(int e=0;e<16;e++){
    int idx = tid + e*256;
    int ll = idx>>6, n = idx&63;
    Ct[ll][n] = xcb[(size_t)(c*CKS + lt*64 + ll)*CVD + (DIN+DST) + n];
  }
  float acc[16];
  #pragma unroll
  for(int j=0;j<16;j++) acc[j]=0.f;
  int ntiles = 2*lt+2;
  for(int st=0; st<ntiles; ++st){
    int s0 = st*32;
    __syncthreads();
    #pragma unroll
    for(int e=0;e<8;e++){
      int idx = tid + e*256;
      int sl = idx>>6, n = idx&63;
      int gs = c*CKS + s0 + sl;
      Bt[sl][n] = xcb[(size_t)gs*CVD + DIN + n];
      Xt[sl][n] = xcb[(size_t)gs*CVD + h*HD + n] * DT[(size_t)(b*SEQL+gs)*NH + h];
    }
    __syncthreads();
    #pragma unroll
    for(int e=0;e<8;e++){
      int idx = tid*8 + e;
      int ll = idx>>5, sp = idx&31;
      int l = lt*64 + ll;
      int sg = s0 + sp;
      float g = 0.f;
      if(sg <= l){
        float dot=0.f;
        #pragma unroll
        for(int n=0;n<64;n++) dot += Ct[ll][n]*Bt[sp][n];
        g = expf(Ac[l]-Ac[sg]) * dot;
      }
      Gt[ll][sp] = g;
    }
    __syncthreads();
    #pragma unroll
    for(int j=0;j<16;j++){
      int ll = lq*16 + j;
      float a = 0.f;
      #pragma unroll
      for(int sp=0;sp<32;sp++) a += Gt[ll][sp]*Xt[sp][p];
      acc[j] += a;
    }
  }
  #pragma unroll
  for(int j=0;j<16;j++){
    int l = lt*64 + lq*16 + j;
    Y[(size_t)(b*SEQL + c*CKS + l)*DIN + h*HD + p] = acc[j];
  }
}

__global__ void k_states(const float* __restrict__ XC, const float* __restrict__ DT,
                         const float* __restrict__ ACUM, float* __restrict__ ST){
  int blk = blockIdx.x;
  int h = blk & 15, c = (blk>>4)&7, b = blk>>7;
  int tid = threadIdx.x;
  int n = tid & 63, pq = tid >> 6;
  __shared__ float Ac[256];
  __shared__ float Bt[32][64];
  __shared__ float Xt[32][64];
  Ac[tid] = ACUM[(size_t)blk*CKS + tid];
  float acc[16];
  #pragma unroll
  for(int k=0;k<16;k++) acc[k]=0.f;
  const float* xcb = XC + (size_t)b*SEQL*CVD;
  for(int st=0; st<8; ++st){
    __syncthreads();
    #pragma unroll
    for(int e=0;e<8;e++){
      int idx = tid + e*256;
      int sl = idx>>6, nn = idx&63;
      int gs = c*CKS + st*32 + sl;
      Bt[sl][nn] = xcb[(size_t)gs*CVD + DIN + nn];
      float dec = expf(Ac[255] - Ac[st*32+sl]);
      Xt[sl][nn] = xcb[(size_t)gs*CVD + h*HD + nn] * DT[(size_t)(b*SEQL+gs)*NH + h] * dec;
    }
    __syncthreads();
    #pragma unroll
    for(int l=0;l<32;l++){
      float bv = Bt[l][n];
      #pragma unroll
      for(int k=0;k<16;k++) acc[k] += bv * Xt[l][pq + 4*k];
    }
  }
  #pragma unroll
  for(int k=0;k<16;k++){
    int p = pq + 4*k;
    ST[(size_t)blk*4096 + p*64 + n] = acc[k];
  }
}

__global__ void k_scan(const float* __restrict__ ST, const float* __restrict__ CDEC,
                       float* __restrict__ PREV){
  int i = blockIdx.x*256 + threadIdx.x;
  if(i >= BS*NH*4096) return;
  int pn = i & 4095;
  int h = (i>>12) & 15;
  int b = i >> 16;
  float run = 0.f;
  for(int c=0;c<8;c++){
    size_t idx = (size_t)((b*8+c)*16+h)*4096 + pn;
    PREV[idx] = run;
    run = run*CDEC[(b*8+c)*16+h] + ST[idx];
  }
}

__global__ void k_yfinal(const float* __restrict__ XC, const float* __restrict__ ACUM,
                         const float* __restrict__ PREV, const float* __restrict__ ZB,
                         const float* __restrict__ Dp, float* __restrict__ Y){
  int i = blockIdx.x*256 + threadIdx.x;
  if(i >= BS*SEQL*DIN) return;
  int p = i & 63;
  int h = (i>>6) & 15;
  int l = (i>>10) & (SEQL-1);
  int b = i >> 21;
  int c = l >> 8;
  int lc = l & 255;
  const float* prev = PREV + (size_t)((b*8+c)*16+h)*4096 + p*64;
  const float* crow = XC + (size_t)(b*SEQL+l)*CVD + (DIN+DST);
  float s = 0.f;
  #pragma unroll
  for(int n=0;n<64;n++) s += crow[n]*prev[n];
  float yoff = expf(ACUM[(size_t)((b*8+c)*16+h)*CKS + lc]) * s;
  float xh = XC[(size_t)(b*SEQL+l)*CVD + h*HD + p];
  float z  = ZB[(size_t)(b*SEQL+l)*DIP + h*HD + p];
  float v = Y[i] + yoff + Dp[h]*xh;
  float sig = 1.f/(1.f+expf(-z));
  Y[i] = v * (z*sig);
}

// ---------------- attention helpers ----------------
__global__ void k_extract(const float* __restrict__ HF, float* __restrict__ QIN,
                          float* __restrict__ CIN){
  int i = blockIdx.x*256 + threadIdx.x;
  if(i >= BS*1024*DM) return;
  int d = i & (DM-1);
  int q = (i>>9) & 1023;
  int b = i >> 19;
  QIN[i] = HF[(size_t)(b*SEQL + 1024 + q)*DM + d];
  CIN[i] = HF[(size_t)(b*SEQL + q)*DM + d];
}

// ---------------- host ----------------
extern "C" void kernel_launch(void* const* d_in, const int* in_sizes, int n_in,
                              void* d_out, int out_size, void* d_ws, size_t ws_size,
                              hipStream_t stream) {
  (void)in_sizes; (void)n_in; (void)out_size; (void)ws_size;
  const float* x_enc     = (const float*)d_in[0];
  const float* in_proj_w = (const float*)d_in[2];
  const float* conv_w    = (const float*)d_in[3];
  const float* conv_b    = (const float*)d_in[4];
  const float* dt_bias   = (const float*)d_in[5];
  const float* A_log     = (const float*)d_in[6];
  const float* D_param   = (const float*)d_in[7];
  const float* gnorm_w   = (const float*)d_in[8];
  const float* out_proj_w= (const float*)d_in[9];
  const float* norm_w    = (const float*)d_in[10];
  const float* norm_b    = (const float*)d_in[11];
  const float* normf_w   = (const float*)d_in[12];
  const float* normf_b   = (const float*)d_in[13];
  const float* ca_nq_w   = (const float*)d_in[14];
  const float* ca_nq_b   = (const float*)d_in[15];
  const float* ca_nkv_w  = (const float*)d_in[16];
  const float* ca_nkv_b  = (const float*)d_in[17];
  const float* ca_qw     = (const float*)d_in[18];
  const float* ca_kw     = (const float*)d_in[19];
  const float* ca_vw     = (const float*)d_in[20];
  const float* ca_ow     = (const float*)d_in[21];
  const float* ca_qb     = (const float*)d_in[22];
  const float* ca_kb     = (const float*)d_in[23];
  const float* ca_vb     = (const float*)d_in[24];
  const float* ca_ob     = (const float*)d_in[25];
  const float* qp_w      = (const float*)d_in[26];
  const float* qp_b      = (const float*)d_in[27];
  const float* cp_w      = (const float*)d_in[28];
  const float* cp_b      = (const float*)d_in[29];
  const float* dec1_w    = (const float*)d_in[30];
  const float* dec1_b    = (const float*)d_in[31];
  const float* dec2_w    = (const float*)d_in[32];
  const float* dec2_b    = (const float*)d_in[33];

  float* W = (float*)d_ws;
  size_t off = 0;
  auto alloc = [&](size_t n){ float* pp = W + off; off += n; return pp; };
  float* RES  = alloc((size_t)NTOK);
  float* H    = alloc((size_t)NTOK);
  float* HN   = alloc((size_t)NTOK);
  float* HNF  = alloc((size_t)NTOK);
  float* ZB   = alloc((size_t)NROWS*DIP);        // 17,956,864
  float* XC   = alloc((size_t)NROWS*CVD);        //  9,437,184
  float* DT   = alloc((size_t)NROWS*NH);
  float* DA   = alloc((size_t)NROWS*NH);
  float* ACUM = alloc((size_t)BS*NC*NH*CKS);
  float* CDEC = alloc((size_t)BS*NC*NH);
  float* Y    = alloc((size_t)NROWS*DIN);        //  8,388,608
  float* ST   = alloc((size_t)BS*NC*NH*4096);
  float* PREV = alloc((size_t)BS*NC*NH*4096);
  float* YD   = alloc((size_t)NTOK);
  float* HF   = alloc((size_t)NTOK);
  // byte-identical to the proven round-1 layout (61,768,192 floats)

  // mamba staging aliases (round-9 proven):
  u16* Ubf    = (u16*)HF;
  u16* WinTc  = (u16*)(HF + 2097152);
  u16* WoutTc = (u16*)(HF + 2097152 + 561152);
  u16* Ybf    = (u16*)HNF;

  const int TPB = 256;
  const int gTok = (NTOK+TPB-1)/TPB;
  dim3 tb(32,8);

  hipMemcpyAsync(RES, x_enc, (size_t)NTOK*4, hipMemcpyDeviceToDevice, stream);

  for(int layer=0; layer<2; ++layer){
    if(layer>0) k_add_flip<<<gTok,TPB,0,stream>>>(RES, H, 0);
    k_ln<<<NROWS,TPB,0,stream>>>(RES, norm_w + layer*DM, norm_b + layer*DM, HN);
    hipMemsetAsync(H, 0, (size_t)NTOK*4, stream);
    for(int dir=0; dir<2; ++dir){
      int idx = layer*2 + dir;
      const float* cw   = conv_w   + (size_t)idx*CVD*4;
      const float* cb   = conv_b   + (size_t)idx*CVD;
      const float* dtb  = dt_bias  + (size_t)idx*NH;
      const float* Alog = A_log    + (size_t)idx*NH;
      const float* Dp   = D_param  + (size_t)idx*NH;
      const float* gw   = gnorm_w  + (size_t)idx*DIN;

      if(dir==0){
        k_cvt<<<(NTOK/4+TPB-1)/TPB,TPB,0,stream>>>(HN, Ubf, NTOK/4);
      }else{
        k_flip<<<gTok,TPB,0,stream>>>(HNF, HN);
        k_cvt<<<(NTOK/4+TPB-1)/TPB,TPB,0,stream>>>(HNF, Ubf, NTOK/4);
      }
      k_wt2<<<dim3(69,16),tb,0,stream>>>(in_proj_w + (size_t)idx*DM*DIP, WinTc, 512, 2192, 2192);
      k_mg<<<dim3(18,64),256,0,stream>>>(Ubf, WinTc, ZB, 8192, 2192, 512, 512, 512, 2192);

      k_conv<<<(BS*SEQL*CVD+TPB-1)/TPB,TPB,0,stream>>>(ZB, cw, cb, XC);
      k_dt<<<(BS*SEQL*NH+TPB-1)/TPB,TPB,0,stream>>>(ZB, dtb, Alog, DT, DA);
      k_acum<<<BS*NC*NH,256,0,stream>>>(DA, ACUM, CDEC);
      k_ydiag<<<BS*NC*NH*4,256,0,stream>>>(XC, DT, ACUM, Y);
      k_states<<<BS*NC*NH,256,0,stream>>>(XC, DT, ACUM, ST);
      k_scan<<<(BS*NH*4096+TPB-1)/TPB,TPB,0,stream>>>(ST, CDEC, PREV);
      k_yfinal<<<(BS*SEQL*DIN+TPB-1)/TPB,TPB,0,stream>>>(XC, ACUM, PREV, ZB, Dp, Y);
      k_rms<<<NROWS,256,0,stream>>>(Y, gw);

      k_cvt<<<(2097152+TPB-1)/TPB,TPB,0,stream>>>(Y, Ybf, 2097152);
      k_wt2<<<dim3(16,32),tb,0,stream>>>(out_proj_w + (size_t)idx*DIN*DM, WoutTc, 1024, 512, 512);
      k_mg<<<dim3(4,64),256,0,stream>>>(Ybf, WoutTc, YD, 8192, 512, 1024, 1024, 1024, 512);

      k_add_flip<<<gTok,TPB,0,stream>>>(H, YD, dir);
    }
  }
  k_add_flip<<<gTok,TPB,0,stream>>>(RES, H, 0);
  k_ln<<<NROWS,TPB,0,stream>>>(RES, normf_w, normf_b, HF);

  // ================= attention head — MFMA (verified tool-set) =================
  // pool = ZB..YD (40,796,672 floats, all dead; HF stays live)
  float* P0   = ZB;
  float* QIN  = P0 + 0;
  float* CIN  = P0 + 2097152;
  float* QPb  = P0 + 4194304;    // residual, live until o-proj
  float* CPb  = P0 + 6291456;
  float* QN   = P0 + 8388608;
  float* CN   = P0 + 10485760;
  float* AO   = P0 + 12582912;
  float* O1   = P0 + 14680064;
  float* D1   = P0 + 16777216;   // 4M; VV shares first 2M (disjoint lifetime)
  float* VV   = D1;
  u16* U0     = (u16*)(P0 + 20971520);
  u16* Qbf    = U0 + 0;
  u16* Cbf    = U0 + 2097152;
  u16* QNbf   = U0 + 4194304;
  u16* CNbf   = U0 + 6291456;
  u16* QQbf   = U0 + 8388608;
  u16* KKbf   = U0 + 10485760;
  u16* VTbf   = U0 + 12582912;   // [16][128][1024]
  u16* AObf   = U0 + 14680064;
  u16* O1bf   = U0 + 16777216;
  u16* qpT    = U0 + 18874368;
  u16* cpT    = qpT + 262144;
  u16* qwT    = qpT + 524288;
  u16* kwT    = qpT + 786432;
  u16* vwT    = qpT + 1048576;
  u16* owT    = qpT + 1310720;
  u16* dec1T  = qpT + 1572864;   // [1024][512]
  u16* Pbf    = qpT + 2097152;   // [16384][1024] = 16,777,216 u16

  const int M2 = BS*1024;   // 4096
  k_extract<<<(BS*1024*DM+TPB-1)/TPB,TPB,0,stream>>>(HF, QIN, CIN);
  k_cvt<<<(2097152/4+TPB-1)/TPB,TPB,0,stream>>>(QIN, Qbf, 2097152/4);
  k_cvt<<<(2097152/4+TPB-1)/TPB,TPB,0,stream>>>(CIN, Cbf, 2097152/4);
  k_wt2<<<dim3(16,16),tb,0,stream>>>(qp_w, qpT, 512, 512, 512);
  k_wt2<<<dim3(16,16),tb,0,stream>>>(cp_w, cpT, 512, 512, 512);
  k_wt2<<<dim3(16,16),tb,0,stream>>>(ca_qw, qwT, 512, 512, 512);
  k_wt2<<<dim3(16,16),tb,0,stream>>>(ca_kw, kwT, 512, 512, 512);
  k_wt2<<<dim3(16,16),tb,0,stream>>>(ca_vw, vwT, 512, 512, 512);
  k_wt2<<<dim3(16,16),tb,0,stream>>>(ca_ow, owT, 512, 512, 512);
  k_wt2<<<dim3(32,16),tb,0,stream>>>(dec1_w, dec1T, 512, 1024, 1024);

  // qp/cp projections (f32 out)
  k_mge<<<dim3(4,32),256,0,stream>>>(Qbf, qpT, qp_b, nullptr, QPb, nullptr,
                                     M2, 512, 512, 512, 512, 512, 1.f, 0);
  k_mge<<<dim3(4,32),256,0,stream>>>(Cbf, cpT, cp_b, nullptr, CPb, nullptr,
                                     M2, 512, 512, 512, 512, 512, 1.f, 0);
  k_ln<<<M2,TPB,0,stream>>>(QPb, ca_nq_w, ca_nq_b, QN);
  k_ln<<<M2,TPB,0,stream>>>(CPb, ca_nkv_w, ca_nkv_b, CN);
  k_cvt<<<(2097152/4+TPB-1)/TPB,TPB,0,stream>>>(QN, QNbf, 2097152/4);
  k_cvt<<<(2097152/4+TPB-1)/TPB,TPB,0,stream>>>(CN, CNbf, 2097152/4);
  // q/k (bf16 out), v (f32 out for transpose)
  k_mge<<<dim3(4,32),256,0,stream>>>(QNbf, qwT, ca_qb, nullptr, nullptr, QQbf,
                                     M2, 512, 512, 512, 512, 512, 1.f, 0);
  k_mge<<<dim3(4,32),256,0,stream>>>(CNbf, kwT, ca_kb, nullptr, nullptr, KKbf,
                                     M2, 512, 512, 512, 512, 512, 1.f, 0);
  k_mge<<<dim3(4,32),256,0,stream>>>(CNbf, vwT, ca_vb, nullptr, VV, nullptr,
                                     M2, 512, 512, 512, 512, 512, 1.f, 0);
  // V^T per (b,h): [128][1024] bf16
  for(int z=0; z<16; ++z){
    int b = z>>2, h = z&3;
    k_wt2<<<dim3(4,32),tb,0,stream>>>(VV + (size_t)b*1024*512 + h*128,
                                      VTbf + (size_t)z*131072, 1024, 128, 512);
  }
  // scores per (b,h): bf16( (Q@K^T) / sqrt(128) )
  const float scl = 0.088388347648318447f;
  for(int z=0; z<16; ++z){
    int b = z>>2, h = z&3;
    k_mge<<<dim3(8,8),256,0,stream>>>(QQbf + (size_t)b*1024*512 + h*128,
                                      KKbf + (size_t)b*1024*512 + h*128,
                                      nullptr, nullptr, nullptr,
                                      Pbf + (size_t)z*1048576,
                                      1024, 1024, 128, 512, 512, 1024, scl, 0);
  }
  k_sm<<<16384,256,0,stream>>>(Pbf);
  // AO per (b,h) = P @ V
  for(int z=0; z<16; ++z){
    int b = z>>2, h = z&3;
    k_mge<<<dim3(1,8),256,0,stream>>>(Pbf + (size_t)z*1048576,
                                      VTbf + (size_t)z*131072,
                                      nullptr, nullptr,
                                      AO + (size_t)b*1024*512 + h*128, nullptr,
                                      1024, 128, 1024, 1024, 1024, 512, 1.f, 0);
  }
  k_cvt<<<(2097152/4+TPB-1)/TPB,TPB,0,stream>>>(AO, AObf, 2097152/4);
  // o-proj + residual(QPb)
  k_mge<<<dim3(4,32),256,0,stream>>>(AObf, owT, ca_ob, QPb, O1, nullptr,
                                     M2, 512, 512, 512, 512, 512, 1.f, 0);
  k_cvt<<<(2097152/4+TPB-1)/TPB,TPB,0,stream>>>(O1, O1bf, 2097152/4);
  // dec1 + GELU
  k_mge<<<dim3(8,32),256,0,stream>>>(O1bf, dec1T, dec1_b, nullptr, D1, nullptr,
                                     M2, 1024, 512, 512, 512, 1024, 1.f, 1);
  // dec2 (tiny, f32)
  {
    dim3 g((10+63)/64, M2/64), b2(16,16);
    k_gemm<<<g,b2,0,stream>>>(D1, dec2_w, dec2_b, nullptr, (float*)d_out, M2, 10, 1024, 0);
  }
}

// Round 11
// 4072.901 us; speedup vs baseline: 79.7690x; 1.3171x over previous
//
#include <hip/hip_runtime.h>
#include <hip/hip_bf16.h>

#define BS 4
#define SEQL 2048
#define DM 512
#define DIN 1024
#define NH 16
#define HD 64
#define DST 64
#define NC 8
#define CKS 256
#define DIP 2192
#define CVD 1152
#define NROWS (BS*SEQL)          /* 8192 */
#define NTOK (BS*SEQL*DM)        /* 4194304 */

typedef unsigned short u16;
typedef __bf16 bf16x8 __attribute__((ext_vector_type(8)));
typedef float f32x4 __attribute__((ext_vector_type(4)));

__device__ __forceinline__ u16 cvt_bf16(float f){
  unsigned int x = __float_as_uint(f);
  unsigned int r = x + 0x7fffu + ((x>>16)&1u);
  return (u16)(r>>16);
}
__device__ __forceinline__ float bf2f(u16 u){
  return __uint_as_float(((unsigned int)u)<<16);
}

// ---------------- elementwise (proven) ----------------
__global__ void k_add_flip(float* __restrict__ dst, const float* __restrict__ src, int flip){
  int i = blockIdx.x*256 + threadIdx.x;
  if(i >= NTOK) return;
  int d = i & (DM-1);
  int l = (i >> 9) & (SEQL-1);
  int b = i >> 20;
  int sl = flip ? (SEQL-1-l) : l;
  dst[i] += src[(b*SEQL + sl)*DM + d];
}

__global__ void k_flip(float* __restrict__ dst, const float* __restrict__ src){
  int i = blockIdx.x*256 + threadIdx.x;
  if(i >= NTOK) return;
  int d = i & (DM-1);
  int l = (i >> 9) & (SEQL-1);
  int b = i >> 20;
  dst[i] = src[(b*SEQL + (SEQL-1-l))*DM + d];
}

// f32 -> bf16 (verified round-8)
__global__ void k_cvt(const float* __restrict__ src, u16* __restrict__ dst, int n4){
  int i = blockIdx.x*256 + threadIdx.x;
  if(i >= n4) return;
  float4 f = reinterpret_cast<const float4*>(src)[i];
  ushort4 o; o.x=cvt_bf16(f.x); o.y=cvt_bf16(f.y); o.z=cvt_bf16(f.z); o.w=cvt_bf16(f.w);
  reinterpret_cast<ushort4*>(dst)[i] = o;
}

__global__ void k_ln(const float* __restrict__ X, const float* __restrict__ w,
                     const float* __restrict__ bb, float* __restrict__ O){
  int row = blockIdx.x, tid = threadIdx.x;
  const float* x = X + (size_t)row*DM;
  float* o = O + (size_t)row*DM;
  float s=0.f, s2=0.f;
  for(int j=tid;j<DM;j+=256){ float v=x[j]; s+=v; s2+=v*v; }
  __shared__ float r1[256], r2[256];
  r1[tid]=s; r2[tid]=s2; __syncthreads();
  for(int off=128;off>0;off>>=1){
    if(tid<off){ r1[tid]+=r1[tid+off]; r2[tid]+=r2[tid+off]; }
    __syncthreads();
  }
  float m = r1[0]*(1.f/DM);
  float var = r2[0]*(1.f/DM) - m*m;
  float inv = rsqrtf(var + 1e-5f);
  for(int j=tid;j<DM;j+=256) o[j] = (x[j]-m)*inv*w[j] + bb[j];
}

__global__ void k_rms(float* __restrict__ Y, const float* __restrict__ gw){
  int row = blockIdx.x, tid = threadIdx.x;
  float* y = Y + (size_t)row*DIN;
  float ss=0.f;
  for(int j=tid;j<DIN;j+=256){ float v=y[j]; ss+=v*v; }
  __shared__ float red[256];
  red[tid]=ss; __syncthreads();
  for(int off=128;off>0;off>>=1){
    if(tid<off) red[tid]+=red[tid+off];
    __syncthreads();
  }
  float inv = rsqrtf(red[0]*(1.f/DIN) + 1e-5f);
  for(int j=tid;j<DIN;j+=256) y[j] = y[j]*inv*gw[j];
}

// ---------------- f32 GEMM (dec2 only) ----------------
__global__ void k_gemm(const float* __restrict__ A, const float* __restrict__ B,
                       const float* __restrict__ bias, const float* __restrict__ res,
                       float* __restrict__ C, int M, int N, int K, int act){
  __shared__ float As[64][17];
  __shared__ float Bs[16][65];
  int tx = threadIdx.x, ty = threadIdx.y;
  int tid = ty*16+tx;
  int r0 = blockIdx.y*64, c0 = blockIdx.x*64;
  float acc[4][4];
  #pragma unroll
  for(int i=0;i<4;i++)
    #pragma unroll
    for(int j=0;j<4;j++) acc[i][j]=0.f;
  for(int k0=0;k0<K;k0+=16){
    #pragma unroll
    for(int e=0;e<4;e++){
      int idx = tid + e*256;
      int ar = idx>>4, ac = idx&15;
      As[ar][ac] = A[(size_t)(r0+ar)*K + k0+ac];
      int br = idx>>6, bc = idx&63;
      float bv = 0.f;
      if(c0+bc < N) bv = B[(size_t)(k0+br)*N + c0+bc];
      Bs[br][bc] = bv;
    }
    __syncthreads();
    #pragma unroll
    for(int kk=0;kk<16;kk++){
      float a0=As[ty*4+0][kk],a1=As[ty*4+1][kk],a2=As[ty*4+2][kk],a3=As[ty*4+3][kk];
      float b0=Bs[kk][tx*4+0],b1=Bs[kk][tx*4+1],b2=Bs[kk][tx*4+2],b3=Bs[kk][tx*4+3];
      acc[0][0]+=a0*b0; acc[0][1]+=a0*b1; acc[0][2]+=a0*b2; acc[0][3]+=a0*b3;
      acc[1][0]+=a1*b0; acc[1][1]+=a1*b1; acc[1][2]+=a1*b2; acc[1][3]+=a1*b3;
      acc[2][0]+=a2*b0; acc[2][1]+=a2*b1; acc[2][2]+=a2*b2; acc[2][3]+=a2*b3;
      acc[3][0]+=a3*b0; acc[3][1]+=a3*b1; acc[3][2]+=a3*b2; acc[3][3]+=a3*b3;
    }
    __syncthreads();
  }
  #pragma unroll
  for(int i=0;i<4;i++){
    int r = r0 + ty*4 + i;
    #pragma unroll
    for(int j=0;j<4;j++){
      int c = c0 + tx*4 + j;
      if(c < N){
        float v = acc[i][j];
        if(bias) v += bias[c];
        if(act==1) v = 0.5f*v*(1.f+erff(v*0.70710678118654752f));
        if(res) v += res[(size_t)r*N + c];
        C[(size_t)r*N + c] = v;
      }
    }
  }
}

// transpose-convert with explicit src ld (verified): src[K][lds] f32 -> dst[N][K] bf16
__global__ void k_wt2(const float* __restrict__ src, u16* __restrict__ dst,
                      int K, int N, int lds){
  __shared__ float t[32][33];
  int n0 = blockIdx.x*32, k0 = blockIdx.y*32;
  int tx = threadIdx.x, ty = threadIdx.y;
  #pragma unroll
  for(int i=0;i<32;i+=8){
    int k = k0+ty+i, n = n0+tx;
    t[ty+i][tx] = (n<N) ? src[(size_t)k*lds+n] : 0.f;
  }
  __syncthreads();
  #pragma unroll
  for(int i=0;i<32;i+=8){
    int n = n0+ty+i, k = k0+tx;
    if(n<N) dst[(size_t)n*K+k] = cvt_bf16(t[tx][ty+i]);
  }
}

// ---------------- MFMA bf16 GEMM, emap0 (HW-verified) ----------------
__global__ __launch_bounds__(256) void k_mg(
    const u16* __restrict__ A, const u16* __restrict__ BT,
    float* __restrict__ C, int M, int N, int K, int lda, int ldb, int ldc)
{
  __shared__ uint4 As4[128*5];
  __shared__ uint4 Bs4[128*5];
  const int tid = threadIdx.x;
  const int row0 = blockIdx.y*128, col0 = blockIdx.x*128;
  const int lane = tid & 63, wave = tid >> 6;
  const int wm = wave >> 1, wn = wave & 1;
  const int lr = lane & 15, ksg = (lane >> 4);
  f32x4 acc[4][4];
  #pragma unroll
  for(int i=0;i<4;i++)
    #pragma unroll
    for(int j=0;j<4;j++) acc[i][j] = (f32x4){0.f,0.f,0.f,0.f};
  for(int k0=0;k0<K;k0+=32){
    #pragma unroll
    for(int i=0;i<2;i++){
      int t2 = tid + i*256;
      int rr = t2 >> 2, sg = (t2 & 3);
      uint4 av = *reinterpret_cast<const uint4*>(A + (size_t)(row0+rr)*lda + k0 + sg*8);
      uint4 bv = {0u,0u,0u,0u};
      if(col0+rr < N) bv = *reinterpret_cast<const uint4*>(BT + (size_t)(col0+rr)*ldb + k0 + sg*8);
      As4[rr*5 + sg] = av;
      Bs4[rr*5 + sg] = bv;
    }
    __syncthreads();
    bf16x8 afr[4], bfr[4];
    #pragma unroll
    for(int i=0;i<4;i++) afr[i] = *reinterpret_cast<const bf16x8*>(&As4[(wm*64+i*16+lr)*5 + ksg]);
    #pragma unroll
    for(int j=0;j<4;j++) bfr[j] = *reinterpret_cast<const bf16x8*>(&Bs4[(wn*64+j*16+lr)*5 + ksg]);
    #pragma unroll
    for(int i=0;i<4;i++)
      #pragma unroll
      for(int j=0;j<4;j++)
        acc[i][j] = __builtin_amdgcn_mfma_f32_16x16x32_bf16(afr[i], bfr[j], acc[i][j], 0, 0, 0);
    __syncthreads();
  }
  const int hi = lane >> 4, lo = lane & 15;
  #pragma unroll
  for(int i=0;i<4;i++)
    #pragma unroll
    for(int j=0;j<4;j++)
      #pragma unroll
      for(int r=0;r<4;r++){
        int row = row0 + wm*64 + i*16 + 4*hi + r;
        int col = col0 + wn*64 + j*16 + lo;
        if(col < N) C[(size_t)row*ldc + col] = acc[i][j][r];
      }
}

// batched variant: verified core + z-strided base offsets only
__global__ __launch_bounds__(256) void k_mgb(
    const u16* __restrict__ A0, const u16* __restrict__ BT0,
    float* __restrict__ C0, int M, int N, int K, int lda, int ldb, int ldc,
    long sAz, long sBz, long sCo, long sCi, int shC)
{
  const int z = blockIdx.z;
  const u16* A  = A0  + (size_t)z*sAz;
  const u16* BT = BT0 + (size_t)z*sBz;
  float* C = C0 + (size_t)(z>>shC)*sCo + (size_t)(z & ((1<<shC)-1))*sCi;
  __shared__ uint4 As4[128*5];
  __shared__ uint4 Bs4[128*5];
  const int tid = threadIdx.x;
  const int row0 = blockIdx.y*128, col0 = blockIdx.x*128;
  const int lane = tid & 63, wave = tid >> 6;
  const int wm = wave >> 1, wn = wave & 1;
  const int lr = lane & 15, ksg = (lane >> 4);
  f32x4 acc[4][4];
  #pragma unroll
  for(int i=0;i<4;i++)
    #pragma unroll
    for(int j=0;j<4;j++) acc[i][j] = (f32x4){0.f,0.f,0.f,0.f};
  for(int k0=0;k0<K;k0+=32){
    #pragma unroll
    for(int i=0;i<2;i++){
      int t2 = tid + i*256;
      int rr = t2 >> 2, sg = (t2 & 3);
      uint4 av = *reinterpret_cast<const uint4*>(A + (size_t)(row0+rr)*lda + k0 + sg*8);
      uint4 bv = {0u,0u,0u,0u};
      if(col0+rr < N) bv = *reinterpret_cast<const uint4*>(BT + (size_t)(col0+rr)*ldb + k0 + sg*8);
      As4[rr*5 + sg] = av;
      Bs4[rr*5 + sg] = bv;
    }
    __syncthreads();
    bf16x8 afr[4], bfr[4];
    #pragma unroll
    for(int i=0;i<4;i++) afr[i] = *reinterpret_cast<const bf16x8*>(&As4[(wm*64+i*16+lr)*5 + ksg]);
    #pragma unroll
    for(int j=0;j<4;j++) bfr[j] = *reinterpret_cast<const bf16x8*>(&Bs4[(wn*64+j*16+lr)*5 + ksg]);
    #pragma unroll
    for(int i=0;i<4;i++)
      #pragma unroll
      for(int j=0;j<4;j++)
        acc[i][j] = __builtin_amdgcn_mfma_f32_16x16x32_bf16(afr[i], bfr[j], acc[i][j], 0, 0, 0);
    __syncthreads();
  }
  const int hi = lane >> 4, lo = lane & 15;
  #pragma unroll
  for(int i=0;i<4;i++)
    #pragma unroll
    for(int j=0;j<4;j++)
      #pragma unroll
      for(int r=0;r<4;r++){
        int row = row0 + wm*64 + i*16 + 4*hi + r;
        int col = col0 + wn*64 + j*16 + lo;
        if(col < N) C[(size_t)row*ldc + col] = acc[i][j][r];
      }
}

// same verified core + arithmetic epilogue (attention head)
__global__ __launch_bounds__(256) void k_mge(
    const u16* __restrict__ A, const u16* __restrict__ BT,
    const float* __restrict__ bias, const float* __restrict__ res,
    float* __restrict__ C, u16* __restrict__ Cbf,
    int M, int N, int K, int lda, int ldb, int ldc, float scale, int act)
{
  __shared__ uint4 As4[128*5];
  __shared__ uint4 Bs4[128*5];
  const int tid = threadIdx.x;
  const int row0 = blockIdx.y*128, col0 = blockIdx.x*128;
  const int lane = tid & 63, wave = tid >> 6;
  const int wm = wave >> 1, wn = wave & 1;
  const int lr = lane & 15, ksg = (lane >> 4);
  f32x4 acc[4][4];
  #pragma unroll
  for(int i=0;i<4;i++)
    #pragma unroll
    for(int j=0;j<4;j++) acc[i][j] = (f32x4){0.f,0.f,0.f,0.f};
  for(int k0=0;k0<K;k0+=32){
    #pragma unroll
    for(int i=0;i<2;i++){
      int t2 = tid + i*256;
      int rr = t2 >> 2, sg = (t2 & 3);
      uint4 av = *reinterpret_cast<const uint4*>(A + (size_t)(row0+rr)*lda + k0 + sg*8);
      uint4 bv = {0u,0u,0u,0u};
      if(col0+rr < N) bv = *reinterpret_cast<const uint4*>(BT + (size_t)(col0+rr)*ldb + k0 + sg*8);
      As4[rr*5 + sg] = av;
      Bs4[rr*5 + sg] = bv;
    }
    __syncthreads();
    bf16x8 afr[4], bfr[4];
    #pragma unroll
    for(int i=0;i<4;i++) afr[i] = *reinterpret_cast<const bf16x8*>(&As4[(wm*64+i*16+lr)*5 + ksg]);
    #pragma unroll
    for(int j=0;j<4;j++) bfr[j] = *reinterpret_cast<const bf16x8*>(&Bs4[(wn*64+j*16+lr)*5 + ksg]);
    #pragma unroll
    for(int i=0;i<4;i++)
      #pragma unroll
      for(int j=0;j<4;j++)
        acc[i][j] = __builtin_amdgcn_mfma_f32_16x16x32_bf16(afr[i], bfr[j], acc[i][j], 0, 0, 0);
    __syncthreads();
  }
  const int hi = lane >> 4, lo = lane & 15;
  #pragma unroll
  for(int i=0;i<4;i++)
    #pragma unroll
    for(int j=0;j<4;j++)
      #pragma unroll
      for(int r=0;r<4;r++){
        int row = row0 + wm*64 + i*16 + 4*hi + r;
        int col = col0 + wn*64 + j*16 + lo;
        if(col < N){
          float v = acc[i][j][r];
          if(bias) v += bias[col];
          v *= scale;
          if(act==1) v = 0.5f*v*(1.f+erff(v*0.70710678118654752f));
          size_t ci = (size_t)row*ldc + col;
          if(res) v += res[ci];
          if(C) C[ci] = v;
          else  Cbf[ci] = cvt_bf16(v);
        }
      }
}

// in-place row softmax over 1024 bf16
__global__ void k_sm(u16* __restrict__ S){
  size_t row = blockIdx.x;
  u16* p = S + row*1024;
  int tid = threadIdx.x;
  ushort4 u = reinterpret_cast<ushort4*>(p)[tid];
  float v0=bf2f(u.x), v1=bf2f(u.y), v2=bf2f(u.z), v3=bf2f(u.w);
  float m = fmaxf(fmaxf(v0,v1),fmaxf(v2,v3));
  __shared__ float red[256];
  red[tid]=m; __syncthreads();
  for(int o=128;o>0;o>>=1){ if(tid<o) red[tid]=fmaxf(red[tid],red[tid+o]); __syncthreads(); }
  m = red[0]; __syncthreads();
  v0=__expf(v0-m); v1=__expf(v1-m); v2=__expf(v2-m); v3=__expf(v3-m);
  float s = v0+v1+v2+v3;
  red[tid]=s; __syncthreads();
  for(int o=128;o>0;o>>=1){ if(tid<o) red[tid]+=red[tid+o]; __syncthreads(); }
  float inv = 1.f/red[0];
  ushort4 o4; o4.x=cvt_bf16(v0*inv); o4.y=cvt_bf16(v1*inv); o4.z=cvt_bf16(v2*inv); o4.w=cvt_bf16(v3*inv);
  reinterpret_cast<ushort4*>(p)[tid] = o4;
}

// ---------------- mamba pieces ----------------
__global__ void k_conv(const float* __restrict__ ZB, const float* __restrict__ cw,
                       const float* __restrict__ cb, float* __restrict__ XC){
  int i = blockIdx.x*256 + threadIdx.x;
  if(i >= BS*SEQL*CVD) return;
  int cch = i % CVD;
  int l = (i / CVD) & (SEQL-1);
  int b = i / (CVD*SEQL);
  float v = cb[cch];
  #pragma unroll
  for(int k=0;k<4;k++){
    int sl = l + k - 3;
    if(sl >= 0) v += ZB[(size_t)(b*SEQL+sl)*DIP + DIN + cch] * cw[cch*4 + k];
  }
  float sig = 1.f/(1.f+expf(-v));
  XC[i] = v*sig;
}

__global__ void k_dt(const float* __restrict__ ZB, const float* __restrict__ dtb,
                     const float* __restrict__ Alog, float* __restrict__ DT,
                     float* __restrict__ DA){
  int i = blockIdx.x*256 + threadIdx.x;
  if(i >= BS*SEQL*NH) return;
  int h = i & (NH-1);
  int row = i >> 4;
  float raw = ZB[(size_t)row*DIP + (DIN+CVD) + h] + dtb[h];
  float dt = fmaxf(raw,0.f) + log1pf(expf(-fabsf(raw)));
  DT[i] = dt;
  DA[i] = dt * (-expf(Alog[h]));
}

__global__ void k_acum(const float* __restrict__ DA, float* __restrict__ ACUM,
                       float* __restrict__ CDEC){
  int blk = blockIdx.x;
  int h = blk & 15, c = (blk>>4)&7, b = blk>>7;
  int l = threadIdx.x;
  __shared__ float s[256];
  int gl = c*CKS + l;
  s[l] = DA[(size_t)(b*SEQL + gl)*NH + h];
  __syncthreads();
  for(int off=1; off<256; off<<=1){
    float v = (l>=off) ? s[l-off] : 0.f;
    __syncthreads();
    s[l] += v;
    __syncthreads();
  }
  ACUM[(size_t)blk*CKS + l] = s[l];
  if(l==255) CDEC[blk] = expf(s[255]);
}

// extract B,C as bf16 [8192][64]
__global__ void k_bc(const float* __restrict__ XC, u16* __restrict__ Bbf,
                     u16* __restrict__ Cbf){
  int i = blockIdx.x*256 + threadIdx.x;
  if(i >= NROWS*DST) return;
  int g = i >> 6, n = i & 63;
  Bbf[i] = cvt_bf16(XC[(size_t)g*CVD + DIN + n]);
  Cbf[i] = cvt_bf16(XC[(size_t)g*CVD + DIN + DST + n]);
}

// XdT_b[(c*16+h)][p][s] = bf16( XC[b, c*256+s, h*64+p] * DT[b, c*256+s, h] )
__global__ void k_xdt(const float* __restrict__ XC, const float* __restrict__ DT,
                      u16* __restrict__ XdT, int b){
  int i = blockIdx.x*256 + threadIdx.x;
  if(i >= 8*16*64*256) return;
  int s = i & 255, p = (i>>8) & 63, h = (i>>14) & 15, c = i >> 18;
  int g = b*SEQL + c*CKS + s;
  float v = XC[(size_t)g*CVD + h*HD + p] * DT[(size_t)g*NH + h];
  XdT[i] = cvt_bf16(v);
}

// Gb[(c*16+h)][l][s] = bf16( (s<=l) ? exp(Ac[l]-Ac[s]) * S[b,c][l][s] : 0 )
__global__ void k_gform(const float* __restrict__ Sf, const float* __restrict__ ACUM,
                        u16* __restrict__ Gb, int b){
  int i = blockIdx.x*256 + threadIdx.x;
  if(i >= 8*16*256*256) return;
  int s = i & 255, l = (i>>8) & 255, h = (i>>16) & 15, c = i >> 20;
  u16 g = 0;
  if(s <= l){
    const float* Ac = ACUM + (size_t)((b*NC+c)*NH + h)*CKS;
    float sv = Sf[(size_t)(b*NC+c)*65536 + l*256 + s];
    g = cvt_bf16(__expf(Ac[l]-Ac[s]) * sv);
  }
  Gb[i] = g;
}

__global__ void k_states(const float* __restrict__ XC, const float* __restrict__ DT,
                         const float* __restrict__ ACUM, float* __restrict__ ST){
  int blk = blockIdx.x;
  int h = blk & 15, c = (blk>>4)&7, b = blk>>7;
  int tid = threadIdx.x;
  int n = tid & 63, pq = tid >> 6;
  __shared__ float Ac[256];
  __shared__ float Bt[32][64];
  __shared__ float Xt[32][64];
  Ac[tid] = ACUM[(size_t)blk*CKS + tid];
  float acc[16];
  #pragma unroll
  for(int k=0;k<16;k++) acc[k]=0.f;
  const float* xcb = XC + (size_t)b*SEQL*CVD;
  for(int st=0; st<8; ++st){
    __syncthreads();
    #pragma unroll
    for(int e=0;e<8;e++){
      int idx = tid + e*256;
      int sl = idx>>6, nn = idx&63;
      int gs = c*CKS + st*32 + sl;
      Bt[sl][nn] = xcb[(size_t)gs*CVD + DIN + nn];
      float dec = expf(Ac[255] - Ac[st*32+sl]);
      Xt[sl][nn] = xcb[(size_t)gs*CVD + h*HD + nn] * DT[(size_t)(b*SEQL+gs)*NH + h] * dec;
    }
    __syncthreads();
    #pragma unroll
    for(int l=0;l<32;l++){
      float bv = Bt[l][n];
      #pragma unroll
      for(int k=0;k<16;k++) acc[k] += bv * Xt[l][pq + 4*k];
    }
  }
  #pragma unroll
  for(int k=0;k<16;k++){
    int p = pq + 4*k;
    ST[(size_t)blk*4096 + p*64 + n] = acc[k];
  }
}

__global__ void k_scan(const float* __restrict__ ST, const float* __restrict__ CDEC,
                       float* __restrict__ PREV){
  int i = blockIdx.x*256 + threadIdx.x;
  if(i >= BS*NH*4096) return;
  int pn = i & 4095;
  int h = (i>>12) & 15;
  int b = i >> 16;
  float run = 0.f;
  for(int c=0;c<8;c++){
    size_t idx = (size_t)((b*8+c)*16+h)*4096 + pn;
    PREV[idx] = run;
    run = run*CDEC[(b*8+c)*16+h] + ST[idx];
  }
}

__global__ void k_yfinal(const float* __restrict__ XC, const float* __restrict__ ACUM,
                         const float* __restrict__ PREV, const float* __restrict__ ZB,
                         const float* __restrict__ Dp, float* __restrict__ Y){
  int i = blockIdx.x*256 + threadIdx.x;
  if(i >= BS*SEQL*DIN) return;
  int p = i & 63;
  int h = (i>>6) & 15;
  int l = (i>>10) & (SEQL-1);
  int b = i >> 21;
  int c = l >> 8;
  int lc = l & 255;
  const float* prev = PREV + (size_t)((b*8+c)*16+h)*4096 + p*64;
  const float* crow = XC + (size_t)(b*SEQL+l)*CVD + (DIN+DST);
  float s = 0.f;
  #pragma unroll
  for(int n=0;n<64;n++) s += crow[n]*prev[n];
  float yoff = expf(ACUM[(size_t)((b*8+c)*16+h)*CKS + lc]) * s;
  float xh = XC[(size_t)(b*SEQL+l)*CVD + h*HD + p];
  float z  = ZB[(size_t)(b*SEQL+l)*DIP + h*HD + p];
  float v = Y[i] + yoff + Dp[h]*xh;
  float sig = 1.f/(1.f+expf(-z));
  Y[i] = v * (z*sig);
}

// ---------------- attention helpers ----------------
__global__ void k_extract(const float* __restrict__ HF, float* __restrict__ QIN,
                          float* __restrict__ CIN){
  int i = blockIdx.x*256 + threadIdx.x;
  if(i >= BS*1024*DM) return;
  int d = i & (DM-1);
  int q = (i>>9) & 1023;
  int b = i >> 19;
  QIN[i] = HF[(size_t)(b*SEQL + 1024 + q)*DM + d];
  CIN[i] = HF[(size_t)(b*SEQL + q)*DM + d];
}

// ---------------- host ----------------
extern "C" void kernel_launch(void* const* d_in, const int* in_sizes, int n_in,
                              void* d_out, int out_size, void* d_ws, size_t ws_size,
                              hipStream_t stream) {
  (void)in_sizes; (void)n_in; (void)out_size; (void)ws_size;
  const float* x_enc     = (const float*)d_in[0];
  const float* in_proj_w = (const float*)d_in[2];
  const float* conv_w    = (const float*)d_in[3];
  const float* conv_b    = (const float*)d_in[4];
  const float* dt_bias   = (const float*)d_in[5];
  const float* A_log     = (const float*)d_in[6];
  const float* D_param   = (const float*)d_in[7];
  const float* gnorm_w   = (const float*)d_in[8];
  const float* out_proj_w= (const float*)d_in[9];
  const float* norm_w    = (const float*)d_in[10];
  const float* norm_b    = (const float*)d_in[11];
  const float* normf_w   = (const float*)d_in[12];
  const float* normf_b   = (const float*)d_in[13];
  const float* ca_nq_w   = (const float*)d_in[14];
  const float* ca_nq_b   = (const float*)d_in[15];
  const float* ca_nkv_w  = (const float*)d_in[16];
  const float* ca_nkv_b  = (const float*)d_in[17];
  const float* ca_qw     = (const float*)d_in[18];
  const float* ca_kw     = (const float*)d_in[19];
  const float* ca_vw     = (const float*)d_in[20];
  const float* ca_ow     = (const float*)d_in[21];
  const float* ca_qb     = (const float*)d_in[22];
  const float* ca_kb     = (const float*)d_in[23];
  const float* ca_vb     = (const float*)d_in[24];
  const float* ca_ob     = (const float*)d_in[25];
  const float* qp_w      = (const float*)d_in[26];
  const float* qp_b      = (const float*)d_in[27];
  const float* cp_w      = (const float*)d_in[28];
  const float* cp_b      = (const float*)d_in[29];
  const float* dec1_w    = (const float*)d_in[30];
  const float* dec1_b    = (const float*)d_in[31];
  const float* dec2_w    = (const float*)d_in[32];
  const float* dec2_b    = (const float*)d_in[33];

  float* W = (float*)d_ws;
  size_t off = 0;
  auto alloc = [&](size_t n){ float* pp = W + off; off += n; return pp; };
  float* RES  = alloc((size_t)NTOK);
  float* H    = alloc((size_t)NTOK);
  float* HN   = alloc((size_t)NTOK);
  float* HNF  = alloc((size_t)NTOK);
  float* ZB   = alloc((size_t)NROWS*DIP);        // 17,956,864
  float* XC   = alloc((size_t)NROWS*CVD);        //  9,437,184
  float* DT   = alloc((size_t)NROWS*NH);
  float* DA   = alloc((size_t)NROWS*NH);
  float* ACUM = alloc((size_t)BS*NC*NH*CKS);
  float* CDEC = alloc((size_t)BS*NC*NH);
  float* Y    = alloc((size_t)NROWS*DIN);        //  8,388,608
  float* ST   = alloc((size_t)BS*NC*NH*4096);
  float* PREV = alloc((size_t)BS*NC*NH*4096);
  float* YD   = alloc((size_t)NTOK);
  float* HF   = alloc((size_t)NTOK);
  // byte-identical to the proven round-1 layout (61,768,192 floats)

  // mamba staging aliases (proven lifetimes):
  u16* Ubf    = (u16*)HF;
  u16* WinTc  = (u16*)(HF + 2097152);
  u16* WoutTc = (u16*)(HF + 2097152 + 561152);
  u16* Ybf    = (u16*)HNF;                    // used only at out_proj staging
  // SSD staging (dead regions during SSD phase):
  u16*   Bbf  = (u16*)HNF;                    //   524,288 u16
  u16*   Cbf  = Bbf + 524288;                 //   524,288 u16
  float* Sf   = HNF + 524288;                 // 2,097,152 fl
  u16*   XdTb = (u16*)(HNF + 2621440);        // 2,097,152 u16 (ends 3,670,016 fl < 4.19M)
  u16*   Gb   = (u16*)YD;                     // 8,388,608 u16 (YD fully)

  const int TPB = 256;
  const int gTok = (NTOK+TPB-1)/TPB;
  dim3 tb(32,8);

  hipMemcpyAsync(RES, x_enc, (size_t)NTOK*4, hipMemcpyDeviceToDevice, stream);

  for(int layer=0; layer<2; ++layer){
    if(layer>0) k_add_flip<<<gTok,TPB,0,stream>>>(RES, H, 0);
    k_ln<<<NROWS,TPB,0,stream>>>(RES, norm_w + layer*DM, norm_b + layer*DM, HN);
    hipMemsetAsync(H, 0, (size_t)NTOK*4, stream);
    for(int dir=0; dir<2; ++dir){
      int idx = layer*2 + dir;
      const float* cw   = conv_w   + (size_t)idx*CVD*4;
      const float* cb   = conv_b   + (size_t)idx*CVD;
      const float* dtb  = dt_bias  + (size_t)idx*NH;
      const float* Alog = A_log    + (size_t)idx*NH;
      const float* Dp   = D_param  + (size_t)idx*NH;
      const float* gw   = gnorm_w  + (size_t)idx*DIN;

      if(dir==0){
        k_cvt<<<(NTOK/4+TPB-1)/TPB,TPB,0,stream>>>(HN, Ubf, NTOK/4);
      }else{
        k_flip<<<gTok,TPB,0,stream>>>(HNF, HN);
        k_cvt<<<(NTOK/4+TPB-1)/TPB,TPB,0,stream>>>(HNF, Ubf, NTOK/4);
      }
      k_wt2<<<dim3(69,16),tb,0,stream>>>(in_proj_w + (size_t)idx*DM*DIP, WinTc, 512, 2192, 2192);
      k_mg<<<dim3(18,64),256,0,stream>>>(Ubf, WinTc, ZB, 8192, 2192, 512, 512, 512, 2192);

      k_conv<<<(BS*SEQL*CVD+TPB-1)/TPB,TPB,0,stream>>>(ZB, cw, cb, XC);
      k_dt<<<(BS*SEQL*NH+TPB-1)/TPB,TPB,0,stream>>>(ZB, dtb, Alog, DT, DA);
      k_acum<<<BS*NC*NH,256,0,stream>>>(DA, ACUM, CDEC);

      // ---- Y_diag via MFMA ----
      k_bc<<<(NROWS*DST+TPB-1)/TPB,TPB,0,stream>>>(XC, Bbf, Cbf);
      // S[b,c] = C·B^T : 32 batches, M=N=256, K=64
      k_mgb<<<dim3(2,2,32),256,0,stream>>>(Cbf, Bbf, Sf,
            256, 256, 64, 64, 64, 256, 16384, 16384, 65536, 0, 0);
      for(int bb=0; bb<BS; ++bb){
        k_xdt<<<(2097152+TPB-1)/TPB,TPB,0,stream>>>(XC, DT, XdTb, bb);
        k_gform<<<(8388608+TPB-1)/TPB,TPB,0,stream>>>(Sf, ACUM, Gb, bb);
        // Y_diag[b] : 128 batches (c,h), M=256, N=64, K=256
        k_mgb<<<dim3(1,2,128),256,0,stream>>>(Gb, XdTb, Y + (size_t)bb*2097152,
              256, 64, 256, 256, 256, 1024, 65536, 16384, 262144, 64, 4);
      }

      k_states<<<BS*NC*NH,256,0,stream>>>(XC, DT, ACUM, ST);
      k_scan<<<(BS*NH*4096+TPB-1)/TPB,TPB,0,stream>>>(ST, CDEC, PREV);
      k_yfinal<<<(BS*SEQL*DIN+TPB-1)/TPB,TPB,0,stream>>>(XC, ACUM, PREV, ZB, Dp, Y);
      k_rms<<<NROWS,256,0,stream>>>(Y, gw);

      k_cvt<<<(2097152+TPB-1)/TPB,TPB,0,stream>>>(Y, Ybf, 2097152);
      k_wt2<<<dim3(16,32),tb,0,stream>>>(out_proj_w + (size_t)idx*DIN*DM, WoutTc, 1024, 512, 512);
      k_mg<<<dim3(4,64),256,0,stream>>>(Ybf, WoutTc, YD, 8192, 512, 1024, 1024, 1024, 512);

      k_add_flip<<<gTok,TPB,0,stream>>>(H, YD, dir);
    }
  }
  k_add_flip<<<gTok,TPB,0,stream>>>(RES, H, 0);
  k_ln<<<NROWS,TPB,0,stream>>>(RES, normf_w, normf_b, HF);

  // ================= attention head — MFMA (round-10 proven) =================
  float* P0   = ZB;
  float* QIN  = P0 + 0;
  float* CIN  = P0 + 2097152;
  float* QPb  = P0 + 4194304;
  float* CPb  = P0 + 6291456;
  float* QN   = P0 + 8388608;
  float* CN   = P0 + 10485760;
  float* AO   = P0 + 12582912;
  float* O1   = P0 + 14680064;
  float* D1   = P0 + 16777216;
  float* VV   = D1;
  u16* U0     = (u16*)(P0 + 20971520);
  u16* Qbf    = U0 + 0;
  u16* Cbf2   = U0 + 2097152;
  u16* QNbf   = U0 + 4194304;
  u16* CNbf   = U0 + 6291456;
  u16* QQbf   = U0 + 8388608;
  u16* KKbf   = U0 + 10485760;
  u16* VTbf   = U0 + 12582912;
  u16* AObf   = U0 + 14680064;
  u16* O1bf   = U0 + 16777216;
  u16* qpT    = U0 + 18874368;
  u16* cpT    = qpT + 262144;
  u16* qwT    = qpT + 524288;
  u16* kwT    = qpT + 786432;
  u16* vwT    = qpT + 1048576;
  u16* owT    = qpT + 1310720;
  u16* dec1T  = qpT + 1572864;
  u16* Pbf    = qpT + 2097152;

  const int M2 = BS*1024;
  k_extract<<<(BS*1024*DM+TPB-1)/TPB,TPB,0,stream>>>(HF, QIN, CIN);
  k_cvt<<<(2097152/4+TPB-1)/TPB,TPB,0,stream>>>(QIN, Qbf, 2097152/4);
  k_cvt<<<(2097152/4+TPB-1)/TPB,TPB,0,stream>>>(CIN, Cbf2, 2097152/4);
  k_wt2<<<dim3(16,16),tb,0,stream>>>(qp_w, qpT, 512, 512, 512);
  k_wt2<<<dim3(16,16),tb,0,stream>>>(cp_w, cpT, 512, 512, 512);
  k_wt2<<<dim3(16,16),tb,0,stream>>>(ca_qw, qwT, 512, 512, 512);
  k_wt2<<<dim3(16,16),tb,0,stream>>>(ca_kw, kwT, 512, 512, 512);
  k_wt2<<<dim3(16,16),tb,0,stream>>>(ca_vw, vwT, 512, 512, 512);
  k_wt2<<<dim3(16,16),tb,0,stream>>>(ca_ow, owT, 512, 512, 512);
  k_wt2<<<dim3(32,16),tb,0,stream>>>(dec1_w, dec1T, 512, 1024, 1024);

  k_mge<<<dim3(4,32),256,0,stream>>>(Qbf, qpT, qp_b, nullptr, QPb, nullptr,
                                     M2, 512, 512, 512, 512, 512, 1.f, 0);
  k_mge<<<dim3(4,32),256,0,stream>>>(Cbf2, cpT, cp_b, nullptr, CPb, nullptr,
                                     M2, 512, 512, 512, 512, 512, 1.f, 0);
  k_ln<<<M2,TPB,0,stream>>>(QPb, ca_nq_w, ca_nq_b, QN);
  k_ln<<<M2,TPB,0,stream>>>(CPb, ca_nkv_w, ca_nkv_b, CN);
  k_cvt<<<(2097152/4+TPB-1)/TPB,TPB,0,stream>>>(QN, QNbf, 2097152/4);
  k_cvt<<<(2097152/4+TPB-1)/TPB,TPB,0,stream>>>(CN, CNbf, 2097152/4);
  k_mge<<<dim3(4,32),256,0,stream>>>(QNbf, qwT, ca_qb, nullptr, nullptr, QQbf,
                                     M2, 512, 512, 512, 512, 512, 1.f, 0);
  k_mge<<<dim3(4,32),256,0,stream>>>(CNbf, kwT, ca_kb, nullptr, nullptr, KKbf,
                                     M2, 512, 512, 512, 512, 512, 1.f, 0);
  k_mge<<<dim3(4,32),256,0,stream>>>(CNbf, vwT, ca_vb, nullptr, VV, nullptr,
                                     M2, 512, 512, 512, 512, 512, 1.f, 0);
  for(int z=0; z<16; ++z){
    int b = z>>2, h = z&3;
    k_wt2<<<dim3(4,32),tb,0,stream>>>(VV + (size_t)b*1024*512 + h*128,
                                      VTbf + (size_t)z*131072, 1024, 128, 512);
  }
  const float scl = 0.088388347648318447f;
  for(int z=0; z<16; ++z){
    int b = z>>2, h = z&3;
    k_mge<<<dim3(8,8),256,0,stream>>>(QQbf + (size_t)b*1024*512 + h*128,
                                      KKbf + (size_t)b*1024*512 + h*128,
                                      nullptr, nullptr, nullptr,
                                      Pbf + (size_t)z*1048576,
                                      1024, 1024, 128, 512, 512, 1024, scl, 0);
  }
  k_sm<<<16384,256,0,stream>>>(Pbf);
  for(int z=0; z<16; ++z){
    int b = z>>2, h = z&3;
    k_mge<<<dim3(1,8),256,0,stream>>>(Pbf + (size_t)z*1048576,
                                      VTbf + (size_t)z*131072,
                                      nullptr, nullptr,
                                      AO + (size_t)b*1024*512 + h*128, nullptr,
                                      1024, 128, 1024, 1024, 1024, 512, 1.f, 0);
  }
  k_cvt<<<(2097152/4+TPB-1)/TPB,TPB,0,stream>>>(AO, AObf, 2097152/4);
  k_mge<<<dim3(4,32),256,0,stream>>>(AObf, owT, ca_ob, QPb, O1, nullptr,
                                     M2, 512, 512, 512, 512, 512, 1.f, 0);
  k_cvt<<<(2097152/4+TPB-1)/TPB,TPB,0,stream>>>(O1, O1bf, 2097152/4);
  k_mge<<<dim3(8,32),256,0,stream>>>(O1bf, dec1T, dec1_b, nullptr, D1, nullptr,
                                     M2, 1024, 512, 512, 512, 1024, 1.f, 1);
  {
    dim3 g((10+63)/64, M2/64), b2(16,16);
    k_gemm<<<g,b2,0,stream>>>(D1, dec2_w, dec2_b, nullptr, (float*)d_out, M2, 10, 1024, 0);
  }
}

// Round 12
// 2946.433 us; speedup vs baseline: 110.2659x; 1.3823x over previous
//
#include <hip/hip_runtime.h>
#include <hip/hip_bf16.h>

#define BS 4
#define SEQL 2048
#define DM 512
#define DIN 1024
#define NH 16
#define HD 64
#define DST 64
#define NC 8
#define CKS 256
#define DIP 2192
#define CVD 1152
#define NROWS (BS*SEQL)          /* 8192 */
#define NTOK (BS*SEQL*DM)        /* 4194304 */

typedef unsigned short u16;
typedef __bf16 bf16x8 __attribute__((ext_vector_type(8)));
typedef float f32x4 __attribute__((ext_vector_type(4)));

__device__ __forceinline__ u16 cvt_bf16(float f){
  unsigned int x = __float_as_uint(f);
  unsigned int r = x + 0x7fffu + ((x>>16)&1u);
  return (u16)(r>>16);
}
__device__ __forceinline__ float bf2f(u16 u){
  return __uint_as_float(((unsigned int)u)<<16);
}

// ---------------- elementwise (proven) ----------------
__global__ void k_add_flip(float* __restrict__ dst, const float* __restrict__ src, int flip){
  int i = blockIdx.x*256 + threadIdx.x;
  if(i >= NTOK) return;
  int d = i & (DM-1);
  int l = (i >> 9) & (SEQL-1);
  int b = i >> 20;
  int sl = flip ? (SEQL-1-l) : l;
  dst[i] += src[(b*SEQL + sl)*DM + d];
}

__global__ void k_flip(float* __restrict__ dst, const float* __restrict__ src){
  int i = blockIdx.x*256 + threadIdx.x;
  if(i >= NTOK) return;
  int d = i & (DM-1);
  int l = (i >> 9) & (SEQL-1);
  int b = i >> 20;
  dst[i] = src[(b*SEQL + (SEQL-1-l))*DM + d];
}

// f32 -> bf16 (verified round-8)
__global__ void k_cvt(const float* __restrict__ src, u16* __restrict__ dst, int n4){
  int i = blockIdx.x*256 + threadIdx.x;
  if(i >= n4) return;
  float4 f = reinterpret_cast<const float4*>(src)[i];
  ushort4 o; o.x=cvt_bf16(f.x); o.y=cvt_bf16(f.y); o.z=cvt_bf16(f.z); o.w=cvt_bf16(f.w);
  reinterpret_cast<ushort4*>(dst)[i] = o;
}

__global__ void k_ln(const float* __restrict__ X, const float* __restrict__ w,
                     const float* __restrict__ bb, float* __restrict__ O){
  int row = blockIdx.x, tid = threadIdx.x;
  const float* x = X + (size_t)row*DM;
  float* o = O + (size_t)row*DM;
  float s=0.f, s2=0.f;
  for(int j=tid;j<DM;j+=256){ float v=x[j]; s+=v; s2+=v*v; }
  __shared__ float r1[256], r2[256];
  r1[tid]=s; r2[tid]=s2; __syncthreads();
  for(int off=128;off>0;off>>=1){
    if(tid<off){ r1[tid]+=r1[tid+off]; r2[tid]+=r2[tid+off]; }
    __syncthreads();
  }
  float m = r1[0]*(1.f/DM);
  float var = r2[0]*(1.f/DM) - m*m;
  float inv = rsqrtf(var + 1e-5f);
  for(int j=tid;j<DM;j+=256) o[j] = (x[j]-m)*inv*w[j] + bb[j];
}

__global__ void k_rms(float* __restrict__ Y, const float* __restrict__ gw){
  int row = blockIdx.x, tid = threadIdx.x;
  float* y = Y + (size_t)row*DIN;
  float ss=0.f;
  for(int j=tid;j<DIN;j+=256){ float v=y[j]; ss+=v*v; }
  __shared__ float red[256];
  red[tid]=ss; __syncthreads();
  for(int off=128;off>0;off>>=1){
    if(tid<off) red[tid]+=red[tid+off];
    __syncthreads();
  }
  float inv = rsqrtf(red[0]*(1.f/DIN) + 1e-5f);
  for(int j=tid;j<DIN;j+=256) y[j] = y[j]*inv*gw[j];
}

// ---------------- f32 GEMM (dec2 only) ----------------
__global__ void k_gemm(const float* __restrict__ A, const float* __restrict__ B,
                       const float* __restrict__ bias, const float* __restrict__ res,
                       float* __restrict__ C, int M, int N, int K, int act){
  __shared__ float As[64][17];
  __shared__ float Bs[16][65];
  int tx = threadIdx.x, ty = threadIdx.y;
  int tid = ty*16+tx;
  int r0 = blockIdx.y*64, c0 = blockIdx.x*64;
  float acc[4][4];
  #pragma unroll
  for(int i=0;i<4;i++)
    #pragma unroll
    for(int j=0;j<4;j++) acc[i][j]=0.f;
  for(int k0=0;k0<K;k0+=16){
    #pragma unroll
    for(int e=0;e<4;e++){
      int idx = tid + e*256;
      int ar = idx>>4, ac = idx&15;
      As[ar][ac] = A[(size_t)(r0+ar)*K + k0+ac];
      int br = idx>>6, bc = idx&63;
      float bv = 0.f;
      if(c0+bc < N) bv = B[(size_t)(k0+br)*N + c0+bc];
      Bs[br][bc] = bv;
    }
    __syncthreads();
    #pragma unroll
    for(int kk=0;kk<16;kk++){
      float a0=As[ty*4+0][kk],a1=As[ty*4+1][kk],a2=As[ty*4+2][kk],a3=As[ty*4+3][kk];
      float b0=Bs[kk][tx*4+0],b1=Bs[kk][tx*4+1],b2=Bs[kk][tx*4+2],b3=Bs[kk][tx*4+3];
      acc[0][0]+=a0*b0; acc[0][1]+=a0*b1; acc[0][2]+=a0*b2; acc[0][3]+=a0*b3;
      acc[1][0]+=a1*b0; acc[1][1]+=a1*b1; acc[1][2]+=a1*b2; acc[1][3]+=a1*b3;
      acc[2][0]+=a2*b0; acc[2][1]+=a2*b1; acc[2][2]+=a2*b2; acc[2][3]+=a2*b3;
      acc[3][0]+=a3*b0; acc[3][1]+=a3*b1; acc[3][2]+=a3*b2; acc[3][3]+=a3*b3;
    }
    __syncthreads();
  }
  #pragma unroll
  for(int i=0;i<4;i++){
    int r = r0 + ty*4 + i;
    #pragma unroll
    for(int j=0;j<4;j++){
      int c = c0 + tx*4 + j;
      if(c < N){
        float v = acc[i][j];
        if(bias) v += bias[c];
        if(act==1) v = 0.5f*v*(1.f+erff(v*0.70710678118654752f));
        if(res) v += res[(size_t)r*N + c];
        C[(size_t)r*N + c] = v;
      }
    }
  }
}

// transpose-convert with explicit src ld (verified): src[K][lds] f32 -> dst[N][K] bf16
__global__ void k_wt2(const float* __restrict__ src, u16* __restrict__ dst,
                      int K, int N, int lds){
  __shared__ float t[32][33];
  int n0 = blockIdx.x*32, k0 = blockIdx.y*32;
  int tx = threadIdx.x, ty = threadIdx.y;
  #pragma unroll
  for(int i=0;i<32;i+=8){
    int k = k0+ty+i, n = n0+tx;
    t[ty+i][tx] = (n<N) ? src[(size_t)k*lds+n] : 0.f;
  }
  __syncthreads();
  #pragma unroll
  for(int i=0;i<32;i+=8){
    int n = n0+ty+i, k = k0+tx;
    if(n<N) dst[(size_t)n*K+k] = cvt_bf16(t[tx][ty+i]);
  }
}

// ---------------- MFMA bf16 GEMM, emap0 (HW-verified) ----------------
__global__ __launch_bounds__(256) void k_mg(
    const u16* __restrict__ A, const u16* __restrict__ BT,
    float* __restrict__ C, int M, int N, int K, int lda, int ldb, int ldc)
{
  __shared__ uint4 As4[128*5];
  __shared__ uint4 Bs4[128*5];
  const int tid = threadIdx.x;
  const int row0 = blockIdx.y*128, col0 = blockIdx.x*128;
  const int lane = tid & 63, wave = tid >> 6;
  const int wm = wave >> 1, wn = wave & 1;
  const int lr = lane & 15, ksg = (lane >> 4);
  f32x4 acc[4][4];
  #pragma unroll
  for(int i=0;i<4;i++)
    #pragma unroll
    for(int j=0;j<4;j++) acc[i][j] = (f32x4){0.f,0.f,0.f,0.f};
  for(int k0=0;k0<K;k0+=32){
    #pragma unroll
    for(int i=0;i<2;i++){
      int t2 = tid + i*256;
      int rr = t2 >> 2, sg = (t2 & 3);
      uint4 av = *reinterpret_cast<const uint4*>(A + (size_t)(row0+rr)*lda + k0 + sg*8);
      uint4 bv = {0u,0u,0u,0u};
      if(col0+rr < N) bv = *reinterpret_cast<const uint4*>(BT + (size_t)(col0+rr)*ldb + k0 + sg*8);
      As4[rr*5 + sg] = av;
      Bs4[rr*5 + sg] = bv;
    }
    __syncthreads();
    bf16x8 afr[4], bfr[4];
    #pragma unroll
    for(int i=0;i<4;i++) afr[i] = *reinterpret_cast<const bf16x8*>(&As4[(wm*64+i*16+lr)*5 + ksg]);
    #pragma unroll
    for(int j=0;j<4;j++) bfr[j] = *reinterpret_cast<const bf16x8*>(&Bs4[(wn*64+j*16+lr)*5 + ksg]);
    #pragma unroll
    for(int i=0;i<4;i++)
      #pragma unroll
      for(int j=0;j<4;j++)
        acc[i][j] = __builtin_amdgcn_mfma_f32_16x16x32_bf16(afr[i], bfr[j], acc[i][j], 0, 0, 0);
    __syncthreads();
  }
  const int hi = lane >> 4, lo = lane & 15;
  #pragma unroll
  for(int i=0;i<4;i++)
    #pragma unroll
    for(int j=0;j<4;j++)
      #pragma unroll
      for(int r=0;r<4;r++){
        int row = row0 + wm*64 + i*16 + 4*hi + r;
        int col = col0 + wn*64 + j*16 + lo;
        if(col < N) C[(size_t)row*ldc + col] = acc[i][j][r];
      }
}

// batched variant: verified core + z-strided base offsets only
__global__ __launch_bounds__(256) void k_mgb(
    const u16* __restrict__ A0, const u16* __restrict__ BT0,
    float* __restrict__ C0, int M, int N, int K, int lda, int ldb, int ldc,
    long sAz, long sBz, long sCo, long sCi, int shC)
{
  const int z = blockIdx.z;
  const u16* A  = A0  + (size_t)z*sAz;
  const u16* BT = BT0 + (size_t)z*sBz;
  float* C = C0 + (size_t)(z>>shC)*sCo + (size_t)(z & ((1<<shC)-1))*sCi;
  __shared__ uint4 As4[128*5];
  __shared__ uint4 Bs4[128*5];
  const int tid = threadIdx.x;
  const int row0 = blockIdx.y*128, col0 = blockIdx.x*128;
  const int lane = tid & 63, wave = tid >> 6;
  const int wm = wave >> 1, wn = wave & 1;
  const int lr = lane & 15, ksg = (lane >> 4);
  f32x4 acc[4][4];
  #pragma unroll
  for(int i=0;i<4;i++)
    #pragma unroll
    for(int j=0;j<4;j++) acc[i][j] = (f32x4){0.f,0.f,0.f,0.f};
  for(int k0=0;k0<K;k0+=32){
    #pragma unroll
    for(int i=0;i<2;i++){
      int t2 = tid + i*256;
      int rr = t2 >> 2, sg = (t2 & 3);
      uint4 av = *reinterpret_cast<const uint4*>(A + (size_t)(row0+rr)*lda + k0 + sg*8);
      uint4 bv = {0u,0u,0u,0u};
      if(col0+rr < N) bv = *reinterpret_cast<const uint4*>(BT + (size_t)(col0+rr)*ldb + k0 + sg*8);
      As4[rr*5 + sg] = av;
      Bs4[rr*5 + sg] = bv;
    }
    __syncthreads();
    bf16x8 afr[4], bfr[4];
    #pragma unroll
    for(int i=0;i<4;i++) afr[i] = *reinterpret_cast<const bf16x8*>(&As4[(wm*64+i*16+lr)*5 + ksg]);
    #pragma unroll
    for(int j=0;j<4;j++) bfr[j] = *reinterpret_cast<const bf16x8*>(&Bs4[(wn*64+j*16+lr)*5 + ksg]);
    #pragma unroll
    for(int i=0;i<4;i++)
      #pragma unroll
      for(int j=0;j<4;j++)
        acc[i][j] = __builtin_amdgcn_mfma_f32_16x16x32_bf16(afr[i], bfr[j], acc[i][j], 0, 0, 0);
    __syncthreads();
  }
  const int hi = lane >> 4, lo = lane & 15;
  #pragma unroll
  for(int i=0;i<4;i++)
    #pragma unroll
    for(int j=0;j<4;j++)
      #pragma unroll
      for(int r=0;r<4;r++){
        int row = row0 + wm*64 + i*16 + 4*hi + r;
        int col = col0 + wn*64 + j*16 + lo;
        if(col < N) C[(size_t)row*ldc + col] = acc[i][j][r];
      }
}

// Y_off GEMM fused with yfinal epilogue: per z=(b*8+c),
// acc = C_chunk[256x64] @ prev^T[1024x64]; then
// Y = (Y + exp(Ac)*acc + D*xh) * silu(zgate)
__global__ __launch_bounds__(256) void k_mgy(
    const u16* __restrict__ Cb0, const u16* __restrict__ PV0,
    const float* __restrict__ ACUM, const float* __restrict__ XCp,
    const float* __restrict__ ZBp, const float* __restrict__ Dp,
    float* __restrict__ Y)
{
  const int z = blockIdx.z;                 // b*8+c
  const int b = z>>3, c = z&7;
  const u16* A  = Cb0 + (size_t)z*16384;    // [256][64] bf16
  const u16* BT = PV0 + (size_t)z*65536;    // [1024][64] bf16
  const int M = 256, N = 1024;
  __shared__ uint4 As4[128*5];
  __shared__ uint4 Bs4[128*5];
  const int tid = threadIdx.x;
  const int row0 = blockIdx.y*128, col0 = blockIdx.x*128;
  const int lane = tid & 63, wave = tid >> 6;
  const int wm = wave >> 1, wn = wave & 1;
  const int lr = lane & 15, ksg = (lane >> 4);
  f32x4 acc[4][4];
  #pragma unroll
  for(int i=0;i<4;i++)
    #pragma unroll
    for(int j=0;j<4;j++) acc[i][j] = (f32x4){0.f,0.f,0.f,0.f};
  for(int k0=0;k0<64;k0+=32){
    #pragma unroll
    for(int i=0;i<2;i++){
      int t2 = tid + i*256;
      int rr = t2 >> 2, sg = (t2 & 3);
      uint4 av = *reinterpret_cast<const uint4*>(A + (size_t)(row0+rr)*64 + k0 + sg*8);
      uint4 bv = {0u,0u,0u,0u};
      if(col0+rr < N) bv = *reinterpret_cast<const uint4*>(BT + (size_t)(col0+rr)*64 + k0 + sg*8);
      As4[rr*5 + sg] = av;
      Bs4[rr*5 + sg] = bv;
    }
    __syncthreads();
    bf16x8 afr[4], bfr[4];
    #pragma unroll
    for(int i=0;i<4;i++) afr[i] = *reinterpret_cast<const bf16x8*>(&As4[(wm*64+i*16+lr)*5 + ksg]);
    #pragma unroll
    for(int j=0;j<4;j++) bfr[j] = *reinterpret_cast<const bf16x8*>(&Bs4[(wn*64+j*16+lr)*5 + ksg]);
    #pragma unroll
    for(int i=0;i<4;i++)
      #pragma unroll
      for(int j=0;j<4;j++)
        acc[i][j] = __builtin_amdgcn_mfma_f32_16x16x32_bf16(afr[i], bfr[j], acc[i][j], 0, 0, 0);
    __syncthreads();
  }
  const int hi = lane >> 4, lo = lane & 15;
  #pragma unroll
  for(int i=0;i<4;i++)
    #pragma unroll
    for(int j=0;j<4;j++)
      #pragma unroll
      for(int r=0;r<4;r++){
        int row = row0 + wm*64 + i*16 + 4*hi + r;   // l in 0..255
        int col = col0 + wn*64 + j*16 + lo;         // h*64+p in 0..1023
        int h = col >> 6;
        int g = b*SEQL + c*CKS + row;               // global row
        float ac = ACUM[((size_t)z*NH + h)*CKS + row];
        float xh = XCp[(size_t)g*CVD + col];
        float zg = ZBp[(size_t)g*DIP + col];
        size_t ci = (size_t)g*DIN + col;
        float v = Y[ci] + expf(ac)*acc[i][j][r] + Dp[h]*xh;
        float sig = 1.f/(1.f+expf(-zg));
        Y[ci] = v * (zg*sig);
      }
}

// same verified core + arithmetic epilogue (attention head)
__global__ __launch_bounds__(256) void k_mge(
    const u16* __restrict__ A, const u16* __restrict__ BT,
    const float* __restrict__ bias, const float* __restrict__ res,
    float* __restrict__ C, u16* __restrict__ Cbf,
    int M, int N, int K, int lda, int ldb, int ldc, float scale, int act)
{
  __shared__ uint4 As4[128*5];
  __shared__ uint4 Bs4[128*5];
  const int tid = threadIdx.x;
  const int row0 = blockIdx.y*128, col0 = blockIdx.x*128;
  const int lane = tid & 63, wave = tid >> 6;
  const int wm = wave >> 1, wn = wave & 1;
  const int lr = lane & 15, ksg = (lane >> 4);
  f32x4 acc[4][4];
  #pragma unroll
  for(int i=0;i<4;i++)
    #pragma unroll
    for(int j=0;j<4;j++) acc[i][j] = (f32x4){0.f,0.f,0.f,0.f};
  for(int k0=0;k0<K;k0+=32){
    #pragma unroll
    for(int i=0;i<2;i++){
      int t2 = tid + i*256;
      int rr = t2 >> 2, sg = (t2 & 3);
      uint4 av = *reinterpret_cast<const uint4*>(A + (size_t)(row0+rr)*lda + k0 + sg*8);
      uint4 bv = {0u,0u,0u,0u};
      if(col0+rr < N) bv = *reinterpret_cast<const uint4*>(BT + (size_t)(col0+rr)*ldb + k0 + sg*8);
      As4[rr*5 + sg] = av;
      Bs4[rr*5 + sg] = bv;
    }
    __syncthreads();
    bf16x8 afr[4], bfr[4];
    #pragma unroll
    for(int i=0;i<4;i++) afr[i] = *reinterpret_cast<const bf16x8*>(&As4[(wm*64+i*16+lr)*5 + ksg]);
    #pragma unroll
    for(int j=0;j<4;j++) bfr[j] = *reinterpret_cast<const bf16x8*>(&Bs4[(wn*64+j*16+lr)*5 + ksg]);
    #pragma unroll
    for(int i=0;i<4;i++)
      #pragma unroll
      for(int j=0;j<4;j++)
        acc[i][j] = __builtin_amdgcn_mfma_f32_16x16x32_bf16(afr[i], bfr[j], acc[i][j], 0, 0, 0);
    __syncthreads();
  }
  const int hi = lane >> 4, lo = lane & 15;
  #pragma unroll
  for(int i=0;i<4;i++)
    #pragma unroll
    for(int j=0;j<4;j++)
      #pragma unroll
      for(int r=0;r<4;r++){
        int row = row0 + wm*64 + i*16 + 4*hi + r;
        int col = col0 + wn*64 + j*16 + lo;
        if(col < N){
          float v = acc[i][j][r];
          if(bias) v += bias[col];
          v *= scale;
          if(act==1) v = 0.5f*v*(1.f+erff(v*0.70710678118654752f));
          size_t ci = (size_t)row*ldc + col;
          if(res) v += res[ci];
          if(C) C[ci] = v;
          else  Cbf[ci] = cvt_bf16(v);
        }
      }
}

// in-place row softmax over 1024 bf16
__global__ void k_sm(u16* __restrict__ S){
  size_t row = blockIdx.x;
  u16* p = S + row*1024;
  int tid = threadIdx.x;
  ushort4 u = reinterpret_cast<ushort4*>(p)[tid];
  float v0=bf2f(u.x), v1=bf2f(u.y), v2=bf2f(u.z), v3=bf2f(u.w);
  float m = fmaxf(fmaxf(v0,v1),fmaxf(v2,v3));
  __shared__ float red[256];
  red[tid]=m; __syncthreads();
  for(int o=128;o>0;o>>=1){ if(tid<o) red[tid]=fmaxf(red[tid],red[tid+o]); __syncthreads(); }
  m = red[0]; __syncthreads();
  v0=__expf(v0-m); v1=__expf(v1-m); v2=__expf(v2-m); v3=__expf(v3-m);
  float s = v0+v1+v2+v3;
  red[tid]=s; __syncthreads();
  for(int o=128;o>0;o>>=1){ if(tid<o) red[tid]+=red[tid+o]; __syncthreads(); }
  float inv = 1.f/red[0];
  ushort4 o4; o4.x=cvt_bf16(v0*inv); o4.y=cvt_bf16(v1*inv); o4.z=cvt_bf16(v2*inv); o4.w=cvt_bf16(v3*inv);
  reinterpret_cast<ushort4*>(p)[tid] = o4;
}

// ---------------- mamba pieces ----------------
__global__ void k_conv(const float* __restrict__ ZB, const float* __restrict__ cw,
                       const float* __restrict__ cb, float* __restrict__ XC){
  int i = blockIdx.x*256 + threadIdx.x;
  if(i >= BS*SEQL*CVD) return;
  int cch = i % CVD;
  int l = (i / CVD) & (SEQL-1);
  int b = i / (CVD*SEQL);
  float v = cb[cch];
  #pragma unroll
  for(int k=0;k<4;k++){
    int sl = l + k - 3;
    if(sl >= 0) v += ZB[(size_t)(b*SEQL+sl)*DIP + DIN + cch] * cw[cch*4 + k];
  }
  float sig = 1.f/(1.f+expf(-v));
  XC[i] = v*sig;
}

__global__ void k_dt(const float* __restrict__ ZB, const float* __restrict__ dtb,
                     const float* __restrict__ Alog, float* __restrict__ DT,
                     float* __restrict__ DA){
  int i = blockIdx.x*256 + threadIdx.x;
  if(i >= BS*SEQL*NH) return;
  int h = i & (NH-1);
  int row = i >> 4;
  float raw = ZB[(size_t)row*DIP + (DIN+CVD) + h] + dtb[h];
  float dt = fmaxf(raw,0.f) + log1pf(expf(-fabsf(raw)));
  DT[i] = dt;
  DA[i] = dt * (-expf(Alog[h]));
}

__global__ void k_acum(const float* __restrict__ DA, float* __restrict__ ACUM,
                       float* __restrict__ CDEC){
  int blk = blockIdx.x;
  int h = blk & 15, c = (blk>>4)&7, b = blk>>7;
  int l = threadIdx.x;
  __shared__ float s[256];
  int gl = c*CKS + l;
  s[l] = DA[(size_t)(b*SEQL + gl)*NH + h];
  __syncthreads();
  for(int off=1; off<256; off<<=1){
    float v = (l>=off) ? s[l-off] : 0.f;
    __syncthreads();
    s[l] += v;
    __syncthreads();
  }
  ACUM[(size_t)blk*CKS + l] = s[l];
  if(l==255) CDEC[blk] = expf(s[255]);
}

// extract B,C as bf16 [8192][64]
__global__ void k_bc(const float* __restrict__ XC, u16* __restrict__ Bbf,
                     u16* __restrict__ Cbf){
  int i = blockIdx.x*256 + threadIdx.x;
  if(i >= NROWS*DST) return;
  int g = i >> 6, n = i & 63;
  Bbf[i] = cvt_bf16(XC[(size_t)g*CVD + DIN + n]);
  Cbf[i] = cvt_bf16(XC[(size_t)g*CVD + DIN + DST + n]);
}

// XdT_b[(c*16+h)][p][s] = bf16( XC[b, c*256+s, h*64+p] * DT[b, c*256+s, h] )
__global__ void k_xdt(const float* __restrict__ XC, const float* __restrict__ DT,
                      u16* __restrict__ XdT, int b){
  int i = blockIdx.x*256 + threadIdx.x;
  if(i >= 8*16*64*256) return;
  int s = i & 255, p = (i>>8) & 63, h = (i>>14) & 15, c = i >> 18;
  int g = b*SEQL + c*CKS + s;
  float v = XC[(size_t)g*CVD + h*HD + p] * DT[(size_t)g*NH + h];
  XdT[i] = cvt_bf16(v);
}

// Gb[(c*16+h)][l][s] = bf16( (s<=l) ? exp(Ac[l]-Ac[s]) * S[b,c][l][s] : 0 )
__global__ void k_gform(const float* __restrict__ Sf, const float* __restrict__ ACUM,
                        u16* __restrict__ Gb, int b){
  int i = blockIdx.x*256 + threadIdx.x;
  if(i >= 8*16*256*256) return;
  int s = i & 255, l = (i>>8) & 255, h = (i>>16) & 15, c = i >> 20;
  u16 g = 0;
  if(s <= l){
    const float* Ac = ACUM + (size_t)((b*NC+c)*NH + h)*CKS;
    float sv = Sf[(size_t)(b*NC+c)*65536 + l*256 + s];
    g = cvt_bf16(__expf(Ac[l]-Ac[s]) * sv);
  }
  Gb[i] = g;
}

__global__ void k_states(const float* __restrict__ XC, const float* __restrict__ DT,
                         const float* __restrict__ ACUM, float* __restrict__ ST){
  int blk = blockIdx.x;
  int h = blk & 15, c = (blk>>4)&7, b = blk>>7;
  int tid = threadIdx.x;
  int n = tid & 63, pq = tid >> 6;
  __shared__ float Ac[256];
  __shared__ float Bt[32][64];
  __shared__ float Xt[32][64];
  Ac[tid] = ACUM[(size_t)blk*CKS + tid];
  float acc[16];
  #pragma unroll
  for(int k=0;k<16;k++) acc[k]=0.f;
  const float* xcb = XC + (size_t)b*SEQL*CVD;
  for(int st=0; st<8; ++st){
    __syncthreads();
    #pragma unroll
    for(int e=0;e<8;e++){
      int idx = tid + e*256;
      int sl = idx>>6, nn = idx&63;
      int gs = c*CKS + st*32 + sl;
      Bt[sl][nn] = xcb[(size_t)gs*CVD + DIN + nn];
      float dec = expf(Ac[255] - Ac[st*32+sl]);
      Xt[sl][nn] = xcb[(size_t)gs*CVD + h*HD + nn] * DT[(size_t)(b*SEQL+gs)*NH + h] * dec;
    }
    __syncthreads();
    #pragma unroll
    for(int l=0;l<32;l++){
      float bv = Bt[l][n];
      #pragma unroll
      for(int k=0;k<16;k++) acc[k] += bv * Xt[l][pq + 4*k];
    }
  }
  #pragma unroll
  for(int k=0;k<16;k++){
    int p = pq + 4*k;
    ST[(size_t)blk*4096 + p*64 + n] = acc[k];
  }
}

__global__ void k_scan(const float* __restrict__ ST, const float* __restrict__ CDEC,
                       float* __restrict__ PREV){
  int i = blockIdx.x*256 + threadIdx.x;
  if(i >= BS*NH*4096) return;
  int pn = i & 4095;
  int h = (i>>12) & 15;
  int b = i >> 16;
  float run = 0.f;
  for(int c=0;c<8;c++){
    size_t idx = (size_t)((b*8+c)*16+h)*4096 + pn;
    PREV[idx] = run;
    run = run*CDEC[(b*8+c)*16+h] + ST[idx];
  }
}

// ---------------- attention helpers ----------------
__global__ void k_extract(const float* __restrict__ HF, float* __restrict__ QIN,
                          float* __restrict__ CIN){
  int i = blockIdx.x*256 + threadIdx.x;
  if(i >= BS*1024*DM) return;
  int d = i & (DM-1);
  int q = (i>>9) & 1023;
  int b = i >> 19;
  QIN[i] = HF[(size_t)(b*SEQL + 1024 + q)*DM + d];
  CIN[i] = HF[(size_t)(b*SEQL + q)*DM + d];
}

// ---------------- host ----------------
extern "C" void kernel_launch(void* const* d_in, const int* in_sizes, int n_in,
                              void* d_out, int out_size, void* d_ws, size_t ws_size,
                              hipStream_t stream) {
  (void)in_sizes; (void)n_in; (void)out_size; (void)ws_size;
  const float* x_enc     = (const float*)d_in[0];
  const float* in_proj_w = (const float*)d_in[2];
  const float* conv_w    = (const float*)d_in[3];
  const float* conv_b    = (const float*)d_in[4];
  const float* dt_bias   = (const float*)d_in[5];
  const float* A_log     = (const float*)d_in[6];
  const float* D_param   = (const float*)d_in[7];
  const float* gnorm_w   = (const float*)d_in[8];
  const float* out_proj_w= (const float*)d_in[9];
  const float* norm_w    = (const float*)d_in[10];
  const float* norm_b    = (const float*)d_in[11];
  const float* normf_w   = (const float*)d_in[12];
  const float* normf_b   = (const float*)d_in[13];
  const float* ca_nq_w   = (const float*)d_in[14];
  const float* ca_nq_b   = (const float*)d_in[15];
  const float* ca_nkv_w  = (const float*)d_in[16];
  const float* ca_nkv_b  = (const float*)d_in[17];
  const float* ca_qw     = (const float*)d_in[18];
  const float* ca_kw     = (const float*)d_in[19];
  const float* ca_vw     = (const float*)d_in[20];
  const float* ca_ow     = (const float*)d_in[21];
  const float* ca_qb     = (const float*)d_in[22];
  const float* ca_kb     = (const float*)d_in[23];
  const float* ca_vb     = (const float*)d_in[24];
  const float* ca_ob     = (const float*)d_in[25];
  const float* qp_w      = (const float*)d_in[26];
  const float* qp_b      = (const float*)d_in[27];
  const float* cp_w      = (const float*)d_in[28];
  const float* cp_b      = (const float*)d_in[29];
  const float* dec1_w    = (const float*)d_in[30];
  const float* dec1_b    = (const float*)d_in[31];
  const float* dec2_w    = (const float*)d_in[32];
  const float* dec2_b    = (const float*)d_in[33];

  float* W = (float*)d_ws;
  size_t off = 0;
  auto alloc = [&](size_t n){ float* pp = W + off; off += n; return pp; };
  float* RES  = alloc((size_t)NTOK);
  float* H    = alloc((size_t)NTOK);
  float* HN   = alloc((size_t)NTOK);
  float* HNF  = alloc((size_t)NTOK);
  float* ZB   = alloc((size_t)NROWS*DIP);        // 17,956,864
  float* XC   = alloc((size_t)NROWS*CVD);        //  9,437,184
  float* DT   = alloc((size_t)NROWS*NH);
  float* DA   = alloc((size_t)NROWS*NH);
  float* ACUM = alloc((size_t)BS*NC*NH*CKS);
  float* CDEC = alloc((size_t)BS*NC*NH);
  float* Y    = alloc((size_t)NROWS*DIN);        //  8,388,608
  float* ST   = alloc((size_t)BS*NC*NH*4096);
  float* PREV = alloc((size_t)BS*NC*NH*4096);
  float* YD   = alloc((size_t)NTOK);
  float* HF   = alloc((size_t)NTOK);
  // byte-identical to the proven round-1 layout (61,768,192 floats)

  // mamba staging aliases (proven lifetimes):
  u16* Ubf    = (u16*)HF;
  u16* WinTc  = (u16*)(HF + 2097152);
  u16* WoutTc = (u16*)(HF + 2097152 + 561152);
  u16* Ybf    = (u16*)HNF;                    // out_proj staging (after SSD)
  // SSD staging (dead regions during SSD phase):
  u16*   Bbf    = (u16*)HNF;                  //   524,288 u16
  u16*   Cbf    = Bbf + 524288;               //   524,288 u16
  float* Sf     = HNF + 524288;               // 2,097,152 fl
  u16*   PREVbf = (u16*)Sf;                   // 2,097,152 u16 (after Sf dead)
  u16*   XdTb   = (u16*)(HNF + 2621440);      // 2,097,152 u16
  u16*   Gb     = (u16*)YD;                   // 8,388,608 u16

  const int TPB = 256;
  const int gTok = (NTOK+TPB-1)/TPB;
  dim3 tb(32,8);

  hipMemcpyAsync(RES, x_enc, (size_t)NTOK*4, hipMemcpyDeviceToDevice, stream);

  for(int layer=0; layer<2; ++layer){
    if(layer>0) k_add_flip<<<gTok,TPB,0,stream>>>(RES, H, 0);
    k_ln<<<NROWS,TPB,0,stream>>>(RES, norm_w + layer*DM, norm_b + layer*DM, HN);
    hipMemsetAsync(H, 0, (size_t)NTOK*4, stream);
    for(int dir=0; dir<2; ++dir){
      int idx = layer*2 + dir;
      const float* cw   = conv_w   + (size_t)idx*CVD*4;
      const float* cb   = conv_b   + (size_t)idx*CVD;
      const float* dtb  = dt_bias  + (size_t)idx*NH;
      const float* Alog = A_log    + (size_t)idx*NH;
      const float* Dp   = D_param  + (size_t)idx*NH;
      const float* gw   = gnorm_w  + (size_t)idx*DIN;

      if(dir==0){
        k_cvt<<<(NTOK/4+TPB-1)/TPB,TPB,0,stream>>>(HN, Ubf, NTOK/4);
      }else{
        k_flip<<<gTok,TPB,0,stream>>>(HNF, HN);
        k_cvt<<<(NTOK/4+TPB-1)/TPB,TPB,0,stream>>>(HNF, Ubf, NTOK/4);
      }
      k_wt2<<<dim3(69,16),tb,0,stream>>>(in_proj_w + (size_t)idx*DM*DIP, WinTc, 512, 2192, 2192);
      k_mg<<<dim3(18,64),256,0,stream>>>(Ubf, WinTc, ZB, 8192, 2192, 512, 512, 512, 2192);

      k_conv<<<(BS*SEQL*CVD+TPB-1)/TPB,TPB,0,stream>>>(ZB, cw, cb, XC);
      k_dt<<<(BS*SEQL*NH+TPB-1)/TPB,TPB,0,stream>>>(ZB, dtb, Alog, DT, DA);
      k_acum<<<BS*NC*NH,256,0,stream>>>(DA, ACUM, CDEC);

      // ---- Y_diag via MFMA ----
      k_bc<<<(NROWS*DST+TPB-1)/TPB,TPB,0,stream>>>(XC, Bbf, Cbf);
      k_mgb<<<dim3(2,2,32),256,0,stream>>>(Cbf, Bbf, Sf,
            256, 256, 64, 64, 64, 256, 16384, 16384, 65536, 0, 0);
      for(int bb=0; bb<BS; ++bb){
        k_xdt<<<(2097152+TPB-1)/TPB,TPB,0,stream>>>(XC, DT, XdTb, bb);
        k_gform<<<(8388608+TPB-1)/TPB,TPB,0,stream>>>(Sf, ACUM, Gb, bb);
        k_mgb<<<dim3(1,2,128),256,0,stream>>>(Gb, XdTb, Y + (size_t)bb*2097152,
              256, 64, 256, 256, 256, 1024, 65536, 16384, 262144, 64, 4);
      }

      k_states<<<BS*NC*NH,256,0,stream>>>(XC, DT, ACUM, ST);
      k_scan<<<(BS*NH*4096+TPB-1)/TPB,TPB,0,stream>>>(ST, CDEC, PREV);
      // ---- Y_off via MFMA + fused gate epilogue (replaces k_yfinal) ----
      k_cvt<<<(2097152/4+TPB-1)/TPB,TPB,0,stream>>>(PREV, PREVbf, 2097152/4);
      k_mgy<<<dim3(8,2,32),256,0,stream>>>(Cbf, PREVbf, ACUM, XC, ZB, Dp, Y);

      k_rms<<<NROWS,256,0,stream>>>(Y, gw);

      k_cvt<<<(2097152+TPB-1)/TPB,TPB,0,stream>>>(Y, Ybf, 2097152);
      k_wt2<<<dim3(16,32),tb,0,stream>>>(out_proj_w + (size_t)idx*DIN*DM, WoutTc, 1024, 512, 512);
      k_mg<<<dim3(4,64),256,0,stream>>>(Ybf, WoutTc, YD, 8192, 512, 1024, 1024, 1024, 512);

      k_add_flip<<<gTok,TPB,0,stream>>>(H, YD, dir);
    }
  }
  k_add_flip<<<gTok,TPB,0,stream>>>(RES, H, 0);
  k_ln<<<NROWS,TPB,0,stream>>>(RES, normf_w, normf_b, HF);

  // ================= attention head — MFMA (round-10 proven) =================
  float* P0   = ZB;
  float* QIN  = P0 + 0;
  float* CIN  = P0 + 2097152;
  float* QPb  = P0 + 4194304;
  float* CPb  = P0 + 6291456;
  float* QN   = P0 + 8388608;
  float* CN   = P0 + 10485760;
  float* AO   = P0 + 12582912;
  float* O1   = P0 + 14680064;
  float* D1   = P0 + 16777216;
  float* VV   = D1;
  u16* U0     = (u16*)(P0 + 20971520);
  u16* Qbf    = U0 + 0;
  u16* Cbf2   = U0 + 2097152;
  u16* QNbf   = U0 + 4194304;
  u16* CNbf   = U0 + 6291456;
  u16* QQbf   = U0 + 8388608;
  u16* KKbf   = U0 + 10485760;
  u16* VTbf   = U0 + 12582912;
  u16* AObf   = U0 + 14680064;
  u16* O1bf   = U0 + 16777216;
  u16* qpT    = U0 + 18874368;
  u16* cpT    = qpT + 262144;
  u16* qwT    = qpT + 524288;
  u16* kwT    = qpT + 786432;
  u16* vwT    = qpT + 1048576;
  u16* owT    = qpT + 1310720;
  u16* dec1T  = qpT + 1572864;
  u16* Pbf    = qpT + 2097152;

  const int M2 = BS*1024;
  k_extract<<<(BS*1024*DM+TPB-1)/TPB,TPB,0,stream>>>(HF, QIN, CIN);
  k_cvt<<<(2097152/4+TPB-1)/TPB,TPB,0,stream>>>(QIN, Qbf, 2097152/4);
  k_cvt<<<(2097152/4+TPB-1)/TPB,TPB,0,stream>>>(CIN, Cbf2, 2097152/4);
  k_wt2<<<dim3(16,16),tb,0,stream>>>(qp_w, qpT, 512, 512, 512);
  k_wt2<<<dim3(16,16),tb,0,stream>>>(cp_w, cpT, 512, 512, 512);
  k_wt2<<<dim3(16,16),tb,0,stream>>>(ca_qw, qwT, 512, 512, 512);
  k_wt2<<<dim3(16,16),tb,0,stream>>>(ca_kw, kwT, 512, 512, 512);
  k_wt2<<<dim3(16,16),tb,0,stream>>>(ca_vw, vwT, 512, 512, 512);
  k_wt2<<<dim3(16,16),tb,0,stream>>>(ca_ow, owT, 512, 512, 512);
  k_wt2<<<dim3(32,16),tb,0,stream>>>(dec1_w, dec1T, 512, 1024, 1024);

  k_mge<<<dim3(4,32),256,0,stream>>>(Qbf, qpT, qp_b, nullptr, QPb, nullptr,
                                     M2, 512, 512, 512, 512, 512, 1.f, 0);
  k_mge<<<dim3(4,32),256,0,stream>>>(Cbf2, cpT, cp_b, nullptr, CPb, nullptr,
                                     M2, 512, 512, 512, 512, 512, 1.f, 0);
  k_ln<<<M2,TPB,0,stream>>>(QPb, ca_nq_w, ca_nq_b, QN);
  k_ln<<<M2,TPB,0,stream>>>(CPb, ca_nkv_w, ca_nkv_b, CN);
  k_cvt<<<(2097152/4+TPB-1)/TPB,TPB,0,stream>>>(QN, QNbf, 2097152/4);
  k_cvt<<<(2097152/4+TPB-1)/TPB,TPB,0,stream>>>(CN, CNbf, 2097152/4);
  k_mge<<<dim3(4,32),256,0,stream>>>(QNbf, qwT, ca_qb, nullptr, nullptr, QQbf,
                                     M2, 512, 512, 512, 512, 512, 1.f, 0);
  k_mge<<<dim3(4,32),256,0,stream>>>(CNbf, kwT, ca_kb, nullptr, nullptr, KKbf,
                                     M2, 512, 512, 512, 512, 512, 1.f, 0);
  k_mge<<<dim3(4,32),256,0,stream>>>(CNbf, vwT, ca_vb, nullptr, VV, nullptr,
                                     M2, 512, 512, 512, 512, 512, 1.f, 0);
  for(int z=0; z<16; ++z){
    int b = z>>2, h = z&3;
    k_wt2<<<dim3(4,32),tb,0,stream>>>(VV + (size_t)b*1024*512 + h*128,
                                      VTbf + (size_t)z*131072, 1024, 128, 512);
  }
  const float scl = 0.088388347648318447f;
  for(int z=0; z<16; ++z){
    int b = z>>2, h = z&3;
    k_mge<<<dim3(8,8),256,0,stream>>>(QQbf + (size_t)b*1024*512 + h*128,
                                      KKbf + (size_t)b*1024*512 + h*128,
                                      nullptr, nullptr, nullptr,
                                      Pbf + (size_t)z*1048576,
                                      1024, 1024, 128, 512, 512, 1024, scl, 0);
  }
  k_sm<<<16384,256,0,stream>>>(Pbf);
  for(int z=0; z<16; ++z){
    int b = z>>2, h = z&3;
    k_mge<<<dim3(1,8),256,0,stream>>>(Pbf + (size_t)z*1048576,
                                      VTbf + (size_t)z*131072,
                                      nullptr, nullptr,
                                      AO + (size_t)b*1024*512 + h*128, nullptr,
                                      1024, 128, 1024, 1024, 1024, 512, 1.f, 0);
  }
  k_cvt<<<(2097152/4+TPB-1)/TPB,TPB,0,stream>>>(AO, AObf, 2097152/4);
  k_mge<<<dim3(4,32),256,0,stream>>>(AObf, owT, ca_ob, QPb, O1, nullptr,
                                     M2, 512, 512, 512, 512, 512, 1.f, 0);
  k_cvt<<<(2097152/4+TPB-1)/TPB,TPB,0,stream>>>(O1, O1bf, 2097152/4);
  k_mge<<<dim3(8,32),256,0,stream>>>(O1bf, dec1T, dec1_b, nullptr, D1, nullptr,
                                     M2, 1024, 512, 512, 512, 1024, 1.f, 1);
  {
    dim3 g((10+63)/64, M2/64), b2(16,16);
    k_gemm<<<g,b2,0,stream>>>(D1, dec2_w, dec2_b, nullptr, (float*)d_out, M2, 10, 1024, 0);
  }
}

// Round 13
// 2141.934 us; speedup vs baseline: 151.6812x; 1.3756x over previous
//
#include <hip/hip_runtime.h>
#include <hip/hip_bf16.h>

#define BS 4
#define SEQL 2048
#define DM 512
#define DIN 1024
#define NH 16
#define HD 64
#define DST 64
#define NC 8
#define CKS 256
#define DIP 2192
#define CVD 1152
#define NROWS (BS*SEQL)          /* 8192 */
#define NTOK (BS*SEQL*DM)        /* 4194304 */

typedef unsigned short u16;
typedef __bf16 bf16x8 __attribute__((ext_vector_type(8)));
typedef float f32x4 __attribute__((ext_vector_type(4)));

__device__ __forceinline__ u16 cvt_bf16(float f){
  unsigned int x = __float_as_uint(f);
  unsigned int r = x + 0x7fffu + ((x>>16)&1u);
  return (u16)(r>>16);
}
__device__ __forceinline__ float bf2f(u16 u){
  return __uint_as_float(((unsigned int)u)<<16);
}

// ---------------- elementwise (proven) ----------------
__global__ void k_add_flip(float* __restrict__ dst, const float* __restrict__ src, int flip){
  int i = blockIdx.x*256 + threadIdx.x;
  if(i >= NTOK) return;
  int d = i & (DM-1);
  int l = (i >> 9) & (SEQL-1);
  int b = i >> 20;
  int sl = flip ? (SEQL-1-l) : l;
  dst[i] += src[(b*SEQL + sl)*DM + d];
}

__global__ void k_flip(float* __restrict__ dst, const float* __restrict__ src){
  int i = blockIdx.x*256 + threadIdx.x;
  if(i >= NTOK) return;
  int d = i & (DM-1);
  int l = (i >> 9) & (SEQL-1);
  int b = i >> 20;
  dst[i] = src[(b*SEQL + (SEQL-1-l))*DM + d];
}

// f32 -> bf16 (verified round-8)
__global__ void k_cvt(const float* __restrict__ src, u16* __restrict__ dst, int n4){
  int i = blockIdx.x*256 + threadIdx.x;
  if(i >= n4) return;
  float4 f = reinterpret_cast<const float4*>(src)[i];
  ushort4 o; o.x=cvt_bf16(f.x); o.y=cvt_bf16(f.y); o.z=cvt_bf16(f.z); o.w=cvt_bf16(f.w);
  reinterpret_cast<ushort4*>(dst)[i] = o;
}

__global__ void k_ln(const float* __restrict__ X, const float* __restrict__ w,
                     const float* __restrict__ bb, float* __restrict__ O){
  int row = blockIdx.x, tid = threadIdx.x;
  const float* x = X + (size_t)row*DM;
  float* o = O + (size_t)row*DM;
  float s=0.f, s2=0.f;
  for(int j=tid;j<DM;j+=256){ float v=x[j]; s+=v; s2+=v*v; }
  __shared__ float r1[256], r2[256];
  r1[tid]=s; r2[tid]=s2; __syncthreads();
  for(int off=128;off>0;off>>=1){
    if(tid<off){ r1[tid]+=r1[tid+off]; r2[tid]+=r2[tid+off]; }
    __syncthreads();
  }
  float m = r1[0]*(1.f/DM);
  float var = r2[0]*(1.f/DM) - m*m;
  float inv = rsqrtf(var + 1e-5f);
  for(int j=tid;j<DM;j+=256) o[j] = (x[j]-m)*inv*w[j] + bb[j];
}

__global__ void k_rms(float* __restrict__ Y, const float* __restrict__ gw){
  int row = blockIdx.x, tid = threadIdx.x;
  float* y = Y + (size_t)row*DIN;
  float ss=0.f;
  for(int j=tid;j<DIN;j+=256){ float v=y[j]; ss+=v*v; }
  __shared__ float red[256];
  red[tid]=ss; __syncthreads();
  for(int off=128;off>0;off>>=1){
    if(tid<off) red[tid]+=red[tid+off];
    __syncthreads();
  }
  float inv = rsqrtf(red[0]*(1.f/DIN) + 1e-5f);
  for(int j=tid;j<DIN;j+=256) y[j] = y[j]*inv*gw[j];
}

// dec2: out[row][0..9] = D1[row]·dec2_w + b ; one block per row
__global__ void k_dec2(const float* __restrict__ D1, const float* __restrict__ w,
                       const float* __restrict__ bb, float* __restrict__ out){
  int row = blockIdx.x, tid = threadIdx.x;
  int lane = tid & 63, wave = tid >> 6;
  const float* x = D1 + (size_t)row*1024;
  float acc[10];
  #pragma unroll
  for(int o=0;o<10;o++) acc[o]=0.f;
  for(int j=tid;j<1024;j+=256){
    float v = x[j];
    const float* wr = w + (size_t)j*10;
    #pragma unroll
    for(int o=0;o<10;o++) acc[o] += v*wr[o];
  }
  __shared__ float red[4][10];
  #pragma unroll
  for(int o=0;o<10;o++){
    float v = acc[o];
    #pragma unroll
    for(int s=32;s>0;s>>=1) v += __shfl_down(v, s, 64);
    if(lane==0) red[wave][o] = v;
  }
  __syncthreads();
  if(tid < 10)
    out[(size_t)row*10 + tid] = red[0][tid]+red[1][tid]+red[2][tid]+red[3][tid] + bb[tid];
}

// transpose-convert with explicit src ld (verified): src[K][lds] f32 -> dst[N][K] bf16
__global__ void k_wt2(const float* __restrict__ src, u16* __restrict__ dst,
                      int K, int N, int lds){
  __shared__ float t[32][33];
  int n0 = blockIdx.x*32, k0 = blockIdx.y*32;
  int tx = threadIdx.x, ty = threadIdx.y;
  #pragma unroll
  for(int i=0;i<32;i+=8){
    int k = k0+ty+i, n = n0+tx;
    t[ty+i][tx] = (n<N) ? src[(size_t)k*lds+n] : 0.f;
  }
  __syncthreads();
  #pragma unroll
  for(int i=0;i<32;i+=8){
    int n = n0+ty+i, k = k0+tx;
    if(n<N) dst[(size_t)n*K+k] = cvt_bf16(t[tx][ty+i]);
  }
}

// batched V-transpose: per z=(b*4+h): src=VV+b*524288+h*128 [1024][128 of 512] -> dst [128][1024]
__global__ void k_vtb(const float* __restrict__ VV, u16* __restrict__ VT){
  __shared__ float t[32][33];
  int z = blockIdx.z, b = z>>2, h = z&3;
  const float* src = VV + (size_t)b*524288 + h*128;
  u16* dst = VT + (size_t)z*131072;
  int n0 = blockIdx.x*32, k0 = blockIdx.y*32;   // n<128, k<1024
  int tx = threadIdx.x, ty = threadIdx.y;
  #pragma unroll
  for(int i=0;i<32;i+=8){
    int k = k0+ty+i, n = n0+tx;
    t[ty+i][tx] = src[(size_t)k*512+n];
  }
  __syncthreads();
  #pragma unroll
  for(int i=0;i<32;i+=8){
    int n = n0+ty+i, k = k0+tx;
    dst[(size_t)n*1024+k] = cvt_bf16(t[tx][ty+i]);
  }
}

// ---------------- MFMA bf16 GEMM, emap0 (HW-verified) ----------------
__global__ __launch_bounds__(256) void k_mg(
    const u16* __restrict__ A, const u16* __restrict__ BT,
    float* __restrict__ C, int M, int N, int K, int lda, int ldb, int ldc)
{
  __shared__ uint4 As4[128*5];
  __shared__ uint4 Bs4[128*5];
  const int tid = threadIdx.x;
  const int row0 = blockIdx.y*128, col0 = blockIdx.x*128;
  const int lane = tid & 63, wave = tid >> 6;
  const int wm = wave >> 1, wn = wave & 1;
  const int lr = lane & 15, ksg = (lane >> 4);
  f32x4 acc[4][4];
  #pragma unroll
  for(int i=0;i<4;i++)
    #pragma unroll
    for(int j=0;j<4;j++) acc[i][j] = (f32x4){0.f,0.f,0.f,0.f};
  for(int k0=0;k0<K;k0+=32){
    #pragma unroll
    for(int i=0;i<2;i++){
      int t2 = tid + i*256;
      int rr = t2 >> 2, sg = (t2 & 3);
      uint4 av = *reinterpret_cast<const uint4*>(A + (size_t)(row0+rr)*lda + k0 + sg*8);
      uint4 bv = {0u,0u,0u,0u};
      if(col0+rr < N) bv = *reinterpret_cast<const uint4*>(BT + (size_t)(col0+rr)*ldb + k0 + sg*8);
      As4[rr*5 + sg] = av;
      Bs4[rr*5 + sg] = bv;
    }
    __syncthreads();
    bf16x8 afr[4], bfr[4];
    #pragma unroll
    for(int i=0;i<4;i++) afr[i] = *reinterpret_cast<const bf16x8*>(&As4[(wm*64+i*16+lr)*5 + ksg]);
    #pragma unroll
    for(int j=0;j<4;j++) bfr[j] = *reinterpret_cast<const bf16x8*>(&Bs4[(wn*64+j*16+lr)*5 + ksg]);
    #pragma unroll
    for(int i=0;i<4;i++)
      #pragma unroll
      for(int j=0;j<4;j++)
        acc[i][j] = __builtin_amdgcn_mfma_f32_16x16x32_bf16(afr[i], bfr[j], acc[i][j], 0, 0, 0);
    __syncthreads();
  }
  const int hi = lane >> 4, lo = lane & 15;
  #pragma unroll
  for(int i=0;i<4;i++)
    #pragma unroll
    for(int j=0;j<4;j++)
      #pragma unroll
      for(int r=0;r<4;r++){
        int row = row0 + wm*64 + i*16 + 4*hi + r;
        int col = col0 + wn*64 + j*16 + lo;
        if(col < N) C[(size_t)row*ldc + col] = acc[i][j][r];
      }
}

// batched variant: verified core + z-strided base offsets only
__global__ __launch_bounds__(256) void k_mgb(
    const u16* __restrict__ A0, const u16* __restrict__ BT0,
    float* __restrict__ C0, int M, int N, int K, int lda, int ldb, int ldc,
    long sAz, long sBz, long sCo, long sCi, int shC)
{
  const int z = blockIdx.z;
  const u16* A  = A0  + (size_t)z*sAz;
  const u16* BT = BT0 + (size_t)z*sBz;
  float* C = C0 + (size_t)(z>>shC)*sCo + (size_t)(z & ((1<<shC)-1))*sCi;
  __shared__ uint4 As4[128*5];
  __shared__ uint4 Bs4[128*5];
  const int tid = threadIdx.x;
  const int row0 = blockIdx.y*128, col0 = blockIdx.x*128;
  const int lane = tid & 63, wave = tid >> 6;
  const int wm = wave >> 1, wn = wave & 1;
  const int lr = lane & 15, ksg = (lane >> 4);
  f32x4 acc[4][4];
  #pragma unroll
  for(int i=0;i<4;i++)
    #pragma unroll
    for(int j=0;j<4;j++) acc[i][j] = (f32x4){0.f,0.f,0.f,0.f};
  for(int k0=0;k0<K;k0+=32){
    #pragma unroll
    for(int i=0;i<2;i++){
      int t2 = tid + i*256;
      int rr = t2 >> 2, sg = (t2 & 3);
      uint4 av = *reinterpret_cast<const uint4*>(A + (size_t)(row0+rr)*lda + k0 + sg*8);
      uint4 bv = {0u,0u,0u,0u};
      if(col0+rr < N) bv = *reinterpret_cast<const uint4*>(BT + (size_t)(col0+rr)*ldb + k0 + sg*8);
      As4[rr*5 + sg] = av;
      Bs4[rr*5 + sg] = bv;
    }
    __syncthreads();
    bf16x8 afr[4], bfr[4];
    #pragma unroll
    for(int i=0;i<4;i++) afr[i] = *reinterpret_cast<const bf16x8*>(&As4[(wm*64+i*16+lr)*5 + ksg]);
    #pragma unroll
    for(int j=0;j<4;j++) bfr[j] = *reinterpret_cast<const bf16x8*>(&Bs4[(wn*64+j*16+lr)*5 + ksg]);
    #pragma unroll
    for(int i=0;i<4;i++)
      #pragma unroll
      for(int j=0;j<4;j++)
        acc[i][j] = __builtin_amdgcn_mfma_f32_16x16x32_bf16(afr[i], bfr[j], acc[i][j], 0, 0, 0);
    __syncthreads();
  }
  const int hi = lane >> 4, lo = lane & 15;
  #pragma unroll
  for(int i=0;i<4;i++)
    #pragma unroll
    for(int j=0;j<4;j++)
      #pragma unroll
      for(int r=0;r<4;r++){
        int row = row0 + wm*64 + i*16 + 4*hi + r;
        int col = col0 + wn*64 + j*16 + lo;
        if(col < N) C[(size_t)row*ldc + col] = acc[i][j][r];
      }
}

// batched attention GEMM: (z>>2)/(z&3) offsets for A/B/C, scale, f32 or bf16 out
__global__ __launch_bounds__(256) void k_mgab(
    const u16* __restrict__ A0, const u16* __restrict__ BT0,
    float* __restrict__ C0, u16* __restrict__ Cb0,
    int M, int N, int K, int lda, int ldb, int ldc,
    long sAo, long sAi, long sBo, long sBi, long sCo, long sCi, float scale)
{
  const int z = blockIdx.z;
  const u16* A  = A0  + (size_t)(z>>2)*sAo + (size_t)(z&3)*sAi;
  const u16* BT = BT0 + (size_t)(z>>2)*sBo + (size_t)(z&3)*sBi;
  const size_t offC = (size_t)(z>>2)*sCo + (size_t)(z&3)*sCi;
  __shared__ uint4 As4[128*5];
  __shared__ uint4 Bs4[128*5];
  const int tid = threadIdx.x;
  const int row0 = blockIdx.y*128, col0 = blockIdx.x*128;
  const int lane = tid & 63, wave = tid >> 6;
  const int wm = wave >> 1, wn = wave & 1;
  const int lr = lane & 15, ksg = (lane >> 4);
  f32x4 acc[4][4];
  #pragma unroll
  for(int i=0;i<4;i++)
    #pragma unroll
    for(int j=0;j<4;j++) acc[i][j] = (f32x4){0.f,0.f,0.f,0.f};
  for(int k0=0;k0<K;k0+=32){
    #pragma unroll
    for(int i=0;i<2;i++){
      int t2 = tid + i*256;
      int rr = t2 >> 2, sg = (t2 & 3);
      uint4 av = *reinterpret_cast<const uint4*>(A + (size_t)(row0+rr)*lda + k0 + sg*8);
      uint4 bv = {0u,0u,0u,0u};
      if(col0+rr < N) bv = *reinterpret_cast<const uint4*>(BT + (size_t)(col0+rr)*ldb + k0 + sg*8);
      As4[rr*5 + sg] = av;
      Bs4[rr*5 + sg] = bv;
    }
    __syncthreads();
    bf16x8 afr[4], bfr[4];
    #pragma unroll
    for(int i=0;i<4;i++) afr[i] = *reinterpret_cast<const bf16x8*>(&As4[(wm*64+i*16+lr)*5 + ksg]);
    #pragma unroll
    for(int j=0;j<4;j++) bfr[j] = *reinterpret_cast<const bf16x8*>(&Bs4[(wn*64+j*16+lr)*5 + ksg]);
    #pragma unroll
    for(int i=0;i<4;i++)
      #pragma unroll
      for(int j=0;j<4;j++)
        acc[i][j] = __builtin_amdgcn_mfma_f32_16x16x32_bf16(afr[i], bfr[j], acc[i][j], 0, 0, 0);
    __syncthreads();
  }
  const int hi = lane >> 4, lo = lane & 15;
  #pragma unroll
  for(int i=0;i<4;i++)
    #pragma unroll
    for(int j=0;j<4;j++)
      #pragma unroll
      for(int r=0;r<4;r++){
        int row = row0 + wm*64 + i*16 + 4*hi + r;
        int col = col0 + wn*64 + j*16 + lo;
        if(col < N){
          float v = acc[i][j][r] * scale;
          size_t ci = offC + (size_t)row*ldc + col;
          if(C0) C0[ci] = v;
          else   Cb0[ci] = cvt_bf16(v);
        }
      }
}

// Y_off GEMM fused with yfinal epilogue
__global__ __launch_bounds__(256) void k_mgy(
    const u16* __restrict__ Cb0, const u16* __restrict__ PV0,
    const float* __restrict__ ACUM, const float* __restrict__ XCp,
    const float* __restrict__ ZBp, const float* __restrict__ Dp,
    float* __restrict__ Y)
{
  const int z = blockIdx.z;                 // b*8+c
  const int b = z>>3, c = z&7;
  const u16* A  = Cb0 + (size_t)z*16384;    // [256][64] bf16
  const u16* BT = PV0 + (size_t)z*65536;    // [1024][64] bf16
  const int N = 1024;
  __shared__ uint4 As4[128*5];
  __shared__ uint4 Bs4[128*5];
  const int tid = threadIdx.x;
  const int row0 = blockIdx.y*128, col0 = blockIdx.x*128;
  const int lane = tid & 63, wave = tid >> 6;
  const int wm = wave >> 1, wn = wave & 1;
  const int lr = lane & 15, ksg = (lane >> 4);
  f32x4 acc[4][4];
  #pragma unroll
  for(int i=0;i<4;i++)
    #pragma unroll
    for(int j=0;j<4;j++) acc[i][j] = (f32x4){0.f,0.f,0.f,0.f};
  for(int k0=0;k0<64;k0+=32){
    #pragma unroll
    for(int i=0;i<2;i++){
      int t2 = tid + i*256;
      int rr = t2 >> 2, sg = (t2 & 3);
      uint4 av = *reinterpret_cast<const uint4*>(A + (size_t)(row0+rr)*64 + k0 + sg*8);
      uint4 bv = {0u,0u,0u,0u};
      if(col0+rr < N) bv = *reinterpret_cast<const uint4*>(BT + (size_t)(col0+rr)*64 + k0 + sg*8);
      As4[rr*5 + sg] = av;
      Bs4[rr*5 + sg] = bv;
    }
    __syncthreads();
    bf16x8 afr[4], bfr[4];
    #pragma unroll
    for(int i=0;i<4;i++) afr[i] = *reinterpret_cast<const bf16x8*>(&As4[(wm*64+i*16+lr)*5 + ksg]);
    #pragma unroll
    for(int j=0;j<4;j++) bfr[j] = *reinterpret_cast<const bf16x8*>(&Bs4[(wn*64+j*16+lr)*5 + ksg]);
    #pragma unroll
    for(int i=0;i<4;i++)
      #pragma unroll
      for(int j=0;j<4;j++)
        acc[i][j] = __builtin_amdgcn_mfma_f32_16x16x32_bf16(afr[i], bfr[j], acc[i][j], 0, 0, 0);
    __syncthreads();
  }
  const int hi = lane >> 4, lo = lane & 15;
  #pragma unroll
  for(int i=0;i<4;i++)
    #pragma unroll
    for(int j=0;j<4;j++)
      #pragma unroll
      for(int r=0;r<4;r++){
        int row = row0 + wm*64 + i*16 + 4*hi + r;
        int col = col0 + wn*64 + j*16 + lo;
        int h = col >> 6;
        int g = b*SEQL + c*CKS + row;
        float ac = ACUM[((size_t)z*NH + h)*CKS + row];
        float xh = XCp[(size_t)g*CVD + col];
        float zg = ZBp[(size_t)g*DIP + col];
        size_t ci = (size_t)g*DIN + col;
        float v = Y[ci] + expf(ac)*acc[i][j][r] + Dp[h]*xh;
        float sig = 1.f/(1.f+expf(-zg));
        Y[ci] = v * (zg*sig);
      }
}

// verified core + arithmetic epilogue (attention projections)
__global__ __launch_bounds__(256) void k_mge(
    const u16* __restrict__ A, const u16* __restrict__ BT,
    const float* __restrict__ bias, const float* __restrict__ res,
    float* __restrict__ C, u16* __restrict__ Cbf,
    int M, int N, int K, int lda, int ldb, int ldc, float scale, int act)
{
  __shared__ uint4 As4[128*5];
  __shared__ uint4 Bs4[128*5];
  const int tid = threadIdx.x;
  const int row0 = blockIdx.y*128, col0 = blockIdx.x*128;
  const int lane = tid & 63, wave = tid >> 6;
  const int wm = wave >> 1, wn = wave & 1;
  const int lr = lane & 15, ksg = (lane >> 4);
  f32x4 acc[4][4];
  #pragma unroll
  for(int i=0;i<4;i++)
    #pragma unroll
    for(int j=0;j<4;j++) acc[i][j] = (f32x4){0.f,0.f,0.f,0.f};
  for(int k0=0;k0<K;k0+=32){
    #pragma unroll
    for(int i=0;i<2;i++){
      int t2 = tid + i*256;
      int rr = t2 >> 2, sg = (t2 & 3);
      uint4 av = *reinterpret_cast<const uint4*>(A + (size_t)(row0+rr)*lda + k0 + sg*8);
      uint4 bv = {0u,0u,0u,0u};
      if(col0+rr < N) bv = *reinterpret_cast<const uint4*>(BT + (size_t)(col0+rr)*ldb + k0 + sg*8);
      As4[rr*5 + sg] = av;
      Bs4[rr*5 + sg] = bv;
    }
    __syncthreads();
    bf16x8 afr[4], bfr[4];
    #pragma unroll
    for(int i=0;i<4;i++) afr[i] = *reinterpret_cast<const bf16x8*>(&As4[(wm*64+i*16+lr)*5 + ksg]);
    #pragma unroll
    for(int j=0;j<4;j++) bfr[j] = *reinterpret_cast<const bf16x8*>(&Bs4[(wn*64+j*16+lr)*5 + ksg]);
    #pragma unroll
    for(int i=0;i<4;i++)
      #pragma unroll
      for(int j=0;j<4;j++)
        acc[i][j] = __builtin_amdgcn_mfma_f32_16x16x32_bf16(afr[i], bfr[j], acc[i][j], 0, 0, 0);
    __syncthreads();
  }
  const int hi = lane >> 4, lo = lane & 15;
  #pragma unroll
  for(int i=0;i<4;i++)
    #pragma unroll
    for(int j=0;j<4;j++)
      #pragma unroll
      for(int r=0;r<4;r++){
        int row = row0 + wm*64 + i*16 + 4*hi + r;
        int col = col0 + wn*64 + j*16 + lo;
        if(col < N){
          float v = acc[i][j][r];
          if(bias) v += bias[col];
          v *= scale;
          if(act==1) v = 0.5f*v*(1.f+erff(v*0.70710678118654752f));
          size_t ci = (size_t)row*ldc + col;
          if(res) v += res[ci];
          if(C) C[ci] = v;
          else  Cbf[ci] = cvt_bf16(v);
        }
      }
}

// in-place row softmax over 1024 bf16
__global__ void k_sm(u16* __restrict__ S){
  size_t row = blockIdx.x;
  u16* p = S + row*1024;
  int tid = threadIdx.x;
  ushort4 u = reinterpret_cast<ushort4*>(p)[tid];
  float v0=bf2f(u.x), v1=bf2f(u.y), v2=bf2f(u.z), v3=bf2f(u.w);
  float m = fmaxf(fmaxf(v0,v1),fmaxf(v2,v3));
  __shared__ float red[256];
  red[tid]=m; __syncthreads();
  for(int o=128;o>0;o>>=1){ if(tid<o) red[tid]=fmaxf(red[tid],red[tid+o]); __syncthreads(); }
  m = red[0]; __syncthreads();
  v0=__expf(v0-m); v1=__expf(v1-m); v2=__expf(v2-m); v3=__expf(v3-m);
  float s = v0+v1+v2+v3;
  red[tid]=s; __syncthreads();
  for(int o=128;o>0;o>>=1){ if(tid<o) red[tid]+=red[tid+o]; __syncthreads(); }
  float inv = 1.f/red[0];
  ushort4 o4; o4.x=cvt_bf16(v0*inv); o4.y=cvt_bf16(v1*inv); o4.z=cvt_bf16(v2*inv); o4.w=cvt_bf16(v3*inv);
  reinterpret_cast<ushort4*>(p)[tid] = o4;
}

// ---------------- mamba pieces ----------------
__global__ void k_conv(const float* __restrict__ ZB, const float* __restrict__ cw,
                       const float* __restrict__ cb, float* __restrict__ XC){
  int i = blockIdx.x*256 + threadIdx.x;
  if(i >= BS*SEQL*CVD) return;
  int cch = i % CVD;
  int l = (i / CVD) & (SEQL-1);
  int b = i / (CVD*SEQL);
  float v = cb[cch];
  #pragma unroll
  for(int k=0;k<4;k++){
    int sl = l + k - 3;
    if(sl >= 0) v += ZB[(size_t)(b*SEQL+sl)*DIP + DIN + cch] * cw[cch*4 + k];
  }
  float sig = 1.f/(1.f+expf(-v));
  XC[i] = v*sig;
}

__global__ void k_dt(const float* __restrict__ ZB, const float* __restrict__ dtb,
                     const float* __restrict__ Alog, float* __restrict__ DT,
                     float* __restrict__ DA){
  int i = blockIdx.x*256 + threadIdx.x;
  if(i >= BS*SEQL*NH) return;
  int h = i & (NH-1);
  int row = i >> 4;
  float raw = ZB[(size_t)row*DIP + (DIN+CVD) + h] + dtb[h];
  float dt = fmaxf(raw,0.f) + log1pf(expf(-fabsf(raw)));
  DT[i] = dt;
  DA[i] = dt * (-expf(Alog[h]));
}

__global__ void k_acum(const float* __restrict__ DA, float* __restrict__ ACUM,
                       float* __restrict__ CDEC){
  int blk = blockIdx.x;
  int h = blk & 15, c = (blk>>4)&7, b = blk>>7;
  int l = threadIdx.x;
  __shared__ float s[256];
  int gl = c*CKS + l;
  s[l] = DA[(size_t)(b*SEQL + gl)*NH + h];
  __syncthreads();
  for(int off=1; off<256; off<<=1){
    float v = (l>=off) ? s[l-off] : 0.f;
    __syncthreads();
    s[l] += v;
    __syncthreads();
  }
  ACUM[(size_t)blk*CKS + l] = s[l];
  if(l==255) CDEC[blk] = expf(s[255]);
}

// extract B,C as bf16 [8192][64]
__global__ void k_bc(const float* __restrict__ XC, u16* __restrict__ Bbf,
                     u16* __restrict__ Cbf){
  int i = blockIdx.x*256 + threadIdx.x;
  if(i >= NROWS*DST) return;
  int g = i >> 6, n = i & 63;
  Bbf[i] = cvt_bf16(XC[(size_t)g*CVD + DIN + n]);
  Cbf[i] = cvt_bf16(XC[(size_t)g*CVD + DIN + DST + n]);
}

// XdT_b[(c*16+h)][p][s] = bf16( XC[b, c*256+s, h*64+p] * DT[b, c*256+s, h] )
__global__ void k_xdt(const float* __restrict__ XC, const float* __restrict__ DT,
                      u16* __restrict__ XdT, int b){
  int i = blockIdx.x*256 + threadIdx.x;
  if(i >= 8*16*64*256) return;
  int s = i & 255, p = (i>>8) & 63, h = (i>>14) & 15, c = i >> 18;
  int g = b*SEQL + c*CKS + s;
  float v = XC[(size_t)g*CVD + h*HD + p] * DT[(size_t)g*NH + h];
  XdT[i] = cvt_bf16(v);
}

// Gb[(c*16+h)][l][s] = bf16( (s<=l) ? exp(Ac[l]-Ac[s]) * S[b,c][l][s] : 0 )
__global__ void k_gform(const float* __restrict__ Sf, const float* __restrict__ ACUM,
                        u16* __restrict__ Gb, int b){
  int i = blockIdx.x*256 + threadIdx.x;
  if(i >= 8*16*256*256) return;
  int s = i & 255, l = (i>>8) & 255, h = (i>>16) & 15, c = i >> 20;
  u16 g = 0;
  if(s <= l){
    const float* Ac = ACUM + (size_t)((b*NC+c)*NH + h)*CKS;
    float sv = Sf[(size_t)(b*NC+c)*65536 + l*256 + s];
    g = cvt_bf16(__expf(Ac[l]-Ac[s]) * sv);
  }
  Gb[i] = g;
}

__global__ void k_states(const float* __restrict__ XC, const float* __restrict__ DT,
                         const float* __restrict__ ACUM, float* __restrict__ ST){
  int blk = blockIdx.x;
  int h = blk & 15, c = (blk>>4)&7, b = blk>>7;
  int tid = threadIdx.x;
  int n = tid & 63, pq = tid >> 6;
  __shared__ float Ac[256];
  __shared__ float Bt[32][64];
  __shared__ float Xt[32][64];
  Ac[tid] = ACUM[(size_t)blk*CKS + tid];
  float acc[16];
  #pragma unroll
  for(int k=0;k<16;k++) acc[k]=0.f;
  const float* xcb = XC + (size_t)b*SEQL*CVD;
  for(int st=0; st<8; ++st){
    __syncthreads();
    #pragma unroll
    for(int e=0;e<8;e++){
      int idx = tid + e*256;
      int sl = idx>>6, nn = idx&63;
      int gs = c*CKS + st*32 + sl;
      Bt[sl][nn] = xcb[(size_t)gs*CVD + DIN + nn];
      float dec = expf(Ac[255] - Ac[st*32+sl]);
      Xt[sl][nn] = xcb[(size_t)gs*CVD + h*HD + nn] * DT[(size_t)(b*SEQL+gs)*NH + h] * dec;
    }
    __syncthreads();
    #pragma unroll
    for(int l=0;l<32;l++){
      float bv = Bt[l][n];
      #pragma unroll
      for(int k=0;k<16;k++) acc[k] += bv * Xt[l][pq + 4*k];
    }
  }
  #pragma unroll
  for(int k=0;k<16;k++){
    int p = pq + 4*k;
    ST[(size_t)blk*4096 + p*64 + n] = acc[k];
  }
}

__global__ void k_scan(const float* __restrict__ ST, const float* __restrict__ CDEC,
                       float* __restrict__ PREV){
  int i = blockIdx.x*256 + threadIdx.x;
  if(i >= BS*NH*4096) return;
  int pn = i & 4095;
  int h = (i>>12) & 15;
  int b = i >> 16;
  float run = 0.f;
  for(int c=0;c<8;c++){
    size_t idx = (size_t)((b*8+c)*16+h)*4096 + pn;
    PREV[idx] = run;
    run = run*CDEC[(b*8+c)*16+h] + ST[idx];
  }
}

// ---------------- attention helpers ----------------
__global__ void k_extract(const float* __restrict__ HF, float* __restrict__ QIN,
                          float* __restrict__ CIN){
  int i = blockIdx.x*256 + threadIdx.x;
  if(i >= BS*1024*DM) return;
  int d = i & (DM-1);
  int q = (i>>9) & 1023;
  int b = i >> 19;
  QIN[i] = HF[(size_t)(b*SEQL + 1024 + q)*DM + d];
  CIN[i] = HF[(size_t)(b*SEQL + q)*DM + d];
}

// ---------------- host ----------------
extern "C" void kernel_launch(void* const* d_in, const int* in_sizes, int n_in,
                              void* d_out, int out_size, void* d_ws, size_t ws_size,
                              hipStream_t stream) {
  (void)in_sizes; (void)n_in; (void)out_size; (void)ws_size;
  const float* x_enc     = (const float*)d_in[0];
  const float* in_proj_w = (const float*)d_in[2];
  const float* conv_w    = (const float*)d_in[3];
  const float* conv_b    = (const float*)d_in[4];
  const float* dt_bias   = (const float*)d_in[5];
  const float* A_log     = (const float*)d_in[6];
  const float* D_param   = (const float*)d_in[7];
  const float* gnorm_w   = (const float*)d_in[8];
  const float* out_proj_w= (const float*)d_in[9];
  const float* norm_w    = (const float*)d_in[10];
  const float* norm_b    = (const float*)d_in[11];
  const float* normf_w   = (const float*)d_in[12];
  const float* normf_b   = (const float*)d_in[13];
  const float* ca_nq_w   = (const float*)d_in[14];
  const float* ca_nq_b   = (const float*)d_in[15];
  const float* ca_nkv_w  = (const float*)d_in[16];
  const float* ca_nkv_b  = (const float*)d_in[17];
  const float* ca_qw     = (const float*)d_in[18];
  const float* ca_kw     = (const float*)d_in[19];
  const float* ca_vw     = (const float*)d_in[20];
  const float* ca_ow     = (const float*)d_in[21];
  const float* ca_qb     = (const float*)d_in[22];
  const float* ca_kb     = (const float*)d_in[23];
  const float* ca_vb     = (const float*)d_in[24];
  const float* ca_ob     = (const float*)d_in[25];
  const float* qp_w      = (const float*)d_in[26];
  const float* qp_b      = (const float*)d_in[27];
  const float* cp_w      = (const float*)d_in[28];
  const float* cp_b      = (const float*)d_in[29];
  const float* dec1_w    = (const float*)d_in[30];
  const float* dec1_b    = (const float*)d_in[31];
  const float* dec2_w    = (const float*)d_in[32];
  const float* dec2_b    = (const float*)d_in[33];

  float* W = (float*)d_ws;
  size_t off = 0;
  auto alloc = [&](size_t n){ float* pp = W + off; off += n; return pp; };
  float* RES  = alloc((size_t)NTOK);
  float* H    = alloc((size_t)NTOK);
  float* HN   = alloc((size_t)NTOK);
  float* HNF  = alloc((size_t)NTOK);
  float* ZB   = alloc((size_t)NROWS*DIP);        // 17,956,864
  float* XC   = alloc((size_t)NROWS*CVD);        //  9,437,184
  float* DT   = alloc((size_t)NROWS*NH);
  float* DA   = alloc((size_t)NROWS*NH);
  float* ACUM = alloc((size_t)BS*NC*NH*CKS);
  float* CDEC = alloc((size_t)BS*NC*NH);
  float* Y    = alloc((size_t)NROWS*DIN);        //  8,388,608
  float* ST   = alloc((size_t)BS*NC*NH*4096);
  float* PREV = alloc((size_t)BS*NC*NH*4096);
  float* YD   = alloc((size_t)NTOK);
  float* HF   = alloc((size_t)NTOK);
  // byte-identical to the proven round-1 layout (61,768,192 floats)

  // mamba staging aliases (proven lifetimes):
  u16* Ubf    = (u16*)HF;
  u16* WinTc  = (u16*)(HF + 2097152);
  u16* WoutTc = (u16*)(HF + 2097152 + 561152);
  u16* Ybf    = (u16*)HNF;
  // SSD staging:
  u16*   Bbf    = (u16*)HNF;
  u16*   Cbf    = Bbf + 524288;
  float* Sf     = HNF + 524288;
  u16*   PREVbf = (u16*)Sf;
  u16*   XdTb   = (u16*)(HNF + 2621440);
  u16*   Gb     = (u16*)YD;

  const int TPB = 256;
  const int gTok = (NTOK+TPB-1)/TPB;
  dim3 tb(32,8);

  hipMemcpyAsync(RES, x_enc, (size_t)NTOK*4, hipMemcpyDeviceToDevice, stream);

  for(int layer=0; layer<2; ++layer){
    if(layer>0) k_add_flip<<<gTok,TPB,0,stream>>>(RES, H, 0);
    k_ln<<<NROWS,TPB,0,stream>>>(RES, norm_w + layer*DM, norm_b + layer*DM, HN);
    hipMemsetAsync(H, 0, (size_t)NTOK*4, stream);
    for(int dir=0; dir<2; ++dir){
      int idx = layer*2 + dir;
      const float* cw   = conv_w   + (size_t)idx*CVD*4;
      const float* cb   = conv_b   + (size_t)idx*CVD;
      const float* dtb  = dt_bias  + (size_t)idx*NH;
      const float* Alog = A_log    + (size_t)idx*NH;
      const float* Dp   = D_param  + (size_t)idx*NH;
      const float* gw   = gnorm_w  + (size_t)idx*DIN;

      if(dir==0){
        k_cvt<<<(NTOK/4+TPB-1)/TPB,TPB,0,stream>>>(HN, Ubf, NTOK/4);
      }else{
        k_flip<<<gTok,TPB,0,stream>>>(HNF, HN);
        k_cvt<<<(NTOK/4+TPB-1)/TPB,TPB,0,stream>>>(HNF, Ubf, NTOK/4);
      }
      k_wt2<<<dim3(69,16),tb,0,stream>>>(in_proj_w + (size_t)idx*DM*DIP, WinTc, 512, 2192, 2192);
      k_mg<<<dim3(18,64),256,0,stream>>>(Ubf, WinTc, ZB, 8192, 2192, 512, 512, 512, 2192);

      k_conv<<<(BS*SEQL*CVD+TPB-1)/TPB,TPB,0,stream>>>(ZB, cw, cb, XC);
      k_dt<<<(BS*SEQL*NH+TPB-1)/TPB,TPB,0,stream>>>(ZB, dtb, Alog, DT, DA);
      k_acum<<<BS*NC*NH,256,0,stream>>>(DA, ACUM, CDEC);

      // ---- Y_diag via MFMA ----
      k_bc<<<(NROWS*DST+TPB-1)/TPB,TPB,0,stream>>>(XC, Bbf, Cbf);
      k_mgb<<<dim3(2,2,32),256,0,stream>>>(Cbf, Bbf, Sf,
            256, 256, 64, 64, 64, 256, 16384, 16384, 65536, 0, 0);
      for(int bb=0; bb<BS; ++bb){
        k_xdt<<<(2097152+TPB-1)/TPB,TPB,0,stream>>>(XC, DT, XdTb, bb);
        k_gform<<<(8388608+TPB-1)/TPB,TPB,0,stream>>>(Sf, ACUM, Gb, bb);
        k_mgb<<<dim3(1,2,128),256,0,stream>>>(Gb, XdTb, Y + (size_t)bb*2097152,
              256, 64, 256, 256, 256, 1024, 65536, 16384, 262144, 64, 4);
      }

      k_states<<<BS*NC*NH,256,0,stream>>>(XC, DT, ACUM, ST);
      k_scan<<<(BS*NH*4096+TPB-1)/TPB,TPB,0,stream>>>(ST, CDEC, PREV);
      // ---- Y_off via MFMA + fused gate epilogue ----
      k_cvt<<<(2097152/4+TPB-1)/TPB,TPB,0,stream>>>(PREV, PREVbf, 2097152/4);
      k_mgy<<<dim3(8,2,32),256,0,stream>>>(Cbf, PREVbf, ACUM, XC, ZB, Dp, Y);

      k_rms<<<NROWS,256,0,stream>>>(Y, gw);

      k_cvt<<<(2097152+TPB-1)/TPB,TPB,0,stream>>>(Y, Ybf, 2097152);
      k_wt2<<<dim3(16,32),tb,0,stream>>>(out_proj_w + (size_t)idx*DIN*DM, WoutTc, 1024, 512, 512);
      k_mg<<<dim3(4,64),256,0,stream>>>(Ybf, WoutTc, YD, 8192, 512, 1024, 1024, 1024, 512);

      k_add_flip<<<gTok,TPB,0,stream>>>(H, YD, dir);
    }
  }
  k_add_flip<<<gTok,TPB,0,stream>>>(RES, H, 0);
  k_ln<<<NROWS,TPB,0,stream>>>(RES, normf_w, normf_b, HF);

  // ================= attention head — MFMA (batched) =================
  float* P0   = ZB;
  float* QIN  = P0 + 0;
  float* CIN  = P0 + 2097152;
  float* QPb  = P0 + 4194304;
  float* CPb  = P0 + 6291456;
  float* QN   = P0 + 8388608;
  float* CN   = P0 + 10485760;
  float* AO   = P0 + 12582912;
  float* O1   = P0 + 14680064;
  float* D1   = P0 + 16777216;
  float* VV   = D1;
  u16* U0     = (u16*)(P0 + 20971520);
  u16* Qbf    = U0 + 0;
  u16* Cbf2   = U0 + 2097152;
  u16* QNbf   = U0 + 4194304;
  u16* CNbf   = U0 + 6291456;
  u16* QQbf   = U0 + 8388608;
  u16* KKbf   = U0 + 10485760;
  u16* VTbf   = U0 + 12582912;
  u16* AObf   = U0 + 14680064;
  u16* O1bf   = U0 + 16777216;
  u16* qpT    = U0 + 18874368;
  u16* cpT    = qpT + 262144;
  u16* qwT    = qpT + 524288;
  u16* kwT    = qpT + 786432;
  u16* vwT    = qpT + 1048576;
  u16* owT    = qpT + 1310720;
  u16* dec1T  = qpT + 1572864;
  u16* Pbf    = qpT + 2097152;

  const int M2 = BS*1024;
  k_extract<<<(BS*1024*DM+TPB-1)/TPB,TPB,0,stream>>>(HF, QIN, CIN);
  k_cvt<<<(2097152/4+TPB-1)/TPB,TPB,0,stream>>>(QIN, Qbf, 2097152/4);
  k_cvt<<<(2097152/4+TPB-1)/TPB,TPB,0,stream>>>(CIN, Cbf2, 2097152/4);
  k_wt2<<<dim3(16,16),tb,0,stream>>>(qp_w, qpT, 512, 512, 512);
  k_wt2<<<dim3(16,16),tb,0,stream>>>(cp_w, cpT, 512, 512, 512);
  k_wt2<<<dim3(16,16),tb,0,stream>>>(ca_qw, qwT, 512, 512, 512);
  k_wt2<<<dim3(16,16),tb,0,stream>>>(ca_kw, kwT, 512, 512, 512);
  k_wt2<<<dim3(16,16),tb,0,stream>>>(ca_vw, vwT, 512, 512, 512);
  k_wt2<<<dim3(16,16),tb,0,stream>>>(ca_ow, owT, 512, 512, 512);
  k_wt2<<<dim3(32,16),tb,0,stream>>>(dec1_w, dec1T, 512, 1024, 1024);

  k_mge<<<dim3(4,32),256,0,stream>>>(Qbf, qpT, qp_b, nullptr, QPb, nullptr,
                                     M2, 512, 512, 512, 512, 512, 1.f, 0);
  k_mge<<<dim3(4,32),256,0,stream>>>(Cbf2, cpT, cp_b, nullptr, CPb, nullptr,
                                     M2, 512, 512, 512, 512, 512, 1.f, 0);
  k_ln<<<M2,TPB,0,stream>>>(QPb, ca_nq_w, ca_nq_b, QN);
  k_ln<<<M2,TPB,0,stream>>>(CPb, ca_nkv_w, ca_nkv_b, CN);
  k_cvt<<<(2097152/4+TPB-1)/TPB,TPB,0,stream>>>(QN, QNbf, 2097152/4);
  k_cvt<<<(2097152/4+TPB-1)/TPB,TPB,0,stream>>>(CN, CNbf, 2097152/4);
  k_mge<<<dim3(4,32),256,0,stream>>>(QNbf, qwT, ca_qb, nullptr, nullptr, QQbf,
                                     M2, 512, 512, 512, 512, 512, 1.f, 0);
  k_mge<<<dim3(4,32),256,0,stream>>>(CNbf, kwT, ca_kb, nullptr, nullptr, KKbf,
                                     M2, 512, 512, 512, 512, 512, 1.f, 0);
  k_mge<<<dim3(4,32),256,0,stream>>>(CNbf, vwT, ca_vb, nullptr, VV, nullptr,
                                     M2, 512, 512, 512, 512, 512, 1.f, 0);
  // batched V^T: one dispatch
  k_vtb<<<dim3(4,32,16),tb,0,stream>>>(VV, VTbf);
  // batched scores: one dispatch, z=(b*4+h)
  const float scl = 0.088388347648318447f;
  k_mgab<<<dim3(8,8,16),256,0,stream>>>(QQbf, KKbf, nullptr, Pbf,
        1024, 1024, 128, 512, 512, 1024,
        524288, 128, 524288, 128, 4194304, 1048576, scl);
  k_sm<<<16384,256,0,stream>>>(Pbf);
  // batched PV: one dispatch
  k_mgab<<<dim3(1,8,16),256,0,stream>>>(Pbf, VTbf, AO, nullptr,
        1024, 128, 1024, 1024, 1024, 512,
        4194304, 1048576, 524288, 131072, 524288, 128, 1.f);
  k_cvt<<<(2097152/4+TPB-1)/TPB,TPB,0,stream>>>(AO, AObf, 2097152/4);
  k_mge<<<dim3(4,32),256,0,stream>>>(AObf, owT, ca_ob, QPb, O1, nullptr,
                                     M2, 512, 512, 512, 512, 512, 1.f, 0);
  k_cvt<<<(2097152/4+TPB-1)/TPB,TPB,0,stream>>>(O1, O1bf, 2097152/4);
  k_mge<<<dim3(8,32),256,0,stream>>>(O1bf, dec1T, dec1_b, nullptr, D1, nullptr,
                                     M2, 1024, 512, 512, 512, 1024, 1.f, 1);
  // dec2: dedicated reduction kernel
  k_dec2<<<M2,256,0,stream>>>(D1, dec2_w, dec2_b, (float*)d_out);
}

// Round 14
// 1732.653 us; speedup vs baseline: 187.5108x; 1.2362x over previous
//
#include <hip/hip_runtime.h>
#include <hip/hip_bf16.h>

#define BS 4
#define SEQL 2048
#define DM 512
#define DIN 1024
#define NH 16
#define HD 64
#define DST 64
#define NC 8
#define CKS 256
#define DIP 2192
#define CVD 1152
#define NROWS (BS*SEQL)          /* 8192 */
#define NTOK (BS*SEQL*DM)        /* 4194304 */

typedef unsigned short u16;
typedef __bf16 bf16x8 __attribute__((ext_vector_type(8)));
typedef float f32x4 __attribute__((ext_vector_type(4)));

__device__ __forceinline__ u16 cvt_bf16(float f){
  unsigned int x = __float_as_uint(f);
  unsigned int r = x + 0x7fffu + ((x>>16)&1u);
  return (u16)(r>>16);
}
__device__ __forceinline__ float bf2f(u16 u){
  return __uint_as_float(((unsigned int)u)<<16);
}

// ---------------- elementwise (proven) ----------------
__global__ void k_add_flip(float* __restrict__ dst, const float* __restrict__ src, int flip){
  int i = blockIdx.x*256 + threadIdx.x;
  if(i >= NTOK) return;
  int d = i & (DM-1);
  int l = (i >> 9) & (SEQL-1);
  int b = i >> 20;
  int sl = flip ? (SEQL-1-l) : l;
  dst[i] += src[(b*SEQL + sl)*DM + d];
}

__global__ void k_flip(float* __restrict__ dst, const float* __restrict__ src){
  int i = blockIdx.x*256 + threadIdx.x;
  if(i >= NTOK) return;
  int d = i & (DM-1);
  int l = (i >> 9) & (SEQL-1);
  int b = i >> 20;
  dst[i] = src[(b*SEQL + (SEQL-1-l))*DM + d];
}

// f32 -> bf16 (verified round-8)
__global__ void k_cvt(const float* __restrict__ src, u16* __restrict__ dst, int n4){
  int i = blockIdx.x*256 + threadIdx.x;
  if(i >= n4) return;
  float4 f = reinterpret_cast<const float4*>(src)[i];
  ushort4 o; o.x=cvt_bf16(f.x); o.y=cvt_bf16(f.y); o.z=cvt_bf16(f.z); o.w=cvt_bf16(f.w);
  reinterpret_cast<ushort4*>(dst)[i] = o;
}

__global__ void k_ln(const float* __restrict__ X, const float* __restrict__ w,
                     const float* __restrict__ bb, float* __restrict__ O){
  int row = blockIdx.x, tid = threadIdx.x;
  const float* x = X + (size_t)row*DM;
  float* o = O + (size_t)row*DM;
  float s=0.f, s2=0.f;
  for(int j=tid;j<DM;j+=256){ float v=x[j]; s+=v; s2+=v*v; }
  __shared__ float r1[256], r2[256];
  r1[tid]=s; r2[tid]=s2; __syncthreads();
  for(int off=128;off>0;off>>=1){
    if(tid<off){ r1[tid]+=r1[tid+off]; r2[tid]+=r2[tid+off]; }
    __syncthreads();
  }
  float m = r1[0]*(1.f/DM);
  float var = r2[0]*(1.f/DM) - m*m;
  float inv = rsqrtf(var + 1e-5f);
  for(int j=tid;j<DM;j+=256) o[j] = (x[j]-m)*inv*w[j] + bb[j];
}

__global__ void k_rms(float* __restrict__ Y, const float* __restrict__ gw){
  int row = blockIdx.x, tid = threadIdx.x;
  float* y = Y + (size_t)row*DIN;
  float ss=0.f;
  for(int j=tid;j<DIN;j+=256){ float v=y[j]; ss+=v*v; }
  __shared__ float red[256];
  red[tid]=ss; __syncthreads();
  for(int off=128;off>0;off>>=1){
    if(tid<off) red[tid]+=red[tid+off];
    __syncthreads();
  }
  float inv = rsqrtf(red[0]*(1.f/DIN) + 1e-5f);
  for(int j=tid;j<DIN;j+=256) y[j] = y[j]*inv*gw[j];
}

// dec2: out[row][0..9] = D1[row]·dec2_w + b ; one block per row
__global__ void k_dec2(const float* __restrict__ D1, const float* __restrict__ w,
                       const float* __restrict__ bb, float* __restrict__ out){
  int row = blockIdx.x, tid = threadIdx.x;
  int lane = tid & 63, wave = tid >> 6;
  const float* x = D1 + (size_t)row*1024;
  float acc[10];
  #pragma unroll
  for(int o=0;o<10;o++) acc[o]=0.f;
  for(int j=tid;j<1024;j+=256){
    float v = x[j];
    const float* wr = w + (size_t)j*10;
    #pragma unroll
    for(int o=0;o<10;o++) acc[o] += v*wr[o];
  }
  __shared__ float red[4][10];
  #pragma unroll
  for(int o=0;o<10;o++){
    float v = acc[o];
    #pragma unroll
    for(int s=32;s>0;s>>=1) v += __shfl_down(v, s, 64);
    if(lane==0) red[wave][o] = v;
  }
  __syncthreads();
  if(tid < 10)
    out[(size_t)row*10 + tid] = red[0][tid]+red[1][tid]+red[2][tid]+red[3][tid] + bb[tid];
}

// transpose-convert with explicit src ld (verified): src[K][lds] f32 -> dst[N][K] bf16
__global__ void k_wt2(const float* __restrict__ src, u16* __restrict__ dst,
                      int K, int N, int lds){
  __shared__ float t[32][33];
  int n0 = blockIdx.x*32, k0 = blockIdx.y*32;
  int tx = threadIdx.x, ty = threadIdx.y;
  #pragma unroll
  for(int i=0;i<32;i+=8){
    int k = k0+ty+i, n = n0+tx;
    t[ty+i][tx] = (n<N) ? src[(size_t)k*lds+n] : 0.f;
  }
  __syncthreads();
  #pragma unroll
  for(int i=0;i<32;i+=8){
    int n = n0+ty+i, k = k0+tx;
    if(n<N) dst[(size_t)n*K+k] = cvt_bf16(t[tx][ty+i]);
  }
}

// batched V-transpose: per z=(b*4+h): src=VV+b*524288+h*128 [1024][128 of 512] -> dst [128][1024]
__global__ void k_vtb(const float* __restrict__ VV, u16* __restrict__ VT){
  __shared__ float t[32][33];
  int z = blockIdx.z, b = z>>2, h = z&3;
  const float* src = VV + (size_t)b*524288 + h*128;
  u16* dst = VT + (size_t)z*131072;
  int n0 = blockIdx.x*32, k0 = blockIdx.y*32;
  int tx = threadIdx.x, ty = threadIdx.y;
  #pragma unroll
  for(int i=0;i<32;i+=8){
    int k = k0+ty+i, n = n0+tx;
    t[ty+i][tx] = src[(size_t)k*512+n];
  }
  __syncthreads();
  #pragma unroll
  for(int i=0;i<32;i+=8){
    int n = n0+ty+i, k = k0+tx;
    dst[(size_t)n*1024+k] = cvt_bf16(t[tx][ty+i]);
  }
}

// ---------------- MFMA bf16 GEMM, emap0 (HW-verified) ----------------
__global__ __launch_bounds__(256) void k_mg(
    const u16* __restrict__ A, const u16* __restrict__ BT,
    float* __restrict__ C, int M, int N, int K, int lda, int ldb, int ldc)
{
  __shared__ uint4 As4[128*5];
  __shared__ uint4 Bs4[128*5];
  const int tid = threadIdx.x;
  const int row0 = blockIdx.y*128, col0 = blockIdx.x*128;
  const int lane = tid & 63, wave = tid >> 6;
  const int wm = wave >> 1, wn = wave & 1;
  const int lr = lane & 15, ksg = (lane >> 4);
  f32x4 acc[4][4];
  #pragma unroll
  for(int i=0;i<4;i++)
    #pragma unroll
    for(int j=0;j<4;j++) acc[i][j] = (f32x4){0.f,0.f,0.f,0.f};
  for(int k0=0;k0<K;k0+=32){
    #pragma unroll
    for(int i=0;i<2;i++){
      int t2 = tid + i*256;
      int rr = t2 >> 2, sg = (t2 & 3);
      uint4 av = *reinterpret_cast<const uint4*>(A + (size_t)(row0+rr)*lda + k0 + sg*8);
      uint4 bv = {0u,0u,0u,0u};
      if(col0+rr < N) bv = *reinterpret_cast<const uint4*>(BT + (size_t)(col0+rr)*ldb + k0 + sg*8);
      As4[rr*5 + sg] = av;
      Bs4[rr*5 + sg] = bv;
    }
    __syncthreads();
    bf16x8 afr[4], bfr[4];
    #pragma unroll
    for(int i=0;i<4;i++) afr[i] = *reinterpret_cast<const bf16x8*>(&As4[(wm*64+i*16+lr)*5 + ksg]);
    #pragma unroll
    for(int j=0;j<4;j++) bfr[j] = *reinterpret_cast<const bf16x8*>(&Bs4[(wn*64+j*16+lr)*5 + ksg]);
    #pragma unroll
    for(int i=0;i<4;i++)
      #pragma unroll
      for(int j=0;j<4;j++)
        acc[i][j] = __builtin_amdgcn_mfma_f32_16x16x32_bf16(afr[i], bfr[j], acc[i][j], 0, 0, 0);
    __syncthreads();
  }
  const int hi = lane >> 4, lo = lane & 15;
  #pragma unroll
  for(int i=0;i<4;i++)
    #pragma unroll
    for(int j=0;j<4;j++)
      #pragma unroll
      for(int r=0;r<4;r++){
        int row = row0 + wm*64 + i*16 + 4*hi + r;
        int col = col0 + wn*64 + j*16 + lo;
        if(col < N) C[(size_t)row*ldc + col] = acc[i][j][r];
      }
}

// batched variant: verified core + z-strided base offsets only
__global__ __launch_bounds__(256) void k_mgb(
    const u16* __restrict__ A0, const u16* __restrict__ BT0,
    float* __restrict__ C0, int M, int N, int K, int lda, int ldb, int ldc,
    long sAz, long sBz, long sCo, long sCi, int shC)
{
  const int z = blockIdx.z;
  const u16* A  = A0  + (size_t)z*sAz;
  const u16* BT = BT0 + (size_t)z*sBz;
  float* C = C0 + (size_t)(z>>shC)*sCo + (size_t)(z & ((1<<shC)-1))*sCi;
  __shared__ uint4 As4[128*5];
  __shared__ uint4 Bs4[128*5];
  const int tid = threadIdx.x;
  const int row0 = blockIdx.y*128, col0 = blockIdx.x*128;
  const int lane = tid & 63, wave = tid >> 6;
  const int wm = wave >> 1, wn = wave & 1;
  const int lr = lane & 15, ksg = (lane >> 4);
  f32x4 acc[4][4];
  #pragma unroll
  for(int i=0;i<4;i++)
    #pragma unroll
    for(int j=0;j<4;j++) acc[i][j] = (f32x4){0.f,0.f,0.f,0.f};
  for(int k0=0;k0<K;k0+=32){
    #pragma unroll
    for(int i=0;i<2;i++){
      int t2 = tid + i*256;
      int rr = t2 >> 2, sg = (t2 & 3);
      uint4 av = *reinterpret_cast<const uint4*>(A + (size_t)(row0+rr)*lda + k0 + sg*8);
      uint4 bv = {0u,0u,0u,0u};
      if(col0+rr < N) bv = *reinterpret_cast<const uint4*>(BT + (size_t)(col0+rr)*ldb + k0 + sg*8);
      As4[rr*5 + sg] = av;
      Bs4[rr*5 + sg] = bv;
    }
    __syncthreads();
    bf16x8 afr[4], bfr[4];
    #pragma unroll
    for(int i=0;i<4;i++) afr[i] = *reinterpret_cast<const bf16x8*>(&As4[(wm*64+i*16+lr)*5 + ksg]);
    #pragma unroll
    for(int j=0;j<4;j++) bfr[j] = *reinterpret_cast<const bf16x8*>(&Bs4[(wn*64+j*16+lr)*5 + ksg]);
    #pragma unroll
    for(int i=0;i<4;i++)
      #pragma unroll
      for(int j=0;j<4;j++)
        acc[i][j] = __builtin_amdgcn_mfma_f32_16x16x32_bf16(afr[i], bfr[j], acc[i][j], 0, 0, 0);
    __syncthreads();
  }
  const int hi = lane >> 4, lo = lane & 15;
  #pragma unroll
  for(int i=0;i<4;i++)
    #pragma unroll
    for(int j=0;j<4;j++)
      #pragma unroll
      for(int r=0;r<4;r++){
        int row = row0 + wm*64 + i*16 + 4*hi + r;
        int col = col0 + wn*64 + j*16 + lo;
        if(col < N) C[(size_t)row*ldc + col] = acc[i][j][r];
      }
}

// Y_diag GEMM with fused G-formation in A-staging:
// per z=(b*8+c)*16+h: A[l][s] = (s<=l ? exp(Ac[l]-Ac[s]) : 0) * Sf[b*8+c][l][s]  (bf16)
// B = XdT[z] ([64][256] bf16), C += into Y[b][c*256+l][h*64+p]  (plain store; Y_diag is first writer)
__global__ __launch_bounds__(256) void k_mgg(
    const float* __restrict__ Sf, const float* __restrict__ ACUM,
    const u16* __restrict__ XdT, float* __restrict__ Y)
{
  const int z = blockIdx.z;
  const int h = z & 15, bc = z >> 4;
  const int b = bc >> 3, c = bc & 7;
  const float* Az = Sf + (size_t)bc*65536;
  const float* Acp = ACUM + (size_t)z*256;
  const u16* BT = XdT + (size_t)z*16384;
  float* Cp = Y + (size_t)b*2097152 + (size_t)c*262144 + h*64;
  __shared__ uint4 As4[128*5];
  __shared__ uint4 Bs4[128*5];
  __shared__ float AcS[256];
  const int tid = threadIdx.x;
  AcS[tid] = Acp[tid];
  __syncthreads();
  const int row0 = blockIdx.y*128;
  const int lane = tid & 63, wave = tid >> 6;
  const int wm = wave >> 1, wn = wave & 1;
  const int lr = lane & 15, ksg = (lane >> 4);
  f32x4 acc[4][4];
  #pragma unroll
  for(int i=0;i<4;i++)
    #pragma unroll
    for(int j=0;j<4;j++) acc[i][j] = (f32x4){0.f,0.f,0.f,0.f};
  for(int k0=0;k0<256;k0+=32){
    #pragma unroll
    for(int i=0;i<2;i++){
      int t2 = tid + i*256;
      int rr = t2 >> 2, sg = (t2 & 3);
      int l = row0 + rr;
      int sbase = k0 + sg*8;
      float4 v0 = *reinterpret_cast<const float4*>(Az + (size_t)l*256 + sbase);
      float4 v1 = *reinterpret_cast<const float4*>(Az + (size_t)l*256 + sbase + 4);
      float acl = AcS[l];
      float vv[8] = {v0.x,v0.y,v0.z,v0.w,v1.x,v1.y,v1.z,v1.w};
      u16 gbuf[8];
      #pragma unroll
      for(int e=0;e<8;e++){
        int s = sbase + e;
        float g = 0.f;
        if(s <= l) g = __expf(acl - AcS[s]) * vv[e];
        gbuf[e] = cvt_bf16(g);
      }
      As4[rr*5 + sg] = *reinterpret_cast<uint4*>(gbuf);
      uint4 bv = {0u,0u,0u,0u};
      if(rr < 64) bv = *reinterpret_cast<const uint4*>(BT + (size_t)rr*256 + sbase);
      Bs4[rr*5 + sg] = bv;
    }
    __syncthreads();
    bf16x8 afr[4], bfr[4];
    #pragma unroll
    for(int i=0;i<4;i++) afr[i] = *reinterpret_cast<const bf16x8*>(&As4[(wm*64+i*16+lr)*5 + ksg]);
    #pragma unroll
    for(int j=0;j<4;j++) bfr[j] = *reinterpret_cast<const bf16x8*>(&Bs4[(wn*64+j*16+lr)*5 + ksg]);
    #pragma unroll
    for(int i=0;i<4;i++)
      #pragma unroll
      for(int j=0;j<4;j++)
        acc[i][j] = __builtin_amdgcn_mfma_f32_16x16x32_bf16(afr[i], bfr[j], acc[i][j], 0, 0, 0);
    __syncthreads();
  }
  const int hi = lane >> 4, lo = lane & 15;
  #pragma unroll
  for(int i=0;i<4;i++)
    #pragma unroll
    for(int j=0;j<4;j++)
      #pragma unroll
      for(int r=0;r<4;r++){
        int row = row0 + wm*64 + i*16 + 4*hi + r;
        int col = wn*64 + j*16 + lo;
        if(col < 64) Cp[(size_t)row*1024 + col] = acc[i][j][r];
      }
}

// batched attention GEMM: (z>>2)/(z&3) offsets for A/B/C, scale, f32 or bf16 out
__global__ __launch_bounds__(256) void k_mgab(
    const u16* __restrict__ A0, const u16* __restrict__ BT0,
    float* __restrict__ C0, u16* __restrict__ Cb0,
    int M, int N, int K, int lda, int ldb, int ldc,
    long sAo, long sAi, long sBo, long sBi, long sCo, long sCi, float scale)
{
  const int z = blockIdx.z;
  const u16* A  = A0  + (size_t)(z>>2)*sAo + (size_t)(z&3)*sAi;
  const u16* BT = BT0 + (size_t)(z>>2)*sBo + (size_t)(z&3)*sBi;
  const size_t offC = (size_t)(z>>2)*sCo + (size_t)(z&3)*sCi;
  __shared__ uint4 As4[128*5];
  __shared__ uint4 Bs4[128*5];
  const int tid = threadIdx.x;
  const int row0 = blockIdx.y*128, col0 = blockIdx.x*128;
  const int lane = tid & 63, wave = tid >> 6;
  const int wm = wave >> 1, wn = wave & 1;
  const int lr = lane & 15, ksg = (lane >> 4);
  f32x4 acc[4][4];
  #pragma unroll
  for(int i=0;i<4;i++)
    #pragma unroll
    for(int j=0;j<4;j++) acc[i][j] = (f32x4){0.f,0.f,0.f,0.f};
  for(int k0=0;k0<K;k0+=32){
    #pragma unroll
    for(int i=0;i<2;i++){
      int t2 = tid + i*256;
      int rr = t2 >> 2, sg = (t2 & 3);
      uint4 av = *reinterpret_cast<const uint4*>(A + (size_t)(row0+rr)*lda + k0 + sg*8);
      uint4 bv = {0u,0u,0u,0u};
      if(col0+rr < N) bv = *reinterpret_cast<const uint4*>(BT + (size_t)(col0+rr)*ldb + k0 + sg*8);
      As4[rr*5 + sg] = av;
      Bs4[rr*5 + sg] = bv;
    }
    __syncthreads();
    bf16x8 afr[4], bfr[4];
    #pragma unroll
    for(int i=0;i<4;i++) afr[i] = *reinterpret_cast<const bf16x8*>(&As4[(wm*64+i*16+lr)*5 + ksg]);
    #pragma unroll
    for(int j=0;j<4;j++) bfr[j] = *reinterpret_cast<const bf16x8*>(&Bs4[(wn*64+j*16+lr)*5 + ksg]);
    #pragma unroll
    for(int i=0;i<4;i++)
      #pragma unroll
      for(int j=0;j<4;j++)
        acc[i][j] = __builtin_amdgcn_mfma_f32_16x16x32_bf16(afr[i], bfr[j], acc[i][j], 0, 0, 0);
    __syncthreads();
  }
  const int hi = lane >> 4, lo = lane & 15;
  #pragma unroll
  for(int i=0;i<4;i++)
    #pragma unroll
    for(int j=0;j<4;j++)
      #pragma unroll
      for(int r=0;r<4;r++){
        int row = row0 + wm*64 + i*16 + 4*hi + r;
        int col = col0 + wn*64 + j*16 + lo;
        if(col < N){
          float v = acc[i][j][r] * scale;
          size_t ci = offC + (size_t)row*ldc + col;
          if(C0) C0[ci] = v;
          else   Cb0[ci] = cvt_bf16(v);
        }
      }
}

// Y_off GEMM fused with yfinal epilogue
__global__ __launch_bounds__(256) void k_mgy(
    const u16* __restrict__ Cb0, const u16* __restrict__ PV0,
    const float* __restrict__ ACUM, const float* __restrict__ XCp,
    const float* __restrict__ ZBp, const float* __restrict__ Dp,
    float* __restrict__ Y)
{
  const int z = blockIdx.z;                 // b*8+c
  const int b = z>>3, c = z&7;
  const u16* A  = Cb0 + (size_t)z*16384;    // [256][64] bf16
  const u16* BT = PV0 + (size_t)z*65536;    // [1024][64] bf16
  const int N = 1024;
  __shared__ uint4 As4[128*5];
  __shared__ uint4 Bs4[128*5];
  const int tid = threadIdx.x;
  const int row0 = blockIdx.y*128, col0 = blockIdx.x*128;
  const int lane = tid & 63, wave = tid >> 6;
  const int wm = wave >> 1, wn = wave & 1;
  const int lr = lane & 15, ksg = (lane >> 4);
  f32x4 acc[4][4];
  #pragma unroll
  for(int i=0;i<4;i++)
    #pragma unroll
    for(int j=0;j<4;j++) acc[i][j] = (f32x4){0.f,0.f,0.f,0.f};
  for(int k0=0;k0<64;k0+=32){
    #pragma unroll
    for(int i=0;i<2;i++){
      int t2 = tid + i*256;
      int rr = t2 >> 2, sg = (t2 & 3);
      uint4 av = *reinterpret_cast<const uint4*>(A + (size_t)(row0+rr)*64 + k0 + sg*8);
      uint4 bv = {0u,0u,0u,0u};
      if(col0+rr < N) bv = *reinterpret_cast<const uint4*>(BT + (size_t)(col0+rr)*64 + k0 + sg*8);
      As4[rr*5 + sg] = av;
      Bs4[rr*5 + sg] = bv;
    }
    __syncthreads();
    bf16x8 afr[4], bfr[4];
    #pragma unroll
    for(int i=0;i<4;i++) afr[i] = *reinterpret_cast<const bf16x8*>(&As4[(wm*64+i*16+lr)*5 + ksg]);
    #pragma unroll
    for(int j=0;j<4;j++) bfr[j] = *reinterpret_cast<const bf16x8*>(&Bs4[(wn*64+j*16+lr)*5 + ksg]);
    #pragma unroll
    for(int i=0;i<4;i++)
      #pragma unroll
      for(int j=0;j<4;j++)
        acc[i][j] = __builtin_amdgcn_mfma_f32_16x16x32_bf16(afr[i], bfr[j], acc[i][j], 0, 0, 0);
    __syncthreads();
  }
  const int hi = lane >> 4, lo = lane & 15;
  #pragma unroll
  for(int i=0;i<4;i++)
    #pragma unroll
    for(int j=0;j<4;j++)
      #pragma unroll
      for(int r=0;r<4;r++){
        int row = row0 + wm*64 + i*16 + 4*hi + r;
        int col = col0 + wn*64 + j*16 + lo;
        int h = col >> 6;
        int g = b*SEQL + c*CKS + row;
        float ac = ACUM[((size_t)z*NH + h)*CKS + row];
        float xh = XCp[(size_t)g*CVD + col];
        float zg = ZBp[(size_t)g*DIP + col];
        size_t ci = (size_t)g*DIN + col;
        float v = Y[ci] + expf(ac)*acc[i][j][r] + Dp[h]*xh;
        float sig = 1.f/(1.f+expf(-zg));
        Y[ci] = v * (zg*sig);
      }
}

// verified core + arithmetic epilogue (attention projections)
__global__ __launch_bounds__(256) void k_mge(
    const u16* __restrict__ A, const u16* __restrict__ BT,
    const float* __restrict__ bias, const float* __restrict__ res,
    float* __restrict__ C, u16* __restrict__ Cbf,
    int M, int N, int K, int lda, int ldb, int ldc, float scale, int act)
{
  __shared__ uint4 As4[128*5];
  __shared__ uint4 Bs4[128*5];
  const int tid = threadIdx.x;
  const int row0 = blockIdx.y*128, col0 = blockIdx.x*128;
  const int lane = tid & 63, wave = tid >> 6;
  const int wm = wave >> 1, wn = wave & 1;
  const int lr = lane & 15, ksg = (lane >> 4);
  f32x4 acc[4][4];
  #pragma unroll
  for(int i=0;i<4;i++)
    #pragma unroll
    for(int j=0;j<4;j++) acc[i][j] = (f32x4){0.f,0.f,0.f,0.f};
  for(int k0=0;k0<K;k0+=32){
    #pragma unroll
    for(int i=0;i<2;i++){
      int t2 = tid + i*256;
      int rr = t2 >> 2, sg = (t2 & 3);
      uint4 av = *reinterpret_cast<const uint4*>(A + (size_t)(row0+rr)*lda + k0 + sg*8);
      uint4 bv = {0u,0u,0u,0u};
      if(col0+rr < N) bv = *reinterpret_cast<const uint4*>(BT + (size_t)(col0+rr)*ldb + k0 + sg*8);
      As4[rr*5 + sg] = av;
      Bs4[rr*5 + sg] = bv;
    }
    __syncthreads();
    bf16x8 afr[4], bfr[4];
    #pragma unroll
    for(int i=0;i<4;i++) afr[i] = *reinterpret_cast<const bf16x8*>(&As4[(wm*64+i*16+lr)*5 + ksg]);
    #pragma unroll
    for(int j=0;j<4;j++) bfr[j] = *reinterpret_cast<const bf16x8*>(&Bs4[(wn*64+j*16+lr)*5 + ksg]);
    #pragma unroll
    for(int i=0;i<4;i++)
      #pragma unroll
      for(int j=0;j<4;j++)
        acc[i][j] = __builtin_amdgcn_mfma_f32_16x16x32_bf16(afr[i], bfr[j], acc[i][j], 0, 0, 0);
    __syncthreads();
  }
  const int hi = lane >> 4, lo = lane & 15;
  #pragma unroll
  for(int i=0;i<4;i++)
    #pragma unroll
    for(int j=0;j<4;j++)
      #pragma unroll
      for(int r=0;r<4;r++){
        int row = row0 + wm*64 + i*16 + 4*hi + r;
        int col = col0 + wn*64 + j*16 + lo;
        if(col < N){
          float v = acc[i][j][r];
          if(bias) v += bias[col];
          v *= scale;
          if(act==1) v = 0.5f*v*(1.f+erff(v*0.70710678118654752f));
          size_t ci = (size_t)row*ldc + col;
          if(res) v += res[ci];
          if(C) C[ci] = v;
          else  Cbf[ci] = cvt_bf16(v);
        }
      }
}

// in-place row softmax over 1024 bf16
__global__ void k_sm(u16* __restrict__ S){
  size_t row = blockIdx.x;
  u16* p = S + row*1024;
  int tid = threadIdx.x;
  ushort4 u = reinterpret_cast<ushort4*>(p)[tid];
  float v0=bf2f(u.x), v1=bf2f(u.y), v2=bf2f(u.z), v3=bf2f(u.w);
  float m = fmaxf(fmaxf(v0,v1),fmaxf(v2,v3));
  __shared__ float red[256];
  red[tid]=m; __syncthreads();
  for(int o=128;o>0;o>>=1){ if(tid<o) red[tid]=fmaxf(red[tid],red[tid+o]); __syncthreads(); }
  m = red[0]; __syncthreads();
  v0=__expf(v0-m); v1=__expf(v1-m); v2=__expf(v2-m); v3=__expf(v3-m);
  float s = v0+v1+v2+v3;
  red[tid]=s; __syncthreads();
  for(int o=128;o>0;o>>=1){ if(tid<o) red[tid]+=red[tid+o]; __syncthreads(); }
  float inv = 1.f/red[0];
  ushort4 o4; o4.x=cvt_bf16(v0*inv); o4.y=cvt_bf16(v1*inv); o4.z=cvt_bf16(v2*inv); o4.w=cvt_bf16(v3*inv);
  reinterpret_cast<ushort4*>(p)[tid] = o4;
}

// ---------------- mamba pieces ----------------
// conv: 4 seq positions per thread (7-tap window), cuts re-fetch
__global__ void k_conv4(const float* __restrict__ ZB, const float* __restrict__ cw,
                        const float* __restrict__ cb, float* __restrict__ XC){
  int i = blockIdx.x*256 + threadIdx.x;   // over BS*512*CVD
  if(i >= BS*512*CVD) return;
  int cch = i % CVD;
  int lq = (i / CVD) & 511;
  int b = i / (CVD*512);
  int l0 = lq*4;
  float w[7];
  #pragma unroll
  for(int t=0;t<7;t++){
    int sl = l0 - 3 + t;
    w[t] = (sl >= 0) ? ZB[(size_t)(b*SEQL+sl)*DIP + DIN + cch] : 0.f;
  }
  float c0 = cw[cch*4+0], c1 = cw[cch*4+1], c2 = cw[cch*4+2], c3 = cw[cch*4+3];
  float bb2 = cb[cch];
  #pragma unroll
  for(int j=0;j<4;j++){
    float v = bb2 + w[j]*c0 + w[j+1]*c1 + w[j+2]*c2 + w[j+3]*c3;
    float sig = 1.f/(1.f+expf(-v));
    XC[(size_t)(b*SEQL + l0 + j)*CVD + cch] = v*sig;
  }
}

__global__ void k_dt(const float* __restrict__ ZB, const float* __restrict__ dtb,
                     const float* __restrict__ Alog, float* __restrict__ DT,
                     float* __restrict__ DA){
  int i = blockIdx.x*256 + threadIdx.x;
  if(i >= BS*SEQL*NH) return;
  int h = i & (NH-1);
  int row = i >> 4;
  float raw = ZB[(size_t)row*DIP + (DIN+CVD) + h] + dtb[h];
  float dt = fmaxf(raw,0.f) + log1pf(expf(-fabsf(raw)));
  DT[i] = dt;
  DA[i] = dt * (-expf(Alog[h]));
}

__global__ void k_acum(const float* __restrict__ DA, float* __restrict__ ACUM,
                       float* __restrict__ CDEC){
  int blk = blockIdx.x;
  int h = blk & 15, c = (blk>>4)&7, b = blk>>7;
  int l = threadIdx.x;
  __shared__ float s[256];
  int gl = c*CKS + l;
  s[l] = DA[(size_t)(b*SEQL + gl)*NH + h];
  __syncthreads();
  for(int off=1; off<256; off<<=1){
    float v = (l>=off) ? s[l-off] : 0.f;
    __syncthreads();
    s[l] += v;
    __syncthreads();
  }
  ACUM[(size_t)blk*CKS + l] = s[l];
  if(l==255) CDEC[blk] = expf(s[255]);
}

// extract B,C as bf16 [8192][64]
__global__ void k_bc(const float* __restrict__ XC, u16* __restrict__ Bbf,
                     u16* __restrict__ Cbf){
  int i = blockIdx.x*256 + threadIdx.x;
  if(i >= NROWS*DST) return;
  int g = i >> 6, n = i & 63;
  Bbf[i] = cvt_bf16(XC[(size_t)g*CVD + DIN + n]);
  Cbf[i] = cvt_bf16(XC[(size_t)g*CVD + DIN + DST + n]);
}

// XdT all-b: XdT[((b*8+c)*16+h)][p][s] = bf16( XC[b, c*256+s, h*64+p]*DT[b, c*256+s, h] )
__global__ void k_xdt2(const float* __restrict__ XC, const float* __restrict__ DT,
                       u16* __restrict__ XdT){
  int i = blockIdx.x*256 + threadIdx.x;   // 512*64*256 = 8,388,608
  if(i >= 8388608) return;
  int s = i & 255, p = (i>>8) & 63, h = (i>>14) & 15, bc = i >> 18;
  int b = bc >> 3, c = bc & 7;
  int g = b*SEQL + c*CKS + s;
  XdT[i] = cvt_bf16(XC[(size_t)g*CVD + h*HD + p] * DT[(size_t)g*NH + h]);
}

__global__ void k_states(const float* __restrict__ XC, const float* __restrict__ DT,
                         const float* __restrict__ ACUM, float* __restrict__ ST){
  int blk = blockIdx.x;
  int h = blk & 15, c = (blk>>4)&7, b = blk>>7;
  int tid = threadIdx.x;
  int n = tid & 63, pq = tid >> 6;
  __shared__ float Ac[256];
  __shared__ float Bt[32][64];
  __shared__ float Xt[32][64];
  Ac[tid] = ACUM[(size_t)blk*CKS + tid];
  float acc[16];
  #pragma unroll
  for(int k=0;k<16;k++) acc[k]=0.f;
  const float* xcb = XC + (size_t)b*SEQL*CVD;
  for(int st=0; st<8; ++st){
    __syncthreads();
    #pragma unroll
    for(int e=0;e<8;e++){
      int idx = tid + e*256;
      int sl = idx>>6, nn = idx&63;
      int gs = c*CKS + st*32 + sl;
      Bt[sl][nn] = xcb[(size_t)gs*CVD + DIN + nn];
      float dec = expf(Ac[255] - Ac[st*32+sl]);
      Xt[sl][nn] = xcb[(size_t)gs*CVD + h*HD + nn] * DT[(size_t)(b*SEQL+gs)*NH + h] * dec;
    }
    __syncthreads();
    #pragma unroll
    for(int l=0;l<32;l++){
      float bv = Bt[l][n];
      #pragma unroll
      for(int k=0;k<16;k++) acc[k] += bv * Xt[l][pq + 4*k];
    }
  }
  #pragma unroll
  for(int k=0;k<16;k++){
    int p = pq + 4*k;
    ST[(size_t)blk*4096 + p*64 + n] = acc[k];
  }
}

__global__ void k_scan(const float* __restrict__ ST, const float* __restrict__ CDEC,
                       float* __restrict__ PREV){
  int i = blockIdx.x*256 + threadIdx.x;
  if(i >= BS*NH*4096) return;
  int pn = i & 4095;
  int h = (i>>12) & 15;
  int b = i >> 16;
  float run = 0.f;
  for(int c=0;c<8;c++){
    size_t idx = (size_t)((b*8+c)*16+h)*4096 + pn;
    PREV[idx] = run;
    run = run*CDEC[(b*8+c)*16+h] + ST[idx];
  }
}

// ---------------- attention helpers ----------------
__global__ void k_extract(const float* __restrict__ HF, float* __restrict__ QIN,
                          float* __restrict__ CIN){
  int i = blockIdx.x*256 + threadIdx.x;
  if(i >= BS*1024*DM) return;
  int d = i & (DM-1);
  int q = (i>>9) & 1023;
  int b = i >> 19;
  QIN[i] = HF[(size_t)(b*SEQL + 1024 + q)*DM + d];
  CIN[i] = HF[(size_t)(b*SEQL + q)*DM + d];
}

// ---------------- host ----------------
extern "C" void kernel_launch(void* const* d_in, const int* in_sizes, int n_in,
                              void* d_out, int out_size, void* d_ws, size_t ws_size,
                              hipStream_t stream) {
  (void)in_sizes; (void)n_in; (void)out_size; (void)ws_size;
  const float* x_enc     = (const float*)d_in[0];
  const float* in_proj_w = (const float*)d_in[2];
  const float* conv_w    = (const float*)d_in[3];
  const float* conv_b    = (const float*)d_in[4];
  const float* dt_bias   = (const float*)d_in[5];
  const float* A_log     = (const float*)d_in[6];
  const float* D_param   = (const float*)d_in[7];
  const float* gnorm_w   = (const float*)d_in[8];
  const float* out_proj_w= (const float*)d_in[9];
  const float* norm_w    = (const float*)d_in[10];
  const float* norm_b    = (const float*)d_in[11];
  const float* normf_w   = (const float*)d_in[12];
  const float* normf_b   = (const float*)d_in[13];
  const float* ca_nq_w   = (const float*)d_in[14];
  const float* ca_nq_b   = (const float*)d_in[15];
  const float* ca_nkv_w  = (const float*)d_in[16];
  const float* ca_nkv_b  = (const float*)d_in[17];
  const float* ca_qw     = (const float*)d_in[18];
  const float* ca_kw     = (const float*)d_in[19];
  const float* ca_vw     = (const float*)d_in[20];
  const float* ca_ow     = (const float*)d_in[21];
  const float* ca_qb     = (const float*)d_in[22];
  const float* ca_kb     = (const float*)d_in[23];
  const float* ca_vb     = (const float*)d_in[24];
  const float* ca_ob     = (const float*)d_in[25];
  const float* qp_w      = (const float*)d_in[26];
  const float* qp_b      = (const float*)d_in[27];
  const float* cp_w      = (const float*)d_in[28];
  const float* cp_b      = (const float*)d_in[29];
  const float* dec1_w    = (const float*)d_in[30];
  const float* dec1_b    = (const float*)d_in[31];
  const float* dec2_w    = (const float*)d_in[32];
  const float* dec2_b    = (const float*)d_in[33];

  float* W = (float*)d_ws;
  size_t off = 0;
  auto alloc = [&](size_t n){ float* pp = W + off; off += n; return pp; };
  float* RES  = alloc((size_t)NTOK);
  float* H    = alloc((size_t)NTOK);
  float* HN   = alloc((size_t)NTOK);
  float* HNF  = alloc((size_t)NTOK);
  float* ZB   = alloc((size_t)NROWS*DIP);        // 17,956,864
  float* XC   = alloc((size_t)NROWS*CVD);        //  9,437,184
  float* DT   = alloc((size_t)NROWS*NH);
  float* DA   = alloc((size_t)NROWS*NH);
  float* ACUM = alloc((size_t)BS*NC*NH*CKS);
  float* CDEC = alloc((size_t)BS*NC*NH);
  float* Y    = alloc((size_t)NROWS*DIN);        //  8,388,608
  float* ST   = alloc((size_t)BS*NC*NH*4096);
  float* PREV = alloc((size_t)BS*NC*NH*4096);
  float* YD   = alloc((size_t)NTOK);
  float* HF   = alloc((size_t)NTOK);
  // byte-identical to the proven round-1 layout (61,768,192 floats)

  // mamba staging aliases (proven lifetimes):
  u16* Ubf    = (u16*)HF;
  u16* WinTc  = (u16*)(HF + 2097152);
  u16* WoutTc = (u16*)(HF + 2097152 + 561152);
  u16* Ybf    = (u16*)HNF;
  // SSD staging:
  u16*   Bbf    = (u16*)HNF;
  u16*   Cbf    = Bbf + 524288;
  float* Sf     = HNF + 524288;
  u16*   PREVbf = (u16*)Sf;
  u16*   XdTg   = (u16*)YD;          // all-b XdT: 8,388,608 u16 (YD dead until out_proj)

  const int TPB = 256;
  const int gTok = (NTOK+TPB-1)/TPB;
  dim3 tb(32,8);

  hipMemcpyAsync(RES, x_enc, (size_t)NTOK*4, hipMemcpyDeviceToDevice, stream);

  for(int layer=0; layer<2; ++layer){
    if(layer>0) k_add_flip<<<gTok,TPB,0,stream>>>(RES, H, 0);
    k_ln<<<NROWS,TPB,0,stream>>>(RES, norm_w + layer*DM, norm_b + layer*DM, HN);
    hipMemsetAsync(H, 0, (size_t)NTOK*4, stream);
    for(int dir=0; dir<2; ++dir){
      int idx = layer*2 + dir;
      const float* cw   = conv_w   + (size_t)idx*CVD*4;
      const float* cb   = conv_b   + (size_t)idx*CVD;
      const float* dtb  = dt_bias  + (size_t)idx*NH;
      const float* Alog = A_log    + (size_t)idx*NH;
      const float* Dp   = D_param  + (size_t)idx*NH;
      const float* gw   = gnorm_w  + (size_t)idx*DIN;

      if(dir==0){
        k_cvt<<<(NTOK/4+TPB-1)/TPB,TPB,0,stream>>>(HN, Ubf, NTOK/4);
      }else{
        k_flip<<<gTok,TPB,0,stream>>>(HNF, HN);
        k_cvt<<<(NTOK/4+TPB-1)/TPB,TPB,0,stream>>>(HNF, Ubf, NTOK/4);
      }
      k_wt2<<<dim3(69,16),tb,0,stream>>>(in_proj_w + (size_t)idx*DM*DIP, WinTc, 512, 2192, 2192);
      k_mg<<<dim3(18,64),256,0,stream>>>(Ubf, WinTc, ZB, 8192, 2192, 512, 512, 512, 2192);

      k_conv4<<<(BS*512*CVD+TPB-1)/TPB,TPB,0,stream>>>(ZB, cw, cb, XC);
      k_dt<<<(BS*SEQL*NH+TPB-1)/TPB,TPB,0,stream>>>(ZB, dtb, Alog, DT, DA);
      k_acum<<<BS*NC*NH,256,0,stream>>>(DA, ACUM, CDEC);

      // ---- Y_diag via MFMA with fused G-formation ----
      k_bc<<<(NROWS*DST+TPB-1)/TPB,TPB,0,stream>>>(XC, Bbf, Cbf);
      k_mgb<<<dim3(2,2,32),256,0,stream>>>(Cbf, Bbf, Sf,
            256, 256, 64, 64, 64, 256, 16384, 16384, 65536, 0, 0);
      k_xdt2<<<(8388608+TPB-1)/TPB,TPB,0,stream>>>(XC, DT, XdTg);
      k_mgg<<<dim3(1,2,512),256,0,stream>>>(Sf, ACUM, XdTg, Y);

      k_states<<<BS*NC*NH,256,0,stream>>>(XC, DT, ACUM, ST);
      k_scan<<<(BS*NH*4096+TPB-1)/TPB,TPB,0,stream>>>(ST, CDEC, PREV);
      // ---- Y_off via MFMA + fused gate epilogue ----
      k_cvt<<<(2097152/4+TPB-1)/TPB,TPB,0,stream>>>(PREV, PREVbf, 2097152/4);
      k_mgy<<<dim3(8,2,32),256,0,stream>>>(Cbf, PREVbf, ACUM, XC, ZB, Dp, Y);

      k_rms<<<NROWS,256,0,stream>>>(Y, gw);

      k_cvt<<<(2097152+TPB-1)/TPB,TPB,0,stream>>>(Y, Ybf, 2097152);
      k_wt2<<<dim3(16,32),tb,0,stream>>>(out_proj_w + (size_t)idx*DIN*DM, WoutTc, 1024, 512, 512);
      k_mg<<<dim3(4,64),256,0,stream>>>(Ybf, WoutTc, YD, 8192, 512, 1024, 1024, 1024, 512);

      k_add_flip<<<gTok,TPB,0,stream>>>(H, YD, dir);
    }
  }
  k_add_flip<<<gTok,TPB,0,stream>>>(RES, H, 0);
  k_ln<<<NROWS,TPB,0,stream>>>(RES, normf_w, normf_b, HF);

  // ================= attention head — MFMA (batched) =================
  float* P0   = ZB;
  float* QIN  = P0 + 0;
  float* CIN  = P0 + 2097152;
  float* QPb  = P0 + 4194304;
  float* CPb  = P0 + 6291456;
  float* QN   = P0 + 8388608;
  float* CN   = P0 + 10485760;
  float* AO   = P0 + 12582912;
  float* O1   = P0 + 14680064;
  float* D1   = P0 + 16777216;
  float* VV   = D1;
  u16* U0     = (u16*)(P0 + 20971520);
  u16* Qbf    = U0 + 0;
  u16* Cbf2   = U0 + 2097152;
  u16* QNbf   = U0 + 4194304;
  u16* CNbf   = U0 + 6291456;
  u16* QQbf   = U0 + 8388608;
  u16* KKbf   = U0 + 10485760;
  u16* VTbf   = U0 + 12582912;
  u16* AObf   = U0 + 14680064;
  u16* O1bf   = U0 + 16777216;
  u16* qpT    = U0 + 18874368;
  u16* cpT    = qpT + 262144;
  u16* qwT    = qpT + 524288;
  u16* kwT    = qpT + 786432;
  u16* vwT    = qpT + 1048576;
  u16* owT    = qpT + 1310720;
  u16* dec1T  = qpT + 1572864;
  u16* Pbf    = qpT + 2097152;

  const int M2 = BS*1024;
  k_extract<<<(BS*1024*DM+TPB-1)/TPB,TPB,0,stream>>>(HF, QIN, CIN);
  k_cvt<<<(2097152/4+TPB-1)/TPB,TPB,0,stream>>>(QIN, Qbf, 2097152/4);
  k_cvt<<<(2097152/4+TPB-1)/TPB,TPB,0,stream>>>(CIN, Cbf2, 2097152/4);
  k_wt2<<<dim3(16,16),tb,0,stream>>>(qp_w, qpT, 512, 512, 512);
  k_wt2<<<dim3(16,16),tb,0,stream>>>(cp_w, cpT, 512, 512, 512);
  k_wt2<<<dim3(16,16),tb,0,stream>>>(ca_qw, qwT, 512, 512, 512);
  k_wt2<<<dim3(16,16),tb,0,stream>>>(ca_kw, kwT, 512, 512, 512);
  k_wt2<<<dim3(16,16),tb,0,stream>>>(ca_vw, vwT, 512, 512, 512);
  k_wt2<<<dim3(16,16),tb,0,stream>>>(ca_ow, owT, 512, 512, 512);
  k_wt2<<<dim3(32,16),tb,0,stream>>>(dec1_w, dec1T, 512, 1024, 1024);

  k_mge<<<dim3(4,32),256,0,stream>>>(Qbf, qpT, qp_b, nullptr, QPb, nullptr,
                                     M2, 512, 512, 512, 512, 512, 1.f, 0);
  k_mge<<<dim3(4,32),256,0,stream>>>(Cbf2, cpT, cp_b, nullptr, CPb, nullptr,
                                     M2, 512, 512, 512, 512, 512, 1.f, 0);
  k_ln<<<M2,TPB,0,stream>>>(QPb, ca_nq_w, ca_nq_b, QN);
  k_ln<<<M2,TPB,0,stream>>>(CPb, ca_nkv_w, ca_nkv_b, CN);
  k_cvt<<<(2097152/4+TPB-1)/TPB,TPB,0,stream>>>(QN, QNbf, 2097152/4);
  k_cvt<<<(2097152/4+TPB-1)/TPB,TPB,0,stream>>>(CN, CNbf, 2097152/4);
  k_mge<<<dim3(4,32),256,0,stream>>>(QNbf, qwT, ca_qb, nullptr, nullptr, QQbf,
                                     M2, 512, 512, 512, 512, 512, 1.f, 0);
  k_mge<<<dim3(4,32),256,0,stream>>>(CNbf, kwT, ca_kb, nullptr, nullptr, KKbf,
                                     M2, 512, 512, 512, 512, 512, 1.f, 0);
  k_mge<<<dim3(4,32),256,0,stream>>>(CNbf, vwT, ca_vb, nullptr, VV, nullptr,
                                     M2, 512, 512, 512, 512, 512, 1.f, 0);
  k_vtb<<<dim3(4,32,16),tb,0,stream>>>(VV, VTbf);
  const float scl = 0.088388347648318447f;
  k_mgab<<<dim3(8,8,16),256,0,stream>>>(QQbf, KKbf, nullptr, Pbf,
        1024, 1024, 128, 512, 512, 1024,
        524288, 128, 524288, 128, 4194304, 1048576, scl);
  k_sm<<<16384,256,0,stream>>>(Pbf);
  k_mgab<<<dim3(1,8,16),256,0,stream>>>(Pbf, VTbf, AO, nullptr,
        1024, 128, 1024, 1024, 1024, 512,
        4194304, 1048576, 524288, 131072, 524288, 128, 1.f);
  k_cvt<<<(2097152/4+TPB-1)/TPB,TPB,0,stream>>>(AO, AObf, 2097152/4);
  k_mge<<<dim3(4,32),256,0,stream>>>(AObf, owT, ca_ob, QPb, O1, nullptr,
                                     M2, 512, 512, 512, 512, 512, 1.f, 0);
  k_cvt<<<(2097152/4+TPB-1)/TPB,TPB,0,stream>>>(O1, O1bf, 2097152/4);
  k_mge<<<dim3(8,32),256,0,stream>>>(O1bf, dec1T, dec1_b, nullptr, D1, nullptr,
                                     M2, 1024, 512, 512, 512, 1024, 1.f, 1);
  k_dec2<<<M2,256,0,stream>>>(D1, dec2_w, dec2_b, (float*)d_out);
}

// Round 15
// 1545.029 us; speedup vs baseline: 210.2816x; 1.1214x over previous
//
#include <hip/hip_runtime.h>
#include <hip/hip_bf16.h>

#define BS 4
#define SEQL 2048
#define DM 512
#define DIN 1024
#define NH 16
#define HD 64
#define DST 64
#define NC 8
#define CKS 256
#define DIP 2192
#define CVD 1152
#define NROWS (BS*SEQL)          /* 8192 */
#define NTOK (BS*SEQL*DM)        /* 4194304 */

typedef unsigned short u16;
typedef __bf16 bf16x8 __attribute__((ext_vector_type(8)));
typedef float f32x4 __attribute__((ext_vector_type(4)));

__device__ __forceinline__ u16 cvt_bf16(float f){
  unsigned int x = __float_as_uint(f);
  unsigned int r = x + 0x7fffu + ((x>>16)&1u);
  return (u16)(r>>16);
}
__device__ __forceinline__ float bf2f(u16 u){
  return __uint_as_float(((unsigned int)u)<<16);
}

// ---------------- elementwise (proven) ----------------
__global__ void k_add_flip(float* __restrict__ dst, const float* __restrict__ src, int flip){
  int i = blockIdx.x*256 + threadIdx.x;
  if(i >= NTOK) return;
  int d = i & (DM-1);
  int l = (i >> 9) & (SEQL-1);
  int b = i >> 20;
  int sl = flip ? (SEQL-1-l) : l;
  dst[i] += src[(b*SEQL + sl)*DM + d];
}

__global__ void k_flip(float* __restrict__ dst, const float* __restrict__ src){
  int i = blockIdx.x*256 + threadIdx.x;
  if(i >= NTOK) return;
  int d = i & (DM-1);
  int l = (i >> 9) & (SEQL-1);
  int b = i >> 20;
  dst[i] = src[(b*SEQL + (SEQL-1-l))*DM + d];
}

// f32 -> bf16 (verified round-8)
__global__ void k_cvt(const float* __restrict__ src, u16* __restrict__ dst, int n4){
  int i = blockIdx.x*256 + threadIdx.x;
  if(i >= n4) return;
  float4 f = reinterpret_cast<const float4*>(src)[i];
  ushort4 o; o.x=cvt_bf16(f.x); o.y=cvt_bf16(f.y); o.z=cvt_bf16(f.z); o.w=cvt_bf16(f.w);
  reinterpret_cast<ushort4*>(dst)[i] = o;
}

__global__ void k_ln(const float* __restrict__ X, const float* __restrict__ w,
                     const float* __restrict__ bb, float* __restrict__ O){
  int row = blockIdx.x, tid = threadIdx.x;
  const float* x = X + (size_t)row*DM;
  float* o = O + (size_t)row*DM;
  float s=0.f, s2=0.f;
  for(int j=tid;j<DM;j+=256){ float v=x[j]; s+=v; s2+=v*v; }
  __shared__ float r1[256], r2[256];
  r1[tid]=s; r2[tid]=s2; __syncthreads();
  for(int off=128;off>0;off>>=1){
    if(tid<off){ r1[tid]+=r1[tid+off]; r2[tid]+=r2[tid+off]; }
    __syncthreads();
  }
  float m = r1[0]*(1.f/DM);
  float var = r2[0]*(1.f/DM) - m*m;
  float inv = rsqrtf(var + 1e-5f);
  for(int j=tid;j<DM;j+=256) o[j] = (x[j]-m)*inv*w[j] + bb[j];
}

__global__ void k_rms(float* __restrict__ Y, const float* __restrict__ gw){
  int row = blockIdx.x, tid = threadIdx.x;
  float* y = Y + (size_t)row*DIN;
  float ss=0.f;
  for(int j=tid;j<DIN;j+=256){ float v=y[j]; ss+=v*v; }
  __shared__ float red[256];
  red[tid]=ss; __syncthreads();
  for(int off=128;off>0;off>>=1){
    if(tid<off) red[tid]+=red[tid+off];
    __syncthreads();
  }
  float inv = rsqrtf(red[0]*(1.f/DIN) + 1e-5f);
  for(int j=tid;j<DIN;j+=256) y[j] = y[j]*inv*gw[j];
}

// dec2: out[row][0..9] = D1[row]·dec2_w + b ; one block per row
__global__ void k_dec2(const float* __restrict__ D1, const float* __restrict__ w,
                       const float* __restrict__ bb, float* __restrict__ out){
  int row = blockIdx.x, tid = threadIdx.x;
  int lane = tid & 63, wave = tid >> 6;
  const float* x = D1 + (size_t)row*1024;
  float acc[10];
  #pragma unroll
  for(int o=0;o<10;o++) acc[o]=0.f;
  for(int j=tid;j<1024;j+=256){
    float v = x[j];
    const float* wr = w + (size_t)j*10;
    #pragma unroll
    for(int o=0;o<10;o++) acc[o] += v*wr[o];
  }
  __shared__ float red[4][10];
  #pragma unroll
  for(int o=0;o<10;o++){
    float v = acc[o];
    #pragma unroll
    for(int s=32;s>0;s>>=1) v += __shfl_down(v, s, 64);
    if(lane==0) red[wave][o] = v;
  }
  __syncthreads();
  if(tid < 10)
    out[(size_t)row*10 + tid] = red[0][tid]+red[1][tid]+red[2][tid]+red[3][tid] + bb[tid];
}

// transpose-convert with explicit src ld (verified): src[K][lds] f32 -> dst[N][K] bf16
__global__ void k_wt2(const float* __restrict__ src, u16* __restrict__ dst,
                      int K, int N, int lds){
  __shared__ float t[32][33];
  int n0 = blockIdx.x*32, k0 = blockIdx.y*32;
  int tx = threadIdx.x, ty = threadIdx.y;
  #pragma unroll
  for(int i=0;i<32;i+=8){
    int k = k0+ty+i, n = n0+tx;
    t[ty+i][tx] = (n<N) ? src[(size_t)k*lds+n] : 0.f;
  }
  __syncthreads();
  #pragma unroll
  for(int i=0;i<32;i+=8){
    int n = n0+ty+i, k = k0+tx;
    if(n<N) dst[(size_t)n*K+k] = cvt_bf16(t[tx][ty+i]);
  }
}

// batched V-transpose: per z=(b*4+h): src=VV+b*524288+h*128 [1024][128 of 512] -> dst [128][1024]
__global__ void k_vtb(const float* __restrict__ VV, u16* __restrict__ VT){
  __shared__ float t[32][33];
  int z = blockIdx.z, b = z>>2, h = z&3;
  const float* src = VV + (size_t)b*524288 + h*128;
  u16* dst = VT + (size_t)z*131072;
  int n0 = blockIdx.x*32, k0 = blockIdx.y*32;
  int tx = threadIdx.x, ty = threadIdx.y;
  #pragma unroll
  for(int i=0;i<32;i+=8){
    int k = k0+ty+i, n = n0+tx;
    t[ty+i][tx] = src[(size_t)k*512+n];
  }
  __syncthreads();
  #pragma unroll
  for(int i=0;i<32;i+=8){
    int n = n0+ty+i, k = k0+tx;
    dst[(size_t)n*1024+k] = cvt_bf16(t[tx][ty+i]);
  }
}

// XdT via LDS-tiled transpose (k_wt2 pattern): per z=(bc*16+h),
// XdT[z][p][s] = bf16( XC[b,c*256+s,h*64+p] * DT[b,c*256+s,h] )
__global__ void k_xdtt(const float* __restrict__ XC, const float* __restrict__ DT,
                       u16* __restrict__ XdT){
  __shared__ float t[32][33];
  int z = blockIdx.z;
  int h = z & 15, bc = z >> 4;
  int b = bc >> 3, c = bc & 7;
  int p0 = blockIdx.x*32, s0 = blockIdx.y*32;
  int tx = threadIdx.x, ty = threadIdx.y;
  int gbase = b*SEQL + c*CKS;
  #pragma unroll
  for(int i=0;i<32;i+=8){
    int s = s0+ty+i, p = p0+tx;
    int g = gbase + s;
    t[ty+i][tx] = XC[(size_t)g*CVD + h*HD + p] * DT[(size_t)g*NH + h];
  }
  __syncthreads();
  u16* dst = XdT + (size_t)z*16384;
  #pragma unroll
  for(int i=0;i<32;i+=8){
    int p = p0+ty+i, s = s0+tx;
    dst[(size_t)p*256 + s] = cvt_bf16(t[tx][ty+i]);
  }
}

// ---------------- MFMA bf16 GEMM, emap0 (HW-verified) ----------------
__global__ __launch_bounds__(256) void k_mg(
    const u16* __restrict__ A, const u16* __restrict__ BT,
    float* __restrict__ C, int M, int N, int K, int lda, int ldb, int ldc)
{
  __shared__ uint4 As4[128*5];
  __shared__ uint4 Bs4[128*5];
  const int tid = threadIdx.x;
  const int row0 = blockIdx.y*128, col0 = blockIdx.x*128;
  const int lane = tid & 63, wave = tid >> 6;
  const int wm = wave >> 1, wn = wave & 1;
  const int lr = lane & 15, ksg = (lane >> 4);
  f32x4 acc[4][4];
  #pragma unroll
  for(int i=0;i<4;i++)
    #pragma unroll
    for(int j=0;j<4;j++) acc[i][j] = (f32x4){0.f,0.f,0.f,0.f};
  for(int k0=0;k0<K;k0+=32){
    #pragma unroll
    for(int i=0;i<2;i++){
      int t2 = tid + i*256;
      int rr = t2 >> 2, sg = (t2 & 3);
      uint4 av = *reinterpret_cast<const uint4*>(A + (size_t)(row0+rr)*lda + k0 + sg*8);
      uint4 bv = {0u,0u,0u,0u};
      if(col0+rr < N) bv = *reinterpret_cast<const uint4*>(BT + (size_t)(col0+rr)*ldb + k0 + sg*8);
      As4[rr*5 + sg] = av;
      Bs4[rr*5 + sg] = bv;
    }
    __syncthreads();
    bf16x8 afr[4], bfr[4];
    #pragma unroll
    for(int i=0;i<4;i++) afr[i] = *reinterpret_cast<const bf16x8*>(&As4[(wm*64+i*16+lr)*5 + ksg]);
    #pragma unroll
    for(int j=0;j<4;j++) bfr[j] = *reinterpret_cast<const bf16x8*>(&Bs4[(wn*64+j*16+lr)*5 + ksg]);
    #pragma unroll
    for(int i=0;i<4;i++)
      #pragma unroll
      for(int j=0;j<4;j++)
        acc[i][j] = __builtin_amdgcn_mfma_f32_16x16x32_bf16(afr[i], bfr[j], acc[i][j], 0, 0, 0);
    __syncthreads();
  }
  const int hi = lane >> 4, lo = lane & 15;
  #pragma unroll
  for(int i=0;i<4;i++)
    #pragma unroll
    for(int j=0;j<4;j++)
      #pragma unroll
      for(int r=0;r<4;r++){
        int row = row0 + wm*64 + i*16 + 4*hi + r;
        int col = col0 + wn*64 + j*16 + lo;
        if(col < N) C[(size_t)row*ldc + col] = acc[i][j][r];
      }
}

// batched variant: verified core + z-strided base offsets only
__global__ __launch_bounds__(256) void k_mgb(
    const u16* __restrict__ A0, const u16* __restrict__ BT0,
    float* __restrict__ C0, int M, int N, int K, int lda, int ldb, int ldc,
    long sAz, long sBz, long sCo, long sCi, int shC)
{
  const int z = blockIdx.z;
  const u16* A  = A0  + (size_t)z*sAz;
  const u16* BT = BT0 + (size_t)z*sBz;
  float* C = C0 + (size_t)(z>>shC)*sCo + (size_t)(z & ((1<<shC)-1))*sCi;
  __shared__ uint4 As4[128*5];
  __shared__ uint4 Bs4[128*5];
  const int tid = threadIdx.x;
  const int row0 = blockIdx.y*128, col0 = blockIdx.x*128;
  const int lane = tid & 63, wave = tid >> 6;
  const int wm = wave >> 1, wn = wave & 1;
  const int lr = lane & 15, ksg = (lane >> 4);
  f32x4 acc[4][4];
  #pragma unroll
  for(int i=0;i<4;i++)
    #pragma unroll
    for(int j=0;j<4;j++) acc[i][j] = (f32x4){0.f,0.f,0.f,0.f};
  for(int k0=0;k0<K;k0+=32){
    #pragma unroll
    for(int i=0;i<2;i++){
      int t2 = tid + i*256;
      int rr = t2 >> 2, sg = (t2 & 3);
      uint4 av = *reinterpret_cast<const uint4*>(A + (size_t)(row0+rr)*lda + k0 + sg*8);
      uint4 bv = {0u,0u,0u,0u};
      if(col0+rr < N) bv = *reinterpret_cast<const uint4*>(BT + (size_t)(col0+rr)*ldb + k0 + sg*8);
      As4[rr*5 + sg] = av;
      Bs4[rr*5 + sg] = bv;
    }
    __syncthreads();
    bf16x8 afr[4], bfr[4];
    #pragma unroll
    for(int i=0;i<4;i++) afr[i] = *reinterpret_cast<const bf16x8*>(&As4[(wm*64+i*16+lr)*5 + ksg]);
    #pragma unroll
    for(int j=0;j<4;j++) bfr[j] = *reinterpret_cast<const bf16x8*>(&Bs4[(wn*64+j*16+lr)*5 + ksg]);
    #pragma unroll
    for(int i=0;i<4;i++)
      #pragma unroll
      for(int j=0;j<4;j++)
        acc[i][j] = __builtin_amdgcn_mfma_f32_16x16x32_bf16(afr[i], bfr[j], acc[i][j], 0, 0, 0);
    __syncthreads();
  }
  const int hi = lane >> 4, lo = lane & 15;
  #pragma unroll
  for(int i=0;i<4;i++)
    #pragma unroll
    for(int j=0;j<4;j++)
      #pragma unroll
      for(int r=0;r<4;r++){
        int row = row0 + wm*64 + i*16 + 4*hi + r;
        int col = col0 + wn*64 + j*16 + lo;
        if(col < N) C[(size_t)row*ldc + col] = acc[i][j][r];
      }
}

// Y_diag GEMM with fused G-formation in A-staging
__global__ __launch_bounds__(256) void k_mgg(
    const float* __restrict__ Sf, const float* __restrict__ ACUM,
    const u16* __restrict__ XdT, float* __restrict__ Y)
{
  const int z = blockIdx.z;
  const int h = z & 15, bc = z >> 4;
  const int b = bc >> 3, c = bc & 7;
  const float* Az = Sf + (size_t)bc*65536;
  const float* Acp = ACUM + (size_t)z*256;
  const u16* BT = XdT + (size_t)z*16384;
  float* Cp = Y + (size_t)b*2097152 + (size_t)c*262144 + h*64;
  __shared__ uint4 As4[128*5];
  __shared__ uint4 Bs4[128*5];
  __shared__ float AcS[256];
  const int tid = threadIdx.x;
  AcS[tid] = Acp[tid];
  __syncthreads();
  const int row0 = blockIdx.y*128;
  const int lane = tid & 63, wave = tid >> 6;
  const int wm = wave >> 1, wn = wave & 1;
  const int lr = lane & 15, ksg = (lane >> 4);
  f32x4 acc[4][4];
  #pragma unroll
  for(int i=0;i<4;i++)
    #pragma unroll
    for(int j=0;j<4;j++) acc[i][j] = (f32x4){0.f,0.f,0.f,0.f};
  for(int k0=0;k0<256;k0+=32){
    #pragma unroll
    for(int i=0;i<2;i++){
      int t2 = tid + i*256;
      int rr = t2 >> 2, sg = (t2 & 3);
      int l = row0 + rr;
      int sbase = k0 + sg*8;
      float4 v0 = *reinterpret_cast<const float4*>(Az + (size_t)l*256 + sbase);
      float4 v1 = *reinterpret_cast<const float4*>(Az + (size_t)l*256 + sbase + 4);
      float acl = AcS[l];
      float vv[8] = {v0.x,v0.y,v0.z,v0.w,v1.x,v1.y,v1.z,v1.w};
      u16 gbuf[8];
      #pragma unroll
      for(int e=0;e<8;e++){
        int s = sbase + e;
        float g = 0.f;
        if(s <= l) g = __expf(acl - AcS[s]) * vv[e];
        gbuf[e] = cvt_bf16(g);
      }
      As4[rr*5 + sg] = *reinterpret_cast<uint4*>(gbuf);
      uint4 bv = {0u,0u,0u,0u};
      if(rr < 64) bv = *reinterpret_cast<const uint4*>(BT + (size_t)rr*256 + sbase);
      Bs4[rr*5 + sg] = bv;
    }
    __syncthreads();
    bf16x8 afr[4], bfr[4];
    #pragma unroll
    for(int i=0;i<4;i++) afr[i] = *reinterpret_cast<const bf16x8*>(&As4[(wm*64+i*16+lr)*5 + ksg]);
    #pragma unroll
    for(int j=0;j<4;j++) bfr[j] = *reinterpret_cast<const bf16x8*>(&Bs4[(wn*64+j*16+lr)*5 + ksg]);
    #pragma unroll
    for(int i=0;i<4;i++)
      #pragma unroll
      for(int j=0;j<4;j++)
        acc[i][j] = __builtin_amdgcn_mfma_f32_16x16x32_bf16(afr[i], bfr[j], acc[i][j], 0, 0, 0);
    __syncthreads();
  }
  const int hi = lane >> 4, lo = lane & 15;
  #pragma unroll
  for(int i=0;i<4;i++)
    #pragma unroll
    for(int j=0;j<4;j++)
      #pragma unroll
      for(int r=0;r<4;r++){
        int row = row0 + wm*64 + i*16 + 4*hi + r;
        int col = wn*64 + j*16 + lo;
        if(col < 64) Cp[(size_t)row*1024 + col] = acc[i][j][r];
      }
}

// batched attention GEMM: (z>>2)/(z&3) offsets for A/B/C, scale, f32 or bf16 out
__global__ __launch_bounds__(256) void k_mgab(
    const u16* __restrict__ A0, const u16* __restrict__ BT0,
    float* __restrict__ C0, u16* __restrict__ Cb0,
    int M, int N, int K, int lda, int ldb, int ldc,
    long sAo, long sAi, long sBo, long sBi, long sCo, long sCi, float scale)
{
  const int z = blockIdx.z;
  const u16* A  = A0  + (size_t)(z>>2)*sAo + (size_t)(z&3)*sAi;
  const u16* BT = BT0 + (size_t)(z>>2)*sBo + (size_t)(z&3)*sBi;
  const size_t offC = (size_t)(z>>2)*sCo + (size_t)(z&3)*sCi;
  __shared__ uint4 As4[128*5];
  __shared__ uint4 Bs4[128*5];
  const int tid = threadIdx.x;
  const int row0 = blockIdx.y*128, col0 = blockIdx.x*128;
  const int lane = tid & 63, wave = tid >> 6;
  const int wm = wave >> 1, wn = wave & 1;
  const int lr = lane & 15, ksg = (lane >> 4);
  f32x4 acc[4][4];
  #pragma unroll
  for(int i=0;i<4;i++)
    #pragma unroll
    for(int j=0;j<4;j++) acc[i][j] = (f32x4){0.f,0.f,0.f,0.f};
  for(int k0=0;k0<K;k0+=32){
    #pragma unroll
    for(int i=0;i<2;i++){
      int t2 = tid + i*256;
      int rr = t2 >> 2, sg = (t2 & 3);
      uint4 av = *reinterpret_cast<const uint4*>(A + (size_t)(row0+rr)*lda + k0 + sg*8);
      uint4 bv = {0u,0u,0u,0u};
      if(col0+rr < N) bv = *reinterpret_cast<const uint4*>(BT + (size_t)(col0+rr)*ldb + k0 + sg*8);
      As4[rr*5 + sg] = av;
      Bs4[rr*5 + sg] = bv;
    }
    __syncthreads();
    bf16x8 afr[4], bfr[4];
    #pragma unroll
    for(int i=0;i<4;i++) afr[i] = *reinterpret_cast<const bf16x8*>(&As4[(wm*64+i*16+lr)*5 + ksg]);
    #pragma unroll
    for(int j=0;j<4;j++) bfr[j] = *reinterpret_cast<const bf16x8*>(&Bs4[(wn*64+j*16+lr)*5 + ksg]);
    #pragma unroll
    for(int i=0;i<4;i++)
      #pragma unroll
      for(int j=0;j<4;j++)
        acc[i][j] = __builtin_amdgcn_mfma_f32_16x16x32_bf16(afr[i], bfr[j], acc[i][j], 0, 0, 0);
    __syncthreads();
  }
  const int hi = lane >> 4, lo = lane & 15;
  #pragma unroll
  for(int i=0;i<4;i++)
    #pragma unroll
    for(int j=0;j<4;j++)
      #pragma unroll
      for(int r=0;r<4;r++){
        int row = row0 + wm*64 + i*16 + 4*hi + r;
        int col = col0 + wn*64 + j*16 + lo;
        if(col < N){
          float v = acc[i][j][r] * scale;
          size_t ci = offC + (size_t)row*ldc + col;
          if(C0) C0[ci] = v;
          else   Cb0[ci] = cvt_bf16(v);
        }
      }
}

// Y_off GEMM fused with yfinal epilogue
__global__ __launch_bounds__(256) void k_mgy(
    const u16* __restrict__ Cb0, const u16* __restrict__ PV0,
    const float* __restrict__ ACUM, const float* __restrict__ XCp,
    const float* __restrict__ ZBp, const float* __restrict__ Dp,
    float* __restrict__ Y)
{
  const int z = blockIdx.z;                 // b*8+c
  const int b = z>>3, c = z&7;
  const u16* A  = Cb0 + (size_t)z*16384;    // [256][64] bf16
  const u16* BT = PV0 + (size_t)z*65536;    // [1024][64] bf16
  const int N = 1024;
  __shared__ uint4 As4[128*5];
  __shared__ uint4 Bs4[128*5];
  const int tid = threadIdx.x;
  const int row0 = blockIdx.y*128, col0 = blockIdx.x*128;
  const int lane = tid & 63, wave = tid >> 6;
  const int wm = wave >> 1, wn = wave & 1;
  const int lr = lane & 15, ksg = (lane >> 4);
  f32x4 acc[4][4];
  #pragma unroll
  for(int i=0;i<4;i++)
    #pragma unroll
    for(int j=0;j<4;j++) acc[i][j] = (f32x4){0.f,0.f,0.f,0.f};
  for(int k0=0;k0<64;k0+=32){
    #pragma unroll
    for(int i=0;i<2;i++){
      int t2 = tid + i*256;
      int rr = t2 >> 2, sg = (t2 & 3);
      uint4 av = *reinterpret_cast<const uint4*>(A + (size_t)(row0+rr)*64 + k0 + sg*8);
      uint4 bv = {0u,0u,0u,0u};
      if(col0+rr < N) bv = *reinterpret_cast<const uint4*>(BT + (size_t)(col0+rr)*64 + k0 + sg*8);
      As4[rr*5 + sg] = av;
      Bs4[rr*5 + sg] = bv;
    }
    __syncthreads();
    bf16x8 afr[4], bfr[4];
    #pragma unroll
    for(int i=0;i<4;i++) afr[i] = *reinterpret_cast<const bf16x8*>(&As4[(wm*64+i*16+lr)*5 + ksg]);
    #pragma unroll
    for(int j=0;j<4;j++) bfr[j] = *reinterpret_cast<const bf16x8*>(&Bs4[(wn*64+j*16+lr)*5 + ksg]);
    #pragma unroll
    for(int i=0;i<4;i++)
      #pragma unroll
      for(int j=0;j<4;j++)
        acc[i][j] = __builtin_amdgcn_mfma_f32_16x16x32_bf16(afr[i], bfr[j], acc[i][j], 0, 0, 0);
    __syncthreads();
  }
  const int hi = lane >> 4, lo = lane & 15;
  #pragma unroll
  for(int i=0;i<4;i++)
    #pragma unroll
    for(int j=0;j<4;j++)
      #pragma unroll
      for(int r=0;r<4;r++){
        int row = row0 + wm*64 + i*16 + 4*hi + r;
        int col = col0 + wn*64 + j*16 + lo;
        int h = col >> 6;
        int g = b*SEQL + c*CKS + row;
        float ac = ACUM[((size_t)z*NH + h)*CKS + row];
        float xh = XCp[(size_t)g*CVD + col];
        float zg = ZBp[(size_t)g*DIP + col];
        size_t ci = (size_t)g*DIN + col;
        float v = Y[ci] + expf(ac)*acc[i][j][r] + Dp[h]*xh;
        float sig = 1.f/(1.f+expf(-zg));
        Y[ci] = v * (zg*sig);
      }
}

// verified core + arithmetic epilogue (attention projections)
__global__ __launch_bounds__(256) void k_mge(
    const u16* __restrict__ A, const u16* __restrict__ BT,
    const float* __restrict__ bias, const float* __restrict__ res,
    float* __restrict__ C, u16* __restrict__ Cbf,
    int M, int N, int K, int lda, int ldb, int ldc, float scale, int act)
{
  __shared__ uint4 As4[128*5];
  __shared__ uint4 Bs4[128*5];
  const int tid = threadIdx.x;
  const int row0 = blockIdx.y*128, col0 = blockIdx.x*128;
  const int lane = tid & 63, wave = tid >> 6;
  const int wm = wave >> 1, wn = wave & 1;
  const int lr = lane & 15, ksg = (lane >> 4);
  f32x4 acc[4][4];
  #pragma unroll
  for(int i=0;i<4;i++)
    #pragma unroll
    for(int j=0;j<4;j++) acc[i][j] = (f32x4){0.f,0.f,0.f,0.f};
  for(int k0=0;k0<K;k0+=32){
    #pragma unroll
    for(int i=0;i<2;i++){
      int t2 = tid + i*256;
      int rr = t2 >> 2, sg = (t2 & 3);
      uint4 av = *reinterpret_cast<const uint4*>(A + (size_t)(row0+rr)*lda + k0 + sg*8);
      uint4 bv = {0u,0u,0u,0u};
      if(col0+rr < N) bv = *reinterpret_cast<const uint4*>(BT + (size_t)(col0+rr)*ldb + k0 + sg*8);
      As4[rr*5 + sg] = av;
      Bs4[rr*5 + sg] = bv;
    }
    __syncthreads();
    bf16x8 afr[4], bfr[4];
    #pragma unroll
    for(int i=0;i<4;i++) afr[i] = *reinterpret_cast<const bf16x8*>(&As4[(wm*64+i*16+lr)*5 + ksg]);
    #pragma unroll
    for(int j=0;j<4;j++) bfr[j] = *reinterpret_cast<const bf16x8*>(&Bs4[(wn*64+j*16+lr)*5 + ksg]);
    #pragma unroll
    for(int i=0;i<4;i++)
      #pragma unroll
      for(int j=0;j<4;j++)
        acc[i][j] = __builtin_amdgcn_mfma_f32_16x16x32_bf16(afr[i], bfr[j], acc[i][j], 0, 0, 0);
    __syncthreads();
  }
  const int hi = lane >> 4, lo = lane & 15;
  #pragma unroll
  for(int i=0;i<4;i++)
    #pragma unroll
    for(int j=0;j<4;j++)
      #pragma unroll
      for(int r=0;r<4;r++){
        int row = row0 + wm*64 + i*16 + 4*hi + r;
        int col = col0 + wn*64 + j*16 + lo;
        if(col < N){
          float v = acc[i][j][r];
          if(bias) v += bias[col];
          v *= scale;
          if(act==1) v = 0.5f*v*(1.f+erff(v*0.70710678118654752f));
          size_t ci = (size_t)row*ldc + col;
          if(res) v += res[ci];
          if(C) C[ci] = v;
          else  Cbf[ci] = cvt_bf16(v);
        }
      }
}

// in-place row softmax over 1024 bf16
__global__ void k_sm(u16* __restrict__ S){
  size_t row = blockIdx.x;
  u16* p = S + row*1024;
  int tid = threadIdx.x;
  ushort4 u = reinterpret_cast<ushort4*>(p)[tid];
  float v0=bf2f(u.x), v1=bf2f(u.y), v2=bf2f(u.z), v3=bf2f(u.w);
  float m = fmaxf(fmaxf(v0,v1),fmaxf(v2,v3));
  __shared__ float red[256];
  red[tid]=m; __syncthreads();
  for(int o=128;o>0;o>>=1){ if(tid<o) red[tid]=fmaxf(red[tid],red[tid+o]); __syncthreads(); }
  m = red[0]; __syncthreads();
  v0=__expf(v0-m); v1=__expf(v1-m); v2=__expf(v2-m); v3=__expf(v3-m);
  float s = v0+v1+v2+v3;
  red[tid]=s; __syncthreads();
  for(int o=128;o>0;o>>=1){ if(tid<o) red[tid]+=red[tid+o]; __syncthreads(); }
  float inv = 1.f/red[0];
  ushort4 o4; o4.x=cvt_bf16(v0*inv); o4.y=cvt_bf16(v1*inv); o4.z=cvt_bf16(v2*inv); o4.w=cvt_bf16(v3*inv);
  reinterpret_cast<ushort4*>(p)[tid] = o4;
}

// ---------------- mamba pieces ----------------
__global__ void k_conv4(const float* __restrict__ ZB, const float* __restrict__ cw,
                        const float* __restrict__ cb, float* __restrict__ XC){
  int i = blockIdx.x*256 + threadIdx.x;   // over BS*512*CVD
  if(i >= BS*512*CVD) return;
  int cch = i % CVD;
  int lq = (i / CVD) & 511;
  int b = i / (CVD*512);
  int l0 = lq*4;
  float w[7];
  #pragma unroll
  for(int t=0;t<7;t++){
    int sl = l0 - 3 + t;
    w[t] = (sl >= 0) ? ZB[(size_t)(b*SEQL+sl)*DIP + DIN + cch] : 0.f;
  }
  float c0 = cw[cch*4+0], c1 = cw[cch*4+1], c2 = cw[cch*4+2], c3 = cw[cch*4+3];
  float bb2 = cb[cch];
  #pragma unroll
  for(int j=0;j<4;j++){
    float v = bb2 + w[j]*c0 + w[j+1]*c1 + w[j+2]*c2 + w[j+3]*c3;
    float sig = 1.f/(1.f+expf(-v));
    XC[(size_t)(b*SEQL + l0 + j)*CVD + cch] = v*sig;
  }
}

__global__ void k_dt(const float* __restrict__ ZB, const float* __restrict__ dtb,
                     const float* __restrict__ Alog, float* __restrict__ DT,
                     float* __restrict__ DA){
  int i = blockIdx.x*256 + threadIdx.x;
  if(i >= BS*SEQL*NH) return;
  int h = i & (NH-1);
  int row = i >> 4;
  float raw = ZB[(size_t)row*DIP + (DIN+CVD) + h] + dtb[h];
  float dt = fmaxf(raw,0.f) + log1pf(expf(-fabsf(raw)));
  DT[i] = dt;
  DA[i] = dt * (-expf(Alog[h]));
}

__global__ void k_acum(const float* __restrict__ DA, float* __restrict__ ACUM,
                       float* __restrict__ CDEC){
  int blk = blockIdx.x;
  int h = blk & 15, c = (blk>>4)&7, b = blk>>7;
  int l = threadIdx.x;
  __shared__ float s[256];
  int gl = c*CKS + l;
  s[l] = DA[(size_t)(b*SEQL + gl)*NH + h];
  __syncthreads();
  for(int off=1; off<256; off<<=1){
    float v = (l>=off) ? s[l-off] : 0.f;
    __syncthreads();
    s[l] += v;
    __syncthreads();
  }
  ACUM[(size_t)blk*CKS + l] = s[l];
  if(l==255) CDEC[blk] = expf(s[255]);
}

// extract B,C as bf16 [8192][64]
__global__ void k_bc(const float* __restrict__ XC, u16* __restrict__ Bbf,
                     u16* __restrict__ Cbf){
  int i = blockIdx.x*256 + threadIdx.x;
  if(i >= NROWS*DST) return;
  int g = i >> 6, n = i & 63;
  Bbf[i] = cvt_bf16(XC[(size_t)g*CVD + DIN + n]);
  Cbf[i] = cvt_bf16(XC[(size_t)g*CVD + DIN + DST + n]);
}

__global__ void k_states(const float* __restrict__ XC, const float* __restrict__ DT,
                         const float* __restrict__ ACUM, float* __restrict__ ST){
  int blk = blockIdx.x;
  int h = blk & 15, c = (blk>>4)&7, b = blk>>7;
  int tid = threadIdx.x;
  int n = tid & 63, pq = tid >> 6;
  __shared__ float Ac[256];
  __shared__ float Bt[32][64];
  __shared__ float Xt[32][64];
  Ac[tid] = ACUM[(size_t)blk*CKS + tid];
  float acc[16];
  #pragma unroll
  for(int k=0;k<16;k++) acc[k]=0.f;
  const float* xcb = XC + (size_t)b*SEQL*CVD;
  for(int st=0; st<8; ++st){
    __syncthreads();
    #pragma unroll
    for(int e=0;e<8;e++){
      int idx = tid + e*256;
      int sl = idx>>6, nn = idx&63;
      int gs = c*CKS + st*32 + sl;
      Bt[sl][nn] = xcb[(size_t)gs*CVD + DIN + nn];
      float dec = expf(Ac[255] - Ac[st*32+sl]);
      Xt[sl][nn] = xcb[(size_t)gs*CVD + h*HD + nn] * DT[(size_t)(b*SEQL+gs)*NH + h] * dec;
    }
    __syncthreads();
    #pragma unroll
    for(int l=0;l<32;l++){
      float bv = Bt[l][n];
      #pragma unroll
      for(int k=0;k<16;k++) acc[k] += bv * Xt[l][pq + 4*k];
    }
  }
  #pragma unroll
  for(int k=0;k<16;k++){
    int p = pq + 4*k;
    ST[(size_t)blk*4096 + p*64 + n] = acc[k];
  }
}

__global__ void k_scan(const float* __restrict__ ST, const float* __restrict__ CDEC,
                       float* __restrict__ PREV){
  int i = blockIdx.x*256 + threadIdx.x;
  if(i >= BS*NH*4096) return;
  int pn = i & 4095;
  int h = (i>>12) & 15;
  int b = i >> 16;
  float run = 0.f;
  for(int c=0;c<8;c++){
    size_t idx = (size_t)((b*8+c)*16+h)*4096 + pn;
    PREV[idx] = run;
    run = run*CDEC[(b*8+c)*16+h] + ST[idx];
  }
}

// ---------------- attention helpers ----------------
__global__ void k_extract(const float* __restrict__ HF, float* __restrict__ QIN,
                          float* __restrict__ CIN){
  int i = blockIdx.x*256 + threadIdx.x;
  if(i >= BS*1024*DM) return;
  int d = i & (DM-1);
  int q = (i>>9) & 1023;
  int b = i >> 19;
  QIN[i] = HF[(size_t)(b*SEQL + 1024 + q)*DM + d];
  CIN[i] = HF[(size_t)(b*SEQL + q)*DM + d];
}

// ---------------- host ----------------
extern "C" void kernel_launch(void* const* d_in, const int* in_sizes, int n_in,
                              void* d_out, int out_size, void* d_ws, size_t ws_size,
                              hipStream_t stream) {
  (void)in_sizes; (void)n_in; (void)out_size; (void)ws_size;
  const float* x_enc     = (const float*)d_in[0];
  const float* in_proj_w = (const float*)d_in[2];
  const float* conv_w    = (const float*)d_in[3];
  const float* conv_b    = (const float*)d_in[4];
  const float* dt_bias   = (const float*)d_in[5];
  const float* A_log     = (const float*)d_in[6];
  const float* D_param   = (const float*)d_in[7];
  const float* gnorm_w   = (const float*)d_in[8];
  const float* out_proj_w= (const float*)d_in[9];
  const float* norm_w    = (const float*)d_in[10];
  const float* norm_b    = (const float*)d_in[11];
  const float* normf_w   = (const float*)d_in[12];
  const float* normf_b   = (const float*)d_in[13];
  const float* ca_nq_w   = (const float*)d_in[14];
  const float* ca_nq_b   = (const float*)d_in[15];
  const float* ca_nkv_w  = (const float*)d_in[16];
  const float* ca_nkv_b  = (const float*)d_in[17];
  const float* ca_qw     = (const float*)d_in[18];
  const float* ca_kw     = (const float*)d_in[19];
  const float* ca_vw     = (const float*)d_in[20];
  const float* ca_ow     = (const float*)d_in[21];
  const float* ca_qb     = (const float*)d_in[22];
  const float* ca_kb     = (const float*)d_in[23];
  const float* ca_vb     = (const float*)d_in[24];
  const float* ca_ob     = (const float*)d_in[25];
  const float* qp_w      = (const float*)d_in[26];
  const float* qp_b      = (const float*)d_in[27];
  const float* cp_w      = (const float*)d_in[28];
  const float* cp_b      = (const float*)d_in[29];
  const float* dec1_w    = (const float*)d_in[30];
  const float* dec1_b    = (const float*)d_in[31];
  const float* dec2_w    = (const float*)d_in[32];
  const float* dec2_b    = (const float*)d_in[33];

  float* W = (float*)d_ws;
  size_t off = 0;
  auto alloc = [&](size_t n){ float* pp = W + off; off += n; return pp; };
  float* RES  = alloc((size_t)NTOK);
  float* H    = alloc((size_t)NTOK);
  float* HN   = alloc((size_t)NTOK);
  float* HNF  = alloc((size_t)NTOK);
  float* ZB   = alloc((size_t)NROWS*DIP);        // 17,956,864
  float* XC   = alloc((size_t)NROWS*CVD);        //  9,437,184
  float* DT   = alloc((size_t)NROWS*NH);
  float* DA   = alloc((size_t)NROWS*NH);
  float* ACUM = alloc((size_t)BS*NC*NH*CKS);
  float* CDEC = alloc((size_t)BS*NC*NH);
  float* Y    = alloc((size_t)NROWS*DIN);        //  8,388,608
  float* ST   = alloc((size_t)BS*NC*NH*4096);
  float* PREV = alloc((size_t)BS*NC*NH*4096);
  float* YD   = alloc((size_t)NTOK);
  float* HF   = alloc((size_t)NTOK);
  // byte-identical to the proven round-1 layout (61,768,192 floats)

  // mamba staging aliases (proven lifetimes):
  u16* Ubf    = (u16*)HF;
  u16* WinTc  = (u16*)(HF + 2097152);
  u16* WoutTc = (u16*)(HF + 2097152 + 561152);
  u16* Ybf    = (u16*)HNF;
  // SSD staging:
  u16*   Bbf    = (u16*)HNF;
  u16*   Cbf    = Bbf + 524288;
  float* Sf     = HNF + 524288;
  u16*   PREVbf = (u16*)Sf;
  u16*   XdTg   = (u16*)YD;          // all-b XdT: 8,388,608 u16 (YD dead until out_proj)

  const int TPB = 256;
  const int gTok = (NTOK+TPB-1)/TPB;
  dim3 tb(32,8);

  hipMemcpyAsync(RES, x_enc, (size_t)NTOK*4, hipMemcpyDeviceToDevice, stream);

  for(int layer=0; layer<2; ++layer){
    if(layer>0) k_add_flip<<<gTok,TPB,0,stream>>>(RES, H, 0);
    k_ln<<<NROWS,TPB,0,stream>>>(RES, norm_w + layer*DM, norm_b + layer*DM, HN);
    hipMemsetAsync(H, 0, (size_t)NTOK*4, stream);
    for(int dir=0; dir<2; ++dir){
      int idx = layer*2 + dir;
      const float* cw   = conv_w   + (size_t)idx*CVD*4;
      const float* cb   = conv_b   + (size_t)idx*CVD;
      const float* dtb  = dt_bias  + (size_t)idx*NH;
      const float* Alog = A_log    + (size_t)idx*NH;
      const float* Dp   = D_param  + (size_t)idx*NH;
      const float* gw   = gnorm_w  + (size_t)idx*DIN;

      if(dir==0){
        k_cvt<<<(NTOK/4+TPB-1)/TPB,TPB,0,stream>>>(HN, Ubf, NTOK/4);
      }else{
        k_flip<<<gTok,TPB,0,stream>>>(HNF, HN);
        k_cvt<<<(NTOK/4+TPB-1)/TPB,TPB,0,stream>>>(HNF, Ubf, NTOK/4);
      }
      k_wt2<<<dim3(69,16),tb,0,stream>>>(in_proj_w + (size_t)idx*DM*DIP, WinTc, 512, 2192, 2192);
      k_mg<<<dim3(18,64),256,0,stream>>>(Ubf, WinTc, ZB, 8192, 2192, 512, 512, 512, 2192);

      k_conv4<<<(BS*512*CVD+TPB-1)/TPB,TPB,0,stream>>>(ZB, cw, cb, XC);
      k_dt<<<(BS*SEQL*NH+TPB-1)/TPB,TPB,0,stream>>>(ZB, dtb, Alog, DT, DA);
      k_acum<<<BS*NC*NH,256,0,stream>>>(DA, ACUM, CDEC);

      // ---- Y_diag via MFMA with fused G-formation ----
      k_bc<<<(NROWS*DST+TPB-1)/TPB,TPB,0,stream>>>(XC, Bbf, Cbf);
      k_mgb<<<dim3(2,2,32),256,0,stream>>>(Cbf, Bbf, Sf,
            256, 256, 64, 64, 64, 256, 16384, 16384, 65536, 0, 0);
      k_xdtt<<<dim3(2,8,512),tb,0,stream>>>(XC, DT, XdTg);
      k_mgg<<<dim3(1,2,512),256,0,stream>>>(Sf, ACUM, XdTg, Y);

      k_states<<<BS*NC*NH,256,0,stream>>>(XC, DT, ACUM, ST);
      k_scan<<<(BS*NH*4096+TPB-1)/TPB,TPB,0,stream>>>(ST, CDEC, PREV);
      // ---- Y_off via MFMA + fused gate epilogue ----
      k_cvt<<<(2097152/4+TPB-1)/TPB,TPB,0,stream>>>(PREV, PREVbf, 2097152/4);
      k_mgy<<<dim3(8,2,32),256,0,stream>>>(Cbf, PREVbf, ACUM, XC, ZB, Dp, Y);

      k_rms<<<NROWS,256,0,stream>>>(Y, gw);

      k_cvt<<<(2097152+TPB-1)/TPB,TPB,0,stream>>>(Y, Ybf, 2097152);
      k_wt2<<<dim3(16,32),tb,0,stream>>>(out_proj_w + (size_t)idx*DIN*DM, WoutTc, 1024, 512, 512);
      k_mg<<<dim3(4,64),256,0,stream>>>(Ybf, WoutTc, YD, 8192, 512, 1024, 1024, 1024, 512);

      k_add_flip<<<gTok,TPB,0,stream>>>(H, YD, dir);
    }
  }
  k_add_flip<<<gTok,TPB,0,stream>>>(RES, H, 0);
  k_ln<<<NROWS,TPB,0,stream>>>(RES, normf_w, normf_b, HF);

  // ================= attention head — MFMA (batched) =================
  float* P0   = ZB;
  float* QIN  = P0 + 0;
  float* CIN  = P0 + 2097152;
  float* QPb  = P0 + 4194304;
  float* CPb  = P0 + 6291456;
  float* QN   = P0 + 8388608;
  float* CN   = P0 + 10485760;
  float* AO   = P0 + 12582912;
  float* O1   = P0 + 14680064;
  float* D1   = P0 + 16777216;
  float* VV   = D1;
  u16* U0     = (u16*)(P0 + 20971520);
  u16* Qbf    = U0 + 0;
  u16* Cbf2   = U0 + 2097152;
  u16* QNbf   = U0 + 4194304;
  u16* CNbf   = U0 + 6291456;
  u16* QQbf   = U0 + 8388608;
  u16* KKbf   = U0 + 10485760;
  u16* VTbf   = U0 + 12582912;
  u16* AObf   = U0 + 14680064;
  u16* O1bf   = U0 + 16777216;
  u16* qpT    = U0 + 18874368;
  u16* cpT    = qpT + 262144;
  u16* qwT    = qpT + 524288;
  u16* kwT    = qpT + 786432;
  u16* vwT    = qpT + 1048576;
  u16* owT    = qpT + 1310720;
  u16* dec1T  = qpT + 1572864;
  u16* Pbf    = qpT + 2097152;

  const int M2 = BS*1024;
  k_extract<<<(BS*1024*DM+TPB-1)/TPB,TPB,0,stream>>>(HF, QIN, CIN);
  k_cvt<<<(2097152/4+TPB-1)/TPB,TPB,0,stream>>>(QIN, Qbf, 2097152/4);
  k_cvt<<<(2097152/4+TPB-1)/TPB,TPB,0,stream>>>(CIN, Cbf2, 2097152/4);
  k_wt2<<<dim3(16,16),tb,0,stream>>>(qp_w, qpT, 512, 512, 512);
  k_wt2<<<dim3(16,16),tb,0,stream>>>(cp_w, cpT, 512, 512, 512);
  k_wt2<<<dim3(16,16),tb,0,stream>>>(ca_qw, qwT, 512, 512, 512);
  k_wt2<<<dim3(16,16),tb,0,stream>>>(ca_kw, kwT, 512, 512, 512);
  k_wt2<<<dim3(16,16),tb,0,stream>>>(ca_vw, vwT, 512, 512, 512);
  k_wt2<<<dim3(16,16),tb,0,stream>>>(ca_ow, owT, 512, 512, 512);
  k_wt2<<<dim3(32,16),tb,0,stream>>>(dec1_w, dec1T, 512, 1024, 1024);

  k_mge<<<dim3(4,32),256,0,stream>>>(Qbf, qpT, qp_b, nullptr, QPb, nullptr,
                                     M2, 512, 512, 512, 512, 512, 1.f, 0);
  k_mge<<<dim3(4,32),256,0,stream>>>(Cbf2, cpT, cp_b, nullptr, CPb, nullptr,
                                     M2, 512, 512, 512, 512, 512, 1.f, 0);
  k_ln<<<M2,TPB,0,stream>>>(QPb, ca_nq_w, ca_nq_b, QN);
  k_ln<<<M2,TPB,0,stream>>>(CPb, ca_nkv_w, ca_nkv_b, CN);
  k_cvt<<<(2097152/4+TPB-1)/TPB,TPB,0,stream>>>(QN, QNbf, 2097152/4);
  k_cvt<<<(2097152/4+TPB-1)/TPB,TPB,0,stream>>>(CN, CNbf, 2097152/4);
  k_mge<<<dim3(4,32),256,0,stream>>>(QNbf, qwT, ca_qb, nullptr, nullptr, QQbf,
                                     M2, 512, 512, 512, 512, 512, 1.f, 0);
  k_mge<<<dim3(4,32),256,0,stream>>>(CNbf, kwT, ca_kb, nullptr, nullptr, KKbf,
                                     M2, 512, 512, 512, 512, 512, 1.f, 0);
  k_mge<<<dim3(4,32),256,0,stream>>>(CNbf, vwT, ca_vb, nullptr, VV, nullptr,
                                     M2, 512, 512, 512, 512, 512, 1.f, 0);
  k_vtb<<<dim3(4,32,16),tb,0,stream>>>(VV, VTbf);
  const float scl = 0.088388347648318447f;
  k_mgab<<<dim3(8,8,16),256,0,stream>>>(QQbf, KKbf, nullptr, Pbf,
        1024, 1024, 128, 512, 512, 1024,
        524288, 128, 524288, 128, 4194304, 1048576, scl);
  k_sm<<<16384,256,0,stream>>>(Pbf);
  k_mgab<<<dim3(1,8,16),256,0,stream>>>(Pbf, VTbf, AO, nullptr,
        1024, 128, 1024, 1024, 1024, 512,
        4194304, 1048576, 524288, 131072, 524288, 128, 1.f);
  k_cvt<<<(2097152/4+TPB-1)/TPB,TPB,0,stream>>>(AO, AObf, 2097152/4);
  k_mge<<<dim3(4,32),256,0,stream>>>(AObf, owT, ca_ob, QPb, O1, nullptr,
                                     M2, 512, 512, 512, 512, 512, 1.f, 0);
  k_cvt<<<(2097152/4+TPB-1)/TPB,TPB,0,stream>>>(O1, O1bf, 2097152/4);
  k_mge<<<dim3(8,32),256,0,stream>>>(O1bf, dec1T, dec1_b, nullptr, D1, nullptr,
                                     M2, 1024, 512, 512, 512, 1024, 1.f, 1);
  k_dec2<<<M2,256,0,stream>>>(D1, dec2_w, dec2_b, (float*)d_out);
}

// Round 16
// 1444.758 us; speedup vs baseline: 224.8759x; 1.0694x over previous
//
#include <hip/hip_runtime.h>
#include <hip/hip_bf16.h>

#define BS 4
#define SEQL 2048
#define DM 512
#define DIN 1024
#define NH 16
#define HD 64
#define DST 64
#define NC 8
#define CKS 256
#define DIP 2192
#define CVD 1152
#define NROWS (BS*SEQL)          /* 8192 */
#define NTOK (BS*SEQL*DM)        /* 4194304 */

typedef unsigned short u16;
typedef __bf16 bf16x8 __attribute__((ext_vector_type(8)));
typedef float f32x4 __attribute__((ext_vector_type(4)));

__device__ __forceinline__ u16 cvt_bf16(float f){
  unsigned int x = __float_as_uint(f);
  unsigned int r = x + 0x7fffu + ((x>>16)&1u);
  return (u16)(r>>16);
}
__device__ __forceinline__ float bf2f(u16 u){
  return __uint_as_float(((unsigned int)u)<<16);
}

// ---------------- elementwise (proven) ----------------
__global__ void k_add_flip(float* __restrict__ dst, const float* __restrict__ src, int flip){
  int i = blockIdx.x*256 + threadIdx.x;
  if(i >= NTOK) return;
  int d = i & (DM-1);
  int l = (i >> 9) & (SEQL-1);
  int b = i >> 20;
  int sl = flip ? (SEQL-1-l) : l;
  dst[i] += src[(b*SEQL + sl)*DM + d];
}

__global__ void k_flip(float* __restrict__ dst, const float* __restrict__ src){
  int i = blockIdx.x*256 + threadIdx.x;
  if(i >= NTOK) return;
  int d = i & (DM-1);
  int l = (i >> 9) & (SEQL-1);
  int b = i >> 20;
  dst[i] = src[(b*SEQL + (SEQL-1-l))*DM + d];
}

// f32 -> bf16 (verified round-8)
__global__ void k_cvt(const float* __restrict__ src, u16* __restrict__ dst, int n4){
  int i = blockIdx.x*256 + threadIdx.x;
  if(i >= n4) return;
  float4 f = reinterpret_cast<const float4*>(src)[i];
  ushort4 o; o.x=cvt_bf16(f.x); o.y=cvt_bf16(f.y); o.z=cvt_bf16(f.z); o.w=cvt_bf16(f.w);
  reinterpret_cast<ushort4*>(dst)[i] = o;
}

__global__ void k_ln(const float* __restrict__ X, const float* __restrict__ w,
                     const float* __restrict__ bb, float* __restrict__ O){
  int row = blockIdx.x, tid = threadIdx.x;
  const float* x = X + (size_t)row*DM;
  float* o = O + (size_t)row*DM;
  float s=0.f, s2=0.f;
  for(int j=tid;j<DM;j+=256){ float v=x[j]; s+=v; s2+=v*v; }
  __shared__ float r1[256], r2[256];
  r1[tid]=s; r2[tid]=s2; __syncthreads();
  for(int off=128;off>0;off>>=1){
    if(tid<off){ r1[tid]+=r1[tid+off]; r2[tid]+=r2[tid+off]; }
    __syncthreads();
  }
  float m = r1[0]*(1.f/DM);
  float var = r2[0]*(1.f/DM) - m*m;
  float inv = rsqrtf(var + 1e-5f);
  for(int j=tid;j<DM;j+=256) o[j] = (x[j]-m)*inv*w[j] + bb[j];
}

__global__ void k_rms(float* __restrict__ Y, const float* __restrict__ gw){
  int row = blockIdx.x, tid = threadIdx.x;
  float* y = Y + (size_t)row*DIN;
  float ss=0.f;
  for(int j=tid;j<DIN;j+=256){ float v=y[j]; ss+=v*v; }
  __shared__ float red[256];
  red[tid]=ss; __syncthreads();
  for(int off=128;off>0;off>>=1){
    if(tid<off) red[tid]+=red[tid+off];
    __syncthreads();
  }
  float inv = rsqrtf(red[0]*(1.f/DIN) + 1e-5f);
  for(int j=tid;j<DIN;j+=256) y[j] = y[j]*inv*gw[j];
}

// dec2: out[row][0..9] = D1[row]·dec2_w + b ; one block per row
__global__ void k_dec2(const float* __restrict__ D1, const float* __restrict__ w,
                       const float* __restrict__ bb, float* __restrict__ out){
  int row = blockIdx.x, tid = threadIdx.x;
  int lane = tid & 63, wave = tid >> 6;
  const float* x = D1 + (size_t)row*1024;
  float acc[10];
  #pragma unroll
  for(int o=0;o<10;o++) acc[o]=0.f;
  for(int j=tid;j<1024;j+=256){
    float v = x[j];
    const float* wr = w + (size_t)j*10;
    #pragma unroll
    for(int o=0;o<10;o++) acc[o] += v*wr[o];
  }
  __shared__ float red[4][10];
  #pragma unroll
  for(int o=0;o<10;o++){
    float v = acc[o];
    #pragma unroll
    for(int s=32;s>0;s>>=1) v += __shfl_down(v, s, 64);
    if(lane==0) red[wave][o] = v;
  }
  __syncthreads();
  if(tid < 10)
    out[(size_t)row*10 + tid] = red[0][tid]+red[1][tid]+red[2][tid]+red[3][tid] + bb[tid];
}

// transpose-convert with explicit src ld (verified): src[K][lds] f32 -> dst[N][K] bf16
__global__ void k_wt2(const float* __restrict__ src, u16* __restrict__ dst,
                      int K, int N, int lds){
  __shared__ float t[32][33];
  int n0 = blockIdx.x*32, k0 = blockIdx.y*32;
  int tx = threadIdx.x, ty = threadIdx.y;
  #pragma unroll
  for(int i=0;i<32;i+=8){
    int k = k0+ty+i, n = n0+tx;
    t[ty+i][tx] = (n<N) ? src[(size_t)k*lds+n] : 0.f;
  }
  __syncthreads();
  #pragma unroll
  for(int i=0;i<32;i+=8){
    int n = n0+ty+i, k = k0+tx;
    if(n<N) dst[(size_t)n*K+k] = cvt_bf16(t[tx][ty+i]);
  }
}

// batched V-transpose: per z=(b*4+h): src=VV+b*524288+h*128 [1024][128 of 512] -> dst [128][1024]
__global__ void k_vtb(const float* __restrict__ VV, u16* __restrict__ VT){
  __shared__ float t[32][33];
  int z = blockIdx.z, b = z>>2, h = z&3;
  const float* src = VV + (size_t)b*524288 + h*128;
  u16* dst = VT + (size_t)z*131072;
  int n0 = blockIdx.x*32, k0 = blockIdx.y*32;
  int tx = threadIdx.x, ty = threadIdx.y;
  #pragma unroll
  for(int i=0;i<32;i+=8){
    int k = k0+ty+i, n = n0+tx;
    t[ty+i][tx] = src[(size_t)k*512+n];
  }
  __syncthreads();
  #pragma unroll
  for(int i=0;i<32;i+=8){
    int n = n0+ty+i, k = k0+tx;
    dst[(size_t)n*1024+k] = cvt_bf16(t[tx][ty+i]);
  }
}

// XdT via LDS-tiled transpose: per z=(bc*16+h), XdT[z][p][s] = bf16(XC[..]*DT[..])
__global__ void k_xdtt(const float* __restrict__ XC, const float* __restrict__ DT,
                       u16* __restrict__ XdT){
  __shared__ float t[32][33];
  int z = blockIdx.z;
  int h = z & 15, bc = z >> 4;
  int b = bc >> 3, c = bc & 7;
  int p0 = blockIdx.x*32, s0 = blockIdx.y*32;
  int tx = threadIdx.x, ty = threadIdx.y;
  int gbase = b*SEQL + c*CKS;
  #pragma unroll
  for(int i=0;i<32;i+=8){
    int s = s0+ty+i, p = p0+tx;
    int g = gbase + s;
    t[ty+i][tx] = XC[(size_t)g*CVD + h*HD + p] * DT[(size_t)g*NH + h];
  }
  __syncthreads();
  u16* dst = XdT + (size_t)z*16384;
  #pragma unroll
  for(int i=0;i<32;i+=8){
    int p = p0+ty+i, s = s0+tx;
    dst[(size_t)p*256 + s] = cvt_bf16(t[tx][ty+i]);
  }
}

// batched B-transpose: per bc: Bbf[bc] [256][64] -> BTc[bc][64][256]  (k_wt2 pattern)
__global__ void k_btc(const u16* __restrict__ Bbf, u16* __restrict__ BTc){
  __shared__ u16 t[32][33];
  int bc = blockIdx.z;
  const u16* src = Bbf + (size_t)bc*16384;
  u16* dst = BTc + (size_t)bc*16384;
  int n0 = blockIdx.x*32, l0 = blockIdx.y*32;
  int tx = threadIdx.x, ty = threadIdx.y;
  #pragma unroll
  for(int i=0;i<32;i+=8){
    int l = l0+ty+i, n = n0+tx;
    t[ty+i][tx] = src[(size_t)l*64+n];
  }
  __syncthreads();
  #pragma unroll
  for(int i=0;i<32;i+=8){
    int n = n0+ty+i, l = l0+tx;
    dst[(size_t)n*256+l] = t[tx][ty+i];
  }
}

// ---------------- MFMA bf16 GEMM, emap0 (HW-verified) ----------------
__global__ __launch_bounds__(256) void k_mg(
    const u16* __restrict__ A, const u16* __restrict__ BT,
    float* __restrict__ C, int M, int N, int K, int lda, int ldb, int ldc)
{
  __shared__ uint4 As4[128*5];
  __shared__ uint4 Bs4[128*5];
  const int tid = threadIdx.x;
  const int row0 = blockIdx.y*128, col0 = blockIdx.x*128;
  const int lane = tid & 63, wave = tid >> 6;
  const int wm = wave >> 1, wn = wave & 1;
  const int lr = lane & 15, ksg = (lane >> 4);
  f32x4 acc[4][4];
  #pragma unroll
  for(int i=0;i<4;i++)
    #pragma unroll
    for(int j=0;j<4;j++) acc[i][j] = (f32x4){0.f,0.f,0.f,0.f};
  for(int k0=0;k0<K;k0+=32){
    #pragma unroll
    for(int i=0;i<2;i++){
      int t2 = tid + i*256;
      int rr = t2 >> 2, sg = (t2 & 3);
      uint4 av = *reinterpret_cast<const uint4*>(A + (size_t)(row0+rr)*lda + k0 + sg*8);
      uint4 bv = {0u,0u,0u,0u};
      if(col0+rr < N) bv = *reinterpret_cast<const uint4*>(BT + (size_t)(col0+rr)*ldb + k0 + sg*8);
      As4[rr*5 + sg] = av;
      Bs4[rr*5 + sg] = bv;
    }
    __syncthreads();
    bf16x8 afr[4], bfr[4];
    #pragma unroll
    for(int i=0;i<4;i++) afr[i] = *reinterpret_cast<const bf16x8*>(&As4[(wm*64+i*16+lr)*5 + ksg]);
    #pragma unroll
    for(int j=0;j<4;j++) bfr[j] = *reinterpret_cast<const bf16x8*>(&Bs4[(wn*64+j*16+lr)*5 + ksg]);
    #pragma unroll
    for(int i=0;i<4;i++)
      #pragma unroll
      for(int j=0;j<4;j++)
        acc[i][j] = __builtin_amdgcn_mfma_f32_16x16x32_bf16(afr[i], bfr[j], acc[i][j], 0, 0, 0);
    __syncthreads();
  }
  const int hi = lane >> 4, lo = lane & 15;
  #pragma unroll
  for(int i=0;i<4;i++)
    #pragma unroll
    for(int j=0;j<4;j++)
      #pragma unroll
      for(int r=0;r<4;r++){
        int row = row0 + wm*64 + i*16 + 4*hi + r;
        int col = col0 + wn*64 + j*16 + lo;
        if(col < N) C[(size_t)row*ldc + col] = acc[i][j][r];
      }
}

// batched variant: verified core + z-strided base offsets only
__global__ __launch_bounds__(256) void k_mgb(
    const u16* __restrict__ A0, const u16* __restrict__ BT0,
    float* __restrict__ C0, int M, int N, int K, int lda, int ldb, int ldc,
    long sAz, long sBz, long sCo, long sCi, int shC)
{
  const int z = blockIdx.z;
  const u16* A  = A0  + (size_t)z*sAz;
  const u16* BT = BT0 + (size_t)z*sBz;
  float* C = C0 + (size_t)(z>>shC)*sCo + (size_t)(z & ((1<<shC)-1))*sCi;
  __shared__ uint4 As4[128*5];
  __shared__ uint4 Bs4[128*5];
  const int tid = threadIdx.x;
  const int row0 = blockIdx.y*128, col0 = blockIdx.x*128;
  const int lane = tid & 63, wave = tid >> 6;
  const int wm = wave >> 1, wn = wave & 1;
  const int lr = lane & 15, ksg = (lane >> 4);
  f32x4 acc[4][4];
  #pragma unroll
  for(int i=0;i<4;i++)
    #pragma unroll
    for(int j=0;j<4;j++) acc[i][j] = (f32x4){0.f,0.f,0.f,0.f};
  for(int k0=0;k0<K;k0+=32){
    #pragma unroll
    for(int i=0;i<2;i++){
      int t2 = tid + i*256;
      int rr = t2 >> 2, sg = (t2 & 3);
      uint4 av = *reinterpret_cast<const uint4*>(A + (size_t)(row0+rr)*lda + k0 + sg*8);
      uint4 bv = {0u,0u,0u,0u};
      if(col0+rr < N) bv = *reinterpret_cast<const uint4*>(BT + (size_t)(col0+rr)*ldb + k0 + sg*8);
      As4[rr*5 + sg] = av;
      Bs4[rr*5 + sg] = bv;
    }
    __syncthreads();
    bf16x8 afr[4], bfr[4];
    #pragma unroll
    for(int i=0;i<4;i++) afr[i] = *reinterpret_cast<const bf16x8*>(&As4[(wm*64+i*16+lr)*5 + ksg]);
    #pragma unroll
    for(int j=0;j<4;j++) bfr[j] = *reinterpret_cast<const bf16x8*>(&Bs4[(wn*64+j*16+lr)*5 + ksg]);
    #pragma unroll
    for(int i=0;i<4;i++)
      #pragma unroll
      for(int j=0;j<4;j++)
        acc[i][j] = __builtin_amdgcn_mfma_f32_16x16x32_bf16(afr[i], bfr[j], acc[i][j], 0, 0, 0);
    __syncthreads();
  }
  const int hi = lane >> 4, lo = lane & 15;
  #pragma unroll
  for(int i=0;i<4;i++)
    #pragma unroll
    for(int j=0;j<4;j++)
      #pragma unroll
      for(int r=0;r<4;r++){
        int row = row0 + wm*64 + i*16 + 4*hi + r;
        int col = col0 + wn*64 + j*16 + lo;
        if(col < N) C[(size_t)row*ldc + col] = acc[i][j][r];
      }
}

// Y_diag GEMM with fused G-formation in A-staging
__global__ __launch_bounds__(256) void k_mgg(
    const float* __restrict__ Sf, const float* __restrict__ ACUM,
    const u16* __restrict__ XdT, float* __restrict__ Y)
{
  const int z = blockIdx.z;
  const int h = z & 15, bc = z >> 4;
  const int b = bc >> 3, c = bc & 7;
  const float* Az = Sf + (size_t)bc*65536;
  const float* Acp = ACUM + (size_t)z*256;
  const u16* BT = XdT + (size_t)z*16384;
  float* Cp = Y + (size_t)b*2097152 + (size_t)c*262144 + h*64;
  __shared__ uint4 As4[128*5];
  __shared__ uint4 Bs4[128*5];
  __shared__ float AcS[256];
  const int tid = threadIdx.x;
  AcS[tid] = Acp[tid];
  __syncthreads();
  const int row0 = blockIdx.y*128;
  const int lane = tid & 63, wave = tid >> 6;
  const int wm = wave >> 1, wn = wave & 1;
  const int lr = lane & 15, ksg = (lane >> 4);
  f32x4 acc[4][4];
  #pragma unroll
  for(int i=0;i<4;i++)
    #pragma unroll
    for(int j=0;j<4;j++) acc[i][j] = (f32x4){0.f,0.f,0.f,0.f};
  for(int k0=0;k0<256;k0+=32){
    #pragma unroll
    for(int i=0;i<2;i++){
      int t2 = tid + i*256;
      int rr = t2 >> 2, sg = (t2 & 3);
      int l = row0 + rr;
      int sbase = k0 + sg*8;
      float4 v0 = *reinterpret_cast<const float4*>(Az + (size_t)l*256 + sbase);
      float4 v1 = *reinterpret_cast<const float4*>(Az + (size_t)l*256 + sbase + 4);
      float acl = AcS[l];
      float vv[8] = {v0.x,v0.y,v0.z,v0.w,v1.x,v1.y,v1.z,v1.w};
      u16 gbuf[8];
      #pragma unroll
      for(int e=0;e<8;e++){
        int s = sbase + e;
        float g = 0.f;
        if(s <= l) g = __expf(acl - AcS[s]) * vv[e];
        gbuf[e] = cvt_bf16(g);
      }
      As4[rr*5 + sg] = *reinterpret_cast<uint4*>(gbuf);
      uint4 bv = {0u,0u,0u,0u};
      if(rr < 64) bv = *reinterpret_cast<const uint4*>(BT + (size_t)rr*256 + sbase);
      Bs4[rr*5 + sg] = bv;
    }
    __syncthreads();
    bf16x8 afr[4], bfr[4];
    #pragma unroll
    for(int i=0;i<4;i++) afr[i] = *reinterpret_cast<const bf16x8*>(&As4[(wm*64+i*16+lr)*5 + ksg]);
    #pragma unroll
    for(int j=0;j<4;j++) bfr[j] = *reinterpret_cast<const bf16x8*>(&Bs4[(wn*64+j*16+lr)*5 + ksg]);
    #pragma unroll
    for(int i=0;i<4;i++)
      #pragma unroll
      for(int j=0;j<4;j++)
        acc[i][j] = __builtin_amdgcn_mfma_f32_16x16x32_bf16(afr[i], bfr[j], acc[i][j], 0, 0, 0);
    __syncthreads();
  }
  const int hi = lane >> 4, lo = lane & 15;
  #pragma unroll
  for(int i=0;i<4;i++)
    #pragma unroll
    for(int j=0;j<4;j++)
      #pragma unroll
      for(int r=0;r<4;r++){
        int row = row0 + wm*64 + i*16 + 4*hi + r;
        int col = wn*64 + j*16 + lo;
        if(col < 64) Cp[(size_t)row*1024 + col] = acc[i][j][r];
      }
}

// states via MFMA: per z=(bc*16+h): ST[z][p][n] = sum_l (XdT[z][p][l]*dec[l]) * B[bc][l][n]
__global__ __launch_bounds__(256) void k_mgs(
    const u16* __restrict__ XdT, const u16* __restrict__ BTc,
    const float* __restrict__ ACUM, float* __restrict__ ST)
{
  const int z = blockIdx.z;
  const int bc = z >> 4;
  const u16* Ap = XdT + (size_t)z*16384;
  const u16* BT = BTc + (size_t)bc*16384;
  float* Cp = ST + (size_t)z*4096;
  __shared__ uint4 As4[128*5];
  __shared__ uint4 Bs4[128*5];
  __shared__ float decS[256];
  const int tid = threadIdx.x;
  {
    const float* Acp = ACUM + (size_t)z*256;
    decS[tid] = __expf(Acp[255] - Acp[tid]);
  }
  __syncthreads();
  const int lane = tid & 63, wave = tid >> 6;
  const int wm = wave >> 1, wn = wave & 1;
  const int lr = lane & 15, ksg = (lane >> 4);
  f32x4 acc[4][4];
  #pragma unroll
  for(int i=0;i<4;i++)
    #pragma unroll
    for(int j=0;j<4;j++) acc[i][j] = (f32x4){0.f,0.f,0.f,0.f};
  for(int k0=0;k0<256;k0+=32){
    #pragma unroll
    for(int i=0;i<2;i++){
      int t2 = tid + i*256;
      int rr = t2 >> 2, sg = (t2 & 3);
      int sbase = k0 + sg*8;
      uint4 av = {0u,0u,0u,0u};
      if(rr < 64){
        uint4 raw = *reinterpret_cast<const uint4*>(Ap + (size_t)rr*256 + sbase);
        const u16* rp = reinterpret_cast<const u16*>(&raw);
        u16 buf[8];
        #pragma unroll
        for(int e=0;e<8;e++) buf[e] = cvt_bf16(bf2f(rp[e]) * decS[sbase+e]);
        av = *reinterpret_cast<uint4*>(buf);
      }
      As4[rr*5 + sg] = av;
      uint4 bv = {0u,0u,0u,0u};
      if(rr < 64) bv = *reinterpret_cast<const uint4*>(BT + (size_t)rr*256 + sbase);
      Bs4[rr*5 + sg] = bv;
    }
    __syncthreads();
    bf16x8 afr[4], bfr[4];
    #pragma unroll
    for(int i=0;i<4;i++) afr[i] = *reinterpret_cast<const bf16x8*>(&As4[(wm*64+i*16+lr)*5 + ksg]);
    #pragma unroll
    for(int j=0;j<4;j++) bfr[j] = *reinterpret_cast<const bf16x8*>(&Bs4[(wn*64+j*16+lr)*5 + ksg]);
    #pragma unroll
    for(int i=0;i<4;i++)
      #pragma unroll
      for(int j=0;j<4;j++)
        acc[i][j] = __builtin_amdgcn_mfma_f32_16x16x32_bf16(afr[i], bfr[j], acc[i][j], 0, 0, 0);
    __syncthreads();
  }
  const int hi = lane >> 4, lo = lane & 15;
  #pragma unroll
  for(int i=0;i<4;i++)
    #pragma unroll
    for(int j=0;j<4;j++)
      #pragma unroll
      for(int r=0;r<4;r++){
        int row = wm*64 + i*16 + 4*hi + r;
        int col = wn*64 + j*16 + lo;
        if(row < 64 && col < 64) Cp[(size_t)row*64 + col] = acc[i][j][r];
      }
}

// batched attention GEMM: (z>>2)/(z&3) offsets for A/B/C, scale, f32 or bf16 out
__global__ __launch_bounds__(256) void k_mgab(
    const u16* __restrict__ A0, const u16* __restrict__ BT0,
    float* __restrict__ C0, u16* __restrict__ Cb0,
    int M, int N, int K, int lda, int ldb, int ldc,
    long sAo, long sAi, long sBo, long sBi, long sCo, long sCi, float scale)
{
  const int z = blockIdx.z;
  const u16* A  = A0  + (size_t)(z>>2)*sAo + (size_t)(z&3)*sAi;
  const u16* BT = BT0 + (size_t)(z>>2)*sBo + (size_t)(z&3)*sBi;
  const size_t offC = (size_t)(z>>2)*sCo + (size_t)(z&3)*sCi;
  __shared__ uint4 As4[128*5];
  __shared__ uint4 Bs4[128*5];
  const int tid = threadIdx.x;
  const int row0 = blockIdx.y*128, col0 = blockIdx.x*128;
  const int lane = tid & 63, wave = tid >> 6;
  const int wm = wave >> 1, wn = wave & 1;
  const int lr = lane & 15, ksg = (lane >> 4);
  f32x4 acc[4][4];
  #pragma unroll
  for(int i=0;i<4;i++)
    #pragma unroll
    for(int j=0;j<4;j++) acc[i][j] = (f32x4){0.f,0.f,0.f,0.f};
  for(int k0=0;k0<K;k0+=32){
    #pragma unroll
    for(int i=0;i<2;i++){
      int t2 = tid + i*256;
      int rr = t2 >> 2, sg = (t2 & 3);
      uint4 av = *reinterpret_cast<const uint4*>(A + (size_t)(row0+rr)*lda + k0 + sg*8);
      uint4 bv = {0u,0u,0u,0u};
      if(col0+rr < N) bv = *reinterpret_cast<const uint4*>(BT + (size_t)(col0+rr)*ldb + k0 + sg*8);
      As4[rr*5 + sg] = av;
      Bs4[rr*5 + sg] = bv;
    }
    __syncthreads();
    bf16x8 afr[4], bfr[4];
    #pragma unroll
    for(int i=0;i<4;i++) afr[i] = *reinterpret_cast<const bf16x8*>(&As4[(wm*64+i*16+lr)*5 + ksg]);
    #pragma unroll
    for(int j=0;j<4;j++) bfr[j] = *reinterpret_cast<const bf16x8*>(&Bs4[(wn*64+j*16+lr)*5 + ksg]);
    #pragma unroll
    for(int i=0;i<4;i++)
      #pragma unroll
      for(int j=0;j<4;j++)
        acc[i][j] = __builtin_amdgcn_mfma_f32_16x16x32_bf16(afr[i], bfr[j], acc[i][j], 0, 0, 0);
    __syncthreads();
  }
  const int hi = lane >> 4, lo = lane & 15;
  #pragma unroll
  for(int i=0;i<4;i++)
    #pragma unroll
    for(int j=0;j<4;j++)
      #pragma unroll
      for(int r=0;r<4;r++){
        int row = row0 + wm*64 + i*16 + 4*hi + r;
        int col = col0 + wn*64 + j*16 + lo;
        if(col < N){
          float v = acc[i][j][r] * scale;
          size_t ci = offC + (size_t)row*ldc + col;
          if(C0) C0[ci] = v;
          else   Cb0[ci] = cvt_bf16(v);
        }
      }
}

// Y_off GEMM fused with yfinal epilogue
__global__ __launch_bounds__(256) void k_mgy(
    const u16* __restrict__ Cb0, const u16* __restrict__ PV0,
    const float* __restrict__ ACUM, const float* __restrict__ XCp,
    const float* __restrict__ ZBp, const float* __restrict__ Dp,
    float* __restrict__ Y)
{
  const int z = blockIdx.z;                 // b*8+c
  const int b = z>>3, c = z&7;
  const u16* A  = Cb0 + (size_t)z*16384;    // [256][64] bf16
  const u16* BT = PV0 + (size_t)z*65536;    // [1024][64] bf16
  const int N = 1024;
  __shared__ uint4 As4[128*5];
  __shared__ uint4 Bs4[128*5];
  const int tid = threadIdx.x;
  const int row0 = blockIdx.y*128, col0 = blockIdx.x*128;
  const int lane = tid & 63, wave = tid >> 6;
  const int wm = wave >> 1, wn = wave & 1;
  const int lr = lane & 15, ksg = (lane >> 4);
  f32x4 acc[4][4];
  #pragma unroll
  for(int i=0;i<4;i++)
    #pragma unroll
    for(int j=0;j<4;j++) acc[i][j] = (f32x4){0.f,0.f,0.f,0.f};
  for(int k0=0;k0<64;k0+=32){
    #pragma unroll
    for(int i=0;i<2;i++){
      int t2 = tid + i*256;
      int rr = t2 >> 2, sg = (t2 & 3);
      uint4 av = *reinterpret_cast<const uint4*>(A + (size_t)(row0+rr)*64 + k0 + sg*8);
      uint4 bv = {0u,0u,0u,0u};
      if(col0+rr < N) bv = *reinterpret_cast<const uint4*>(BT + (size_t)(col0+rr)*64 + k0 + sg*8);
      As4[rr*5 + sg] = av;
      Bs4[rr*5 + sg] = bv;
    }
    __syncthreads();
    bf16x8 afr[4], bfr[4];
    #pragma unroll
    for(int i=0;i<4;i++) afr[i] = *reinterpret_cast<const bf16x8*>(&As4[(wm*64+i*16+lr)*5 + ksg]);
    #pragma unroll
    for(int j=0;j<4;j++) bfr[j] = *reinterpret_cast<const bf16x8*>(&Bs4[(wn*64+j*16+lr)*5 + ksg]);
    #pragma unroll
    for(int i=0;i<4;i++)
      #pragma unroll
      for(int j=0;j<4;j++)
        acc[i][j] = __builtin_amdgcn_mfma_f32_16x16x32_bf16(afr[i], bfr[j], acc[i][j], 0, 0, 0);
    __syncthreads();
  }
  const int hi = lane >> 4, lo = lane & 15;
  #pragma unroll
  for(int i=0;i<4;i++)
    #pragma unroll
    for(int j=0;j<4;j++)
      #pragma unroll
      for(int r=0;r<4;r++){
        int row = row0 + wm*64 + i*16 + 4*hi + r;
        int col = col0 + wn*64 + j*16 + lo;
        int h = col >> 6;
        int g = b*SEQL + c*CKS + row;
        float ac = ACUM[((size_t)z*NH + h)*CKS + row];
        float xh = XCp[(size_t)g*CVD + col];
        float zg = ZBp[(size_t)g*DIP + col];
        size_t ci = (size_t)g*DIN + col;
        float v = Y[ci] + expf(ac)*acc[i][j][r] + Dp[h]*xh;
        float sig = 1.f/(1.f+expf(-zg));
        Y[ci] = v * (zg*sig);
      }
}

// verified core + arithmetic epilogue (attention projections)
__global__ __launch_bounds__(256) void k_mge(
    const u16* __restrict__ A, const u16* __restrict__ BT,
    const float* __restrict__ bias, const float* __restrict__ res,
    float* __restrict__ C, u16* __restrict__ Cbf,
    int M, int N, int K, int lda, int ldb, int ldc, float scale, int act)
{
  __shared__ uint4 As4[128*5];
  __shared__ uint4 Bs4[128*5];
  const int tid = threadIdx.x;
  const int row0 = blockIdx.y*128, col0 = blockIdx.x*128;
  const int lane = tid & 63, wave = tid >> 6;
  const int wm = wave >> 1, wn = wave & 1;
  const int lr = lane & 15, ksg = (lane >> 4);
  f32x4 acc[4][4];
  #pragma unroll
  for(int i=0;i<4;i++)
    #pragma unroll
    for(int j=0;j<4;j++) acc[i][j] = (f32x4){0.f,0.f,0.f,0.f};
  for(int k0=0;k0<K;k0+=32){
    #pragma unroll
    for(int i=0;i<2;i++){
      int t2 = tid + i*256;
      int rr = t2 >> 2, sg = (t2 & 3);
      uint4 av = *reinterpret_cast<const uint4*>(A + (size_t)(row0+rr)*lda + k0 + sg*8);
      uint4 bv = {0u,0u,0u,0u};
      if(col0+rr < N) bv = *reinterpret_cast<const uint4*>(BT + (size_t)(col0+rr)*ldb + k0 + sg*8);
      As4[rr*5 + sg] = av;
      Bs4[rr*5 + sg] = bv;
    }
    __syncthreads();
    bf16x8 afr[4], bfr[4];
    #pragma unroll
    for(int i=0;i<4;i++) afr[i] = *reinterpret_cast<const bf16x8*>(&As4[(wm*64+i*16+lr)*5 + ksg]);
    #pragma unroll
    for(int j=0;j<4;j++) bfr[j] = *reinterpret_cast<const bf16x8*>(&Bs4[(wn*64+j*16+lr)*5 + ksg]);
    #pragma unroll
    for(int i=0;i<4;i++)
      #pragma unroll
      for(int j=0;j<4;j++)
        acc[i][j] = __builtin_amdgcn_mfma_f32_16x16x32_bf16(afr[i], bfr[j], acc[i][j], 0, 0, 0);
    __syncthreads();
  }
  const int hi = lane >> 4, lo = lane & 15;
  #pragma unroll
  for(int i=0;i<4;i++)
    #pragma unroll
    for(int j=0;j<4;j++)
      #pragma unroll
      for(int r=0;r<4;r++){
        int row = row0 + wm*64 + i*16 + 4*hi + r;
        int col = col0 + wn*64 + j*16 + lo;
        if(col < N){
          float v = acc[i][j][r];
          if(bias) v += bias[col];
          v *= scale;
          if(act==1) v = 0.5f*v*(1.f+erff(v*0.70710678118654752f));
          size_t ci = (size_t)row*ldc + col;
          if(res) v += res[ci];
          if(C) C[ci] = v;
          else  Cbf[ci] = cvt_bf16(v);
        }
      }
}

// in-place row softmax over 1024 bf16
__global__ void k_sm(u16* __restrict__ S){
  size_t row = blockIdx.x;
  u16* p = S + row*1024;
  int tid = threadIdx.x;
  ushort4 u = reinterpret_cast<ushort4*>(p)[tid];
  float v0=bf2f(u.x), v1=bf2f(u.y), v2=bf2f(u.z), v3=bf2f(u.w);
  float m = fmaxf(fmaxf(v0,v1),fmaxf(v2,v3));
  __shared__ float red[256];
  red[tid]=m; __syncthreads();
  for(int o=128;o>0;o>>=1){ if(tid<o) red[tid]=fmaxf(red[tid],red[tid+o]); __syncthreads(); }
  m = red[0]; __syncthreads();
  v0=__expf(v0-m); v1=__expf(v1-m); v2=__expf(v2-m); v3=__expf(v3-m);
  float s = v0+v1+v2+v3;
  red[tid]=s; __syncthreads();
  for(int o=128;o>0;o>>=1){ if(tid<o) red[tid]+=red[tid+o]; __syncthreads(); }
  float inv = 1.f/red[0];
  ushort4 o4; o4.x=cvt_bf16(v0*inv); o4.y=cvt_bf16(v1*inv); o4.z=cvt_bf16(v2*inv); o4.w=cvt_bf16(v3*inv);
  reinterpret_cast<ushort4*>(p)[tid] = o4;
}

// ---------------- mamba pieces ----------------
__global__ void k_conv4(const float* __restrict__ ZB, const float* __restrict__ cw,
                        const float* __restrict__ cb, float* __restrict__ XC){
  int i = blockIdx.x*256 + threadIdx.x;   // over BS*512*CVD
  if(i >= BS*512*CVD) return;
  int cch = i % CVD;
  int lq = (i / CVD) & 511;
  int b = i / (CVD*512);
  int l0 = lq*4;
  float w[7];
  #pragma unroll
  for(int t=0;t<7;t++){
    int sl = l0 - 3 + t;
    w[t] = (sl >= 0) ? ZB[(size_t)(b*SEQL+sl)*DIP + DIN + cch] : 0.f;
  }
  float c0 = cw[cch*4+0], c1 = cw[cch*4+1], c2 = cw[cch*4+2], c3 = cw[cch*4+3];
  float bb2 = cb[cch];
  #pragma unroll
  for(int j=0;j<4;j++){
    float v = bb2 + w[j]*c0 + w[j+1]*c1 + w[j+2]*c2 + w[j+3]*c3;
    float sig = 1.f/(1.f+expf(-v));
    XC[(size_t)(b*SEQL + l0 + j)*CVD + cch] = v*sig;
  }
}

__global__ void k_dt(const float* __restrict__ ZB, const float* __restrict__ dtb,
                     const float* __restrict__ Alog, float* __restrict__ DT,
                     float* __restrict__ DA){
  int i = blockIdx.x*256 + threadIdx.x;
  if(i >= BS*SEQL*NH) return;
  int h = i & (NH-1);
  int row = i >> 4;
  float raw = ZB[(size_t)row*DIP + (DIN+CVD) + h] + dtb[h];
  float dt = fmaxf(raw,0.f) + log1pf(expf(-fabsf(raw)));
  DT[i] = dt;
  DA[i] = dt * (-expf(Alog[h]));
}

__global__ void k_acum(const float* __restrict__ DA, float* __restrict__ ACUM,
                       float* __restrict__ CDEC){
  int blk = blockIdx.x;
  int h = blk & 15, c = (blk>>4)&7, b = blk>>7;
  int l = threadIdx.x;
  __shared__ float s[256];
  int gl = c*CKS + l;
  s[l] = DA[(size_t)(b*SEQL + gl)*NH + h];
  __syncthreads();
  for(int off=1; off<256; off<<=1){
    float v = (l>=off) ? s[l-off] : 0.f;
    __syncthreads();
    s[l] += v;
    __syncthreads();
  }
  ACUM[(size_t)blk*CKS + l] = s[l];
  if(l==255) CDEC[blk] = expf(s[255]);
}

// extract B,C as bf16 [8192][64]
__global__ void k_bc(const float* __restrict__ XC, u16* __restrict__ Bbf,
                     u16* __restrict__ Cbf){
  int i = blockIdx.x*256 + threadIdx.x;
  if(i >= NROWS*DST) return;
  int g = i >> 6, n = i & 63;
  Bbf[i] = cvt_bf16(XC[(size_t)g*CVD + DIN + n]);
  Cbf[i] = cvt_bf16(XC[(size_t)g*CVD + DIN + DST + n]);
}

__global__ void k_scan(const float* __restrict__ ST, const float* __restrict__ CDEC,
                       float* __restrict__ PREV){
  int i = blockIdx.x*256 + threadIdx.x;
  if(i >= BS*NH*4096) return;
  int pn = i & 4095;
  int h = (i>>12) & 15;
  int b = i >> 16;
  float run = 0.f;
  for(int c=0;c<8;c++){
    size_t idx = (size_t)((b*8+c)*16+h)*4096 + pn;
    PREV[idx] = run;
    run = run*CDEC[(b*8+c)*16+h] + ST[idx];
  }
}

// ---------------- attention helpers ----------------
__global__ void k_extract(const float* __restrict__ HF, float* __restrict__ QIN,
                          float* __restrict__ CIN){
  int i = blockIdx.x*256 + threadIdx.x;
  if(i >= BS*1024*DM) return;
  int d = i & (DM-1);
  int q = (i>>9) & 1023;
  int b = i >> 19;
  QIN[i] = HF[(size_t)(b*SEQL + 1024 + q)*DM + d];
  CIN[i] = HF[(size_t)(b*SEQL + q)*DM + d];
}

// ---------------- host ----------------
extern "C" void kernel_launch(void* const* d_in, const int* in_sizes, int n_in,
                              void* d_out, int out_size, void* d_ws, size_t ws_size,
                              hipStream_t stream) {
  (void)in_sizes; (void)n_in; (void)out_size; (void)ws_size;
  const float* x_enc     = (const float*)d_in[0];
  const float* in_proj_w = (const float*)d_in[2];
  const float* conv_w    = (const float*)d_in[3];
  const float* conv_b    = (const float*)d_in[4];
  const float* dt_bias   = (const float*)d_in[5];
  const float* A_log     = (const float*)d_in[6];
  const float* D_param   = (const float*)d_in[7];
  const float* gnorm_w   = (const float*)d_in[8];
  const float* out_proj_w= (const float*)d_in[9];
  const float* norm_w    = (const float*)d_in[10];
  const float* norm_b    = (const float*)d_in[11];
  const float* normf_w   = (const float*)d_in[12];
  const float* normf_b   = (const float*)d_in[13];
  const float* ca_nq_w   = (const float*)d_in[14];
  const float* ca_nq_b   = (const float*)d_in[15];
  const float* ca_nkv_w  = (const float*)d_in[16];
  const float* ca_nkv_b  = (const float*)d_in[17];
  const float* ca_qw     = (const float*)d_in[18];
  const float* ca_kw     = (const float*)d_in[19];
  const float* ca_vw     = (const float*)d_in[20];
  const float* ca_ow     = (const float*)d_in[21];
  const float* ca_qb     = (const float*)d_in[22];
  const float* ca_kb     = (const float*)d_in[23];
  const float* ca_vb     = (const float*)d_in[24];
  const float* ca_ob     = (const float*)d_in[25];
  const float* qp_w      = (const float*)d_in[26];
  const float* qp_b      = (const float*)d_in[27];
  const float* cp_w      = (const float*)d_in[28];
  const float* cp_b      = (const float*)d_in[29];
  const float* dec1_w    = (const float*)d_in[30];
  const float* dec1_b    = (const float*)d_in[31];
  const float* dec2_w    = (const float*)d_in[32];
  const float* dec2_b    = (const float*)d_in[33];

  float* W = (float*)d_ws;
  size_t off = 0;
  auto alloc = [&](size_t n){ float* pp = W + off; off += n; return pp; };
  float* RES  = alloc((size_t)NTOK);
  float* H    = alloc((size_t)NTOK);
  float* HN   = alloc((size_t)NTOK);
  float* HNF  = alloc((size_t)NTOK);
  float* ZB   = alloc((size_t)NROWS*DIP);        // 17,956,864
  float* XC   = alloc((size_t)NROWS*CVD);        //  9,437,184
  float* DT   = alloc((size_t)NROWS*NH);
  float* DA   = alloc((size_t)NROWS*NH);
  float* ACUM = alloc((size_t)BS*NC*NH*CKS);
  float* CDEC = alloc((size_t)BS*NC*NH);
  float* Y    = alloc((size_t)NROWS*DIN);        //  8,388,608
  float* ST   = alloc((size_t)BS*NC*NH*4096);
  float* PREV = alloc((size_t)BS*NC*NH*4096);
  float* YD   = alloc((size_t)NTOK);
  float* HF   = alloc((size_t)NTOK);
  // byte-identical to the proven round-1 layout (61,768,192 floats)

  // mamba staging aliases (proven lifetimes):
  u16* Ubf    = (u16*)HF;
  u16* WinTc  = (u16*)(HF + 2097152);
  u16* WoutTc = (u16*)(HF + 2097152 + 561152);
  u16* Ybf    = (u16*)HNF;
  // SSD staging:
  u16*   Bbf    = (u16*)HNF;
  u16*   Cbf    = Bbf + 524288;
  float* Sf     = HNF + 524288;
  u16*   PREVbf = (u16*)Sf;
  u16*   BTc    = (u16*)(HNF + 2621440);   // 524,288 u16 (free HNF tail)
  u16*   XdTg   = (u16*)YD;                // 8,388,608 u16 (YD dead until out_proj)

  const int TPB = 256;
  const int gTok = (NTOK+TPB-1)/TPB;
  dim3 tb(32,8);

  hipMemcpyAsync(RES, x_enc, (size_t)NTOK*4, hipMemcpyDeviceToDevice, stream);

  for(int layer=0; layer<2; ++layer){
    if(layer>0) k_add_flip<<<gTok,TPB,0,stream>>>(RES, H, 0);
    k_ln<<<NROWS,TPB,0,stream>>>(RES, norm_w + layer*DM, norm_b + layer*DM, HN);
    hipMemsetAsync(H, 0, (size_t)NTOK*4, stream);
    for(int dir=0; dir<2; ++dir){
      int idx = layer*2 + dir;
      const float* cw   = conv_w   + (size_t)idx*CVD*4;
      const float* cb   = conv_b   + (size_t)idx*CVD;
      const float* dtb  = dt_bias  + (size_t)idx*NH;
      const float* Alog = A_log    + (size_t)idx*NH;
      const float* Dp   = D_param  + (size_t)idx*NH;
      const float* gw   = gnorm_w  + (size_t)idx*DIN;

      if(dir==0){
        k_cvt<<<(NTOK/4+TPB-1)/TPB,TPB,0,stream>>>(HN, Ubf, NTOK/4);
      }else{
        k_flip<<<gTok,TPB,0,stream>>>(HNF, HN);
        k_cvt<<<(NTOK/4+TPB-1)/TPB,TPB,0,stream>>>(HNF, Ubf, NTOK/4);
      }
      k_wt2<<<dim3(69,16),tb,0,stream>>>(in_proj_w + (size_t)idx*DM*DIP, WinTc, 512, 2192, 2192);
      k_mg<<<dim3(18,64),256,0,stream>>>(Ubf, WinTc, ZB, 8192, 2192, 512, 512, 512, 2192);

      k_conv4<<<(BS*512*CVD+TPB-1)/TPB,TPB,0,stream>>>(ZB, cw, cb, XC);
      k_dt<<<(BS*SEQL*NH+TPB-1)/TPB,TPB,0,stream>>>(ZB, dtb, Alog, DT, DA);
      k_acum<<<BS*NC*NH,256,0,stream>>>(DA, ACUM, CDEC);

      // ---- Y_diag via MFMA with fused G-formation ----
      k_bc<<<(NROWS*DST+TPB-1)/TPB,TPB,0,stream>>>(XC, Bbf, Cbf);
      k_mgb<<<dim3(2,2,32),256,0,stream>>>(Cbf, Bbf, Sf,
            256, 256, 64, 64, 64, 256, 16384, 16384, 65536, 0, 0);
      k_xdtt<<<dim3(2,8,512),tb,0,stream>>>(XC, DT, XdTg);
      k_mgg<<<dim3(1,2,512),256,0,stream>>>(Sf, ACUM, XdTg, Y);

      // ---- states via MFMA (replaces k_states) ----
      k_btc<<<dim3(2,8,32),tb,0,stream>>>(Bbf, BTc);
      k_mgs<<<dim3(1,1,512),256,0,stream>>>(XdTg, BTc, ACUM, ST);
      k_scan<<<(BS*NH*4096+TPB-1)/TPB,TPB,0,stream>>>(ST, CDEC, PREV);
      // ---- Y_off via MFMA + fused gate epilogue ----
      k_cvt<<<(2097152/4+TPB-1)/TPB,TPB,0,stream>>>(PREV, PREVbf, 2097152/4);
      k_mgy<<<dim3(8,2,32),256,0,stream>>>(Cbf, PREVbf, ACUM, XC, ZB, Dp, Y);

      k_rms<<<NROWS,256,0,stream>>>(Y, gw);

      k_cvt<<<(2097152+TPB-1)/TPB,TPB,0,stream>>>(Y, Ybf, 2097152);
      k_wt2<<<dim3(16,32),tb,0,stream>>>(out_proj_w + (size_t)idx*DIN*DM, WoutTc, 1024, 512, 512);
      k_mg<<<dim3(4,64),256,0,stream>>>(Ybf, WoutTc, YD, 8192, 512, 1024, 1024, 1024, 512);

      k_add_flip<<<gTok,TPB,0,stream>>>(H, YD, dir);
    }
  }
  k_add_flip<<<gTok,TPB,0,stream>>>(RES, H, 0);
  k_ln<<<NROWS,TPB,0,stream>>>(RES, normf_w, normf_b, HF);

  // ================= attention head — MFMA (batched) =================
  float* P0   = ZB;
  float* QIN  = P0 + 0;
  float* CIN  = P0 + 2097152;
  float* QPb  = P0 + 4194304;
  float* CPb  = P0 + 6291456;
  float* QN   = P0 + 8388608;
  float* CN   = P0 + 10485760;
  float* AO   = P0 + 12582912;
  float* O1   = P0 + 14680064;
  float* D1   = P0 + 16777216;
  float* VV   = D1;
  u16* U0     = (u16*)(P0 + 20971520);
  u16* Qbf    = U0 + 0;
  u16* Cbf2   = U0 + 2097152;
  u16* QNbf   = U0 + 4194304;
  u16* CNbf   = U0 + 6291456;
  u16* QQbf   = U0 + 8388608;
  u16* KKbf   = U0 + 10485760;
  u16* VTbf   = U0 + 12582912;
  u16* AObf   = U0 + 14680064;
  u16* O1bf   = U0 + 16777216;
  u16* qpT    = U0 + 18874368;
  u16* cpT    = qpT + 262144;
  u16* qwT    = qpT + 524288;
  u16* kwT    = qpT + 786432;
  u16* vwT    = qpT + 1048576;
  u16* owT    = qpT + 1310720;
  u16* dec1T  = qpT + 1572864;
  u16* Pbf    = qpT + 2097152;

  const int M2 = BS*1024;
  k_extract<<<(BS*1024*DM+TPB-1)/TPB,TPB,0,stream>>>(HF, QIN, CIN);
  k_cvt<<<(2097152/4+TPB-1)/TPB,TPB,0,stream>>>(QIN, Qbf, 2097152/4);
  k_cvt<<<(2097152/4+TPB-1)/TPB,TPB,0,stream>>>(CIN, Cbf2, 2097152/4);
  k_wt2<<<dim3(16,16),tb,0,stream>>>(qp_w, qpT, 512, 512, 512);
  k_wt2<<<dim3(16,16),tb,0,stream>>>(cp_w, cpT, 512, 512, 512);
  k_wt2<<<dim3(16,16),tb,0,stream>>>(ca_qw, qwT, 512, 512, 512);
  k_wt2<<<dim3(16,16),tb,0,stream>>>(ca_kw, kwT, 512, 512, 512);
  k_wt2<<<dim3(16,16),tb,0,stream>>>(ca_vw, vwT, 512, 512, 512);
  k_wt2<<<dim3(16,16),tb,0,stream>>>(ca_ow, owT, 512, 512, 512);
  k_wt2<<<dim3(32,16),tb,0,stream>>>(dec1_w, dec1T, 512, 1024, 1024);

  k_mge<<<dim3(4,32),256,0,stream>>>(Qbf, qpT, qp_b, nullptr, QPb, nullptr,
                                     M2, 512, 512, 512, 512, 512, 1.f, 0);
  k_mge<<<dim3(4,32),256,0,stream>>>(Cbf2, cpT, cp_b, nullptr, CPb, nullptr,
                                     M2, 512, 512, 512, 512, 512, 1.f, 0);
  k_ln<<<M2,TPB,0,stream>>>(QPb, ca_nq_w, ca_nq_b, QN);
  k_ln<<<M2,TPB,0,stream>>>(CPb, ca_nkv_w, ca_nkv_b, CN);
  k_cvt<<<(2097152/4+TPB-1)/TPB,TPB,0,stream>>>(QN, QNbf, 2097152/4);
  k_cvt<<<(2097152/4+TPB-1)/TPB,TPB,0,stream>>>(CN, CNbf, 2097152/4);
  k_mge<<<dim3(4,32),256,0,stream>>>(QNbf, qwT, ca_qb, nullptr, nullptr, QQbf,
                                     M2, 512, 512, 512, 512, 512, 1.f, 0);
  k_mge<<<dim3(4,32),256,0,stream>>>(CNbf, kwT, ca_kb, nullptr, nullptr, KKbf,
                                     M2, 512, 512, 512, 512, 512, 1.f, 0);
  k_mge<<<dim3(4,32),256,0,stream>>>(CNbf, vwT, ca_vb, nullptr, VV, nullptr,
                                     M2, 512, 512, 512, 512, 512, 1.f, 0);
  k_vtb<<<dim3(4,32,16),tb,0,stream>>>(VV, VTbf);
  const float scl = 0.088388347648318447f;
  k_mgab<<<dim3(8,8,16),256,0,stream>>>(QQbf, KKbf, nullptr, Pbf,
        1024, 1024, 128, 512, 512, 1024,
        524288, 128, 524288, 128, 4194304, 1048576, scl);
  k_sm<<<16384,256,0,stream>>>(Pbf);
  k_mgab<<<dim3(1,8,16),256,0,stream>>>(Pbf, VTbf, AO, nullptr,
        1024, 128, 1024, 1024, 1024, 512,
        4194304, 1048576, 524288, 131072, 524288, 128, 1.f);
  k_cvt<<<(2097152/4+TPB-1)/TPB,TPB,0,stream>>>(AO, AObf, 2097152/4);
  k_mge<<<dim3(4,32),256,0,stream>>>(AObf, owT, ca_ob, QPb, O1, nullptr,
                                     M2, 512, 512, 512, 512, 512, 1.f, 0);
  k_cvt<<<(2097152/4+TPB-1)/TPB,TPB,0,stream>>>(O1, O1bf, 2097152/4);
  k_mge<<<dim3(8,32),256,0,stream>>>(O1bf, dec1T, dec1_b, nullptr, D1, nullptr,
                                     M2, 1024, 512, 512, 512, 1024, 1.f, 1);
  k_dec2<<<M2,256,0,stream>>>(D1, dec2_w, dec2_b, (float*)d_out);
}

// Round 17
// 1369.607 us; speedup vs baseline: 237.2150x; 1.0549x over previous
//
#include <hip/hip_runtime.h>
#include <hip/hip_bf16.h>

#define BS 4
#define SEQL 2048
#define DM 512
#define DIN 1024
#define NH 16
#define HD 64
#define DST 64
#define NC 8
#define CKS 256
#define DIP 2192
#define CVD 1152
#define NROWS (BS*SEQL)          /* 8192 */
#define NTOK (BS*SEQL*DM)        /* 4194304 */

typedef unsigned short u16;
typedef __bf16 bf16x8 __attribute__((ext_vector_type(8)));
typedef float f32x4 __attribute__((ext_vector_type(4)));

__device__ __forceinline__ u16 cvt_bf16(float f){
  unsigned int x = __float_as_uint(f);
  unsigned int r = x + 0x7fffu + ((x>>16)&1u);
  return (u16)(r>>16);
}
__device__ __forceinline__ float bf2f(u16 u){
  return __uint_as_float(((unsigned int)u)<<16);
}

// ---------------- elementwise (proven) ----------------
__global__ void k_add_flip(float* __restrict__ dst, const float* __restrict__ src, int flip){
  int i = blockIdx.x*256 + threadIdx.x;
  if(i >= NTOK) return;
  int d = i & (DM-1);
  int l = (i >> 9) & (SEQL-1);
  int b = i >> 20;
  int sl = flip ? (SEQL-1-l) : l;
  dst[i] += src[(b*SEQL + sl)*DM + d];
}

__global__ void k_flip(float* __restrict__ dst, const float* __restrict__ src){
  int i = blockIdx.x*256 + threadIdx.x;
  if(i >= NTOK) return;
  int d = i & (DM-1);
  int l = (i >> 9) & (SEQL-1);
  int b = i >> 20;
  dst[i] = src[(b*SEQL + (SEQL-1-l))*DM + d];
}

// f32 -> bf16 (verified round-8)
__global__ void k_cvt(const float* __restrict__ src, u16* __restrict__ dst, int n4){
  int i = blockIdx.x*256 + threadIdx.x;
  if(i >= n4) return;
  float4 f = reinterpret_cast<const float4*>(src)[i];
  ushort4 o; o.x=cvt_bf16(f.x); o.y=cvt_bf16(f.y); o.z=cvt_bf16(f.z); o.w=cvt_bf16(f.w);
  reinterpret_cast<ushort4*>(dst)[i] = o;
}

__global__ void k_ln(const float* __restrict__ X, const float* __restrict__ w,
                     const float* __restrict__ bb, float* __restrict__ O){
  int row = blockIdx.x, tid = threadIdx.x;
  const float* x = X + (size_t)row*DM;
  float* o = O + (size_t)row*DM;
  float s=0.f, s2=0.f;
  for(int j=tid;j<DM;j+=256){ float v=x[j]; s+=v; s2+=v*v; }
  __shared__ float r1[256], r2[256];
  r1[tid]=s; r2[tid]=s2; __syncthreads();
  for(int off=128;off>0;off>>=1){
    if(tid<off){ r1[tid]+=r1[tid+off]; r2[tid]+=r2[tid+off]; }
    __syncthreads();
  }
  float m = r1[0]*(1.f/DM);
  float var = r2[0]*(1.f/DM) - m*m;
  float inv = rsqrtf(var + 1e-5f);
  for(int j=tid;j<DM;j+=256) o[j] = (x[j]-m)*inv*w[j] + bb[j];
}

// RMSNorm reading Y f32, writing bf16 only (same rounding point as rms+cvt)
__global__ void k_rmsb(const float* __restrict__ Y, const float* __restrict__ gw,
                       u16* __restrict__ Obf){
  int row = blockIdx.x, tid = threadIdx.x;
  const float* y = Y + (size_t)row*DIN;
  float ss=0.f;
  for(int j=tid;j<DIN;j+=256){ float v=y[j]; ss+=v*v; }
  __shared__ float red[256];
  red[tid]=ss; __syncthreads();
  for(int off=128;off>0;off>>=1){
    if(tid<off) red[tid]+=red[tid+off];
    __syncthreads();
  }
  float inv = rsqrtf(red[0]*(1.f/DIN) + 1e-5f);
  for(int j=tid;j<DIN;j+=256) Obf[(size_t)row*DIN + j] = cvt_bf16(y[j]*inv*gw[j]);
}

// dec2: out[row][0..9] = D1[row]·dec2_w + b ; one block per row
__global__ void k_dec2(const float* __restrict__ D1, const float* __restrict__ w,
                       const float* __restrict__ bb, float* __restrict__ out){
  int row = blockIdx.x, tid = threadIdx.x;
  int lane = tid & 63, wave = tid >> 6;
  const float* x = D1 + (size_t)row*1024;
  float acc[10];
  #pragma unroll
  for(int o=0;o<10;o++) acc[o]=0.f;
  for(int j=tid;j<1024;j+=256){
    float v = x[j];
    const float* wr = w + (size_t)j*10;
    #pragma unroll
    for(int o=0;o<10;o++) acc[o] += v*wr[o];
  }
  __shared__ float red[4][10];
  #pragma unroll
  for(int o=0;o<10;o++){
    float v = acc[o];
    #pragma unroll
    for(int s=32;s>0;s>>=1) v += __shfl_down(v, s, 64);
    if(lane==0) red[wave][o] = v;
  }
  __syncthreads();
  if(tid < 10)
    out[(size_t)row*10 + tid] = red[0][tid]+red[1][tid]+red[2][tid]+red[3][tid] + bb[tid];
}

// transpose-convert with explicit src ld (verified): src[K][lds] f32 -> dst[N][K] bf16
__global__ void k_wt2(const float* __restrict__ src, u16* __restrict__ dst,
                      int K, int N, int lds){
  __shared__ float t[32][33];
  int n0 = blockIdx.x*32, k0 = blockIdx.y*32;
  int tx = threadIdx.x, ty = threadIdx.y;
  #pragma unroll
  for(int i=0;i<32;i+=8){
    int k = k0+ty+i, n = n0+tx;
    t[ty+i][tx] = (n<N) ? src[(size_t)k*lds+n] : 0.f;
  }
  __syncthreads();
  #pragma unroll
  for(int i=0;i<32;i+=8){
    int n = n0+ty+i, k = k0+tx;
    if(n<N) dst[(size_t)n*K+k] = cvt_bf16(t[tx][ty+i]);
  }
}

// batched V-transpose: per z=(b*4+h): src=VV+b*524288+h*128 [1024][128 of 512] -> dst [128][1024]
__global__ void k_vtb(const float* __restrict__ VV, u16* __restrict__ VT){
  __shared__ float t[32][33];
  int z = blockIdx.z, b = z>>2, h = z&3;
  const float* src = VV + (size_t)b*524288 + h*128;
  u16* dst = VT + (size_t)z*131072;
  int n0 = blockIdx.x*32, k0 = blockIdx.y*32;
  int tx = threadIdx.x, ty = threadIdx.y;
  #pragma unroll
  for(int i=0;i<32;i+=8){
    int k = k0+ty+i, n = n0+tx;
    t[ty+i][tx] = src[(size_t)k*512+n];
  }
  __syncthreads();
  #pragma unroll
  for(int i=0;i<32;i+=8){
    int n = n0+ty+i, k = k0+tx;
    dst[(size_t)n*1024+k] = cvt_bf16(t[tx][ty+i]);
  }
}

// XdT via LDS-tiled transpose: per z=(bc*16+h), XdT[z][p][s] = bf16(XC[..]*DT[..])
__global__ void k_xdtt(const float* __restrict__ XC, const float* __restrict__ DT,
                       u16* __restrict__ XdT){
  __shared__ float t[32][33];
  int z = blockIdx.z;
  int h = z & 15, bc = z >> 4;
  int b = bc >> 3, c = bc & 7;
  int p0 = blockIdx.x*32, s0 = blockIdx.y*32;
  int tx = threadIdx.x, ty = threadIdx.y;
  int gbase = b*SEQL + c*CKS;
  #pragma unroll
  for(int i=0;i<32;i+=8){
    int s = s0+ty+i, p = p0+tx;
    int g = gbase + s;
    t[ty+i][tx] = XC[(size_t)g*CVD + h*HD + p] * DT[(size_t)g*NH + h];
  }
  __syncthreads();
  u16* dst = XdT + (size_t)z*16384;
  #pragma unroll
  for(int i=0;i<32;i+=8){
    int p = p0+ty+i, s = s0+tx;
    dst[(size_t)p*256 + s] = cvt_bf16(t[tx][ty+i]);
  }
}

// batched B-transpose: per bc: Bbf[bc] [256][64] -> BTc[bc][64][256]
__global__ void k_btc(const u16* __restrict__ Bbf, u16* __restrict__ BTc){
  __shared__ u16 t[32][33];
  int bc = blockIdx.z;
  const u16* src = Bbf + (size_t)bc*16384;
  u16* dst = BTc + (size_t)bc*16384;
  int n0 = blockIdx.x*32, l0 = blockIdx.y*32;
  int tx = threadIdx.x, ty = threadIdx.y;
  #pragma unroll
  for(int i=0;i<32;i+=8){
    int l = l0+ty+i, n = n0+tx;
    t[ty+i][tx] = src[(size_t)l*64+n];
  }
  __syncthreads();
  #pragma unroll
  for(int i=0;i<32;i+=8){
    int n = n0+ty+i, l = l0+tx;
    dst[(size_t)n*256+l] = t[tx][ty+i];
  }
}

// ---------------- MFMA bf16 GEMM, emap0 (HW-verified) ----------------
__global__ __launch_bounds__(256) void k_mg(
    const u16* __restrict__ A, const u16* __restrict__ BT,
    float* __restrict__ C, int M, int N, int K, int lda, int ldb, int ldc)
{
  __shared__ uint4 As4[128*5];
  __shared__ uint4 Bs4[128*5];
  const int tid = threadIdx.x;
  const int row0 = blockIdx.y*128, col0 = blockIdx.x*128;
  const int lane = tid & 63, wave = tid >> 6;
  const int wm = wave >> 1, wn = wave & 1;
  const int lr = lane & 15, ksg = (lane >> 4);
  f32x4 acc[4][4];
  #pragma unroll
  for(int i=0;i<4;i++)
    #pragma unroll
    for(int j=0;j<4;j++) acc[i][j] = (f32x4){0.f,0.f,0.f,0.f};
  for(int k0=0;k0<K;k0+=32){
    #pragma unroll
    for(int i=0;i<2;i++){
      int t2 = tid + i*256;
      int rr = t2 >> 2, sg = (t2 & 3);
      uint4 av = *reinterpret_cast<const uint4*>(A + (size_t)(row0+rr)*lda + k0 + sg*8);
      uint4 bv = {0u,0u,0u,0u};
      if(col0+rr < N) bv = *reinterpret_cast<const uint4*>(BT + (size_t)(col0+rr)*ldb + k0 + sg*8);
      As4[rr*5 + sg] = av;
      Bs4[rr*5 + sg] = bv;
    }
    __syncthreads();
    bf16x8 afr[4], bfr[4];
    #pragma unroll
    for(int i=0;i<4;i++) afr[i] = *reinterpret_cast<const bf16x8*>(&As4[(wm*64+i*16+lr)*5 + ksg]);
    #pragma unroll
    for(int j=0;j<4;j++) bfr[j] = *reinterpret_cast<const bf16x8*>(&Bs4[(wn*64+j*16+lr)*5 + ksg]);
    #pragma unroll
    for(int i=0;i<4;i++)
      #pragma unroll
      for(int j=0;j<4;j++)
        acc[i][j] = __builtin_amdgcn_mfma_f32_16x16x32_bf16(afr[i], bfr[j], acc[i][j], 0, 0, 0);
    __syncthreads();
  }
  const int hi = lane >> 4, lo = lane & 15;
  #pragma unroll
  for(int i=0;i<4;i++)
    #pragma unroll
    for(int j=0;j<4;j++)
      #pragma unroll
      for(int r=0;r<4;r++){
        int row = row0 + wm*64 + i*16 + 4*hi + r;
        int col = col0 + wn*64 + j*16 + lo;
        if(col < N) C[(size_t)row*ldc + col] = acc[i][j][r];
      }
}

// out_proj GEMM with fused flip-add epilogue: H[(b, flip? 2047-l : l), col] += acc
__global__ __launch_bounds__(256) void k_mgo(
    const u16* __restrict__ A, const u16* __restrict__ BT,
    float* __restrict__ H, int flip)
{
  const int N = 512, K = 1024;
  __shared__ uint4 As4[128*5];
  __shared__ uint4 Bs4[128*5];
  const int tid = threadIdx.x;
  const int row0 = blockIdx.y*128, col0 = blockIdx.x*128;
  const int lane = tid & 63, wave = tid >> 6;
  const int wm = wave >> 1, wn = wave & 1;
  const int lr = lane & 15, ksg = (lane >> 4);
  f32x4 acc[4][4];
  #pragma unroll
  for(int i=0;i<4;i++)
    #pragma unroll
    for(int j=0;j<4;j++) acc[i][j] = (f32x4){0.f,0.f,0.f,0.f};
  for(int k0=0;k0<K;k0+=32){
    #pragma unroll
    for(int i=0;i<2;i++){
      int t2 = tid + i*256;
      int rr = t2 >> 2, sg = (t2 & 3);
      uint4 av = *reinterpret_cast<const uint4*>(A + (size_t)(row0+rr)*K + k0 + sg*8);
      uint4 bv = {0u,0u,0u,0u};
      if(col0+rr < N) bv = *reinterpret_cast<const uint4*>(BT + (size_t)(col0+rr)*K + k0 + sg*8);
      As4[rr*5 + sg] = av;
      Bs4[rr*5 + sg] = bv;
    }
    __syncthreads();
    bf16x8 afr[4], bfr[4];
    #pragma unroll
    for(int i=0;i<4;i++) afr[i] = *reinterpret_cast<const bf16x8*>(&As4[(wm*64+i*16+lr)*5 + ksg]);
    #pragma unroll
    for(int j=0;j<4;j++) bfr[j] = *reinterpret_cast<const bf16x8*>(&Bs4[(wn*64+j*16+lr)*5 + ksg]);
    #pragma unroll
    for(int i=0;i<4;i++)
      #pragma unroll
      for(int j=0;j<4;j++)
        acc[i][j] = __builtin_amdgcn_mfma_f32_16x16x32_bf16(afr[i], bfr[j], acc[i][j], 0, 0, 0);
    __syncthreads();
  }
  const int hi = lane >> 4, lo = lane & 15;
  #pragma unroll
  for(int i=0;i<4;i++)
    #pragma unroll
    for(int j=0;j<4;j++)
      #pragma unroll
      for(int r=0;r<4;r++){
        int row = row0 + wm*64 + i*16 + 4*hi + r;
        int col = col0 + wn*64 + j*16 + lo;
        if(col < N){
          int b = row >> 11, l = row & (SEQL-1);
          int sl = flip ? (SEQL-1-l) : l;
          size_t ci = (size_t)(b*SEQL + sl)*DM + col;
          H[ci] += acc[i][j][r];
        }
      }
}

// batched variant: verified core + z-strided base offsets only
__global__ __launch_bounds__(256) void k_mgb(
    const u16* __restrict__ A0, const u16* __restrict__ BT0,
    float* __restrict__ C0, int M, int N, int K, int lda, int ldb, int ldc,
    long sAz, long sBz, long sCo, long sCi, int shC)
{
  const int z = blockIdx.z;
  const u16* A  = A0  + (size_t)z*sAz;
  const u16* BT = BT0 + (size_t)z*sBz;
  float* C = C0 + (size_t)(z>>shC)*sCo + (size_t)(z & ((1<<shC)-1))*sCi;
  __shared__ uint4 As4[128*5];
  __shared__ uint4 Bs4[128*5];
  const int tid = threadIdx.x;
  const int row0 = blockIdx.y*128, col0 = blockIdx.x*128;
  const int lane = tid & 63, wave = tid >> 6;
  const int wm = wave >> 1, wn = wave & 1;
  const int lr = lane & 15, ksg = (lane >> 4);
  f32x4 acc[4][4];
  #pragma unroll
  for(int i=0;i<4;i++)
    #pragma unroll
    for(int j=0;j<4;j++) acc[i][j] = (f32x4){0.f,0.f,0.f,0.f};
  for(int k0=0;k0<K;k0+=32){
    #pragma unroll
    for(int i=0;i<2;i++){
      int t2 = tid + i*256;
      int rr = t2 >> 2, sg = (t2 & 3);
      uint4 av = *reinterpret_cast<const uint4*>(A + (size_t)(row0+rr)*lda + k0 + sg*8);
      uint4 bv = {0u,0u,0u,0u};
      if(col0+rr < N) bv = *reinterpret_cast<const uint4*>(BT + (size_t)(col0+rr)*ldb + k0 + sg*8);
      As4[rr*5 + sg] = av;
      Bs4[rr*5 + sg] = bv;
    }
    __syncthreads();
    bf16x8 afr[4], bfr[4];
    #pragma unroll
    for(int i=0;i<4;i++) afr[i] = *reinterpret_cast<const bf16x8*>(&As4[(wm*64+i*16+lr)*5 + ksg]);
    #pragma unroll
    for(int j=0;j<4;j++) bfr[j] = *reinterpret_cast<const bf16x8*>(&Bs4[(wn*64+j*16+lr)*5 + ksg]);
    #pragma unroll
    for(int i=0;i<4;i++)
      #pragma unroll
      for(int j=0;j<4;j++)
        acc[i][j] = __builtin_amdgcn_mfma_f32_16x16x32_bf16(afr[i], bfr[j], acc[i][j], 0, 0, 0);
    __syncthreads();
  }
  const int hi = lane >> 4, lo = lane & 15;
  #pragma unroll
  for(int i=0;i<4;i++)
    #pragma unroll
    for(int j=0;j<4;j++)
      #pragma unroll
      for(int r=0;r<4;r++){
        int row = row0 + wm*64 + i*16 + 4*hi + r;
        int col = col0 + wn*64 + j*16 + lo;
        if(col < N) C[(size_t)row*ldc + col] = acc[i][j][r];
      }
}

// Y_diag GEMM with fused G-formation in A-staging
__global__ __launch_bounds__(256) void k_mgg(
    const float* __restrict__ Sf, const float* __restrict__ ACUM,
    const u16* __restrict__ XdT, float* __restrict__ Y)
{
  const int z = blockIdx.z;
  const int h = z & 15, bc = z >> 4;
  const int b = bc >> 3, c = bc & 7;
  const float* Az = Sf + (size_t)bc*65536;
  const float* Acp = ACUM + (size_t)z*256;
  const u16* BT = XdT + (size_t)z*16384;
  float* Cp = Y + (size_t)b*2097152 + (size_t)c*262144 + h*64;
  __shared__ uint4 As4[128*5];
  __shared__ uint4 Bs4[128*5];
  __shared__ float AcS[256];
  const int tid = threadIdx.x;
  AcS[tid] = Acp[tid];
  __syncthreads();
  const int row0 = blockIdx.y*128;
  const int lane = tid & 63, wave = tid >> 6;
  const int wm = wave >> 1, wn = wave & 1;
  const int lr = lane & 15, ksg = (lane >> 4);
  f32x4 acc[4][4];
  #pragma unroll
  for(int i=0;i<4;i++)
    #pragma unroll
    for(int j=0;j<4;j++) acc[i][j] = (f32x4){0.f,0.f,0.f,0.f};
  for(int k0=0;k0<256;k0+=32){
    #pragma unroll
    for(int i=0;i<2;i++){
      int t2 = tid + i*256;
      int rr = t2 >> 2, sg = (t2 & 3);
      int l = row0 + rr;
      int sbase = k0 + sg*8;
      float4 v0 = *reinterpret_cast<const float4*>(Az + (size_t)l*256 + sbase);
      float4 v1 = *reinterpret_cast<const float4*>(Az + (size_t)l*256 + sbase + 4);
      float acl = AcS[l];
      float vv[8] = {v0.x,v0.y,v0.z,v0.w,v1.x,v1.y,v1.z,v1.w};
      u16 gbuf[8];
      #pragma unroll
      for(int e=0;e<8;e++){
        int s = sbase + e;
        float g = 0.f;
        if(s <= l) g = __expf(acl - AcS[s]) * vv[e];
        gbuf[e] = cvt_bf16(g);
      }
      As4[rr*5 + sg] = *reinterpret_cast<uint4*>(gbuf);
      uint4 bv = {0u,0u,0u,0u};
      if(rr < 64) bv = *reinterpret_cast<const uint4*>(BT + (size_t)rr*256 + sbase);
      Bs4[rr*5 + sg] = bv;
    }
    __syncthreads();
    bf16x8 afr[4], bfr[4];
    #pragma unroll
    for(int i=0;i<4;i++) afr[i] = *reinterpret_cast<const bf16x8*>(&As4[(wm*64+i*16+lr)*5 + ksg]);
    #pragma unroll
    for(int j=0;j<4;j++) bfr[j] = *reinterpret_cast<const bf16x8*>(&Bs4[(wn*64+j*16+lr)*5 + ksg]);
    #pragma unroll
    for(int i=0;i<4;i++)
      #pragma unroll
      for(int j=0;j<4;j++)
        acc[i][j] = __builtin_amdgcn_mfma_f32_16x16x32_bf16(afr[i], bfr[j], acc[i][j], 0, 0, 0);
    __syncthreads();
  }
  const int hi = lane >> 4, lo = lane & 15;
  #pragma unroll
  for(int i=0;i<4;i++)
    #pragma unroll
    for(int j=0;j<4;j++)
      #pragma unroll
      for(int r=0;r<4;r++){
        int row = row0 + wm*64 + i*16 + 4*hi + r;
        int col = wn*64 + j*16 + lo;
        if(col < 64) Cp[(size_t)row*1024 + col] = acc[i][j][r];
      }
}

// states via MFMA: per z=(bc*16+h): ST[z][p][n] = sum_l (XdT[z][p][l]*dec[l]) * B[bc][l][n]
__global__ __launch_bounds__(256) void k_mgs(
    const u16* __restrict__ XdT, const u16* __restrict__ BTc,
    const float* __restrict__ ACUM, float* __restrict__ ST)
{
  const int z = blockIdx.z;
  const int bc = z >> 4;
  const u16* Ap = XdT + (size_t)z*16384;
  const u16* BT = BTc + (size_t)bc*16384;
  float* Cp = ST + (size_t)z*4096;
  __shared__ uint4 As4[128*5];
  __shared__ uint4 Bs4[128*5];
  __shared__ float decS[256];
  const int tid = threadIdx.x;
  {
    const float* Acp = ACUM + (size_t)z*256;
    decS[tid] = __expf(Acp[255] - Acp[tid]);
  }
  __syncthreads();
  const int lane = tid & 63, wave = tid >> 6;
  const int wm = wave >> 1, wn = wave & 1;
  const int lr = lane & 15, ksg = (lane >> 4);
  f32x4 acc[4][4];
  #pragma unroll
  for(int i=0;i<4;i++)
    #pragma unroll
    for(int j=0;j<4;j++) acc[i][j] = (f32x4){0.f,0.f,0.f,0.f};
  for(int k0=0;k0<256;k0+=32){
    #pragma unroll
    for(int i=0;i<2;i++){
      int t2 = tid + i*256;
      int rr = t2 >> 2, sg = (t2 & 3);
      int sbase = k0 + sg*8;
      uint4 av = {0u,0u,0u,0u};
      if(rr < 64){
        uint4 raw = *reinterpret_cast<const uint4*>(Ap + (size_t)rr*256 + sbase);
        const u16* rp = reinterpret_cast<const u16*>(&raw);
        u16 buf[8];
        #pragma unroll
        for(int e=0;e<8;e++) buf[e] = cvt_bf16(bf2f(rp[e]) * decS[sbase+e]);
        av = *reinterpret_cast<uint4*>(buf);
      }
      As4[rr*5 + sg] = av;
      uint4 bv = {0u,0u,0u,0u};
      if(rr < 64) bv = *reinterpret_cast<const uint4*>(BT + (size_t)rr*256 + sbase);
      Bs4[rr*5 + sg] = bv;
    }
    __syncthreads();
    bf16x8 afr[4], bfr[4];
    #pragma unroll
    for(int i=0;i<4;i++) afr[i] = *reinterpret_cast<const bf16x8*>(&As4[(wm*64+i*16+lr)*5 + ksg]);
    #pragma unroll
    for(int j=0;j<4;j++) bfr[j] = *reinterpret_cast<const bf16x8*>(&Bs4[(wn*64+j*16+lr)*5 + ksg]);
    #pragma unroll
    for(int i=0;i<4;i++)
      #pragma unroll
      for(int j=0;j<4;j++)
        acc[i][j] = __builtin_amdgcn_mfma_f32_16x16x32_bf16(afr[i], bfr[j], acc[i][j], 0, 0, 0);
    __syncthreads();
  }
  const int hi = lane >> 4, lo = lane & 15;
  #pragma unroll
  for(int i=0;i<4;i++)
    #pragma unroll
    for(int j=0;j<4;j++)
      #pragma unroll
      for(int r=0;r<4;r++){
        int row = wm*64 + i*16 + 4*hi + r;
        int col = wn*64 + j*16 + lo;
        if(row < 64 && col < 64) Cp[(size_t)row*64 + col] = acc[i][j][r];
      }
}

// batched attention GEMM: (z>>2)/(z&3) offsets for A/B/C, scale, f32 or bf16 out
__global__ __launch_bounds__(256) void k_mgab(
    const u16* __restrict__ A0, const u16* __restrict__ BT0,
    float* __restrict__ C0, u16* __restrict__ Cb0,
    int M, int N, int K, int lda, int ldb, int ldc,
    long sAo, long sAi, long sBo, long sBi, long sCo, long sCi, float scale)
{
  const int z = blockIdx.z;
  const u16* A  = A0  + (size_t)(z>>2)*sAo + (size_t)(z&3)*sAi;
  const u16* BT = BT0 + (size_t)(z>>2)*sBo + (size_t)(z&3)*sBi;
  const size_t offC = (size_t)(z>>2)*sCo + (size_t)(z&3)*sCi;
  __shared__ uint4 As4[128*5];
  __shared__ uint4 Bs4[128*5];
  const int tid = threadIdx.x;
  const int row0 = blockIdx.y*128, col0 = blockIdx.x*128;
  const int lane = tid & 63, wave = tid >> 6;
  const int wm = wave >> 1, wn = wave & 1;
  const int lr = lane & 15, ksg = (lane >> 4);
  f32x4 acc[4][4];
  #pragma unroll
  for(int i=0;i<4;i++)
    #pragma unroll
    for(int j=0;j<4;j++) acc[i][j] = (f32x4){0.f,0.f,0.f,0.f};
  for(int k0=0;k0<K;k0+=32){
    #pragma unroll
    for(int i=0;i<2;i++){
      int t2 = tid + i*256;
      int rr = t2 >> 2, sg = (t2 & 3);
      uint4 av = *reinterpret_cast<const uint4*>(A + (size_t)(row0+rr)*lda + k0 + sg*8);
      uint4 bv = {0u,0u,0u,0u};
      if(col0+rr < N) bv = *reinterpret_cast<const uint4*>(BT + (size_t)(col0+rr)*ldb + k0 + sg*8);
      As4[rr*5 + sg] = av;
      Bs4[rr*5 + sg] = bv;
    }
    __syncthreads();
    bf16x8 afr[4], bfr[4];
    #pragma unroll
    for(int i=0;i<4;i++) afr[i] = *reinterpret_cast<const bf16x8*>(&As4[(wm*64+i*16+lr)*5 + ksg]);
    #pragma unroll
    for(int j=0;j<4;j++) bfr[j] = *reinterpret_cast<const bf16x8*>(&Bs4[(wn*64+j*16+lr)*5 + ksg]);
    #pragma unroll
    for(int i=0;i<4;i++)
      #pragma unroll
      for(int j=0;j<4;j++)
        acc[i][j] = __builtin_amdgcn_mfma_f32_16x16x32_bf16(afr[i], bfr[j], acc[i][j], 0, 0, 0);
    __syncthreads();
  }
  const int hi = lane >> 4, lo = lane & 15;
  #pragma unroll
  for(int i=0;i<4;i++)
    #pragma unroll
    for(int j=0;j<4;j++)
      #pragma unroll
      for(int r=0;r<4;r++){
        int row = row0 + wm*64 + i*16 + 4*hi + r;
        int col = col0 + wn*64 + j*16 + lo;
        if(col < N){
          float v = acc[i][j][r] * scale;
          size_t ci = offC + (size_t)row*ldc + col;
          if(C0) C0[ci] = v;
          else   Cb0[ci] = cvt_bf16(v);
        }
      }
}

// Y_off GEMM fused with yfinal epilogue
__global__ __launch_bounds__(256) void k_mgy(
    const u16* __restrict__ Cb0, const u16* __restrict__ PV0,
    const float* __restrict__ ACUM, const float* __restrict__ XCp,
    const float* __restrict__ ZBp, const float* __restrict__ Dp,
    float* __restrict__ Y)
{
  const int z = blockIdx.z;                 // b*8+c
  const int b = z>>3, c = z&7;
  const u16* A  = Cb0 + (size_t)z*16384;    // [256][64] bf16
  const u16* BT = PV0 + (size_t)z*65536;    // [1024][64] bf16
  const int N = 1024;
  __shared__ uint4 As4[128*5];
  __shared__ uint4 Bs4[128*5];
  const int tid = threadIdx.x;
  const int row0 = blockIdx.y*128, col0 = blockIdx.x*128;
  const int lane = tid & 63, wave = tid >> 6;
  const int wm = wave >> 1, wn = wave & 1;
  const int lr = lane & 15, ksg = (lane >> 4);
  f32x4 acc[4][4];
  #pragma unroll
  for(int i=0;i<4;i++)
    #pragma unroll
    for(int j=0;j<4;j++) acc[i][j] = (f32x4){0.f,0.f,0.f,0.f};
  for(int k0=0;k0<64;k0+=32){
    #pragma unroll
    for(int i=0;i<2;i++){
      int t2 = tid + i*256;
      int rr = t2 >> 2, sg = (t2 & 3);
      uint4 av = *reinterpret_cast<const uint4*>(A + (size_t)(row0+rr)*64 + k0 + sg*8);
      uint4 bv = {0u,0u,0u,0u};
      if(col0+rr < N) bv = *reinterpret_cast<const uint4*>(BT + (size_t)(col0+rr)*64 + k0 + sg*8);
      As4[rr*5 + sg] = av;
      Bs4[rr*5 + sg] = bv;
    }
    __syncthreads();
    bf16x8 afr[4], bfr[4];
    #pragma unroll
    for(int i=0;i<4;i++) afr[i] = *reinterpret_cast<const bf16x8*>(&As4[(wm*64+i*16+lr)*5 + ksg]);
    #pragma unroll
    for(int j=0;j<4;j++) bfr[j] = *reinterpret_cast<const bf16x8*>(&Bs4[(wn*64+j*16+lr)*5 + ksg]);
    #pragma unroll
    for(int i=0;i<4;i++)
      #pragma unroll
      for(int j=0;j<4;j++)
        acc[i][j] = __builtin_amdgcn_mfma_f32_16x16x32_bf16(afr[i], bfr[j], acc[i][j], 0, 0, 0);
    __syncthreads();
  }
  const int hi = lane >> 4, lo = lane & 15;
  #pragma unroll
  for(int i=0;i<4;i++)
    #pragma unroll
    for(int j=0;j<4;j++)
      #pragma unroll
      for(int r=0;r<4;r++){
        int row = row0 + wm*64 + i*16 + 4*hi + r;
        int col = col0 + wn*64 + j*16 + lo;
        int h = col >> 6;
        int g = b*SEQL + c*CKS + row;
        float ac = ACUM[((size_t)z*NH + h)*CKS + row];
        float xh = XCp[(size_t)g*CVD + col];
        float zg = ZBp[(size_t)g*DIP + col];
        size_t ci = (size_t)g*DIN + col;
        float v = Y[ci] + expf(ac)*acc[i][j][r] + Dp[h]*xh;
        float sig = 1.f/(1.f+expf(-zg));
        Y[ci] = v * (zg*sig);
      }
}

// verified core + arithmetic epilogue (attention projections)
__global__ __launch_bounds__(256) void k_mge(
    const u16* __restrict__ A, const u16* __restrict__ BT,
    const float* __restrict__ bias, const float* __restrict__ res,
    float* __restrict__ C, u16* __restrict__ Cbf,
    int M, int N, int K, int lda, int ldb, int ldc, float scale, int act)
{
  __shared__ uint4 As4[128*5];
  __shared__ uint4 Bs4[128*5];
  const int tid = threadIdx.x;
  const int row0 = blockIdx.y*128, col0 = blockIdx.x*128;
  const int lane = tid & 63, wave = tid >> 6;
  const int wm = wave >> 1, wn = wave & 1;
  const int lr = lane & 15, ksg = (lane >> 4);
  f32x4 acc[4][4];
  #pragma unroll
  for(int i=0;i<4;i++)
    #pragma unroll
    for(int j=0;j<4;j++) acc[i][j] = (f32x4){0.f,0.f,0.f,0.f};
  for(int k0=0;k0<K;k0+=32){
    #pragma unroll
    for(int i=0;i<2;i++){
      int t2 = tid + i*256;
      int rr = t2 >> 2, sg = (t2 & 3);
      uint4 av = *reinterpret_cast<const uint4*>(A + (size_t)(row0+rr)*lda + k0 + sg*8);
      uint4 bv = {0u,0u,0u,0u};
      if(col0+rr < N) bv = *reinterpret_cast<const uint4*>(BT + (size_t)(col0+rr)*ldb + k0 + sg*8);
      As4[rr*5 + sg] = av;
      Bs4[rr*5 + sg] = bv;
    }
    __syncthreads();
    bf16x8 afr[4], bfr[4];
    #pragma unroll
    for(int i=0;i<4;i++) afr[i] = *reinterpret_cast<const bf16x8*>(&As4[(wm*64+i*16+lr)*5 + ksg]);
    #pragma unroll
    for(int j=0;j<4;j++) bfr[j] = *reinterpret_cast<const bf16x8*>(&Bs4[(wn*64+j*16+lr)*5 + ksg]);
    #pragma unroll
    for(int i=0;i<4;i++)
      #pragma unroll
      for(int j=0;j<4;j++)
        acc[i][j] = __builtin_amdgcn_mfma_f32_16x16x32_bf16(afr[i], bfr[j], acc[i][j], 0, 0, 0);
    __syncthreads();
  }
  const int hi = lane >> 4, lo = lane & 15;
  #pragma unroll
  for(int i=0;i<4;i++)
    #pragma unroll
    for(int j=0;j<4;j++)
      #pragma unroll
      for(int r=0;r<4;r++){
        int row = row0 + wm*64 + i*16 + 4*hi + r;
        int col = col0 + wn*64 + j*16 + lo;
        if(col < N){
          float v = acc[i][j][r];
          if(bias) v += bias[col];
          v *= scale;
          if(act==1) v = 0.5f*v*(1.f+erff(v*0.70710678118654752f));
          size_t ci = (size_t)row*ldc + col;
          if(res) v += res[ci];
          if(C) C[ci] = v;
          else  Cbf[ci] = cvt_bf16(v);
        }
      }
}

// in-place row softmax over 1024 bf16
__global__ void k_sm(u16* __restrict__ S){
  size_t row = blockIdx.x;
  u16* p = S + row*1024;
  int tid = threadIdx.x;
  ushort4 u = reinterpret_cast<ushort4*>(p)[tid];
  float v0=bf2f(u.x), v1=bf2f(u.y), v2=bf2f(u.z), v3=bf2f(u.w);
  float m = fmaxf(fmaxf(v0,v1),fmaxf(v2,v3));
  __shared__ float red[256];
  red[tid]=m; __syncthreads();
  for(int o=128;o>0;o>>=1){ if(tid<o) red[tid]=fmaxf(red[tid],red[tid+o]); __syncthreads(); }
  m = red[0]; __syncthreads();
  v0=__expf(v0-m); v1=__expf(v1-m); v2=__expf(v2-m); v3=__expf(v3-m);
  float s = v0+v1+v2+v3;
  red[tid]=s; __syncthreads();
  for(int o=128;o>0;o>>=1){ if(tid<o) red[tid]+=red[tid+o]; __syncthreads(); }
  float inv = 1.f/red[0];
  ushort4 o4; o4.x=cvt_bf16(v0*inv); o4.y=cvt_bf16(v1*inv); o4.z=cvt_bf16(v2*inv); o4.w=cvt_bf16(v3*inv);
  reinterpret_cast<ushort4*>(p)[tid] = o4;
}

// ---------------- mamba pieces ----------------
__global__ void k_conv4(const float* __restrict__ ZB, const float* __restrict__ cw,
                        const float* __restrict__ cb, float* __restrict__ XC){
  int i = blockIdx.x*256 + threadIdx.x;   // over BS*512*CVD
  if(i >= BS*512*CVD) return;
  int cch = i % CVD;
  int lq = (i / CVD) & 511;
  int b = i / (CVD*512);
  int l0 = lq*4;
  float w[7];
  #pragma unroll
  for(int t=0;t<7;t++){
    int sl = l0 - 3 + t;
    w[t] = (sl >= 0) ? ZB[(size_t)(b*SEQL+sl)*DIP + DIN + cch] : 0.f;
  }
  float c0 = cw[cch*4+0], c1 = cw[cch*4+1], c2 = cw[cch*4+2], c3 = cw[cch*4+3];
  float bb2 = cb[cch];
  #pragma unroll
  for(int j=0;j<4;j++){
    float v = bb2 + w[j]*c0 + w[j+1]*c1 + w[j+2]*c2 + w[j+3]*c3;
    float sig = 1.f/(1.f+expf(-v));
    XC[(size_t)(b*SEQL + l0 + j)*CVD + cch] = v*sig;
  }
}

__global__ void k_dt(const float* __restrict__ ZB, const float* __restrict__ dtb,
                     const float* __restrict__ Alog, float* __restrict__ DT,
                     float* __restrict__ DA){
  int i = blockIdx.x*256 + threadIdx.x;
  if(i >= BS*SEQL*NH) return;
  int h = i & (NH-1);
  int row = i >> 4;
  float raw = ZB[(size_t)row*DIP + (DIN+CVD) + h] + dtb[h];
  float dt = fmaxf(raw,0.f) + log1pf(expf(-fabsf(raw)));
  DT[i] = dt;
  DA[i] = dt * (-expf(Alog[h]));
}

__global__ void k_acum(const float* __restrict__ DA, float* __restrict__ ACUM,
                       float* __restrict__ CDEC){
  int blk = blockIdx.x;
  int h = blk & 15, c = (blk>>4)&7, b = blk>>7;
  int l = threadIdx.x;
  __shared__ float s[256];
  int gl = c*CKS + l;
  s[l] = DA[(size_t)(b*SEQL + gl)*NH + h];
  __syncthreads();
  for(int off=1; off<256; off<<=1){
    float v = (l>=off) ? s[l-off] : 0.f;
    __syncthreads();
    s[l] += v;
    __syncthreads();
  }
  ACUM[(size_t)blk*CKS + l] = s[l];
  if(l==255) CDEC[blk] = expf(s[255]);
}

// extract B,C as bf16 [8192][64]
__global__ void k_bc(const float* __restrict__ XC, u16* __restrict__ Bbf,
                     u16* __restrict__ Cbf){
  int i = blockIdx.x*256 + threadIdx.x;
  if(i >= NROWS*DST) return;
  int g = i >> 6, n = i & 63;
  Bbf[i] = cvt_bf16(XC[(size_t)g*CVD + DIN + n]);
  Cbf[i] = cvt_bf16(XC[(size_t)g*CVD + DIN + DST + n]);
}

__global__ void k_scan(const float* __restrict__ ST, const float* __restrict__ CDEC,
                       float* __restrict__ PREV){
  int i = blockIdx.x*256 + threadIdx.x;
  if(i >= BS*NH*4096) return;
  int pn = i & 4095;
  int h = (i>>12) & 15;
  int b = i >> 16;
  float run = 0.f;
  for(int c=0;c<8;c++){
    size_t idx = (size_t)((b*8+c)*16+h)*4096 + pn;
    PREV[idx] = run;
    run = run*CDEC[(b*8+c)*16+h] + ST[idx];
  }
}

// ---------------- attention helpers ----------------
__global__ void k_extract(const float* __restrict__ HF, float* __restrict__ QIN,
                          float* __restrict__ CIN){
  int i = blockIdx.x*256 + threadIdx.x;
  if(i >= BS*1024*DM) return;
  int d = i & (DM-1);
  int q = (i>>9) & 1023;
  int b = i >> 19;
  QIN[i] = HF[(size_t)(b*SEQL + 1024 + q)*DM + d];
  CIN[i] = HF[(size_t)(b*SEQL + q)*DM + d];
}

// ---------------- host ----------------
extern "C" void kernel_launch(void* const* d_in, const int* in_sizes, int n_in,
                              void* d_out, int out_size, void* d_ws, size_t ws_size,
                              hipStream_t stream) {
  (void)in_sizes; (void)n_in; (void)out_size; (void)ws_size;
  const float* x_enc     = (const float*)d_in[0];
  const float* in_proj_w = (const float*)d_in[2];
  const float* conv_w    = (const float*)d_in[3];
  const float* conv_b    = (const float*)d_in[4];
  const float* dt_bias   = (const float*)d_in[5];
  const float* A_log     = (const float*)d_in[6];
  const float* D_param   = (const float*)d_in[7];
  const float* gnorm_w   = (const float*)d_in[8];
  const float* out_proj_w= (const float*)d_in[9];
  const float* norm_w    = (const float*)d_in[10];
  const float* norm_b    = (const float*)d_in[11];
  const float* normf_w   = (const float*)d_in[12];
  const float* normf_b   = (const float*)d_in[13];
  const float* ca_nq_w   = (const float*)d_in[14];
  const float* ca_nq_b   = (const float*)d_in[15];
  const float* ca_nkv_w  = (const float*)d_in[16];
  const float* ca_nkv_b  = (const float*)d_in[17];
  const float* ca_qw     = (const float*)d_in[18];
  const float* ca_kw     = (const float*)d_in[19];
  const float* ca_vw     = (const float*)d_in[20];
  const float* ca_ow     = (const float*)d_in[21];
  const float* ca_qb     = (const float*)d_in[22];
  const float* ca_kb     = (const float*)d_in[23];
  const float* ca_vb     = (const float*)d_in[24];
  const float* ca_ob     = (const float*)d_in[25];
  const float* qp_w      = (const float*)d_in[26];
  const float* qp_b      = (const float*)d_in[27];
  const float* cp_w      = (const float*)d_in[28];
  const float* cp_b      = (const float*)d_in[29];
  const float* dec1_w    = (const float*)d_in[30];
  const float* dec1_b    = (const float*)d_in[31];
  const float* dec2_w    = (const float*)d_in[32];
  const float* dec2_b    = (const float*)d_in[33];

  float* W = (float*)d_ws;
  size_t off = 0;
  auto alloc = [&](size_t n){ float* pp = W + off; off += n; return pp; };
  float* RES  = alloc((size_t)NTOK);
  float* H    = alloc((size_t)NTOK);
  float* HN   = alloc((size_t)NTOK);
  float* HNF  = alloc((size_t)NTOK);
  float* ZB   = alloc((size_t)NROWS*DIP);        // 17,956,864
  float* XC   = alloc((size_t)NROWS*CVD);        //  9,437,184
  float* DT   = alloc((size_t)NROWS*NH);
  float* DA   = alloc((size_t)NROWS*NH);
  float* ACUM = alloc((size_t)BS*NC*NH*CKS);
  float* CDEC = alloc((size_t)BS*NC*NH);
  float* Y    = alloc((size_t)NROWS*DIN);        //  8,388,608
  float* ST   = alloc((size_t)BS*NC*NH*4096);
  float* PREV = alloc((size_t)BS*NC*NH*4096);
  float* YD   = alloc((size_t)NTOK);
  float* HF   = alloc((size_t)NTOK);
  // byte-identical to the proven round-1 layout (61,768,192 floats)

  // mamba staging aliases (proven lifetimes):
  u16* Ubf    = (u16*)HF;
  u16* WinTc  = (u16*)(HF + 2097152);
  u16* WoutTc = (u16*)(HF + 2097152 + 561152);
  u16* Ybf    = (u16*)HNF;
  // SSD staging:
  u16*   Bbf    = (u16*)HNF;
  u16*   Cbf    = Bbf + 524288;
  float* Sf     = HNF + 524288;
  u16*   PREVbf = (u16*)Sf;
  u16*   BTc    = (u16*)(HNF + 2621440);   // 524,288 u16 (free HNF tail)
  u16*   XdTg   = (u16*)YD;                // 8,388,608 u16 (YD dead in mamba path now)

  const int TPB = 256;
  const int gTok = (NTOK+TPB-1)/TPB;
  dim3 tb(32,8);

  hipMemcpyAsync(RES, x_enc, (size_t)NTOK*4, hipMemcpyDeviceToDevice, stream);

  for(int layer=0; layer<2; ++layer){
    if(layer>0) k_add_flip<<<gTok,TPB,0,stream>>>(RES, H, 0);
    k_ln<<<NROWS,TPB,0,stream>>>(RES, norm_w + layer*DM, norm_b + layer*DM, HN);
    hipMemsetAsync(H, 0, (size_t)NTOK*4, stream);
    for(int dir=0; dir<2; ++dir){
      int idx = layer*2 + dir;
      const float* cw   = conv_w   + (size_t)idx*CVD*4;
      const float* cb   = conv_b   + (size_t)idx*CVD;
      const float* dtb  = dt_bias  + (size_t)idx*NH;
      const float* Alog = A_log    + (size_t)idx*NH;
      const float* Dp   = D_param  + (size_t)idx*NH;
      const float* gw   = gnorm_w  + (size_t)idx*DIN;

      if(dir==0){
        k_cvt<<<(NTOK/4+TPB-1)/TPB,TPB,0,stream>>>(HN, Ubf, NTOK/4);
      }else{
        k_flip<<<gTok,TPB,0,stream>>>(HNF, HN);
        k_cvt<<<(NTOK/4+TPB-1)/TPB,TPB,0,stream>>>(HNF, Ubf, NTOK/4);
      }
      k_wt2<<<dim3(69,16),tb,0,stream>>>(in_proj_w + (size_t)idx*DM*DIP, WinTc, 512, 2192, 2192);
      k_mg<<<dim3(18,64),256,0,stream>>>(Ubf, WinTc, ZB, 8192, 2192, 512, 512, 512, 2192);

      k_conv4<<<(BS*512*CVD+TPB-1)/TPB,TPB,0,stream>>>(ZB, cw, cb, XC);
      k_dt<<<(BS*SEQL*NH+TPB-1)/TPB,TPB,0,stream>>>(ZB, dtb, Alog, DT, DA);
      k_acum<<<BS*NC*NH,256,0,stream>>>(DA, ACUM, CDEC);

      // ---- Y_diag via MFMA with fused G-formation ----
      k_bc<<<(NROWS*DST+TPB-1)/TPB,TPB,0,stream>>>(XC, Bbf, Cbf);
      k_mgb<<<dim3(2,2,32),256,0,stream>>>(Cbf, Bbf, Sf,
            256, 256, 64, 64, 64, 256, 16384, 16384, 65536, 0, 0);
      k_xdtt<<<dim3(2,8,512),tb,0,stream>>>(XC, DT, XdTg);
      k_mgg<<<dim3(1,2,512),256,0,stream>>>(Sf, ACUM, XdTg, Y);

      // ---- states via MFMA ----
      k_btc<<<dim3(2,8,32),tb,0,stream>>>(Bbf, BTc);
      k_mgs<<<dim3(1,1,512),256,0,stream>>>(XdTg, BTc, ACUM, ST);
      k_scan<<<(BS*NH*4096+TPB-1)/TPB,TPB,0,stream>>>(ST, CDEC, PREV);
      // ---- Y_off via MFMA + fused gate epilogue ----
      k_cvt<<<(2097152/4+TPB-1)/TPB,TPB,0,stream>>>(PREV, PREVbf, 2097152/4);
      k_mgy<<<dim3(8,2,32),256,0,stream>>>(Cbf, PREVbf, ACUM, XC, ZB, Dp, Y);

      // ---- RMSNorm -> bf16 directly (skips f32 Y rewrite + cvt) ----
      k_rmsb<<<NROWS,256,0,stream>>>(Y, gw, Ybf);
      k_wt2<<<dim3(16,32),tb,0,stream>>>(out_proj_w + (size_t)idx*DIN*DM, WoutTc, 1024, 512, 512);
      // ---- out_proj with fused flip-add into H ----
      k_mgo<<<dim3(4,64),256,0,stream>>>(Ybf, WoutTc, H, dir);
    }
  }
  k_add_flip<<<gTok,TPB,0,stream>>>(RES, H, 0);
  k_ln<<<NROWS,TPB,0,stream>>>(RES, normf_w, normf_b, HF);

  // ================= attention head — MFMA (batched) =================
  float* P0   = ZB;
  float* QIN  = P0 + 0;
  float* CIN  = P0 + 2097152;
  float* QPb  = P0 + 4194304;
  float* CPb  = P0 + 6291456;
  float* QN   = P0 + 8388608;
  float* CN   = P0 + 10485760;
  float* AO   = P0 + 12582912;
  float* O1   = P0 + 14680064;
  float* D1   = P0 + 16777216;
  float* VV   = D1;
  u16* U0     = (u16*)(P0 + 20971520);
  u16* Qbf    = U0 + 0;
  u16* Cbf2   = U0 + 2097152;
  u16* QNbf   = U0 + 4194304;
  u16* CNbf   = U0 + 6291456;
  u16* QQbf   = U0 + 8388608;
  u16* KKbf   = U0 + 10485760;
  u16* VTbf   = U0 + 12582912;
  u16* AObf   = U0 + 14680064;
  u16* O1bf   = U0 + 16777216;
  u16* qpT    = U0 + 18874368;
  u16* cpT    = qpT + 262144;
  u16* qwT    = qpT + 524288;
  u16* kwT    = qpT + 786432;
  u16* vwT    = qpT + 1048576;
  u16* owT    = qpT + 1310720;
  u16* dec1T  = qpT + 1572864;
  u16* Pbf    = qpT + 2097152;

  const int M2 = BS*1024;
  k_extract<<<(BS*1024*DM+TPB-1)/TPB,TPB,0,stream>>>(HF, QIN, CIN);
  k_cvt<<<(2097152/4+TPB-1)/TPB,TPB,0,stream>>>(QIN, Qbf, 2097152/4);
  k_cvt<<<(2097152/4+TPB-1)/TPB,TPB,0,stream>>>(CIN, Cbf2, 2097152/4);
  k_wt2<<<dim3(16,16),tb,0,stream>>>(qp_w, qpT, 512, 512, 512);
  k_wt2<<<dim3(16,16),tb,0,stream>>>(cp_w, cpT, 512, 512, 512);
  k_wt2<<<dim3(16,16),tb,0,stream>>>(ca_qw, qwT, 512, 512, 512);
  k_wt2<<<dim3(16,16),tb,0,stream>>>(ca_kw, kwT, 512, 512, 512);
  k_wt2<<<dim3(16,16),tb,0,stream>>>(ca_vw, vwT, 512, 512, 512);
  k_wt2<<<dim3(16,16),tb,0,stream>>>(ca_ow, owT, 512, 512, 512);
  k_wt2<<<dim3(32,16),tb,0,stream>>>(dec1_w, dec1T, 512, 1024, 1024);

  k_mge<<<dim3(4,32),256,0,stream>>>(Qbf, qpT, qp_b, nullptr, QPb, nullptr,
                                     M2, 512, 512, 512, 512, 512, 1.f, 0);
  k_mge<<<dim3(4,32),256,0,stream>>>(Cbf2, cpT, cp_b, nullptr, CPb, nullptr,
                                     M2, 512, 512, 512, 512, 512, 1.f, 0);
  k_ln<<<M2,TPB,0,stream>>>(QPb, ca_nq_w, ca_nq_b, QN);
  k_ln<<<M2,TPB,0,stream>>>(CPb, ca_nkv_w, ca_nkv_b, CN);
  k_cvt<<<(2097152/4+TPB-1)/TPB,TPB,0,stream>>>(QN, QNbf, 2097152/4);
  k_cvt<<<(2097152/4+TPB-1)/TPB,TPB,0,stream>>>(CN, CNbf, 2097152/4);
  k_mge<<<dim3(4,32),256,0,stream>>>(QNbf, qwT, ca_qb, nullptr, nullptr, QQbf,
                                     M2, 512, 512, 512, 512, 512, 1.f, 0);
  k_mge<<<dim3(4,32),256,0,stream>>>(CNbf, kwT, ca_kb, nullptr, nullptr, KKbf,
                                     M2, 512, 512, 512, 512, 512, 1.f, 0);
  k_mge<<<dim3(4,32),256,0,stream>>>(CNbf, vwT, ca_vb, nullptr, VV, nullptr,
                                     M2, 512, 512, 512, 512, 512, 1.f, 0);
  k_vtb<<<dim3(4,32,16),tb,0,stream>>>(VV, VTbf);
  const float scl = 0.088388347648318447f;
  k_mgab<<<dim3(8,8,16),256,0,stream>>>(QQbf, KKbf, nullptr, Pbf,
        1024, 1024, 128, 512, 512, 1024,
        524288, 128, 524288, 128, 4194304, 1048576, scl);
  k_sm<<<16384,256,0,stream>>>(Pbf);
  k_mgab<<<dim3(1,8,16),256,0,stream>>>(Pbf, VTbf, AO, nullptr,
        1024, 128, 1024, 1024, 1024, 512,
        4194304, 1048576, 524288, 131072, 524288, 128, 1.f);
  k_cvt<<<(2097152/4+TPB-1)/TPB,TPB,0,stream>>>(AO, AObf, 2097152/4);
  k_mge<<<dim3(4,32),256,0,stream>>>(AObf, owT, ca_ob, QPb, O1, nullptr,
                                     M2, 512, 512, 512, 512, 512, 1.f, 0);
  k_cvt<<<(2097152/4+TPB-1)/TPB,TPB,0,stream>>>(O1, O1bf, 2097152/4);
  k_mge<<<dim3(8,32),256,0,stream>>>(O1bf, dec1T, dec1_b, nullptr, D1, nullptr,
                                     M2, 1024, 512, 512, 512, 1024, 1.f, 1);
  k_dec2<<<M2,256,0,stream>>>(D1, dec2_w, dec2_b, (float*)d_out);
}

// Round 18
// 1337.787 us; speedup vs baseline: 242.8572x; 1.0238x over previous
//
#include <hip/hip_runtime.h>
#include <hip/hip_bf16.h>

#define BS 4
#define SEQL 2048
#define DM 512
#define DIN 1024
#define NH 16
#define HD 64
#define DST 64
#define NC 8
#define CKS 256
#define DIP 2192
#define CVD 1152
#define NROWS (BS*SEQL)          /* 8192 */
#define NTOK (BS*SEQL*DM)        /* 4194304 */

typedef unsigned short u16;
typedef __bf16 bf16x8 __attribute__((ext_vector_type(8)));
typedef float f32x4 __attribute__((ext_vector_type(4)));

__device__ __forceinline__ u16 cvt_bf16(float f){
  unsigned int x = __float_as_uint(f);
  unsigned int r = x + 0x7fffu + ((x>>16)&1u);
  return (u16)(r>>16);
}
__device__ __forceinline__ float bf2f(u16 u){
  return __uint_as_float(((unsigned int)u)<<16);
}

// ---------------- elementwise (proven) ----------------
__global__ void k_add_flip(float* __restrict__ dst, const float* __restrict__ src, int flip){
  int i = blockIdx.x*256 + threadIdx.x;
  if(i >= NTOK) return;
  int d = i & (DM-1);
  int l = (i >> 9) & (SEQL-1);
  int b = i >> 20;
  int sl = flip ? (SEQL-1-l) : l;
  dst[i] += src[(b*SEQL + sl)*DM + d];
}

__global__ void k_flip(float* __restrict__ dst, const float* __restrict__ src){
  int i = blockIdx.x*256 + threadIdx.x;
  if(i >= NTOK) return;
  int d = i & (DM-1);
  int l = (i >> 9) & (SEQL-1);
  int b = i >> 20;
  dst[i] = src[(b*SEQL + (SEQL-1-l))*DM + d];
}

// f32 -> bf16 (verified round-8)
__global__ void k_cvt(const float* __restrict__ src, u16* __restrict__ dst, int n4){
  int i = blockIdx.x*256 + threadIdx.x;
  if(i >= n4) return;
  float4 f = reinterpret_cast<const float4*>(src)[i];
  ushort4 o; o.x=cvt_bf16(f.x); o.y=cvt_bf16(f.y); o.z=cvt_bf16(f.z); o.w=cvt_bf16(f.w);
  reinterpret_cast<ushort4*>(dst)[i] = o;
}

__global__ void k_ln(const float* __restrict__ X, const float* __restrict__ w,
                     const float* __restrict__ bb, float* __restrict__ O){
  int row = blockIdx.x, tid = threadIdx.x;
  const float* x = X + (size_t)row*DM;
  float* o = O + (size_t)row*DM;
  float s=0.f, s2=0.f;
  for(int j=tid;j<DM;j+=256){ float v=x[j]; s+=v; s2+=v*v; }
  __shared__ float r1[256], r2[256];
  r1[tid]=s; r2[tid]=s2; __syncthreads();
  for(int off=128;off>0;off>>=1){
    if(tid<off){ r1[tid]+=r1[tid+off]; r2[tid]+=r2[tid+off]; }
    __syncthreads();
  }
  float m = r1[0]*(1.f/DM);
  float var = r2[0]*(1.f/DM) - m*m;
  float inv = rsqrtf(var + 1e-5f);
  for(int j=tid;j<DM;j+=256) o[j] = (x[j]-m)*inv*w[j] + bb[j];
}

// RMSNorm reading Y f32, writing bf16 only (same rounding point as rms+cvt)
__global__ void k_rmsb(const float* __restrict__ Y, const float* __restrict__ gw,
                       u16* __restrict__ Obf){
  int row = blockIdx.x, tid = threadIdx.x;
  const float* y = Y + (size_t)row*DIN;
  float ss=0.f;
  for(int j=tid;j<DIN;j+=256){ float v=y[j]; ss+=v*v; }
  __shared__ float red[256];
  red[tid]=ss; __syncthreads();
  for(int off=128;off>0;off>>=1){
    if(tid<off) red[tid]+=red[tid+off];
    __syncthreads();
  }
  float inv = rsqrtf(red[0]*(1.f/DIN) + 1e-5f);
  for(int j=tid;j<DIN;j+=256) Obf[(size_t)row*DIN + j] = cvt_bf16(y[j]*inv*gw[j]);
}

// dec2: out[row][0..9] = D1[row]·dec2_w + b ; one block per row
__global__ void k_dec2(const float* __restrict__ D1, const float* __restrict__ w,
                       const float* __restrict__ bb, float* __restrict__ out){
  int row = blockIdx.x, tid = threadIdx.x;
  int lane = tid & 63, wave = tid >> 6;
  const float* x = D1 + (size_t)row*1024;
  float acc[10];
  #pragma unroll
  for(int o=0;o<10;o++) acc[o]=0.f;
  for(int j=tid;j<1024;j+=256){
    float v = x[j];
    const float* wr = w + (size_t)j*10;
    #pragma unroll
    for(int o=0;o<10;o++) acc[o] += v*wr[o];
  }
  __shared__ float red[4][10];
  #pragma unroll
  for(int o=0;o<10;o++){
    float v = acc[o];
    #pragma unroll
    for(int s=32;s>0;s>>=1) v += __shfl_down(v, s, 64);
    if(lane==0) red[wave][o] = v;
  }
  __syncthreads();
  if(tid < 10)
    out[(size_t)row*10 + tid] = red[0][tid]+red[1][tid]+red[2][tid]+red[3][tid] + bb[tid];
}

// transpose-convert with explicit src ld (verified): src[K][lds] f32 -> dst[N][K] bf16
__global__ void k_wt2(const float* __restrict__ src, u16* __restrict__ dst,
                      int K, int N, int lds){
  __shared__ float t[32][33];
  int n0 = blockIdx.x*32, k0 = blockIdx.y*32;
  int tx = threadIdx.x, ty = threadIdx.y;
  #pragma unroll
  for(int i=0;i<32;i+=8){
    int k = k0+ty+i, n = n0+tx;
    t[ty+i][tx] = (n<N) ? src[(size_t)k*lds+n] : 0.f;
  }
  __syncthreads();
  #pragma unroll
  for(int i=0;i<32;i+=8){
    int n = n0+ty+i, k = k0+tx;
    if(n<N) dst[(size_t)n*K+k] = cvt_bf16(t[tx][ty+i]);
  }
}

// batched V-transpose: per z=(b*4+h): src=VV+b*524288+h*128 [1024][128 of 512] -> dst [128][1024]
__global__ void k_vtb(const float* __restrict__ VV, u16* __restrict__ VT){
  __shared__ float t[32][33];
  int z = blockIdx.z, b = z>>2, h = z&3;
  const float* src = VV + (size_t)b*524288 + h*128;
  u16* dst = VT + (size_t)z*131072;
  int n0 = blockIdx.x*32, k0 = blockIdx.y*32;
  int tx = threadIdx.x, ty = threadIdx.y;
  #pragma unroll
  for(int i=0;i<32;i+=8){
    int k = k0+ty+i, n = n0+tx;
    t[ty+i][tx] = src[(size_t)k*512+n];
  }
  __syncthreads();
  #pragma unroll
  for(int i=0;i<32;i+=8){
    int n = n0+ty+i, k = k0+tx;
    dst[(size_t)n*1024+k] = cvt_bf16(t[tx][ty+i]);
  }
}

// XdT via LDS-tiled transpose: per z=(bc*16+h), XdT[z][p][s] = bf16(XC[..]*DT[..])
__global__ void k_xdtt(const float* __restrict__ XC, const float* __restrict__ DT,
                       u16* __restrict__ XdT){
  __shared__ float t[32][33];
  int z = blockIdx.z;
  int h = z & 15, bc = z >> 4;
  int b = bc >> 3, c = bc & 7;
  int p0 = blockIdx.x*32, s0 = blockIdx.y*32;
  int tx = threadIdx.x, ty = threadIdx.y;
  int gbase = b*SEQL + c*CKS;
  #pragma unroll
  for(int i=0;i<32;i+=8){
    int s = s0+ty+i, p = p0+tx;
    int g = gbase + s;
    t[ty+i][tx] = XC[(size_t)g*CVD + h*HD + p] * DT[(size_t)g*NH + h];
  }
  __syncthreads();
  u16* dst = XdT + (size_t)z*16384;
  #pragma unroll
  for(int i=0;i<32;i+=8){
    int p = p0+ty+i, s = s0+tx;
    dst[(size_t)p*256 + s] = cvt_bf16(t[tx][ty+i]);
  }
}

// batched B-transpose: per bc: Bbf[bc] [256][64] -> BTc[bc][64][256]
__global__ void k_btc(const u16* __restrict__ Bbf, u16* __restrict__ BTc){
  __shared__ u16 t[32][33];
  int bc = blockIdx.z;
  const u16* src = Bbf + (size_t)bc*16384;
  u16* dst = BTc + (size_t)bc*16384;
  int n0 = blockIdx.x*32, l0 = blockIdx.y*32;
  int tx = threadIdx.x, ty = threadIdx.y;
  #pragma unroll
  for(int i=0;i<32;i+=8){
    int l = l0+ty+i, n = n0+tx;
    t[ty+i][tx] = src[(size_t)l*64+n];
  }
  __syncthreads();
  #pragma unroll
  for(int i=0;i<32;i+=8){
    int n = n0+ty+i, l = l0+tx;
    dst[(size_t)n*256+l] = t[tx][ty+i];
  }
}

// ---------------- MFMA bf16 GEMM, emap0, global_load_lds staging ----------------
// LDS slot swizzle: physical 16B slot s of row r holds logical kseg s^((r>>1)&3).
__global__ __launch_bounds__(256) void k_mg(
    const u16* __restrict__ A, const u16* __restrict__ BT,
    float* __restrict__ C, int M, int N, int K, int lda, int ldb, int ldc)
{
  __shared__ u16 As[128*32];
  __shared__ u16 Bs[128*32];
  const int tid = threadIdx.x;
  const int row0 = blockIdx.y*128, col0 = blockIdx.x*128;
  const int lane = tid & 63, wave = tid >> 6;
  const int wm = wave >> 1, wn = wave & 1;
  const int lr = lane & 15, ksg = (lane >> 4);
  const int srow = lane >> 2;       // 0..15 within 16-row segment
  const int slot = lane & 3;        // physical 16B slot
  f32x4 acc[4][4];
  #pragma unroll
  for(int i=0;i<4;i++)
    #pragma unroll
    for(int j=0;j<4;j++) acc[i][j] = (f32x4){0.f,0.f,0.f,0.f};
  for(int k0=0;k0<K;k0+=32){
    #pragma unroll
    for(int i=0;i<2;i++){
      int seg = wave*2 + i;
      int row = seg*16 + srow;
      int kk  = slot ^ ((row>>1)&3);
      const u16* ga = A + (size_t)(row0+row)*lda + k0 + kk*8;
      __builtin_amdgcn_global_load_lds(
        (const __attribute__((address_space(1))) void*)ga,
        (__attribute__((address_space(3))) void*)&As[seg*512], 16, 0, 0);
      int bcol = col0 + row; if(bcol > N-1) bcol = N-1;
      const u16* gb = BT + (size_t)bcol*ldb + k0 + kk*8;
      __builtin_amdgcn_global_load_lds(
        (const __attribute__((address_space(1))) void*)gb,
        (__attribute__((address_space(3))) void*)&Bs[seg*512], 16, 0, 0);
    }
    __syncthreads();
    bf16x8 afr[4], bfr[4];
    #pragma unroll
    for(int i=0;i<4;i++){
      int ar = wm*64+i*16+lr;
      afr[i] = *reinterpret_cast<const bf16x8*>(&As[ar*32 + (ksg^((ar>>1)&3))*8]);
    }
    #pragma unroll
    for(int j=0;j<4;j++){
      int br = wn*64+j*16+lr;
      bfr[j] = *reinterpret_cast<const bf16x8*>(&Bs[br*32 + (ksg^((br>>1)&3))*8]);
    }
    #pragma unroll
    for(int i=0;i<4;i++)
      #pragma unroll
      for(int j=0;j<4;j++)
        acc[i][j] = __builtin_amdgcn_mfma_f32_16x16x32_bf16(afr[i], bfr[j], acc[i][j], 0, 0, 0);
    __syncthreads();
  }
  const int hi = lane >> 4, lo = lane & 15;
  #pragma unroll
  for(int i=0;i<4;i++)
    #pragma unroll
    for(int j=0;j<4;j++)
      #pragma unroll
      for(int r=0;r<4;r++){
        int row = row0 + wm*64 + i*16 + 4*hi + r;
        int col = col0 + wn*64 + j*16 + lo;
        if(col < N) C[(size_t)row*ldc + col] = acc[i][j][r];
      }
}

// out_proj GEMM, gload_lds staging + fused flip-add epilogue
__global__ __launch_bounds__(256) void k_mgo(
    const u16* __restrict__ A, const u16* __restrict__ BT,
    float* __restrict__ H, int flip)
{
  const int N = 512, K = 1024;
  __shared__ u16 As[128*32];
  __shared__ u16 Bs[128*32];
  const int tid = threadIdx.x;
  const int row0 = blockIdx.y*128, col0 = blockIdx.x*128;
  const int lane = tid & 63, wave = tid >> 6;
  const int wm = wave >> 1, wn = wave & 1;
  const int lr = lane & 15, ksg = (lane >> 4);
  const int srow = lane >> 2;
  const int slot = lane & 3;
  f32x4 acc[4][4];
  #pragma unroll
  for(int i=0;i<4;i++)
    #pragma unroll
    for(int j=0;j<4;j++) acc[i][j] = (f32x4){0.f,0.f,0.f,0.f};
  for(int k0=0;k0<K;k0+=32){
    #pragma unroll
    for(int i=0;i<2;i++){
      int seg = wave*2 + i;
      int row = seg*16 + srow;
      int kk  = slot ^ ((row>>1)&3);
      const u16* ga = A + (size_t)(row0+row)*K + k0 + kk*8;
      __builtin_amdgcn_global_load_lds(
        (const __attribute__((address_space(1))) void*)ga,
        (__attribute__((address_space(3))) void*)&As[seg*512], 16, 0, 0);
      int bcol = col0 + row; if(bcol > N-1) bcol = N-1;
      const u16* gb = BT + (size_t)bcol*K + k0 + kk*8;
      __builtin_amdgcn_global_load_lds(
        (const __attribute__((address_space(1))) void*)gb,
        (__attribute__((address_space(3))) void*)&Bs[seg*512], 16, 0, 0);
    }
    __syncthreads();
    bf16x8 afr[4], bfr[4];
    #pragma unroll
    for(int i=0;i<4;i++){
      int ar = wm*64+i*16+lr;
      afr[i] = *reinterpret_cast<const bf16x8*>(&As[ar*32 + (ksg^((ar>>1)&3))*8]);
    }
    #pragma unroll
    for(int j=0;j<4;j++){
      int br = wn*64+j*16+lr;
      bfr[j] = *reinterpret_cast<const bf16x8*>(&Bs[br*32 + (ksg^((br>>1)&3))*8]);
    }
    #pragma unroll
    for(int i=0;i<4;i++)
      #pragma unroll
      for(int j=0;j<4;j++)
        acc[i][j] = __builtin_amdgcn_mfma_f32_16x16x32_bf16(afr[i], bfr[j], acc[i][j], 0, 0, 0);
    __syncthreads();
  }
  const int hi = lane >> 4, lo = lane & 15;
  #pragma unroll
  for(int i=0;i<4;i++)
    #pragma unroll
    for(int j=0;j<4;j++)
      #pragma unroll
      for(int r=0;r<4;r++){
        int row = row0 + wm*64 + i*16 + 4*hi + r;
        int col = col0 + wn*64 + j*16 + lo;
        if(col < N){
          int b = row >> 11, l = row & (SEQL-1);
          int sl = flip ? (SEQL-1-l) : l;
          size_t ci = (size_t)(b*SEQL + sl)*DM + col;
          H[ci] += acc[i][j][r];
        }
      }
}

// batched variant: verified core + z-strided base offsets only
__global__ __launch_bounds__(256) void k_mgb(
    const u16* __restrict__ A0, const u16* __restrict__ BT0,
    float* __restrict__ C0, int M, int N, int K, int lda, int ldb, int ldc,
    long sAz, long sBz, long sCo, long sCi, int shC)
{
  const int z = blockIdx.z;
  const u16* A  = A0  + (size_t)z*sAz;
  const u16* BT = BT0 + (size_t)z*sBz;
  float* C = C0 + (size_t)(z>>shC)*sCo + (size_t)(z & ((1<<shC)-1))*sCi;
  __shared__ uint4 As4[128*5];
  __shared__ uint4 Bs4[128*5];
  const int tid = threadIdx.x;
  const int row0 = blockIdx.y*128, col0 = blockIdx.x*128;
  const int lane = tid & 63, wave = tid >> 6;
  const int wm = wave >> 1, wn = wave & 1;
  const int lr = lane & 15, ksg = (lane >> 4);
  f32x4 acc[4][4];
  #pragma unroll
  for(int i=0;i<4;i++)
    #pragma unroll
    for(int j=0;j<4;j++) acc[i][j] = (f32x4){0.f,0.f,0.f,0.f};
  for(int k0=0;k0<K;k0+=32){
    #pragma unroll
    for(int i=0;i<2;i++){
      int t2 = tid + i*256;
      int rr = t2 >> 2, sg = (t2 & 3);
      uint4 av = *reinterpret_cast<const uint4*>(A + (size_t)(row0+rr)*lda + k0 + sg*8);
      uint4 bv = {0u,0u,0u,0u};
      if(col0+rr < N) bv = *reinterpret_cast<const uint4*>(BT + (size_t)(col0+rr)*ldb + k0 + sg*8);
      As4[rr*5 + sg] = av;
      Bs4[rr*5 + sg] = bv;
    }
    __syncthreads();
    bf16x8 afr[4], bfr[4];
    #pragma unroll
    for(int i=0;i<4;i++) afr[i] = *reinterpret_cast<const bf16x8*>(&As4[(wm*64+i*16+lr)*5 + ksg]);
    #pragma unroll
    for(int j=0;j<4;j++) bfr[j] = *reinterpret_cast<const bf16x8*>(&Bs4[(wn*64+j*16+lr)*5 + ksg]);
    #pragma unroll
    for(int i=0;i<4;i++)
      #pragma unroll
      for(int j=0;j<4;j++)
        acc[i][j] = __builtin_amdgcn_mfma_f32_16x16x32_bf16(afr[i], bfr[j], acc[i][j], 0, 0, 0);
    __syncthreads();
  }
  const int hi = lane >> 4, lo = lane & 15;
  #pragma unroll
  for(int i=0;i<4;i++)
    #pragma unroll
    for(int j=0;j<4;j++)
      #pragma unroll
      for(int r=0;r<4;r++){
        int row = row0 + wm*64 + i*16 + 4*hi + r;
        int col = col0 + wn*64 + j*16 + lo;
        if(col < N) C[(size_t)row*ldc + col] = acc[i][j][r];
      }
}

// Y_diag GEMM with fused G-formation in A-staging
__global__ __launch_bounds__(256) void k_mgg(
    const float* __restrict__ Sf, const float* __restrict__ ACUM,
    const u16* __restrict__ XdT, float* __restrict__ Y)
{
  const int z = blockIdx.z;
  const int h = z & 15, bc = z >> 4;
  const int b = bc >> 3, c = bc & 7;
  const float* Az = Sf + (size_t)bc*65536;
  const float* Acp = ACUM + (size_t)z*256;
  const u16* BT = XdT + (size_t)z*16384;
  float* Cp = Y + (size_t)b*2097152 + (size_t)c*262144 + h*64;
  __shared__ uint4 As4[128*5];
  __shared__ uint4 Bs4[128*5];
  __shared__ float AcS[256];
  const int tid = threadIdx.x;
  AcS[tid] = Acp[tid];
  __syncthreads();
  const int row0 = blockIdx.y*128;
  const int lane = tid & 63, wave = tid >> 6;
  const int wm = wave >> 1, wn = wave & 1;
  const int lr = lane & 15, ksg = (lane >> 4);
  f32x4 acc[4][4];
  #pragma unroll
  for(int i=0;i<4;i++)
    #pragma unroll
    for(int j=0;j<4;j++) acc[i][j] = (f32x4){0.f,0.f,0.f,0.f};
  for(int k0=0;k0<256;k0+=32){
    #pragma unroll
    for(int i=0;i<2;i++){
      int t2 = tid + i*256;
      int rr = t2 >> 2, sg = (t2 & 3);
      int l = row0 + rr;
      int sbase = k0 + sg*8;
      float4 v0 = *reinterpret_cast<const float4*>(Az + (size_t)l*256 + sbase);
      float4 v1 = *reinterpret_cast<const float4*>(Az + (size_t)l*256 + sbase + 4);
      float acl = AcS[l];
      float vv[8] = {v0.x,v0.y,v0.z,v0.w,v1.x,v1.y,v1.z,v1.w};
      u16 gbuf[8];
      #pragma unroll
      for(int e=0;e<8;e++){
        int s = sbase + e;
        float g = 0.f;
        if(s <= l) g = __expf(acl - AcS[s]) * vv[e];
        gbuf[e] = cvt_bf16(g);
      }
      As4[rr*5 + sg] = *reinterpret_cast<uint4*>(gbuf);
      uint4 bv = {0u,0u,0u,0u};
      if(rr < 64) bv = *reinterpret_cast<const uint4*>(BT + (size_t)rr*256 + sbase);
      Bs4[rr*5 + sg] = bv;
    }
    __syncthreads();
    bf16x8 afr[4], bfr[4];
    #pragma unroll
    for(int i=0;i<4;i++) afr[i] = *reinterpret_cast<const bf16x8*>(&As4[(wm*64+i*16+lr)*5 + ksg]);
    #pragma unroll
    for(int j=0;j<4;j++) bfr[j] = *reinterpret_cast<const bf16x8*>(&Bs4[(wn*64+j*16+lr)*5 + ksg]);
    #pragma unroll
    for(int i=0;i<4;i++)
      #pragma unroll
      for(int j=0;j<4;j++)
        acc[i][j] = __builtin_amdgcn_mfma_f32_16x16x32_bf16(afr[i], bfr[j], acc[i][j], 0, 0, 0);
    __syncthreads();
  }
  const int hi = lane >> 4, lo = lane & 15;
  #pragma unroll
  for(int i=0;i<4;i++)
    #pragma unroll
    for(int j=0;j<4;j++)
      #pragma unroll
      for(int r=0;r<4;r++){
        int row = row0 + wm*64 + i*16 + 4*hi + r;
        int col = wn*64 + j*16 + lo;
        if(col < 64) Cp[(size_t)row*1024 + col] = acc[i][j][r];
      }
}

// states via MFMA: per z=(bc*16+h): ST[z][p][n] = sum_l (XdT[z][p][l]*dec[l]) * B[bc][l][n]
__global__ __launch_bounds__(256) void k_mgs(
    const u16* __restrict__ XdT, const u16* __restrict__ BTc,
    const float* __restrict__ ACUM, float* __restrict__ ST)
{
  const int z = blockIdx.z;
  const int bc = z >> 4;
  const u16* Ap = XdT + (size_t)z*16384;
  const u16* BT = BTc + (size_t)bc*16384;
  float* Cp = ST + (size_t)z*4096;
  __shared__ uint4 As4[128*5];
  __shared__ uint4 Bs4[128*5];
  __shared__ float decS[256];
  const int tid = threadIdx.x;
  {
    const float* Acp = ACUM + (size_t)z*256;
    decS[tid] = __expf(Acp[255] - Acp[tid]);
  }
  __syncthreads();
  const int lane = tid & 63, wave = tid >> 6;
  const int wm = wave >> 1, wn = wave & 1;
  const int lr = lane & 15, ksg = (lane >> 4);
  f32x4 acc[4][4];
  #pragma unroll
  for(int i=0;i<4;i++)
    #pragma unroll
    for(int j=0;j<4;j++) acc[i][j] = (f32x4){0.f,0.f,0.f,0.f};
  for(int k0=0;k0<256;k0+=32){
    #pragma unroll
    for(int i=0;i<2;i++){
      int t2 = tid + i*256;
      int rr = t2 >> 2, sg = (t2 & 3);
      int sbase = k0 + sg*8;
      uint4 av = {0u,0u,0u,0u};
      if(rr < 64){
        uint4 raw = *reinterpret_cast<const uint4*>(Ap + (size_t)rr*256 + sbase);
        const u16* rp = reinterpret_cast<const u16*>(&raw);
        u16 buf[8];
        #pragma unroll
        for(int e=0;e<8;e++) buf[e] = cvt_bf16(bf2f(rp[e]) * decS[sbase+e]);
        av = *reinterpret_cast<uint4*>(buf);
      }
      As4[rr*5 + sg] = av;
      uint4 bv = {0u,0u,0u,0u};
      if(rr < 64) bv = *reinterpret_cast<const uint4*>(BT + (size_t)rr*256 + sbase);
      Bs4[rr*5 + sg] = bv;
    }
    __syncthreads();
    bf16x8 afr[4], bfr[4];
    #pragma unroll
    for(int i=0;i<4;i++) afr[i] = *reinterpret_cast<const bf16x8*>(&As4[(wm*64+i*16+lr)*5 + ksg]);
    #pragma unroll
    for(int j=0;j<4;j++) bfr[j] = *reinterpret_cast<const bf16x8*>(&Bs4[(wn*64+j*16+lr)*5 + ksg]);
    #pragma unroll
    for(int i=0;i<4;i++)
      #pragma unroll
      for(int j=0;j<4;j++)
        acc[i][j] = __builtin_amdgcn_mfma_f32_16x16x32_bf16(afr[i], bfr[j], acc[i][j], 0, 0, 0);
    __syncthreads();
  }
  const int hi = lane >> 4, lo = lane & 15;
  #pragma unroll
  for(int i=0;i<4;i++)
    #pragma unroll
    for(int j=0;j<4;j++)
      #pragma unroll
      for(int r=0;r<4;r++){
        int row = wm*64 + i*16 + 4*hi + r;
        int col = wn*64 + j*16 + lo;
        if(row < 64 && col < 64) Cp[(size_t)row*64 + col] = acc[i][j][r];
      }
}

// batched attention GEMM: (z>>2)/(z&3) offsets for A/B/C, scale, f32 or bf16 out
__global__ __launch_bounds__(256) void k_mgab(
    const u16* __restrict__ A0, const u16* __restrict__ BT0,
    float* __restrict__ C0, u16* __restrict__ Cb0,
    int M, int N, int K, int lda, int ldb, int ldc,
    long sAo, long sAi, long sBo, long sBi, long sCo, long sCi, float scale)
{
  const int z = blockIdx.z;
  const u16* A  = A0  + (size_t)(z>>2)*sAo + (size_t)(z&3)*sAi;
  const u16* BT = BT0 + (size_t)(z>>2)*sBo + (size_t)(z&3)*sBi;
  const size_t offC = (size_t)(z>>2)*sCo + (size_t)(z&3)*sCi;
  __shared__ uint4 As4[128*5];
  __shared__ uint4 Bs4[128*5];
  const int tid = threadIdx.x;
  const int row0 = blockIdx.y*128, col0 = blockIdx.x*128;
  const int lane = tid & 63, wave = tid >> 6;
  const int wm = wave >> 1, wn = wave & 1;
  const int lr = lane & 15, ksg = (lane >> 4);
  f32x4 acc[4][4];
  #pragma unroll
  for(int i=0;i<4;i++)
    #pragma unroll
    for(int j=0;j<4;j++) acc[i][j] = (f32x4){0.f,0.f,0.f,0.f};
  for(int k0=0;k0<K;k0+=32){
    #pragma unroll
    for(int i=0;i<2;i++){
      int t2 = tid + i*256;
      int rr = t2 >> 2, sg = (t2 & 3);
      uint4 av = *reinterpret_cast<const uint4*>(A + (size_t)(row0+rr)*lda + k0 + sg*8);
      uint4 bv = {0u,0u,0u,0u};
      if(col0+rr < N) bv = *reinterpret_cast<const uint4*>(BT + (size_t)(col0+rr)*ldb + k0 + sg*8);
      As4[rr*5 + sg] = av;
      Bs4[rr*5 + sg] = bv;
    }
    __syncthreads();
    bf16x8 afr[4], bfr[4];
    #pragma unroll
    for(int i=0;i<4;i++) afr[i] = *reinterpret_cast<const bf16x8*>(&As4[(wm*64+i*16+lr)*5 + ksg]);
    #pragma unroll
    for(int j=0;j<4;j++) bfr[j] = *reinterpret_cast<const bf16x8*>(&Bs4[(wn*64+j*16+lr)*5 + ksg]);
    #pragma unroll
    for(int i=0;i<4;i++)
      #pragma unroll
      for(int j=0;j<4;j++)
        acc[i][j] = __builtin_amdgcn_mfma_f32_16x16x32_bf16(afr[i], bfr[j], acc[i][j], 0, 0, 0);
    __syncthreads();
  }
  const int hi = lane >> 4, lo = lane & 15;
  #pragma unroll
  for(int i=0;i<4;i++)
    #pragma unroll
    for(int j=0;j<4;j++)
      #pragma unroll
      for(int r=0;r<4;r++){
        int row = row0 + wm*64 + i*16 + 4*hi + r;
        int col = col0 + wn*64 + j*16 + lo;
        if(col < N){
          float v = acc[i][j][r] * scale;
          size_t ci = offC + (size_t)row*ldc + col;
          if(C0) C0[ci] = v;
          else   Cb0[ci] = cvt_bf16(v);
        }
      }
}

// Y_off GEMM fused with yfinal epilogue
__global__ __launch_bounds__(256) void k_mgy(
    const u16* __restrict__ Cb0, const u16* __restrict__ PV0,
    const float* __restrict__ ACUM, const float* __restrict__ XCp,
    const float* __restrict__ ZBp, const float* __restrict__ Dp,
    float* __restrict__ Y)
{
  const int z = blockIdx.z;                 // b*8+c
  const int b = z>>3, c = z&7;
  const u16* A  = Cb0 + (size_t)z*16384;    // [256][64] bf16
  const u16* BT = PV0 + (size_t)z*65536;    // [1024][64] bf16
  const int N = 1024;
  __shared__ uint4 As4[128*5];
  __shared__ uint4 Bs4[128*5];
  const int tid = threadIdx.x;
  const int row0 = blockIdx.y*128, col0 = blockIdx.x*128;
  const int lane = tid & 63, wave = tid >> 6;
  const int wm = wave >> 1, wn = wave & 1;
  const int lr = lane & 15, ksg = (lane >> 4);
  f32x4 acc[4][4];
  #pragma unroll
  for(int i=0;i<4;i++)
    #pragma unroll
    for(int j=0;j<4;j++) acc[i][j] = (f32x4){0.f,0.f,0.f,0.f};
  for(int k0=0;k0<64;k0+=32){
    #pragma unroll
    for(int i=0;i<2;i++){
      int t2 = tid + i*256;
      int rr = t2 >> 2, sg = (t2 & 3);
      uint4 av = *reinterpret_cast<const uint4*>(A + (size_t)(row0+rr)*64 + k0 + sg*8);
      uint4 bv = {0u,0u,0u,0u};
      if(col0+rr < N) bv = *reinterpret_cast<const uint4*>(BT + (size_t)(col0+rr)*64 + k0 + sg*8);
      As4[rr*5 + sg] = av;
      Bs4[rr*5 + sg] = bv;
    }
    __syncthreads();
    bf16x8 afr[4], bfr[4];
    #pragma unroll
    for(int i=0;i<4;i++) afr[i] = *reinterpret_cast<const bf16x8*>(&As4[(wm*64+i*16+lr)*5 + ksg]);
    #pragma unroll
    for(int j=0;j<4;j++) bfr[j] = *reinterpret_cast<const bf16x8*>(&Bs4[(wn*64+j*16+lr)*5 + ksg]);
    #pragma unroll
    for(int i=0;i<4;i++)
      #pragma unroll
      for(int j=0;j<4;j++)
        acc[i][j] = __builtin_amdgcn_mfma_f32_16x16x32_bf16(afr[i], bfr[j], acc[i][j], 0, 0, 0);
    __syncthreads();
  }
  const int hi = lane >> 4, lo = lane & 15;
  #pragma unroll
  for(int i=0;i<4;i++)
    #pragma unroll
    for(int j=0;j<4;j++)
      #pragma unroll
      for(int r=0;r<4;r++){
        int row = row0 + wm*64 + i*16 + 4*hi + r;
        int col = col0 + wn*64 + j*16 + lo;
        int h = col >> 6;
        int g = b*SEQL + c*CKS + row;
        float ac = ACUM[((size_t)z*NH + h)*CKS + row];
        float xh = XCp[(size_t)g*CVD + col];
        float zg = ZBp[(size_t)g*DIP + col];
        size_t ci = (size_t)g*DIN + col;
        float v = Y[ci] + expf(ac)*acc[i][j][r] + Dp[h]*xh;
        float sig = 1.f/(1.f+expf(-zg));
        Y[ci] = v * (zg*sig);
      }
}

// verified core + arithmetic epilogue (attention projections)
__global__ __launch_bounds__(256) void k_mge(
    const u16* __restrict__ A, const u16* __restrict__ BT,
    const float* __restrict__ bias, const float* __restrict__ res,
    float* __restrict__ C, u16* __restrict__ Cbf,
    int M, int N, int K, int lda, int ldb, int ldc, float scale, int act)
{
  __shared__ uint4 As4[128*5];
  __shared__ uint4 Bs4[128*5];
  const int tid = threadIdx.x;
  const int row0 = blockIdx.y*128, col0 = blockIdx.x*128;
  const int lane = tid & 63, wave = tid >> 6;
  const int wm = wave >> 1, wn = wave & 1;
  const int lr = lane & 15, ksg = (lane >> 4);
  f32x4 acc[4][4];
  #pragma unroll
  for(int i=0;i<4;i++)
    #pragma unroll
    for(int j=0;j<4;j++) acc[i][j] = (f32x4){0.f,0.f,0.f,0.f};
  for(int k0=0;k0<K;k0+=32){
    #pragma unroll
    for(int i=0;i<2;i++){
      int t2 = tid + i*256;
      int rr = t2 >> 2, sg = (t2 & 3);
      uint4 av = *reinterpret_cast<const uint4*>(A + (size_t)(row0+rr)*lda + k0 + sg*8);
      uint4 bv = {0u,0u,0u,0u};
      if(col0+rr < N) bv = *reinterpret_cast<const uint4*>(BT + (size_t)(col0+rr)*ldb + k0 + sg*8);
      As4[rr*5 + sg] = av;
      Bs4[rr*5 + sg] = bv;
    }
    __syncthreads();
    bf16x8 afr[4], bfr[4];
    #pragma unroll
    for(int i=0;i<4;i++) afr[i] = *reinterpret_cast<const bf16x8*>(&As4[(wm*64+i*16+lr)*5 + ksg]);
    #pragma unroll
    for(int j=0;j<4;j++) bfr[j] = *reinterpret_cast<const bf16x8*>(&Bs4[(wn*64+j*16+lr)*5 + ksg]);
    #pragma unroll
    for(int i=0;i<4;i++)
      #pragma unroll
      for(int j=0;j<4;j++)
        acc[i][j] = __builtin_amdgcn_mfma_f32_16x16x32_bf16(afr[i], bfr[j], acc[i][j], 0, 0, 0);
    __syncthreads();
  }
  const int hi = lane >> 4, lo = lane & 15;
  #pragma unroll
  for(int i=0;i<4;i++)
    #pragma unroll
    for(int j=0;j<4;j++)
      #pragma unroll
      for(int r=0;r<4;r++){
        int row = row0 + wm*64 + i*16 + 4*hi + r;
        int col = col0 + wn*64 + j*16 + lo;
        if(col < N){
          float v = acc[i][j][r];
          if(bias) v += bias[col];
          v *= scale;
          if(act==1) v = 0.5f*v*(1.f+erff(v*0.70710678118654752f));
          size_t ci = (size_t)row*ldc + col;
          if(res) v += res[ci];
          if(C) C[ci] = v;
          else  Cbf[ci] = cvt_bf16(v);
        }
      }
}

// in-place row softmax over 1024 bf16
__global__ void k_sm(u16* __restrict__ S){
  size_t row = blockIdx.x;
  u16* p = S + row*1024;
  int tid = threadIdx.x;
  ushort4 u = reinterpret_cast<ushort4*>(p)[tid];
  float v0=bf2f(u.x), v1=bf2f(u.y), v2=bf2f(u.z), v3=bf2f(u.w);
  float m = fmaxf(fmaxf(v0,v1),fmaxf(v2,v3));
  __shared__ float red[256];
  red[tid]=m; __syncthreads();
  for(int o=128;o>0;o>>=1){ if(tid<o) red[tid]=fmaxf(red[tid],red[tid+o]); __syncthreads(); }
  m = red[0]; __syncthreads();
  v0=__expf(v0-m); v1=__expf(v1-m); v2=__expf(v2-m); v3=__expf(v3-m);
  float s = v0+v1+v2+v3;
  red[tid]=s; __syncthreads();
  for(int o=128;o>0;o>>=1){ if(tid<o) red[tid]+=red[tid+o]; __syncthreads(); }
  float inv = 1.f/red[0];
  ushort4 o4; o4.x=cvt_bf16(v0*inv); o4.y=cvt_bf16(v1*inv); o4.z=cvt_bf16(v2*inv); o4.w=cvt_bf16(v3*inv);
  reinterpret_cast<ushort4*>(p)[tid] = o4;
}

// ---------------- mamba pieces ----------------
__global__ void k_conv4(const float* __restrict__ ZB, const float* __restrict__ cw,
                        const float* __restrict__ cb, float* __restrict__ XC){
  int i = blockIdx.x*256 + threadIdx.x;   // over BS*512*CVD
  if(i >= BS*512*CVD) return;
  int cch = i % CVD;
  int lq = (i / CVD) & 511;
  int b = i / (CVD*512);
  int l0 = lq*4;
  float w[7];
  #pragma unroll
  for(int t=0;t<7;t++){
    int sl = l0 - 3 + t;
    w[t] = (sl >= 0) ? ZB[(size_t)(b*SEQL+sl)*DIP + DIN + cch] : 0.f;
  }
  float c0 = cw[cch*4+0], c1 = cw[cch*4+1], c2 = cw[cch*4+2], c3 = cw[cch*4+3];
  float bb2 = cb[cch];
  #pragma unroll
  for(int j=0;j<4;j++){
    float v = bb2 + w[j]*c0 + w[j+1]*c1 + w[j+2]*c2 + w[j+3]*c3;
    float sig = 1.f/(1.f+expf(-v));
    XC[(size_t)(b*SEQL + l0 + j)*CVD + cch] = v*sig;
  }
}

__global__ void k_dt(const float* __restrict__ ZB, const float* __restrict__ dtb,
                     const float* __restrict__ Alog, float* __restrict__ DT,
                     float* __restrict__ DA){
  int i = blockIdx.x*256 + threadIdx.x;
  if(i >= BS*SEQL*NH) return;
  int h = i & (NH-1);
  int row = i >> 4;
  float raw = ZB[(size_t)row*DIP + (DIN+CVD) + h] + dtb[h];
  float dt = fmaxf(raw,0.f) + log1pf(expf(-fabsf(raw)));
  DT[i] = dt;
  DA[i] = dt * (-expf(Alog[h]));
}

__global__ void k_acum(const float* __restrict__ DA, float* __restrict__ ACUM,
                       float* __restrict__ CDEC){
  int blk = blockIdx.x;
  int h = blk & 15, c = (blk>>4)&7, b = blk>>7;
  int l = threadIdx.x;
  __shared__ float s[256];
  int gl = c*CKS + l;
  s[l] = DA[(size_t)(b*SEQL + gl)*NH + h];
  __syncthreads();
  for(int off=1; off<256; off<<=1){
    float v = (l>=off) ? s[l-off] : 0.f;
    __syncthreads();
    s[l] += v;
    __syncthreads();
  }
  ACUM[(size_t)blk*CKS + l] = s[l];
  if(l==255) CDEC[blk] = expf(s[255]);
}

// extract B,C as bf16 [8192][64]
__global__ void k_bc(const float* __restrict__ XC, u16* __restrict__ Bbf,
                     u16* __restrict__ Cbf){
  int i = blockIdx.x*256 + threadIdx.x;
  if(i >= NROWS*DST) return;
  int g = i >> 6, n = i & 63;
  Bbf[i] = cvt_bf16(XC[(size_t)g*CVD + DIN + n]);
  Cbf[i] = cvt_bf16(XC[(size_t)g*CVD + DIN + DST + n]);
}

__global__ void k_scan(const float* __restrict__ ST, const float* __restrict__ CDEC,
                       float* __restrict__ PREV){
  int i = blockIdx.x*256 + threadIdx.x;
  if(i >= BS*NH*4096) return;
  int pn = i & 4095;
  int h = (i>>12) & 15;
  int b = i >> 16;
  float run = 0.f;
  for(int c=0;c<8;c++){
    size_t idx = (size_t)((b*8+c)*16+h)*4096 + pn;
    PREV[idx] = run;
    run = run*CDEC[(b*8+c)*16+h] + ST[idx];
  }
}

// ---------------- attention helpers ----------------
__global__ void k_extract(const float* __restrict__ HF, float* __restrict__ QIN,
                          float* __restrict__ CIN){
  int i = blockIdx.x*256 + threadIdx.x;
  if(i >= BS*1024*DM) return;
  int d = i & (DM-1);
  int q = (i>>9) & 1023;
  int b = i >> 19;
  QIN[i] = HF[(size_t)(b*SEQL + 1024 + q)*DM + d];
  CIN[i] = HF[(size_t)(b*SEQL + q)*DM + d];
}

// ---------------- host ----------------
extern "C" void kernel_launch(void* const* d_in, const int* in_sizes, int n_in,
                              void* d_out, int out_size, void* d_ws, size_t ws_size,
                              hipStream_t stream) {
  (void)in_sizes; (void)n_in; (void)out_size; (void)ws_size;
  const float* x_enc     = (const float*)d_in[0];
  const float* in_proj_w = (const float*)d_in[2];
  const float* conv_w    = (const float*)d_in[3];
  const float* conv_b    = (const float*)d_in[4];
  const float* dt_bias   = (const float*)d_in[5];
  const float* A_log     = (const float*)d_in[6];
  const float* D_param   = (const float*)d_in[7];
  const float* gnorm_w   = (const float*)d_in[8];
  const float* out_proj_w= (const float*)d_in[9];
  const float* norm_w    = (const float*)d_in[10];
  const float* norm_b    = (const float*)d_in[11];
  const float* normf_w   = (const float*)d_in[12];
  const float* normf_b   = (const float*)d_in[13];
  const float* ca_nq_w   = (const float*)d_in[14];
  const float* ca_nq_b   = (const float*)d_in[15];
  const float* ca_nkv_w  = (const float*)d_in[16];
  const float* ca_nkv_b  = (const float*)d_in[17];
  const float* ca_qw     = (const float*)d_in[18];
  const float* ca_kw     = (const float*)d_in[19];
  const float* ca_vw     = (const float*)d_in[20];
  const float* ca_ow     = (const float*)d_in[21];
  const float* ca_qb     = (const float*)d_in[22];
  const float* ca_kb     = (const float*)d_in[23];
  const float* ca_vb     = (const float*)d_in[24];
  const float* ca_ob     = (const float*)d_in[25];
  const float* qp_w      = (const float*)d_in[26];
  const float* qp_b      = (const float*)d_in[27];
  const float* cp_w      = (const float*)d_in[28];
  const float* cp_b      = (const float*)d_in[29];
  const float* dec1_w    = (const float*)d_in[30];
  const float* dec1_b    = (const float*)d_in[31];
  const float* dec2_w    = (const float*)d_in[32];
  const float* dec2_b    = (const float*)d_in[33];

  float* W = (float*)d_ws;
  size_t off = 0;
  auto alloc = [&](size_t n){ float* pp = W + off; off += n; return pp; };
  float* RES  = alloc((size_t)NTOK);
  float* H    = alloc((size_t)NTOK);
  float* HN   = alloc((size_t)NTOK);
  float* HNF  = alloc((size_t)NTOK);
  float* ZB   = alloc((size_t)NROWS*DIP);        // 17,956,864
  float* XC   = alloc((size_t)NROWS*CVD);        //  9,437,184
  float* DT   = alloc((size_t)NROWS*NH);
  float* DA   = alloc((size_t)NROWS*NH);
  float* ACUM = alloc((size_t)BS*NC*NH*CKS);
  float* CDEC = alloc((size_t)BS*NC*NH);
  float* Y    = alloc((size_t)NROWS*DIN);        //  8,388,608
  float* ST   = alloc((size_t)BS*NC*NH*4096);
  float* PREV = alloc((size_t)BS*NC*NH*4096);
  float* YD   = alloc((size_t)NTOK);
  float* HF   = alloc((size_t)NTOK);
  // byte-identical to the proven round-1 layout (61,768,192 floats)

  // mamba staging aliases (proven lifetimes):
  u16* Ubf    = (u16*)HF;
  u16* WinTc  = (u16*)(HF + 2097152);
  u16* WoutTc = (u16*)(HF + 2097152 + 561152);
  u16* Ybf    = (u16*)HNF;
  // SSD staging:
  u16*   Bbf    = (u16*)HNF;
  u16*   Cbf    = Bbf + 524288;
  float* Sf     = HNF + 524288;
  u16*   PREVbf = (u16*)Sf;
  u16*   BTc    = (u16*)(HNF + 2621440);   // 524,288 u16 (free HNF tail)
  u16*   XdTg   = (u16*)YD;                // 8,388,608 u16 (YD dead in mamba path now)

  const int TPB = 256;
  const int gTok = (NTOK+TPB-1)/TPB;
  dim3 tb(32,8);

  hipMemcpyAsync(RES, x_enc, (size_t)NTOK*4, hipMemcpyDeviceToDevice, stream);

  for(int layer=0; layer<2; ++layer){
    if(layer>0) k_add_flip<<<gTok,TPB,0,stream>>>(RES, H, 0);
    k_ln<<<NROWS,TPB,0,stream>>>(RES, norm_w + layer*DM, norm_b + layer*DM, HN);
    hipMemsetAsync(H, 0, (size_t)NTOK*4, stream);
    for(int dir=0; dir<2; ++dir){
      int idx = layer*2 + dir;
      const float* cw   = conv_w   + (size_t)idx*CVD*4;
      const float* cb   = conv_b   + (size_t)idx*CVD;
      const float* dtb  = dt_bias  + (size_t)idx*NH;
      const float* Alog = A_log    + (size_t)idx*NH;
      const float* Dp   = D_param  + (size_t)idx*NH;
      const float* gw   = gnorm_w  + (size_t)idx*DIN;

      if(dir==0){
        k_cvt<<<(NTOK/4+TPB-1)/TPB,TPB,0,stream>>>(HN, Ubf, NTOK/4);
      }else{
        k_flip<<<gTok,TPB,0,stream>>>(HNF, HN);
        k_cvt<<<(NTOK/4+TPB-1)/TPB,TPB,0,stream>>>(HNF, Ubf, NTOK/4);
      }
      k_wt2<<<dim3(69,16),tb,0,stream>>>(in_proj_w + (size_t)idx*DM*DIP, WinTc, 512, 2192, 2192);
      k_mg<<<dim3(18,64),256,0,stream>>>(Ubf, WinTc, ZB, 8192, 2192, 512, 512, 512, 2192);

      k_conv4<<<(BS*512*CVD+TPB-1)/TPB,TPB,0,stream>>>(ZB, cw, cb, XC);
      k_dt<<<(BS*SEQL*NH+TPB-1)/TPB,TPB,0,stream>>>(ZB, dtb, Alog, DT, DA);
      k_acum<<<BS*NC*NH,256,0,stream>>>(DA, ACUM, CDEC);

      // ---- Y_diag via MFMA with fused G-formation ----
      k_bc<<<(NROWS*DST+TPB-1)/TPB,TPB,0,stream>>>(XC, Bbf, Cbf);
      k_mgb<<<dim3(2,2,32),256,0,stream>>>(Cbf, Bbf, Sf,
            256, 256, 64, 64, 64, 256, 16384, 16384, 65536, 0, 0);
      k_xdtt<<<dim3(2,8,512),tb,0,stream>>>(XC, DT, XdTg);
      k_mgg<<<dim3(1,2,512),256,0,stream>>>(Sf, ACUM, XdTg, Y);

      // ---- states via MFMA ----
      k_btc<<<dim3(2,8,32),tb,0,stream>>>(Bbf, BTc);
      k_mgs<<<dim3(1,1,512),256,0,stream>>>(XdTg, BTc, ACUM, ST);
      k_scan<<<(BS*NH*4096+TPB-1)/TPB,TPB,0,stream>>>(ST, CDEC, PREV);
      // ---- Y_off via MFMA + fused gate epilogue ----
      k_cvt<<<(2097152/4+TPB-1)/TPB,TPB,0,stream>>>(PREV, PREVbf, 2097152/4);
      k_mgy<<<dim3(8,2,32),256,0,stream>>>(Cbf, PREVbf, ACUM, XC, ZB, Dp, Y);

      // ---- RMSNorm -> bf16 directly ----
      k_rmsb<<<NROWS,256,0,stream>>>(Y, gw, Ybf);
      k_wt2<<<dim3(16,32),tb,0,stream>>>(out_proj_w + (size_t)idx*DIN*DM, WoutTc, 1024, 512, 512);
      // ---- out_proj with fused flip-add into H ----
      k_mgo<<<dim3(4,64),256,0,stream>>>(Ybf, WoutTc, H, dir);
    }
  }
  k_add_flip<<<gTok,TPB,0,stream>>>(RES, H, 0);
  k_ln<<<NROWS,TPB,0,stream>>>(RES, normf_w, normf_b, HF);

  // ================= attention head — MFMA (batched) =================
  float* P0   = ZB;
  float* QIN  = P0 + 0;
  float* CIN  = P0 + 2097152;
  float* QPb  = P0 + 4194304;
  float* CPb  = P0 + 6291456;
  float* QN   = P0 + 8388608;
  float* CN   = P0 + 10485760;
  float* AO   = P0 + 12582912;
  float* O1   = P0 + 14680064;
  float* D1   = P0 + 16777216;
  float* VV   = D1;
  u16* U0     = (u16*)(P0 + 20971520);
  u16* Qbf    = U0 + 0;
  u16* Cbf2   = U0 + 2097152;
  u16* QNbf   = U0 + 4194304;
  u16* CNbf   = U0 + 6291456;
  u16* QQbf   = U0 + 8388608;
  u16* KKbf   = U0 + 10485760;
  u16* VTbf   = U0 + 12582912;
  u16* AObf   = U0 + 14680064;
  u16* O1bf   = U0 + 16777216;
  u16* qpT    = U0 + 18874368;
  u16* cpT    = qpT + 262144;
  u16* qwT    = qpT + 524288;
  u16* kwT    = qpT + 786432;
  u16* vwT    = qpT + 1048576;
  u16* owT    = qpT + 1310720;
  u16* dec1T  = qpT + 1572864;
  u16* Pbf    = qpT + 2097152;

  const int M2 = BS*1024;
  k_extract<<<(BS*1024*DM+TPB-1)/TPB,TPB,0,stream>>>(HF, QIN, CIN);
  k_cvt<<<(2097152/4+TPB-1)/TPB,TPB,0,stream>>>(QIN, Qbf, 2097152/4);
  k_cvt<<<(2097152/4+TPB-1)/TPB,TPB,0,stream>>>(CIN, Cbf2, 2097152/4);
  k_wt2<<<dim3(16,16),tb,0,stream>>>(qp_w, qpT, 512, 512, 512);
  k_wt2<<<dim3(16,16),tb,0,stream>>>(cp_w, cpT, 512, 512, 512);
  k_wt2<<<dim3(16,16),tb,0,stream>>>(ca_qw, qwT, 512, 512, 512);
  k_wt2<<<dim3(16,16),tb,0,stream>>>(ca_kw, kwT, 512, 512, 512);
  k_wt2<<<dim3(16,16),tb,0,stream>>>(ca_vw, vwT, 512, 512, 512);
  k_wt2<<<dim3(16,16),tb,0,stream>>>(ca_ow, owT, 512, 512, 512);
  k_wt2<<<dim3(32,16),tb,0,stream>>>(dec1_w, dec1T, 512, 1024, 1024);

  k_mge<<<dim3(4,32),256,0,stream>>>(Qbf, qpT, qp_b, nullptr, QPb, nullptr,
                                     M2, 512, 512, 512, 512, 512, 1.f, 0);
  k_mge<<<dim3(4,32),256,0,stream>>>(Cbf2, cpT, cp_b, nullptr, CPb, nullptr,
                                     M2, 512, 512, 512, 512, 512, 1.f, 0);
  k_ln<<<M2,TPB,0,stream>>>(QPb, ca_nq_w, ca_nq_b, QN);
  k_ln<<<M2,TPB,0,stream>>>(CPb, ca_nkv_w, ca_nkv_b, CN);
  k_cvt<<<(2097152/4+TPB-1)/TPB,TPB,0,stream>>>(QN, QNbf, 2097152/4);
  k_cvt<<<(2097152/4+TPB-1)/TPB,TPB,0,stream>>>(CN, CNbf, 2097152/4);
  k_mge<<<dim3(4,32),256,0,stream>>>(QNbf, qwT, ca_qb, nullptr, nullptr, QQbf,
                                     M2, 512, 512, 512, 512, 512, 1.f, 0);
  k_mge<<<dim3(4,32),256,0,stream>>>(CNbf, kwT, ca_kb, nullptr, nullptr, KKbf,
                                     M2, 512, 512, 512, 512, 512, 1.f, 0);
  k_mge<<<dim3(4,32),256,0,stream>>>(CNbf, vwT, ca_vb, nullptr, VV, nullptr,
                                     M2, 512, 512, 512, 512, 512, 1.f, 0);
  k_vtb<<<dim3(4,32,16),tb,0,stream>>>(VV, VTbf);
  const float scl = 0.088388347648318447f;
  k_mgab<<<dim3(8,8,16),256,0,stream>>>(QQbf, KKbf, nullptr, Pbf,
        1024, 1024, 128, 512, 512, 1024,
        524288, 128, 524288, 128, 4194304, 1048576, scl);
  k_sm<<<16384,256,0,stream>>>(Pbf);
  k_mgab<<<dim3(1,8,16),256,0,stream>>>(Pbf, VTbf, AO, nullptr,
        1024, 128, 1024, 1024, 1024, 512,
        4194304, 1048576, 524288, 131072, 524288, 128, 1.f);
  k_cvt<<<(2097152/4+TPB-1)/TPB,TPB,0,stream>>>(AO, AObf, 2097152/4);
  k_mge<<<dim3(4,32),256,0,stream>>>(AObf, owT, ca_ob, QPb, O1, nullptr,
                                     M2, 512, 512, 512, 512, 512, 1.f, 0);
  k_cvt<<<(2097152/4+TPB-1)/TPB,TPB,0,stream>>>(O1, O1bf, 2097152/4);
  k_mge<<<dim3(8,32),256,0,stream>>>(O1bf, dec1T, dec1_b, nullptr, D1, nullptr,
                                     M2, 1024, 512, 512, 512, 1024, 1.f, 1);
  k_dec2<<<M2,256,0,stream>>>(D1, dec2_w, dec2_b, (float*)d_out);
}

// Round 19
// 1309.174 us; speedup vs baseline: 248.1651x; 1.0219x over previous
//
#include <hip/hip_runtime.h>
#include <hip/hip_bf16.h>

#define BS 4
#define SEQL 2048
#define DM 512
#define DIN 1024
#define NH 16
#define HD 64
#define DST 64
#define NC 8
#define CKS 256
#define DIP 2192
#define CVD 1152
#define NROWS (BS*SEQL)          /* 8192 */
#define NTOK (BS*SEQL*DM)        /* 4194304 */

typedef unsigned short u16;
typedef __bf16 bf16x8 __attribute__((ext_vector_type(8)));
typedef float f32x4 __attribute__((ext_vector_type(4)));

__device__ __forceinline__ u16 cvt_bf16(float f){
  unsigned int x = __float_as_uint(f);
  unsigned int r = x + 0x7fffu + ((x>>16)&1u);
  return (u16)(r>>16);
}
__device__ __forceinline__ float bf2f(u16 u){
  return __uint_as_float(((unsigned int)u)<<16);
}

// ---------------- elementwise (proven) ----------------
__global__ void k_add_flip(float* __restrict__ dst, const float* __restrict__ src, int flip){
  int i = blockIdx.x*256 + threadIdx.x;
  if(i >= NTOK) return;
  int d = i & (DM-1);
  int l = (i >> 9) & (SEQL-1);
  int b = i >> 20;
  int sl = flip ? (SEQL-1-l) : l;
  dst[i] += src[(b*SEQL + sl)*DM + d];
}

__global__ void k_flip(float* __restrict__ dst, const float* __restrict__ src){
  int i = blockIdx.x*256 + threadIdx.x;
  if(i >= NTOK) return;
  int d = i & (DM-1);
  int l = (i >> 9) & (SEQL-1);
  int b = i >> 20;
  dst[i] = src[(b*SEQL + (SEQL-1-l))*DM + d];
}

// f32 -> bf16 (verified round-8)
__global__ void k_cvt(const float* __restrict__ src, u16* __restrict__ dst, int n4){
  int i = blockIdx.x*256 + threadIdx.x;
  if(i >= n4) return;
  float4 f = reinterpret_cast<const float4*>(src)[i];
  ushort4 o; o.x=cvt_bf16(f.x); o.y=cvt_bf16(f.y); o.z=cvt_bf16(f.z); o.w=cvt_bf16(f.w);
  reinterpret_cast<ushort4*>(dst)[i] = o;
}

__global__ void k_ln(const float* __restrict__ X, const float* __restrict__ w,
                     const float* __restrict__ bb, float* __restrict__ O){
  int row = blockIdx.x, tid = threadIdx.x;
  const float* x = X + (size_t)row*DM;
  float* o = O + (size_t)row*DM;
  float s=0.f, s2=0.f;
  for(int j=tid;j<DM;j+=256){ float v=x[j]; s+=v; s2+=v*v; }
  __shared__ float r1[256], r2[256];
  r1[tid]=s; r2[tid]=s2; __syncthreads();
  for(int off=128;off>0;off>>=1){
    if(tid<off){ r1[tid]+=r1[tid+off]; r2[tid]+=r2[tid+off]; }
    __syncthreads();
  }
  float m = r1[0]*(1.f/DM);
  float var = r2[0]*(1.f/DM) - m*m;
  float inv = rsqrtf(var + 1e-5f);
  for(int j=tid;j<DM;j+=256) o[j] = (x[j]-m)*inv*w[j] + bb[j];
}

// RMSNorm reading Y f32, writing bf16 only
__global__ void k_rmsb(const float* __restrict__ Y, const float* __restrict__ gw,
                       u16* __restrict__ Obf){
  int row = blockIdx.x, tid = threadIdx.x;
  const float* y = Y + (size_t)row*DIN;
  float ss=0.f;
  for(int j=tid;j<DIN;j+=256){ float v=y[j]; ss+=v*v; }
  __shared__ float red[256];
  red[tid]=ss; __syncthreads();
  for(int off=128;off>0;off>>=1){
    if(tid<off) red[tid]+=red[tid+off];
    __syncthreads();
  }
  float inv = rsqrtf(red[0]*(1.f/DIN) + 1e-5f);
  for(int j=tid;j<DIN;j+=256) Obf[(size_t)row*DIN + j] = cvt_bf16(y[j]*inv*gw[j]);
}

// dec2
__global__ void k_dec2(const float* __restrict__ D1, const float* __restrict__ w,
                       const float* __restrict__ bb, float* __restrict__ out){
  int row = blockIdx.x, tid = threadIdx.x;
  int lane = tid & 63, wave = tid >> 6;
  const float* x = D1 + (size_t)row*1024;
  float acc[10];
  #pragma unroll
  for(int o=0;o<10;o++) acc[o]=0.f;
  for(int j=tid;j<1024;j+=256){
    float v = x[j];
    const float* wr = w + (size_t)j*10;
    #pragma unroll
    for(int o=0;o<10;o++) acc[o] += v*wr[o];
  }
  __shared__ float red[4][10];
  #pragma unroll
  for(int o=0;o<10;o++){
    float v = acc[o];
    #pragma unroll
    for(int s=32;s>0;s>>=1) v += __shfl_down(v, s, 64);
    if(lane==0) red[wave][o] = v;
  }
  __syncthreads();
  if(tid < 10)
    out[(size_t)row*10 + tid] = red[0][tid]+red[1][tid]+red[2][tid]+red[3][tid] + bb[tid];
}

// transpose-convert with explicit src ld (verified)
__global__ void k_wt2(const float* __restrict__ src, u16* __restrict__ dst,
                      int K, int N, int lds){
  __shared__ float t[32][33];
  int n0 = blockIdx.x*32, k0 = blockIdx.y*32;
  int tx = threadIdx.x, ty = threadIdx.y;
  #pragma unroll
  for(int i=0;i<32;i+=8){
    int k = k0+ty+i, n = n0+tx;
    t[ty+i][tx] = (n<N) ? src[(size_t)k*lds+n] : 0.f;
  }
  __syncthreads();
  #pragma unroll
  for(int i=0;i<32;i+=8){
    int n = n0+ty+i, k = k0+tx;
    if(n<N) dst[(size_t)n*K+k] = cvt_bf16(t[tx][ty+i]);
  }
}

// batched V-transpose
__global__ void k_vtb(const float* __restrict__ VV, u16* __restrict__ VT){
  __shared__ float t[32][33];
  int z = blockIdx.z, b = z>>2, h = z&3;
  const float* src = VV + (size_t)b*524288 + h*128;
  u16* dst = VT + (size_t)z*131072;
  int n0 = blockIdx.x*32, k0 = blockIdx.y*32;
  int tx = threadIdx.x, ty = threadIdx.y;
  #pragma unroll
  for(int i=0;i<32;i+=8){
    int k = k0+ty+i, n = n0+tx;
    t[ty+i][tx] = src[(size_t)k*512+n];
  }
  __syncthreads();
  #pragma unroll
  for(int i=0;i<32;i+=8){
    int n = n0+ty+i, k = k0+tx;
    dst[(size_t)n*1024+k] = cvt_bf16(t[tx][ty+i]);
  }
}

// XdT via LDS-tiled transpose
__global__ void k_xdtt(const float* __restrict__ XC, const float* __restrict__ DT,
                       u16* __restrict__ XdT){
  __shared__ float t[32][33];
  int z = blockIdx.z;
  int h = z & 15, bc = z >> 4;
  int b = bc >> 3, c = bc & 7;
  int p0 = blockIdx.x*32, s0 = blockIdx.y*32;
  int tx = threadIdx.x, ty = threadIdx.y;
  int gbase = b*SEQL + c*CKS;
  #pragma unroll
  for(int i=0;i<32;i+=8){
    int s = s0+ty+i, p = p0+tx;
    int g = gbase + s;
    t[ty+i][tx] = XC[(size_t)g*CVD + h*HD + p] * DT[(size_t)g*NH + h];
  }
  __syncthreads();
  u16* dst = XdT + (size_t)z*16384;
  #pragma unroll
  for(int i=0;i<32;i+=8){
    int p = p0+ty+i, s = s0+tx;
    dst[(size_t)p*256 + s] = cvt_bf16(t[tx][ty+i]);
  }
}

// batched B-transpose
__global__ void k_btc(const u16* __restrict__ Bbf, u16* __restrict__ BTc){
  __shared__ u16 t[32][33];
  int bc = blockIdx.z;
  const u16* src = Bbf + (size_t)bc*16384;
  u16* dst = BTc + (size_t)bc*16384;
  int n0 = blockIdx.x*32, l0 = blockIdx.y*32;
  int tx = threadIdx.x, ty = threadIdx.y;
  #pragma unroll
  for(int i=0;i<32;i+=8){
    int l = l0+ty+i, n = n0+tx;
    t[ty+i][tx] = src[(size_t)l*64+n];
  }
  __syncthreads();
  #pragma unroll
  for(int i=0;i<32;i+=8){
    int n = n0+ty+i, l = l0+tx;
    dst[(size_t)n*256+l] = t[tx][ty+i];
  }
}

// ---------------- MFMA bf16 GEMM, emap0, global_load_lds staging ----------------
__global__ __launch_bounds__(256) void k_mg(
    const u16* __restrict__ A, const u16* __restrict__ BT,
    float* __restrict__ C, int M, int N, int K, int lda, int ldb, int ldc)
{
  __shared__ u16 As[128*32];
  __shared__ u16 Bs[128*32];
  const int tid = threadIdx.x;
  const int row0 = blockIdx.y*128, col0 = blockIdx.x*128;
  const int lane = tid & 63, wave = tid >> 6;
  const int wm = wave >> 1, wn = wave & 1;
  const int lr = lane & 15, ksg = (lane >> 4);
  const int srow = lane >> 2;
  const int slot = lane & 3;
  f32x4 acc[4][4];
  #pragma unroll
  for(int i=0;i<4;i++)
    #pragma unroll
    for(int j=0;j<4;j++) acc[i][j] = (f32x4){0.f,0.f,0.f,0.f};
  for(int k0=0;k0<K;k0+=32){
    #pragma unroll
    for(int i=0;i<2;i++){
      int seg = wave*2 + i;
      int row = seg*16 + srow;
      int kk  = slot ^ ((row>>1)&3);
      const u16* ga = A + (size_t)(row0+row)*lda + k0 + kk*8;
      __builtin_amdgcn_global_load_lds(
        (const __attribute__((address_space(1))) void*)ga,
        (__attribute__((address_space(3))) void*)&As[seg*512], 16, 0, 0);
      int bcol = col0 + row; if(bcol > N-1) bcol = N-1;
      const u16* gb = BT + (size_t)bcol*ldb + k0 + kk*8;
      __builtin_amdgcn_global_load_lds(
        (const __attribute__((address_space(1))) void*)gb,
        (__attribute__((address_space(3))) void*)&Bs[seg*512], 16, 0, 0);
    }
    __syncthreads();
    bf16x8 afr[4], bfr[4];
    #pragma unroll
    for(int i=0;i<4;i++){
      int ar = wm*64+i*16+lr;
      afr[i] = *reinterpret_cast<const bf16x8*>(&As[ar*32 + (ksg^((ar>>1)&3))*8]);
    }
    #pragma unroll
    for(int j=0;j<4;j++){
      int br = wn*64+j*16+lr;
      bfr[j] = *reinterpret_cast<const bf16x8*>(&Bs[br*32 + (ksg^((br>>1)&3))*8]);
    }
    #pragma unroll
    for(int i=0;i<4;i++)
      #pragma unroll
      for(int j=0;j<4;j++)
        acc[i][j] = __builtin_amdgcn_mfma_f32_16x16x32_bf16(afr[i], bfr[j], acc[i][j], 0, 0, 0);
    __syncthreads();
  }
  const int hi = lane >> 4, lo = lane & 15;
  #pragma unroll
  for(int i=0;i<4;i++)
    #pragma unroll
    for(int j=0;j<4;j++)
      #pragma unroll
      for(int r=0;r<4;r++){
        int row = row0 + wm*64 + i*16 + 4*hi + r;
        int col = col0 + wn*64 + j*16 + lo;
        if(col < N) C[(size_t)row*ldc + col] = acc[i][j][r];
      }
}

// out_proj GEMM, gload_lds staging + fused flip-add epilogue
__global__ __launch_bounds__(256) void k_mgo(
    const u16* __restrict__ A, const u16* __restrict__ BT,
    float* __restrict__ H, int flip)
{
  const int N = 512, K = 1024;
  __shared__ u16 As[128*32];
  __shared__ u16 Bs[128*32];
  const int tid = threadIdx.x;
  const int row0 = blockIdx.y*128, col0 = blockIdx.x*128;
  const int lane = tid & 63, wave = tid >> 6;
  const int wm = wave >> 1, wn = wave & 1;
  const int lr = lane & 15, ksg = (lane >> 4);
  const int srow = lane >> 2;
  const int slot = lane & 3;
  f32x4 acc[4][4];
  #pragma unroll
  for(int i=0;i<4;i++)
    #pragma unroll
    for(int j=0;j<4;j++) acc[i][j] = (f32x4){0.f,0.f,0.f,0.f};
  for(int k0=0;k0<K;k0+=32){
    #pragma unroll
    for(int i=0;i<2;i++){
      int seg = wave*2 + i;
      int row = seg*16 + srow;
      int kk  = slot ^ ((row>>1)&3);
      const u16* ga = A + (size_t)(row0+row)*K + k0 + kk*8;
      __builtin_amdgcn_global_load_lds(
        (const __attribute__((address_space(1))) void*)ga,
        (__attribute__((address_space(3))) void*)&As[seg*512], 16, 0, 0);
      int bcol = col0 + row; if(bcol > N-1) bcol = N-1;
      const u16* gb = BT + (size_t)bcol*K + k0 + kk*8;
      __builtin_amdgcn_global_load_lds(
        (const __attribute__((address_space(1))) void*)gb,
        (__attribute__((address_space(3))) void*)&Bs[seg*512], 16, 0, 0);
    }
    __syncthreads();
    bf16x8 afr[4], bfr[4];
    #pragma unroll
    for(int i=0;i<4;i++){
      int ar = wm*64+i*16+lr;
      afr[i] = *reinterpret_cast<const bf16x8*>(&As[ar*32 + (ksg^((ar>>1)&3))*8]);
    }
    #pragma unroll
    for(int j=0;j<4;j++){
      int br = wn*64+j*16+lr;
      bfr[j] = *reinterpret_cast<const bf16x8*>(&Bs[br*32 + (ksg^((br>>1)&3))*8]);
    }
    #pragma unroll
    for(int i=0;i<4;i++)
      #pragma unroll
      for(int j=0;j<4;j++)
        acc[i][j] = __builtin_amdgcn_mfma_f32_16x16x32_bf16(afr[i], bfr[j], acc[i][j], 0, 0, 0);
    __syncthreads();
  }
  const int hi = lane >> 4, lo = lane & 15;
  #pragma unroll
  for(int i=0;i<4;i++)
    #pragma unroll
    for(int j=0;j<4;j++)
      #pragma unroll
      for(int r=0;r<4;r++){
        int row = row0 + wm*64 + i*16 + 4*hi + r;
        int col = col0 + wn*64 + j*16 + lo;
        if(col < N){
          int b = row >> 11, l = row & (SEQL-1);
          int sl = flip ? (SEQL-1-l) : l;
          size_t ci = (size_t)(b*SEQL + sl)*DM + col;
          H[ci] += acc[i][j][r];
        }
      }
}

// batched variant: verified core + z-strided base offsets only
__global__ __launch_bounds__(256) void k_mgb(
    const u16* __restrict__ A0, const u16* __restrict__ BT0,
    float* __restrict__ C0, int M, int N, int K, int lda, int ldb, int ldc,
    long sAz, long sBz, long sCo, long sCi, int shC)
{
  const int z = blockIdx.z;
  const u16* A  = A0  + (size_t)z*sAz;
  const u16* BT = BT0 + (size_t)z*sBz;
  float* C = C0 + (size_t)(z>>shC)*sCo + (size_t)(z & ((1<<shC)-1))*sCi;
  __shared__ uint4 As4[128*5];
  __shared__ uint4 Bs4[128*5];
  const int tid = threadIdx.x;
  const int row0 = blockIdx.y*128, col0 = blockIdx.x*128;
  const int lane = tid & 63, wave = tid >> 6;
  const int wm = wave >> 1, wn = wave & 1;
  const int lr = lane & 15, ksg = (lane >> 4);
  f32x4 acc[4][4];
  #pragma unroll
  for(int i=0;i<4;i++)
    #pragma unroll
    for(int j=0;j<4;j++) acc[i][j] = (f32x4){0.f,0.f,0.f,0.f};
  for(int k0=0;k0<K;k0+=32){
    #pragma unroll
    for(int i=0;i<2;i++){
      int t2 = tid + i*256;
      int rr = t2 >> 2, sg = (t2 & 3);
      uint4 av = *reinterpret_cast<const uint4*>(A + (size_t)(row0+rr)*lda + k0 + sg*8);
      uint4 bv = {0u,0u,0u,0u};
      if(col0+rr < N) bv = *reinterpret_cast<const uint4*>(BT + (size_t)(col0+rr)*ldb + k0 + sg*8);
      As4[rr*5 + sg] = av;
      Bs4[rr*5 + sg] = bv;
    }
    __syncthreads();
    bf16x8 afr[4], bfr[4];
    #pragma unroll
    for(int i=0;i<4;i++) afr[i] = *reinterpret_cast<const bf16x8*>(&As4[(wm*64+i*16+lr)*5 + ksg]);
    #pragma unroll
    for(int j=0;j<4;j++) bfr[j] = *reinterpret_cast<const bf16x8*>(&Bs4[(wn*64+j*16+lr)*5 + ksg]);
    #pragma unroll
    for(int i=0;i<4;i++)
      #pragma unroll
      for(int j=0;j<4;j++)
        acc[i][j] = __builtin_amdgcn_mfma_f32_16x16x32_bf16(afr[i], bfr[j], acc[i][j], 0, 0, 0);
    __syncthreads();
  }
  const int hi = lane >> 4, lo = lane & 15;
  #pragma unroll
  for(int i=0;i<4;i++)
    #pragma unroll
    for(int j=0;j<4;j++)
      #pragma unroll
      for(int r=0;r<4;r++){
        int row = row0 + wm*64 + i*16 + 4*hi + r;
        int col = col0 + wn*64 + j*16 + lo;
        if(col < N) C[(size_t)row*ldc + col] = acc[i][j][r];
      }
}

// FUSED Y_diag + Y_off + gate: per z=(bc*16+h)
// acc  = G @ XdT[z]           (K=256, G formed from Sf/ACUM)
//      + (C*exp(Ac[row])) @ prevT[bc,h]  (K=64, scale folded in staging)
// Y[g*DIN + h*64+col] = (acc + D[h]*xh) * silu(zgate)   — write-only Y
__global__ __launch_bounds__(256) void k_mgf(
    const float* __restrict__ Sf, const float* __restrict__ ACUM,
    const u16* __restrict__ XdT, const u16* __restrict__ Cb0,
    const u16* __restrict__ PV0, const float* __restrict__ XCp,
    const float* __restrict__ ZBp, const float* __restrict__ Dp,
    float* __restrict__ Y)
{
  const int z = blockIdx.z;
  const int h = z & 15, bc = z >> 4;
  const int b = bc >> 3, c = bc & 7;
  const float* Az = Sf + (size_t)bc*65536;
  const float* Acp = ACUM + (size_t)z*256;
  const u16* BT1 = XdT + (size_t)z*16384;          // [64][256]
  const u16* A2  = Cb0 + (size_t)bc*16384;         // [256][64]
  const u16* BT2 = PV0 + (size_t)bc*65536 + (size_t)h*4096;  // [64][64]
  __shared__ uint4 As4[128*5];
  __shared__ uint4 Bs4[128*5];
  __shared__ float AcS[256];
  const int tid = threadIdx.x;
  AcS[tid] = Acp[tid];
  __syncthreads();
  const int row0 = blockIdx.y*128;
  const int lane = tid & 63, wave = tid >> 6;
  const int wm = wave >> 1, wn = wave & 1;
  const int lr = lane & 15, ksg = (lane >> 4);
  f32x4 acc[4][4];
  #pragma unroll
  for(int i=0;i<4;i++)
    #pragma unroll
    for(int j=0;j<4;j++) acc[i][j] = (f32x4){0.f,0.f,0.f,0.f};
  // ---- part 1: Y_diag (K=256), G formed in staging ----
  for(int k0=0;k0<256;k0+=32){
    #pragma unroll
    for(int i=0;i<2;i++){
      int t2 = tid + i*256;
      int rr = t2 >> 2, sg = (t2 & 3);
      int l = row0 + rr;
      int sbase = k0 + sg*8;
      float4 v0 = *reinterpret_cast<const float4*>(Az + (size_t)l*256 + sbase);
      float4 v1 = *reinterpret_cast<const float4*>(Az + (size_t)l*256 + sbase + 4);
      float acl = AcS[l];
      float vv[8] = {v0.x,v0.y,v0.z,v0.w,v1.x,v1.y,v1.z,v1.w};
      u16 gbuf[8];
      #pragma unroll
      for(int e=0;e<8;e++){
        int s = sbase + e;
        float g = 0.f;
        if(s <= l) g = __expf(acl - AcS[s]) * vv[e];
        gbuf[e] = cvt_bf16(g);
      }
      As4[rr*5 + sg] = *reinterpret_cast<uint4*>(gbuf);
      uint4 bv = {0u,0u,0u,0u};
      if(rr < 64) bv = *reinterpret_cast<const uint4*>(BT1 + (size_t)rr*256 + sbase);
      Bs4[rr*5 + sg] = bv;
    }
    __syncthreads();
    bf16x8 afr[4], bfr[4];
    #pragma unroll
    for(int i=0;i<4;i++) afr[i] = *reinterpret_cast<const bf16x8*>(&As4[(wm*64+i*16+lr)*5 + ksg]);
    #pragma unroll
    for(int j=0;j<4;j++) bfr[j] = *reinterpret_cast<const bf16x8*>(&Bs4[(wn*64+j*16+lr)*5 + ksg]);
    #pragma unroll
    for(int i=0;i<4;i++)
      #pragma unroll
      for(int j=0;j<4;j++)
        acc[i][j] = __builtin_amdgcn_mfma_f32_16x16x32_bf16(afr[i], bfr[j], acc[i][j], 0, 0, 0);
    __syncthreads();
  }
  // ---- part 2: Y_off (K=64), C rows pre-scaled by exp(Ac[row]) ----
  for(int k0=0;k0<64;k0+=32){
    #pragma unroll
    for(int i=0;i<2;i++){
      int t2 = tid + i*256;
      int rr = t2 >> 2, sg = (t2 & 3);
      int sbase = k0 + sg*8;
      uint4 raw = *reinterpret_cast<const uint4*>(A2 + (size_t)(row0+rr)*64 + sbase);
      const u16* rp = reinterpret_cast<const u16*>(&raw);
      float scale = __expf(AcS[row0+rr]);
      u16 buf[8];
      #pragma unroll
      for(int e=0;e<8;e++) buf[e] = cvt_bf16(bf2f(rp[e]) * scale);
      As4[rr*5 + sg] = *reinterpret_cast<uint4*>(buf);
      uint4 bv = {0u,0u,0u,0u};
      if(rr < 64) bv = *reinterpret_cast<const uint4*>(BT2 + (size_t)rr*64 + sbase);
      Bs4[rr*5 + sg] = bv;
    }
    __syncthreads();
    bf16x8 afr[4], bfr[4];
    #pragma unroll
    for(int i=0;i<4;i++) afr[i] = *reinterpret_cast<const bf16x8*>(&As4[(wm*64+i*16+lr)*5 + ksg]);
    #pragma unroll
    for(int j=0;j<4;j++) bfr[j] = *reinterpret_cast<const bf16x8*>(&Bs4[(wn*64+j*16+lr)*5 + ksg]);
    #pragma unroll
    for(int i=0;i<4;i++)
      #pragma unroll
      for(int j=0;j<4;j++)
        acc[i][j] = __builtin_amdgcn_mfma_f32_16x16x32_bf16(afr[i], bfr[j], acc[i][j], 0, 0, 0);
    __syncthreads();
  }
  // ---- epilogue: gate + write-only Y ----
  const int hi = lane >> 4, lo = lane & 15;
  #pragma unroll
  for(int i=0;i<4;i++)
    #pragma unroll
    for(int j=0;j<4;j++)
      #pragma unroll
      for(int r=0;r<4;r++){
        int row = row0 + wm*64 + i*16 + 4*hi + r;
        int col = wn*64 + j*16 + lo;
        if(col < 64){
          int g = b*SEQL + c*CKS + row;
          int ch = h*HD + col;
          float xh = XCp[(size_t)g*CVD + ch];
          float zg = ZBp[(size_t)g*DIP + ch];
          float v = acc[i][j][r] + Dp[h]*xh;
          float sig = 1.f/(1.f+expf(-zg));
          Y[(size_t)g*DIN + ch] = v * (zg*sig);
        }
      }
}

// states via MFMA
__global__ __launch_bounds__(256) void k_mgs(
    const u16* __restrict__ XdT, const u16* __restrict__ BTc,
    const float* __restrict__ ACUM, float* __restrict__ ST)
{
  const int z = blockIdx.z;
  const int bc = z >> 4;
  const u16* Ap = XdT + (size_t)z*16384;
  const u16* BT = BTc + (size_t)bc*16384;
  float* Cp = ST + (size_t)z*4096;
  __shared__ uint4 As4[128*5];
  __shared__ uint4 Bs4[128*5];
  __shared__ float decS[256];
  const int tid = threadIdx.x;
  {
    const float* Acp = ACUM + (size_t)z*256;
    decS[tid] = __expf(Acp[255] - Acp[tid]);
  }
  __syncthreads();
  const int lane = tid & 63, wave = tid >> 6;
  const int wm = wave >> 1, wn = wave & 1;
  const int lr = lane & 15, ksg = (lane >> 4);
  f32x4 acc[4][4];
  #pragma unroll
  for(int i=0;i<4;i++)
    #pragma unroll
    for(int j=0;j<4;j++) acc[i][j] = (f32x4){0.f,0.f,0.f,0.f};
  for(int k0=0;k0<256;k0+=32){
    #pragma unroll
    for(int i=0;i<2;i++){
      int t2 = tid + i*256;
      int rr = t2 >> 2, sg = (t2 & 3);
      int sbase = k0 + sg*8;
      uint4 av = {0u,0u,0u,0u};
      if(rr < 64){
        uint4 raw = *reinterpret_cast<const uint4*>(Ap + (size_t)rr*256 + sbase);
        const u16* rp = reinterpret_cast<const u16*>(&raw);
        u16 buf[8];
        #pragma unroll
        for(int e=0;e<8;e++) buf[e] = cvt_bf16(bf2f(rp[e]) * decS[sbase+e]);
        av = *reinterpret_cast<uint4*>(buf);
      }
      As4[rr*5 + sg] = av;
      uint4 bv = {0u,0u,0u,0u};
      if(rr < 64) bv = *reinterpret_cast<const uint4*>(BT + (size_t)rr*256 + sbase);
      Bs4[rr*5 + sg] = bv;
    }
    __syncthreads();
    bf16x8 afr[4], bfr[4];
    #pragma unroll
    for(int i=0;i<4;i++) afr[i] = *reinterpret_cast<const bf16x8*>(&As4[(wm*64+i*16+lr)*5 + ksg]);
    #pragma unroll
    for(int j=0;j<4;j++) bfr[j] = *reinterpret_cast<const bf16x8*>(&Bs4[(wn*64+j*16+lr)*5 + ksg]);
    #pragma unroll
    for(int i=0;i<4;i++)
      #pragma unroll
      for(int j=0;j<4;j++)
        acc[i][j] = __builtin_amdgcn_mfma_f32_16x16x32_bf16(afr[i], bfr[j], acc[i][j], 0, 0, 0);
    __syncthreads();
  }
  const int hi = lane >> 4, lo = lane & 15;
  #pragma unroll
  for(int i=0;i<4;i++)
    #pragma unroll
    for(int j=0;j<4;j++)
      #pragma unroll
      for(int r=0;r<4;r++){
        int row = wm*64 + i*16 + 4*hi + r;
        int col = wn*64 + j*16 + lo;
        if(row < 64 && col < 64) Cp[(size_t)row*64 + col] = acc[i][j][r];
      }
}

// batched attention GEMM
__global__ __launch_bounds__(256) void k_mgab(
    const u16* __restrict__ A0, const u16* __restrict__ BT0,
    float* __restrict__ C0, u16* __restrict__ Cb0,
    int M, int N, int K, int lda, int ldb, int ldc,
    long sAo, long sAi, long sBo, long sBi, long sCo, long sCi, float scale)
{
  const int z = blockIdx.z;
  const u16* A  = A0  + (size_t)(z>>2)*sAo + (size_t)(z&3)*sAi;
  const u16* BT = BT0 + (size_t)(z>>2)*sBo + (size_t)(z&3)*sBi;
  const size_t offC = (size_t)(z>>2)*sCo + (size_t)(z&3)*sCi;
  __shared__ uint4 As4[128*5];
  __shared__ uint4 Bs4[128*5];
  const int tid = threadIdx.x;
  const int row0 = blockIdx.y*128, col0 = blockIdx.x*128;
  const int lane = tid & 63, wave = tid >> 6;
  const int wm = wave >> 1, wn = wave & 1;
  const int lr = lane & 15, ksg = (lane >> 4);
  f32x4 acc[4][4];
  #pragma unroll
  for(int i=0;i<4;i++)
    #pragma unroll
    for(int j=0;j<4;j++) acc[i][j] = (f32x4){0.f,0.f,0.f,0.f};
  for(int k0=0;k0<K;k0+=32){
    #pragma unroll
    for(int i=0;i<2;i++){
      int t2 = tid + i*256;
      int rr = t2 >> 2, sg = (t2 & 3);
      uint4 av = *reinterpret_cast<const uint4*>(A + (size_t)(row0+rr)*lda + k0 + sg*8);
      uint4 bv = {0u,0u,0u,0u};
      if(col0+rr < N) bv = *reinterpret_cast<const uint4*>(BT + (size_t)(col0+rr)*ldb + k0 + sg*8);
      As4[rr*5 + sg] = av;
      Bs4[rr*5 + sg] = bv;
    }
    __syncthreads();
    bf16x8 afr[4], bfr[4];
    #pragma unroll
    for(int i=0;i<4;i++) afr[i] = *reinterpret_cast<const bf16x8*>(&As4[(wm*64+i*16+lr)*5 + ksg]);
    #pragma unroll
    for(int j=0;j<4;j++) bfr[j] = *reinterpret_cast<const bf16x8*>(&Bs4[(wn*64+j*16+lr)*5 + ksg]);
    #pragma unroll
    for(int i=0;i<4;i++)
      #pragma unroll
      for(int j=0;j<4;j++)
        acc[i][j] = __builtin_amdgcn_mfma_f32_16x16x32_bf16(afr[i], bfr[j], acc[i][j], 0, 0, 0);
    __syncthreads();
  }
  const int hi = lane >> 4, lo = lane & 15;
  #pragma unroll
  for(int i=0;i<4;i++)
    #pragma unroll
    for(int j=0;j<4;j++)
      #pragma unroll
      for(int r=0;r<4;r++){
        int row = row0 + wm*64 + i*16 + 4*hi + r;
        int col = col0 + wn*64 + j*16 + lo;
        if(col < N){
          float v = acc[i][j][r] * scale;
          size_t ci = offC + (size_t)row*ldc + col;
          if(C0) C0[ci] = v;
          else   Cb0[ci] = cvt_bf16(v);
        }
      }
}

// verified core + arithmetic epilogue (attention projections)
__global__ __launch_bounds__(256) void k_mge(
    const u16* __restrict__ A, const u16* __restrict__ BT,
    const float* __restrict__ bias, const float* __restrict__ res,
    float* __restrict__ C, u16* __restrict__ Cbf,
    int M, int N, int K, int lda, int ldb, int ldc, float scale, int act)
{
  __shared__ uint4 As4[128*5];
  __shared__ uint4 Bs4[128*5];
  const int tid = threadIdx.x;
  const int row0 = blockIdx.y*128, col0 = blockIdx.x*128;
  const int lane = tid & 63, wave = tid >> 6;
  const int wm = wave >> 1, wn = wave & 1;
  const int lr = lane & 15, ksg = (lane >> 4);
  f32x4 acc[4][4];
  #pragma unroll
  for(int i=0;i<4;i++)
    #pragma unroll
    for(int j=0;j<4;j++) acc[i][j] = (f32x4){0.f,0.f,0.f,0.f};
  for(int k0=0;k0<K;k0+=32){
    #pragma unroll
    for(int i=0;i<2;i++){
      int t2 = tid + i*256;
      int rr = t2 >> 2, sg = (t2 & 3);
      uint4 av = *reinterpret_cast<const uint4*>(A + (size_t)(row0+rr)*lda + k0 + sg*8);
      uint4 bv = {0u,0u,0u,0u};
      if(col0+rr < N) bv = *reinterpret_cast<const uint4*>(BT + (size_t)(col0+rr)*ldb + k0 + sg*8);
      As4[rr*5 + sg] = av;
      Bs4[rr*5 + sg] = bv;
    }
    __syncthreads();
    bf16x8 afr[4], bfr[4];
    #pragma unroll
    for(int i=0;i<4;i++) afr[i] = *reinterpret_cast<const bf16x8*>(&As4[(wm*64+i*16+lr)*5 + ksg]);
    #pragma unroll
    for(int j=0;j<4;j++) bfr[j] = *reinterpret_cast<const bf16x8*>(&Bs4[(wn*64+j*16+lr)*5 + ksg]);
    #pragma unroll
    for(int i=0;i<4;i++)
      #pragma unroll
      for(int j=0;j<4;j++)
        acc[i][j] = __builtin_amdgcn_mfma_f32_16x16x32_bf16(afr[i], bfr[j], acc[i][j], 0, 0, 0);
    __syncthreads();
  }
  const int hi = lane >> 4, lo = lane & 15;
  #pragma unroll
  for(int i=0;i<4;i++)
    #pragma unroll
    for(int j=0;j<4;j++)
      #pragma unroll
      for(int r=0;r<4;r++){
        int row = row0 + wm*64 + i*16 + 4*hi + r;
        int col = col0 + wn*64 + j*16 + lo;
        if(col < N){
          float v = acc[i][j][r];
          if(bias) v += bias[col];
          v *= scale;
          if(act==1) v = 0.5f*v*(1.f+erff(v*0.70710678118654752f));
          size_t ci = (size_t)row*ldc + col;
          if(res) v += res[ci];
          if(C) C[ci] = v;
          else  Cbf[ci] = cvt_bf16(v);
        }
      }
}

// in-place row softmax over 1024 bf16
__global__ void k_sm(u16* __restrict__ S){
  size_t row = blockIdx.x;
  u16* p = S + row*1024;
  int tid = threadIdx.x;
  ushort4 u = reinterpret_cast<ushort4*>(p)[tid];
  float v0=bf2f(u.x), v1=bf2f(u.y), v2=bf2f(u.z), v3=bf2f(u.w);
  float m = fmaxf(fmaxf(v0,v1),fmaxf(v2,v3));
  __shared__ float red[256];
  red[tid]=m; __syncthreads();
  for(int o=128;o>0;o>>=1){ if(tid<o) red[tid]=fmaxf(red[tid],red[tid+o]); __syncthreads(); }
  m = red[0]; __syncthreads();
  v0=__expf(v0-m); v1=__expf(v1-m); v2=__expf(v2-m); v3=__expf(v3-m);
  float s = v0+v1+v2+v3;
  red[tid]=s; __syncthreads();
  for(int o=128;o>0;o>>=1){ if(tid<o) red[tid]+=red[tid+o]; __syncthreads(); }
  float inv = 1.f/red[0];
  ushort4 o4; o4.x=cvt_bf16(v0*inv); o4.y=cvt_bf16(v1*inv); o4.z=cvt_bf16(v2*inv); o4.w=cvt_bf16(v3*inv);
  reinterpret_cast<ushort4*>(p)[tid] = o4;
}

// ---------------- mamba pieces ----------------
__global__ void k_conv4(const float* __restrict__ ZB, const float* __restrict__ cw,
                        const float* __restrict__ cb, float* __restrict__ XC){
  int i = blockIdx.x*256 + threadIdx.x;
  if(i >= BS*512*CVD) return;
  int cch = i % CVD;
  int lq = (i / CVD) & 511;
  int b = i / (CVD*512);
  int l0 = lq*4;
  float w[7];
  #pragma unroll
  for(int t=0;t<7;t++){
    int sl = l0 - 3 + t;
    w[t] = (sl >= 0) ? ZB[(size_t)(b*SEQL+sl)*DIP + DIN + cch] : 0.f;
  }
  float c0 = cw[cch*4+0], c1 = cw[cch*4+1], c2 = cw[cch*4+2], c3 = cw[cch*4+3];
  float bb2 = cb[cch];
  #pragma unroll
  for(int j=0;j<4;j++){
    float v = bb2 + w[j]*c0 + w[j+1]*c1 + w[j+2]*c2 + w[j+3]*c3;
    float sig = 1.f/(1.f+expf(-v));
    XC[(size_t)(b*SEQL + l0 + j)*CVD + cch] = v*sig;
  }
}

__global__ void k_dt(const float* __restrict__ ZB, const float* __restrict__ dtb,
                     const float* __restrict__ Alog, float* __restrict__ DT,
                     float* __restrict__ DA){
  int i = blockIdx.x*256 + threadIdx.x;
  if(i >= BS*SEQL*NH) return;
  int h = i & (NH-1);
  int row = i >> 4;
  float raw = ZB[(size_t)row*DIP + (DIN+CVD) + h] + dtb[h];
  float dt = fmaxf(raw,0.f) + log1pf(expf(-fabsf(raw)));
  DT[i] = dt;
  DA[i] = dt * (-expf(Alog[h]));
}

__global__ void k_acum(const float* __restrict__ DA, float* __restrict__ ACUM,
                       float* __restrict__ CDEC){
  int blk = blockIdx.x;
  int h = blk & 15, c = (blk>>4)&7, b = blk>>7;
  int l = threadIdx.x;
  __shared__ float s[256];
  int gl = c*CKS + l;
  s[l] = DA[(size_t)(b*SEQL + gl)*NH + h];
  __syncthreads();
  for(int off=1; off<256; off<<=1){
    float v = (l>=off) ? s[l-off] : 0.f;
    __syncthreads();
    s[l] += v;
    __syncthreads();
  }
  ACUM[(size_t)blk*CKS + l] = s[l];
  if(l==255) CDEC[blk] = expf(s[255]);
}

// extract B,C as bf16 [8192][64]
__global__ void k_bc(const float* __restrict__ XC, u16* __restrict__ Bbf,
                     u16* __restrict__ Cbf){
  int i = blockIdx.x*256 + threadIdx.x;
  if(i >= NROWS*DST) return;
  int g = i >> 6, n = i & 63;
  Bbf[i] = cvt_bf16(XC[(size_t)g*CVD + DIN + n]);
  Cbf[i] = cvt_bf16(XC[(size_t)g*CVD + DIN + DST + n]);
}

__global__ void k_scan(const float* __restrict__ ST, const float* __restrict__ CDEC,
                       float* __restrict__ PREV){
  int i = blockIdx.x*256 + threadIdx.x;
  if(i >= BS*NH*4096) return;
  int pn = i & 4095;
  int h = (i>>12) & 15;
  int b = i >> 16;
  float run = 0.f;
  for(int c=0;c<8;c++){
    size_t idx = (size_t)((b*8+c)*16+h)*4096 + pn;
    PREV[idx] = run;
    run = run*CDEC[(b*8+c)*16+h] + ST[idx];
  }
}

// ---------------- attention helpers ----------------
__global__ void k_extract(const float* __restrict__ HF, float* __restrict__ QIN,
                          float* __restrict__ CIN){
  int i = blockIdx.x*256 + threadIdx.x;
  if(i >= BS*1024*DM) return;
  int d = i & (DM-1);
  int q = (i>>9) & 1023;
  int b = i >> 19;
  QIN[i] = HF[(size_t)(b*SEQL + 1024 + q)*DM + d];
  CIN[i] = HF[(size_t)(b*SEQL + q)*DM + d];
}

// ---------------- host ----------------
extern "C" void kernel_launch(void* const* d_in, const int* in_sizes, int n_in,
                              void* d_out, int out_size, void* d_ws, size_t ws_size,
                              hipStream_t stream) {
  (void)in_sizes; (void)n_in; (void)out_size; (void)ws_size;
  const float* x_enc     = (const float*)d_in[0];
  const float* in_proj_w = (const float*)d_in[2];
  const float* conv_w    = (const float*)d_in[3];
  const float* conv_b    = (const float*)d_in[4];
  const float* dt_bias   = (const float*)d_in[5];
  const float* A_log     = (const float*)d_in[6];
  const float* D_param   = (const float*)d_in[7];
  const float* gnorm_w   = (const float*)d_in[8];
  const float* out_proj_w= (const float*)d_in[9];
  const float* norm_w    = (const float*)d_in[10];
  const float* norm_b    = (const float*)d_in[11];
  const float* normf_w   = (const float*)d_in[12];
  const float* normf_b   = (const float*)d_in[13];
  const float* ca_nq_w   = (const float*)d_in[14];
  const float* ca_nq_b   = (const float*)d_in[15];
  const float* ca_nkv_w  = (const float*)d_in[16];
  const float* ca_nkv_b  = (const float*)d_in[17];
  const float* ca_qw     = (const float*)d_in[18];
  const float* ca_kw     = (const float*)d_in[19];
  const float* ca_vw     = (const float*)d_in[20];
  const float* ca_ow     = (const float*)d_in[21];
  const float* ca_qb     = (const float*)d_in[22];
  const float* ca_kb     = (const float*)d_in[23];
  const float* ca_vb     = (const float*)d_in[24];
  const float* ca_ob     = (const float*)d_in[25];
  const float* qp_w      = (const float*)d_in[26];
  const float* qp_b      = (const float*)d_in[27];
  const float* cp_w      = (const float*)d_in[28];
  const float* cp_b      = (const float*)d_in[29];
  const float* dec1_w    = (const float*)d_in[30];
  const float* dec1_b    = (const float*)d_in[31];
  const float* dec2_w    = (const float*)d_in[32];
  const float* dec2_b    = (const float*)d_in[33];

  float* W = (float*)d_ws;
  size_t off = 0;
  auto alloc = [&](size_t n){ float* pp = W + off; off += n; return pp; };
  float* RES  = alloc((size_t)NTOK);
  float* H    = alloc((size_t)NTOK);
  float* HN   = alloc((size_t)NTOK);
  float* HNF  = alloc((size_t)NTOK);
  float* ZB   = alloc((size_t)NROWS*DIP);        // 17,956,864
  float* XC   = alloc((size_t)NROWS*CVD);        //  9,437,184
  float* DT   = alloc((size_t)NROWS*NH);
  float* DA   = alloc((size_t)NROWS*NH);
  float* ACUM = alloc((size_t)BS*NC*NH*CKS);
  float* CDEC = alloc((size_t)BS*NC*NH);
  float* Y    = alloc((size_t)NROWS*DIN);        //  8,388,608
  float* ST   = alloc((size_t)BS*NC*NH*4096);
  float* PREV = alloc((size_t)BS*NC*NH*4096);
  float* YD   = alloc((size_t)NTOK);
  float* HF   = alloc((size_t)NTOK);
  // byte-identical to the proven round-1 layout (61,768,192 floats)

  // mamba staging aliases (proven lifetimes):
  u16* Ubf    = (u16*)HF;
  u16* WinTc  = (u16*)(HF + 2097152);
  u16* WoutTc = (u16*)(HF + 2097152 + 561152);
  u16* Ybf    = (u16*)HNF;
  // SSD staging (all disjoint within HNF: checked):
  u16*   Bbf    = (u16*)HNF;                 // [0, 262144) fl
  u16*   Cbf    = Bbf + 524288;              // [262144, 524288) fl
  float* Sf     = HNF + 524288;              // [524288, 2621440) fl
  u16*   BTc    = (u16*)(HNF + 2621440);     // [2621440, 2883584) fl
  u16*   PREVbf = (u16*)(HNF + 2883584);     // [2883584, 3932160) fl
  u16*   XdTg   = (u16*)YD;                  // 8,388,608 u16

  const int TPB = 256;
  const int gTok = (NTOK+TPB-1)/TPB;
  dim3 tb(32,8);

  hipMemcpyAsync(RES, x_enc, (size_t)NTOK*4, hipMemcpyDeviceToDevice, stream);

  for(int layer=0; layer<2; ++layer){
    if(layer>0) k_add_flip<<<gTok,TPB,0,stream>>>(RES, H, 0);
    k_ln<<<NROWS,TPB,0,stream>>>(RES, norm_w + layer*DM, norm_b + layer*DM, HN);
    hipMemsetAsync(H, 0, (size_t)NTOK*4, stream);
    for(int dir=0; dir<2; ++dir){
      int idx = layer*2 + dir;
      const float* cw   = conv_w   + (size_t)idx*CVD*4;
      const float* cb   = conv_b   + (size_t)idx*CVD;
      const float* dtb  = dt_bias  + (size_t)idx*NH;
      const float* Alog = A_log    + (size_t)idx*NH;
      const float* Dp   = D_param  + (size_t)idx*NH;
      const float* gw   = gnorm_w  + (size_t)idx*DIN;

      if(dir==0){
        k_cvt<<<(NTOK/4+TPB-1)/TPB,TPB,0,stream>>>(HN, Ubf, NTOK/4);
      }else{
        k_flip<<<gTok,TPB,0,stream>>>(HNF, HN);
        k_cvt<<<(NTOK/4+TPB-1)/TPB,TPB,0,stream>>>(HNF, Ubf, NTOK/4);
      }
      k_wt2<<<dim3(69,16),tb,0,stream>>>(in_proj_w + (size_t)idx*DM*DIP, WinTc, 512, 2192, 2192);
      k_mg<<<dim3(18,64),256,0,stream>>>(Ubf, WinTc, ZB, 8192, 2192, 512, 512, 512, 2192);

      k_conv4<<<(BS*512*CVD+TPB-1)/TPB,TPB,0,stream>>>(ZB, cw, cb, XC);
      k_dt<<<(BS*SEQL*NH+TPB-1)/TPB,TPB,0,stream>>>(ZB, dtb, Alog, DT, DA);
      k_acum<<<BS*NC*NH,256,0,stream>>>(DA, ACUM, CDEC);

      // ---- SSD pre-computation ----
      k_bc<<<(NROWS*DST+TPB-1)/TPB,TPB,0,stream>>>(XC, Bbf, Cbf);
      k_mgb<<<dim3(2,2,32),256,0,stream>>>(Cbf, Bbf, Sf,
            256, 256, 64, 64, 64, 256, 16384, 16384, 65536, 0, 0);
      k_xdtt<<<dim3(2,8,512),tb,0,stream>>>(XC, DT, XdTg);
      // states + inter-chunk scan
      k_btc<<<dim3(2,8,32),tb,0,stream>>>(Bbf, BTc);
      k_mgs<<<dim3(1,1,512),256,0,stream>>>(XdTg, BTc, ACUM, ST);
      k_scan<<<(BS*NH*4096+TPB-1)/TPB,TPB,0,stream>>>(ST, CDEC, PREV);
      k_cvt<<<(2097152/4+TPB-1)/TPB,TPB,0,stream>>>(PREV, PREVbf, 2097152/4);
      // ---- fused Y_diag + Y_off + gate (write-only Y) ----
      k_mgf<<<dim3(1,2,512),256,0,stream>>>(Sf, ACUM, XdTg, Cbf, PREVbf, XC, ZB, Dp, Y);

      // ---- RMSNorm -> bf16 directly ----
      k_rmsb<<<NROWS,256,0,stream>>>(Y, gw, Ybf);
      k_wt2<<<dim3(16,32),tb,0,stream>>>(out_proj_w + (size_t)idx*DIN*DM, WoutTc, 1024, 512, 512);
      // ---- out_proj with fused flip-add into H ----
      k_mgo<<<dim3(4,64),256,0,stream>>>(Ybf, WoutTc, H, dir);
    }
  }
  k_add_flip<<<gTok,TPB,0,stream>>>(RES, H, 0);
  k_ln<<<NROWS,TPB,0,stream>>>(RES, normf_w, normf_b, HF);

  // ================= attention head — MFMA (batched) =================
  float* P0   = ZB;
  float* QIN  = P0 + 0;
  float* CIN  = P0 + 2097152;
  float* QPb  = P0 + 4194304;
  float* CPb  = P0 + 6291456;
  float* QN   = P0 + 8388608;
  float* CN   = P0 + 10485760;
  float* AO   = P0 + 12582912;
  float* O1   = P0 + 14680064;
  float* D1   = P0 + 16777216;
  float* VV   = D1;
  u16* U0     = (u16*)(P0 + 20971520);
  u16* Qbf    = U0 + 0;
  u16* Cbf2   = U0 + 2097152;
  u16* QNbf   = U0 + 4194304;
  u16* CNbf   = U0 + 6291456;
  u16* QQbf   = U0 + 8388608;
  u16* KKbf   = U0 + 10485760;
  u16* VTbf   = U0 + 12582912;
  u16* AObf   = U0 + 14680064;
  u16* O1bf   = U0 + 16777216;
  u16* qpT    = U0 + 18874368;
  u16* cpT    = qpT + 262144;
  u16* qwT    = qpT + 524288;
  u16* kwT    = qpT + 786432;
  u16* vwT    = qpT + 1048576;
  u16* owT    = qpT + 1310720;
  u16* dec1T  = qpT + 1572864;
  u16* Pbf    = qpT + 2097152;

  const int M2 = BS*1024;
  k_extract<<<(BS*1024*DM+TPB-1)/TPB,TPB,0,stream>>>(HF, QIN, CIN);
  k_cvt<<<(2097152/4+TPB-1)/TPB,TPB,0,stream>>>(QIN, Qbf, 2097152/4);
  k_cvt<<<(2097152/4+TPB-1)/TPB,TPB,0,stream>>>(CIN, Cbf2, 2097152/4);
  k_wt2<<<dim3(16,16),tb,0,stream>>>(qp_w, qpT, 512, 512, 512);
  k_wt2<<<dim3(16,16),tb,0,stream>>>(cp_w, cpT, 512, 512, 512);
  k_wt2<<<dim3(16,16),tb,0,stream>>>(ca_qw, qwT, 512, 512, 512);
  k_wt2<<<dim3(16,16),tb,0,stream>>>(ca_kw, kwT, 512, 512, 512);
  k_wt2<<<dim3(16,16),tb,0,stream>>>(ca_vw, vwT, 512, 512, 512);
  k_wt2<<<dim3(16,16),tb,0,stream>>>(ca_ow, owT, 512, 512, 512);
  k_wt2<<<dim3(32,16),tb,0,stream>>>(dec1_w, dec1T, 512, 1024, 1024);

  k_mge<<<dim3(4,32),256,0,stream>>>(Qbf, qpT, qp_b, nullptr, QPb, nullptr,
                                     M2, 512, 512, 512, 512, 512, 1.f, 0);
  k_mge<<<dim3(4,32),256,0,stream>>>(Cbf2, cpT, cp_b, nullptr, CPb, nullptr,
                                     M2, 512, 512, 512, 512, 512, 1.f, 0);
  k_ln<<<M2,TPB,0,stream>>>(QPb, ca_nq_w, ca_nq_b, QN);
  k_ln<<<M2,TPB,0,stream>>>(CPb, ca_nkv_w, ca_nkv_b, CN);
  k_cvt<<<(2097152/4+TPB-1)/TPB,TPB,0,stream>>>(QN, QNbf, 2097152/4);
  k_cvt<<<(2097152/4+TPB-1)/TPB,TPB,0,stream>>>(CN, CNbf, 2097152/4);
  k_mge<<<dim3(4,32),256,0,stream>>>(QNbf, qwT, ca_qb, nullptr, nullptr, QQbf,
                                     M2, 512, 512, 512, 512, 512, 1.f, 0);
  k_mge<<<dim3(4,32),256,0,stream>>>(CNbf, kwT, ca_kb, nullptr, nullptr, KKbf,
                                     M2, 512, 512, 512, 512, 512, 1.f, 0);
  k_mge<<<dim3(4,32),256,0,stream>>>(CNbf, vwT, ca_vb, nullptr, VV, nullptr,
                                     M2, 512, 512, 512, 512, 512, 1.f, 0);
  k_vtb<<<dim3(4,32,16),tb,0,stream>>>(VV, VTbf);
  const float scl = 0.088388347648318447f;
  k_mgab<<<dim3(8,8,16),256,0,stream>>>(QQbf, KKbf, nullptr, Pbf,
        1024, 1024, 128, 512, 512, 1024,
        524288, 128, 524288, 128, 4194304, 1048576, scl);
  k_sm<<<16384,256,0,stream>>>(Pbf);
  k_mgab<<<dim3(1,8,16),256,0,stream>>>(Pbf, VTbf, AO, nullptr,
        1024, 128, 1024, 1024, 1024, 512,
        4194304, 1048576, 524288, 131072, 524288, 128, 1.f);
  k_cvt<<<(2097152/4+TPB-1)/TPB,TPB,0,stream>>>(AO, AObf, 2097152/4);
  k_mge<<<dim3(4,32),256,0,stream>>>(AObf, owT, ca_ob, QPb, O1, nullptr,
                                     M2, 512, 512, 512, 512, 512, 1.f, 0);
  k_cvt<<<(2097152/4+TPB-1)/TPB,TPB,0,stream>>>(O1, O1bf, 2097152/4);
  k_mge<<<dim3(8,32),256,0,stream>>>(O1bf, dec1T, dec1_b, nullptr, D1, nullptr,
                                     M2, 1024, 512, 512, 512, 1024, 1.f, 1);
  k_dec2<<<M2,256,0,stream>>>(D1, dec2_w, dec2_b, (float*)d_out);
}